// Round 2
// baseline (3087.066 us; speedup 1.0000x reference)
//
#include <hip/hip_runtime.h>
#include <hip/hip_bf16.h>

#define B_SZ 2
#define SEQ 4096
#define DMODEL 1024
#define INTER 2048
#define NHEADS 32
#define HDIM 64
#define DSTATE 128
#define DCONV 4
#define CONVDIM 2304
#define PROJDIM 4384
#define CHUNK 256
#define NCHUNK 16
#define ROWS (B_SZ*SEQ)   // 8192

typedef __hip_bfloat16 bf16;

__device__ __forceinline__ float sigmoidf_(float x){ return 1.f/(1.f+expf(-x)); }
__device__ __forceinline__ float b2f(bf16 v){ return __bfloat162float(v); }
__device__ __forceinline__ bf16 f2b(float v){ return __float2bfloat16(v); }

// ---------------- fallback: zero d_out (diagnostic path if ws too small) ----------------
__global__ void zero_out_kernel(float* o, int n){
  int i = blockIdx.x*256 + threadIdx.x;
  if (i < n) o[i] = 0.f;
}

// ---------------- in_proj GEMM: [8192x1024] @ [1024x4384] -> z(bf16)/xBC(bf16)/dtraw(f32) ----------------
__global__ __launch_bounds__(256) void inproj_gemm(const float* __restrict__ A,
    const float* __restrict__ B, bf16* __restrict__ z, bf16* __restrict__ xbc,
    float* __restrict__ dtraw){
  __shared__ float As[64][17];
  __shared__ float Bs[16][65];
  int tid = threadIdx.x, tx = tid & 15, ty = tid >> 4;
  int row0 = blockIdx.y*64, col0 = blockIdx.x*64;
  float acc[4][4] = {};
  for (int k0 = 0; k0 < DMODEL; k0 += 16){
    #pragma unroll
    for (int i = 0; i < 4; i++){
      int idx = tid + i*256;
      As[idx >> 4][idx & 15] = A[(size_t)(row0 + (idx >> 4))*DMODEL + k0 + (idx & 15)];
    }
    #pragma unroll
    for (int i = 0; i < 4; i++){
      int idx = tid + i*256;
      int col = col0 + (idx & 63);
      Bs[idx >> 6][idx & 63] = (col < PROJDIM) ? B[(size_t)(k0 + (idx >> 6))*PROJDIM + col] : 0.f;
    }
    __syncthreads();
    #pragma unroll
    for (int kk = 0; kk < 16; kk++){
      float a[4], bb[4];
      #pragma unroll
      for (int i = 0; i < 4; i++) a[i] = As[ty*4+i][kk];
      #pragma unroll
      for (int j = 0; j < 4; j++) bb[j] = Bs[kk][tx*4+j];
      #pragma unroll
      for (int i = 0; i < 4; i++)
        #pragma unroll
        for (int j = 0; j < 4; j++) acc[i][j] += a[i]*bb[j];
    }
    __syncthreads();
  }
  #pragma unroll
  for (int i = 0; i < 4; i++){
    int r = row0 + ty*4 + i;
    #pragma unroll
    for (int j = 0; j < 4; j++){
      int col = col0 + tx*4 + j;
      if (col >= PROJDIM) continue;
      float v = acc[i][j];
      if (col < INTER)               z[(size_t)r*INTER + col] = f2b(v);
      else if (col < INTER+CONVDIM)  xbc[(size_t)r*CONVDIM + (col-INTER)] = f2b(v);
      else                           dtraw[(size_t)r*NHEADS + (col-INTER-CONVDIM)] = v;
    }
  }
}

// ---------------- conv1d (depthwise, causal, k=4) + silu + split ----------------
__global__ __launch_bounds__(256) void conv_kernel(const bf16* __restrict__ xbc,
    const float* __restrict__ cw, const float* __restrict__ cb,
    bf16* __restrict__ x, float* __restrict__ Bm, float* __restrict__ Cm){
  int bt = blockIdx.x / 9;                       // 0..8191 (b*4096 + t)
  int ch = (blockIdx.x % 9)*256 + threadIdx.x;   // 0..2303
  int t = bt & (SEQ-1);
  float acc = cb[ch];
  #pragma unroll
  for (int i = 0; i < 4; i++){
    int tt = t - 3 + i;
    if (tt >= 0)
      acc = fmaf(b2f(xbc[(size_t)(bt - t + tt)*CONVDIM + ch]), cw[ch*4+i], acc);
  }
  float v = acc * sigmoidf_(acc);
  if (ch < INTER)              x[(size_t)bt*INTER + ch] = f2b(v);
  else if (ch < INTER+DSTATE)  Bm[(size_t)bt*DSTATE + (ch-INTER)] = v;
  else                         Cm[(size_t)bt*DSTATE + (ch-INTER-DSTATE)] = v;
}

// ---------------- dt = softplus(dt_raw + bias) ----------------
__global__ __launch_bounds__(256) void dt_kernel(const float* __restrict__ dtraw,
    const float* __restrict__ dt_bias, float* __restrict__ dt){
  int idx = blockIdx.x*256 + threadIdx.x;  // ROWS*NHEADS
  int h = idx & 31;
  float v = dtraw[idx] + dt_bias[h];
  dt[idx] = (v > 20.f) ? v : log1pf(expf(v));
}

// ---------------- per-chunk inclusive cumsum of dt*A ----------------
// Acum layout: [((b*NHEADS+h)*NCHUNK+c)*CHUNK + l]
__global__ __launch_bounds__(256) void acum_kernel(const float* __restrict__ dt,
    const float* __restrict__ A_log, float* __restrict__ Acum){
  int bi = blockIdx.x;            // (b*NHEADS+h)*NCHUNK + c
  int c = bi & 15; int h = (bi >> 4) & 31; int b = bi >> 9;
  int l = threadIdx.x;
  __shared__ float sbuf[CHUNK];
  float A = -expf(A_log[h]);
  int t = c*CHUNK + l;
  sbuf[l] = dt[(size_t)(b*SEQ + t)*NHEADS + h] * A;
  __syncthreads();
  for (int off = 1; off < CHUNK; off <<= 1){
    float add = (l >= off) ? sbuf[l-off] : 0.f;
    __syncthreads();
    sbuf[l] += add;
    __syncthreads();
  }
  Acum[(size_t)bi*CHUNK + l] = sbuf[l];
}

// ---------------- per-chunk states: states[b,c,h,p,n] ----------------
__global__ __launch_bounds__(256) void chunk_states_kernel(const bf16* __restrict__ x,
    const float* __restrict__ Bm, const float* __restrict__ dt,
    const float* __restrict__ Acum, float* __restrict__ states){
  int bi = blockIdx.x;            // (b*NCHUNK+c)*NHEADS + h
  int h = bi & 31; int c = (bi >> 5) & 15; int b = bi >> 9;
  int tid = threadIdx.x;
  __shared__ float w[CHUNK];
  __shared__ float Bs[64][128];
  __shared__ float xs[64][64];
  const float* AcBase = Acum + ((size_t)(b*NHEADS + h)*NCHUNK + c)*CHUNK;
  float AcLast = AcBase[CHUNK-1];
  {
    int l = tid;
    int t = c*CHUNK + l;
    w[l] = expf(AcLast - AcBase[l]) * dt[(size_t)(b*SEQ + t)*NHEADS + h];
  }
  __syncthreads();
  float acc[32];
  #pragma unroll
  for (int i = 0; i < 32; i++) acc[i] = 0.f;
  int n = tid & 127;
  int p0 = tid >> 7;
  for (int lt = 0; lt < CHUNK; lt += 64){
    #pragma unroll
    for (int i = 0; i < 32; i++){
      int idx = tid + i*256;
      Bs[idx >> 7][idx & 127] = Bm[(size_t)(b*SEQ + c*CHUNK + lt + (idx >> 7))*DSTATE + (idx & 127)];
    }
    #pragma unroll
    for (int i = 0; i < 16; i++){
      int idx = tid + i*256;
      xs[idx >> 6][idx & 63] = b2f(x[(size_t)(b*SEQ + c*CHUNK + lt + (idx >> 6))*INTER + h*HDIM + (idx & 63)]);
    }
    __syncthreads();
    for (int l = 0; l < 64; l++){
      float bn = Bs[l][n] * w[lt + l];
      #pragma unroll
      for (int i = 0; i < 32; i++) acc[i] = fmaf(bn, xs[l][p0 + 2*i], acc[i]);
    }
    __syncthreads();
  }
  size_t base = ((size_t)bi)*HDIM*DSTATE;
  #pragma unroll
  for (int i = 0; i < 32; i++)
    states[base + (size_t)(p0 + 2*i)*DSTATE + n] = acc[i];
}

// ---------------- inter-chunk scan (in-place: states becomes state ENTERING chunk) ----------------
__global__ __launch_bounds__(256) void scan_kernel(float* __restrict__ states,
    const float* __restrict__ Acum){
  int idx = blockIdx.x*256 + threadIdx.x;  // b*h*p*n = 2^19
  int n = idx & 127; int p = (idx >> 7) & 63; int h = (idx >> 13) & 31; int b = idx >> 18;
  float R = 0.f;
  for (int c = 0; c < NCHUNK; c++){
    size_t o = (((size_t)((b*NCHUNK + c)*NHEADS + h))*HDIM + p)*DSTATE + n;
    float s = states[o];
    states[o] = R;
    float dA = expf(Acum[((size_t)(b*NHEADS + h)*NCHUNK + c)*CHUNK + CHUNK-1]);
    R = R*dA + s;
  }
}

// ---------------- scores[b,c,l,s] = sum_n C[l,n] B[s,n]  (lower triangle only) ----------------
__global__ __launch_bounds__(256) void scores_kernel(const float* __restrict__ Bm,
    const float* __restrict__ Cm, float* __restrict__ scores){
  int idx = blockIdx.x*256 + threadIdx.x;  // 2*16*256*256
  int s = idx & 255, l = (idx >> 8) & 255; int bc = idx >> 16;
  if (s > l) return;
  int b = bc >> 4, c = bc & 15;
  const float* Cp = Cm + (size_t)(b*SEQ + c*CHUNK + l)*DSTATE;
  const float* Bp = Bm + (size_t)(b*SEQ + c*CHUNK + s)*DSTATE;
  float acc = 0.f;
  #pragma unroll 4
  for (int n = 0; n < DSTATE; n += 4){
    float4 cv = *(const float4*)(Cp + n);
    float4 bv = *(const float4*)(Bp + n);
    acc += cv.x*bv.x + cv.y*bv.y + cv.z*bv.z + cv.w*bv.w;
  }
  scores[idx] = acc;
}

// ---------------- fused Y: diag + off + D*x, writes y (bf16) ----------------
// y[l,p] = sum_{s<=l} scores[l,s] exp(Ac[l]-Ac[s]) dt[s] x[s,p]
//        + exp(Ac[l]) * sum_n C[l,n] states_in[h,p,n]
//        + D[h]*x[l,p]
__global__ __launch_bounds__(256) void ydiag_fused(const bf16* __restrict__ x,
    const float* __restrict__ dt, const float* __restrict__ Acum,
    const float* __restrict__ scores, const float* __restrict__ Cm,
    const float* __restrict__ states, const float* __restrict__ Dp,
    bf16* __restrict__ y){
  int bi = blockIdx.x;            // (b*NCHUNK+c)*NHEADS + h
  int h = bi & 31; int c = (bi >> 5) & 15; int b = bi >> 9;
  int bc = b*NCHUNK + c;
  int l = threadIdx.x;
  __shared__ float xdt[128][68];  // 34.8KB, reused across 3 phases (row stride 272B, 16B-aligned)
  __shared__ float Ac[CHUNK];
  const float* AcBase = Acum + ((size_t)(b*NHEADS + h)*NCHUNK + c)*CHUNK;
  Ac[l] = AcBase[l];
  float acc[64];
  #pragma unroll
  for (int i = 0; i < 64; i++) acc[i] = 0.f;

  // phase 0: Y_off = exp(Ac[l]) * sum_n C[l,n] * S_in[p,n]; stage S_in transposed into xdt[n][p]
  {
    const float* src = states + (size_t)bi*HDIM*DSTATE;   // [p][n]
    #pragma unroll
    for (int i = 0; i < 32; i++){
      int idx = threadIdx.x + i*256;       // 8192 = 64p * 128n
      xdt[idx & 127][idx >> 7] = src[idx];
    }
  }
  __syncthreads();
  {
    float eAl = expf(Ac[l]);   // own-thread value, written above by this thread
    const float4* Cp = (const float4*)(Cm + (size_t)(b*SEQ + c*CHUNK + l)*DSTATE);
    for (int n4 = 0; n4 < 32; n4++){
      float4 cv = Cp[n4];
      float wv[4] = {cv.x*eAl, cv.y*eAl, cv.z*eAl, cv.w*eAl};
      #pragma unroll
      for (int j = 0; j < 4; j++){
        const float4* xr = (const float4*)xdt[n4*4 + j];
        #pragma unroll
        for (int i = 0; i < 16; i++){
          float4 v = xr[i];
          acc[4*i+0] = fmaf(wv[j], v.x, acc[4*i+0]);
          acc[4*i+1] = fmaf(wv[j], v.y, acc[4*i+1]);
          acc[4*i+2] = fmaf(wv[j], v.z, acc[4*i+2]);
          acc[4*i+3] = fmaf(wv[j], v.w, acc[4*i+3]);
        }
      }
    }
  }

  // phases 1,2: Y_diag over s in two halves of 128
  for (int st = 0; st < 2; st++){
    __syncthreads();
    #pragma unroll
    for (int i = 0; i < 32; i++){
      int idx = threadIdx.x + i*256;        // 8192 = 128r * 64c
      int r = idx >> 6, cc = idx & 63;
      int t = c*CHUNK + st*128 + r;
      xdt[r][cc] = b2f(x[(size_t)(b*SEQ + t)*INTER + h*HDIM + cc])
                 * dt[(size_t)(b*SEQ + t)*NHEADS + h];
    }
    __syncthreads();
    float Al = Ac[l];
    const float* scRow = scores + (size_t)bc*CHUNK*CHUNK + (size_t)l*CHUNK + st*128;
    for (int s2 = 0; s2 < 128; s2++){
      int s = st*128 + s2;
      if (s <= l){
        float wv = scRow[s2] * expf(Al - Ac[s]);
        const float4* xr = (const float4*)xdt[s2];
        #pragma unroll
        for (int i = 0; i < 16; i++){
          float4 v = xr[i];
          acc[4*i+0] = fmaf(wv, v.x, acc[4*i+0]);
          acc[4*i+1] = fmaf(wv, v.y, acc[4*i+1]);
          acc[4*i+2] = fmaf(wv, v.z, acc[4*i+2]);
          acc[4*i+3] = fmaf(wv, v.w, acc[4*i+3]);
        }
      }
    }
  }
  float D = Dp[h];
  size_t rowbase = (size_t)(b*SEQ + c*CHUNK + l)*INTER + h*HDIM;
  #pragma unroll
  for (int i = 0; i < 64; i++)
    y[rowbase + i] = f2b(acc[i] + D*b2f(x[rowbase + i]));
}

// ---------------- gate (y * silu(z)) + RMSNorm * norm_w, in place (bf16) ----------------
__global__ __launch_bounds__(256) void gatenorm_kernel(bf16* __restrict__ y,
    const bf16* __restrict__ z, const float* __restrict__ nw){
  int row = blockIdx.x;
  const bf16* zr = z + (size_t)row*INTER;
  bf16* yr = y + (size_t)row*INTER;
  int tid = threadIdx.x;
  float g[8]; float ss = 0.f;
  #pragma unroll
  for (int i = 0; i < 8; i++){
    int idx = tid + i*256;
    float zv = b2f(zr[idx]);
    float gv = b2f(yr[idx]) * zv * sigmoidf_(zv);
    g[i] = gv; ss += gv*gv;
  }
  #pragma unroll
  for (int off = 32; off > 0; off >>= 1) ss += __shfl_down(ss, off);
  __shared__ float red[4];
  __shared__ float stot;
  int lane = tid & 63, wid = tid >> 6;
  if (lane == 0) red[wid] = ss;
  __syncthreads();
  if (tid == 0) stot = rsqrtf((red[0]+red[1]+red[2]+red[3]) * (1.f/INTER) + 1e-5f);
  __syncthreads();
  float sc = stot;
  #pragma unroll
  for (int i = 0; i < 8; i++){
    int idx = tid + i*256;
    yr[idx] = f2b(g[i]*sc*nw[idx]);
  }
}

// ---------------- out_proj GEMM: y(bf16) [8192x2048] @ w_out(f32) [2048x1024] -> out f32 ----------------
__global__ __launch_bounds__(256) void outproj_gemm(const bf16* __restrict__ A,
    const float* __restrict__ B, float* __restrict__ C){
  __shared__ float As[64][17];
  __shared__ float Bs[16][65];
  int tid = threadIdx.x, tx = tid & 15, ty = tid >> 4;
  int row0 = blockIdx.y*64, col0 = blockIdx.x*64;
  float acc[4][4] = {};
  for (int k0 = 0; k0 < INTER; k0 += 16){
    #pragma unroll
    for (int i = 0; i < 4; i++){
      int idx = tid + i*256;
      As[idx >> 4][idx & 15] = b2f(A[(size_t)(row0 + (idx >> 4))*INTER + k0 + (idx & 15)]);
    }
    #pragma unroll
    for (int i = 0; i < 4; i++){
      int idx = tid + i*256;
      Bs[idx >> 6][idx & 63] = B[(size_t)(k0 + (idx >> 6))*DMODEL + col0 + (idx & 63)];
    }
    __syncthreads();
    #pragma unroll
    for (int kk = 0; kk < 16; kk++){
      float a[4], bb[4];
      #pragma unroll
      for (int i = 0; i < 4; i++) a[i] = As[ty*4+i][kk];
      #pragma unroll
      for (int j = 0; j < 4; j++) bb[j] = Bs[kk][tx*4+j];
      #pragma unroll
      for (int i = 0; i < 4; i++)
        #pragma unroll
        for (int j = 0; j < 4; j++) acc[i][j] += a[i]*bb[j];
    }
    __syncthreads();
  }
  #pragma unroll
  for (int i = 0; i < 4; i++){
    int r = row0 + ty*4 + i;
    #pragma unroll
    for (int j = 0; j < 4; j++)
      C[(size_t)r*DMODEL + col0 + tx*4 + j] = acc[i][j];
  }
}

extern "C" void kernel_launch(void* const* d_in, const int* in_sizes, int n_in,
                              void* d_out, int out_size, void* d_ws, size_t ws_size,
                              hipStream_t stream){
  const float* u    = (const float*)d_in[0];
  const float* w_in = (const float*)d_in[1];
  const float* cw   = (const float*)d_in[2];
  const float* cb   = (const float*)d_in[3];
  const float* dtb  = (const float*)d_in[4];
  const float* Alog = (const float*)d_in[5];
  const float* Dp   = (const float*)d_in[6];
  const float* nw   = (const float*)d_in[7];
  const float* w_out= (const float*)d_in[8];
  float* out = (float*)d_out;
  char* ws = (char*)d_ws;

  // byte offsets (all 256B-aligned)
  const size_t OFF_Z      = 0;                       // bf16 [8192][2048]  33,554,432
  const size_t OFF_XBC    = 33554432;                // bf16 [8192][2304]  37,748,736 ; states f32 aliases here after conv
  const size_t OFF_X      = 71303168;                // bf16 [8192][2048]  33,554,432
  const size_t OFF_Y      = 104857600;               // bf16 [8192][2048]  33,554,432
  const size_t OFF_BM     = 138412032;               // f32  [8192][128]    4,194,304
  const size_t OFF_CM     = 142606336;               // f32  [8192][128]    4,194,304
  const size_t OFF_DTRAW  = 146800640;               // f32  [8192][32]     1,048,576
  const size_t OFF_DT     = 147849216;               // f32  [8192][32]     1,048,576
  const size_t OFF_ACUM   = 148897792;               // f32  [2*32*16*256]  1,048,576
  const size_t OFF_SCORES = 149946368;               // f32  [32*256*256]   8,388,608
  const size_t NEED       = 158334976;               // total bytes

  if (ws_size < NEED){
    // diagnostic fallback: clean numeric fail (absmax ~ ref magnitude) instead of a page fault
    zero_out_kernel<<<(out_size + 255)/256, 256, 0, stream>>>(out, out_size);
    return;
  }

  bf16*  z      = (bf16*)(ws + OFF_Z);
  bf16*  xbc    = (bf16*)(ws + OFF_XBC);
  float* states = (float*)(ws + OFF_XBC);   // alias: xBC dead after conv_kernel
  bf16*  x      = (bf16*)(ws + OFF_X);
  bf16*  y      = (bf16*)(ws + OFF_Y);
  float* Bm     = (float*)(ws + OFF_BM);
  float* Cm     = (float*)(ws + OFF_CM);
  float* dtraw  = (float*)(ws + OFF_DTRAW);
  float* dt     = (float*)(ws + OFF_DT);
  float* Acum   = (float*)(ws + OFF_ACUM);
  float* scores = (float*)(ws + OFF_SCORES);

  // 1) zxbcdt = u @ in_proj_w  (split outputs)
  inproj_gemm<<<dim3((PROJDIM+63)/64, ROWS/64), 256, 0, stream>>>(u, w_in, z, xbc, dtraw);
  // 2) conv + silu + split
  conv_kernel<<<ROWS*9, 256, 0, stream>>>(xbc, cw, cb, x, Bm, Cm);
  // 3) dt softplus
  dt_kernel<<<ROWS*NHEADS/256, 256, 0, stream>>>(dtraw, dtb, dt);
  // 4) per-chunk cumsum of dt*A
  acum_kernel<<<B_SZ*NHEADS*NCHUNK, 256, 0, stream>>>(dt, Alog, Acum);
  // 5) per-chunk states (overwrites xbc region — xbc fully consumed by step 2)
  chunk_states_kernel<<<B_SZ*NCHUNK*NHEADS, 256, 0, stream>>>(x, Bm, dt, Acum, states);
  // 6) inter-chunk scan (in place)
  scan_kernel<<<(B_SZ*NHEADS*HDIM*DSTATE)/256, 256, 0, stream>>>(states, Acum);
  // 7) CB scores (shared across heads)
  scores_kernel<<<(B_SZ*NCHUNK*CHUNK*CHUNK)/256, 256, 0, stream>>>(Bm, Cm, scores);
  // 8) fused Y_diag + Y_off + D*x -> y (bf16)
  ydiag_fused<<<B_SZ*NCHUNK*NHEADS, 256, 0, stream>>>(x, dt, Acum, scores, Cm, states, Dp, y);
  // 9) gate + RMSNorm (in place on y)
  gatenorm_kernel<<<ROWS, 256, 0, stream>>>(y, z, nw);
  // 10) out = y @ out_proj_w
  outproj_gemm<<<dim3(DMODEL/64, ROWS/64), 256, 0, stream>>>(y, w_out, out);
}

// Round 3
// 1248.893 us; speedup vs baseline: 2.4718x; 2.4718x over previous
//
#include <hip/hip_runtime.h>
#include <hip/hip_bf16.h>

#define B_SZ 2
#define SEQ 4096
#define DMODEL 1024
#define INTER 2048
#define NHEADS 32
#define HDIM 64
#define DSTATE 128
#define DCONV 4
#define CONVDIM 2304
#define PROJDIM 4384
#define CHUNK 256
#define NCHUNK 16
#define ROWS (B_SZ*SEQ)   // 8192
#define NGEMM 4352        // z + xBC columns (34 tiles of 128)

typedef __hip_bfloat16 bf16;
typedef short bfx8 __attribute__((ext_vector_type(8)));
typedef float f32x4 __attribute__((ext_vector_type(4)));

__device__ __forceinline__ float sigmoidf_(float x){ return 1.f/(1.f+expf(-x)); }
__device__ __forceinline__ float b2f(bf16 v){ return __bfloat162float(v); }
__device__ __forceinline__ bf16 f2b(float v){ return __float2bfloat16(v); }

// ---------------- fallback: zero d_out (diagnostic path if ws too small) ----------------
__global__ void zero_out_kernel(float* o, int n){
  int i = blockIdx.x*256 + threadIdx.x;
  if (i < n) o[i] = 0.f;
}

// ---------------- cast u (f32) -> bf16, 4 elems/thread ----------------
__global__ __launch_bounds__(256) void castu_kernel(const float* __restrict__ in,
    unsigned short* __restrict__ o){
  int i = blockIdx.x*256 + threadIdx.x;
  float4 v = ((const float4*)in)[i];
  ushort4 w;
  bf16 b;
  b = f2b(v.x); w.x = *(unsigned short*)&b;
  b = f2b(v.y); w.y = *(unsigned short*)&b;
  b = f2b(v.z); w.z = *(unsigned short*)&b;
  b = f2b(v.w); w.w = *(unsigned short*)&b;
  ((ushort4*)o)[i] = w;
}

// ---------------- cast + transpose: in f32 [R][ld] (cols coff..coff+C) -> outT bf16 [C][R] ----------------
__global__ __launch_bounds__(256) void transcast_kernel(const float* __restrict__ in,
    bf16* __restrict__ outT, int R, int ld, int coff){
  __shared__ float t[64][65];
  int r0 = blockIdx.y*64, c0 = blockIdx.x*64;
  int tid = threadIdx.x;
  #pragma unroll
  for (int i = 0; i < 16; i++){
    int idx = tid + i*256;       // 4096 = 64r x 64c
    int r = idx >> 6, c = idx & 63;
    t[r][c] = in[(size_t)(r0+r)*ld + coff + c0 + c];
  }
  __syncthreads();
  #pragma unroll
  for (int i = 0; i < 16; i++){
    int idx = tid + i*256;
    int c = idx >> 6, r = idx & 63;
    outT[(size_t)(c0+c)*R + r0 + r] = f2b(t[r][c]);
  }
}

// ================= bf16 MFMA GEMM core (m97 structure) =================
// A [M][K] bf16 row-major, Bt [N][K] bf16 row-major. 128x128 tile, BK=64,
// 4 waves in 2x2, each wave 64x64 (4x4 fragments of 16x16x32).
#define MFMA_GEMM_BODY(K_, EPILOGUE)                                           \
  __shared__ unsigned short As[128*64];                                        \
  __shared__ unsigned short Bs[128*64];                                        \
  const int tid = threadIdx.x;                                                 \
  const int lane = tid & 63, wid = tid >> 6;                                   \
  const int wm = wid >> 1, wn = wid & 1;                                       \
  const int row0 = blockIdx.y*128, col0 = blockIdx.x*128;                      \
  f32x4 acc[4][4] = {};                                                        \
  const int rstg = wid*32 + ((lane>>3)&7);                                     \
  const int kstg = (lane&7)*8;                                                 \
  for (int k0 = 0; k0 < (K_); k0 += 64){                                       \
    _Pragma("unroll")                                                          \
    for (int j = 0; j < 4; j++){                                               \
      const bf16* gA = A + (size_t)(row0 + rstg + j*8)*(K_) + k0 + kstg;       \
      __builtin_amdgcn_global_load_lds(                                        \
        (const __attribute__((address_space(1))) void*)gA,                     \
        (__attribute__((address_space(3))) void*)(As + (wid*32 + j*8)*64),     \
        16, 0, 0);                                                             \
      const bf16* gB = Bt + (size_t)(col0 + rstg + j*8)*(K_) + k0 + kstg;      \
      __builtin_amdgcn_global_load_lds(                                        \
        (const __attribute__((address_space(1))) void*)gB,                     \
        (__attribute__((address_space(3))) void*)(Bs + (wid*32 + j*8)*64),     \
        16, 0, 0);                                                             \
    }                                                                          \
    __syncthreads();                                                           \
    _Pragma("unroll")                                                          \
    for (int kk = 0; kk < 2; kk++){                                            \
      bfx8 af[4], bfr[4];                                                      \
      _Pragma("unroll")                                                        \
      for (int m = 0; m < 4; m++)                                              \
        af[m] = *(const bfx8*)(As + (wm*64 + m*16 + (lane&15))*64              \
                               + kk*32 + (lane>>4)*8);                         \
      _Pragma("unroll")                                                        \
      for (int n = 0; n < 4; n++)                                              \
        bfr[n] = *(const bfx8*)(Bs + (wn*64 + n*16 + (lane&15))*64             \
                                + kk*32 + (lane>>4)*8);                        \
      _Pragma("unroll")                                                        \
      for (int m = 0; m < 4; m++)                                              \
        _Pragma("unroll")                                                      \
        for (int n = 0; n < 4; n++)                                            \
          acc[m][n] = __builtin_amdgcn_mfma_f32_16x16x32_bf16(                 \
                        af[m], bfr[n], acc[m][n], 0, 0, 0);                    \
    }                                                                          \
    __syncthreads();                                                           \
  }                                                                            \
  _Pragma("unroll")                                                            \
  for (int m = 0; m < 4; m++){                                                 \
    int row = row0 + wm*64 + m*16 + (lane>>4)*4;                               \
    _Pragma("unroll")                                                          \
    for (int n = 0; n < 4; n++){                                               \
      int col = col0 + wn*64 + n*16 + (lane&15);                               \
      _Pragma("unroll")                                                        \
      for (int r = 0; r < 4; r++){                                             \
        float v = acc[m][n][r];                                                \
        int rr = row + r;                                                      \
        EPILOGUE                                                               \
      }                                                                        \
    }                                                                          \
  }

// inproj: cols 0..2047 -> z (bf16), 2048..4351 -> xbc (bf16)
__global__ __launch_bounds__(256) void gemm_mfma_inproj(const bf16* __restrict__ A,
    const bf16* __restrict__ Bt, bf16* __restrict__ z, bf16* __restrict__ xbc){
  MFMA_GEMM_BODY(DMODEL,
    if (col < INTER) z[(size_t)rr*INTER + col] = f2b(v);
    else             xbc[(size_t)rr*CONVDIM + (col - INTER)] = f2b(v);
  )
}

// outproj: plain f32 output [M][1024]
__global__ __launch_bounds__(256) void gemm_mfma_outproj(const bf16* __restrict__ A,
    const bf16* __restrict__ Bt, float* __restrict__ C){
  MFMA_GEMM_BODY(INTER,
    C[(size_t)rr*DMODEL + col] = v;
  )
}

// ---------------- small fp32 GEMM for dt columns (keeps dt path fp32) ----------------
// C[M,N] = A[M,K] @ B[K,N] where B has leading dim ldb (slice of w_in)
__global__ __launch_bounds__(256) void gemm_f32_dt(const float* __restrict__ A,
    const float* __restrict__ B, float* __restrict__ C, int N, int K, int ldb){
  __shared__ float As[64][17];
  __shared__ float Bs[16][65];
  int tid = threadIdx.x, tx = tid & 15, ty = tid >> 4;
  int row0 = blockIdx.y*64, col0 = blockIdx.x*64;
  float acc[4][4] = {};
  for (int k0 = 0; k0 < K; k0 += 16){
    #pragma unroll
    for (int i = 0; i < 4; i++){
      int idx = tid + i*256;
      As[idx >> 4][idx & 15] = A[(size_t)(row0 + (idx >> 4))*K + k0 + (idx & 15)];
    }
    #pragma unroll
    for (int i = 0; i < 4; i++){
      int idx = tid + i*256;
      int col = col0 + (idx & 63);
      Bs[idx >> 6][idx & 63] = (col < N) ? B[(size_t)(k0 + (idx >> 6))*ldb + col] : 0.f;
    }
    __syncthreads();
    #pragma unroll
    for (int kk = 0; kk < 16; kk++){
      float a[4], bb[4];
      #pragma unroll
      for (int i = 0; i < 4; i++) a[i] = As[ty*4+i][kk];
      #pragma unroll
      for (int j = 0; j < 4; j++) bb[j] = Bs[kk][tx*4+j];
      #pragma unroll
      for (int i = 0; i < 4; i++)
        #pragma unroll
        for (int j = 0; j < 4; j++) acc[i][j] += a[i]*bb[j];
    }
    __syncthreads();
  }
  #pragma unroll
  for (int i = 0; i < 4; i++){
    int r = row0 + ty*4 + i;
    #pragma unroll
    for (int j = 0; j < 4; j++){
      int col = col0 + tx*4 + j;
      if (col < N) C[(size_t)r*N + col] = acc[i][j];
    }
  }
}

// ---------------- conv1d (depthwise, causal, k=4) + silu + split ----------------
__global__ __launch_bounds__(256) void conv_kernel(const bf16* __restrict__ xbc,
    const float* __restrict__ cw, const float* __restrict__ cb,
    bf16* __restrict__ x, float* __restrict__ Bm, float* __restrict__ Cm){
  int bt = blockIdx.x / 9;                       // 0..8191 (b*4096 + t)
  int ch = (blockIdx.x % 9)*256 + threadIdx.x;   // 0..2303
  int t = bt & (SEQ-1);
  float acc = cb[ch];
  #pragma unroll
  for (int i = 0; i < 4; i++){
    int tt = t - 3 + i;
    if (tt >= 0)
      acc = fmaf(b2f(xbc[(size_t)(bt - t + tt)*CONVDIM + ch]), cw[ch*4+i], acc);
  }
  float v = acc * sigmoidf_(acc);
  if (ch < INTER)              x[(size_t)bt*INTER + ch] = f2b(v);
  else if (ch < INTER+DSTATE)  Bm[(size_t)bt*DSTATE + (ch-INTER)] = v;
  else                         Cm[(size_t)bt*DSTATE + (ch-INTER-DSTATE)] = v;
}

// ---------------- dt = softplus(dt_raw + bias) ----------------
__global__ __launch_bounds__(256) void dt_kernel(const float* __restrict__ dtraw,
    const float* __restrict__ dt_bias, float* __restrict__ dt){
  int idx = blockIdx.x*256 + threadIdx.x;  // ROWS*NHEADS
  int h = idx & 31;
  float v = dtraw[idx] + dt_bias[h];
  dt[idx] = (v > 20.f) ? v : log1pf(expf(v));
}

// ---------------- per-chunk inclusive cumsum of dt*A ----------------
__global__ __launch_bounds__(256) void acum_kernel(const float* __restrict__ dt,
    const float* __restrict__ A_log, float* __restrict__ Acum){
  int bi = blockIdx.x;            // (b*NHEADS+h)*NCHUNK + c
  int c = bi & 15; int h = (bi >> 4) & 31; int b = bi >> 9;
  int l = threadIdx.x;
  __shared__ float sbuf[CHUNK];
  float A = -expf(A_log[h]);
  int t = c*CHUNK + l;
  sbuf[l] = dt[(size_t)(b*SEQ + t)*NHEADS + h] * A;
  __syncthreads();
  for (int off = 1; off < CHUNK; off <<= 1){
    float add = (l >= off) ? sbuf[l-off] : 0.f;
    __syncthreads();
    sbuf[l] += add;
    __syncthreads();
  }
  Acum[(size_t)bi*CHUNK + l] = sbuf[l];
}

// ---------------- per-chunk states: states[b,c,h,p,n] ----------------
__global__ __launch_bounds__(256) void chunk_states_kernel(const bf16* __restrict__ x,
    const float* __restrict__ Bm, const float* __restrict__ dt,
    const float* __restrict__ Acum, float* __restrict__ states){
  int bi = blockIdx.x;            // (b*NCHUNK+c)*NHEADS + h
  int h = bi & 31; int c = (bi >> 5) & 15; int b = bi >> 9;
  int tid = threadIdx.x;
  __shared__ float w[CHUNK];
  __shared__ float Bsm[64][128];
  __shared__ float xs[64][64];
  const float* AcBase = Acum + ((size_t)(b*NHEADS + h)*NCHUNK + c)*CHUNK;
  float AcLast = AcBase[CHUNK-1];
  {
    int l = tid;
    int t = c*CHUNK + l;
    w[l] = expf(AcLast - AcBase[l]) * dt[(size_t)(b*SEQ + t)*NHEADS + h];
  }
  __syncthreads();
  float acc[32];
  #pragma unroll
  for (int i = 0; i < 32; i++) acc[i] = 0.f;
  int n = tid & 127;
  int p0 = tid >> 7;
  for (int lt = 0; lt < CHUNK; lt += 64){
    #pragma unroll
    for (int i = 0; i < 32; i++){
      int idx = tid + i*256;
      Bsm[idx >> 7][idx & 127] = Bm[(size_t)(b*SEQ + c*CHUNK + lt + (idx >> 7))*DSTATE + (idx & 127)];
    }
    #pragma unroll
    for (int i = 0; i < 16; i++){
      int idx = tid + i*256;
      xs[idx >> 6][idx & 63] = b2f(x[(size_t)(b*SEQ + c*CHUNK + lt + (idx >> 6))*INTER + h*HDIM + (idx & 63)]);
    }
    __syncthreads();
    for (int l = 0; l < 64; l++){
      float bn = Bsm[l][n] * w[lt + l];
      #pragma unroll
      for (int i = 0; i < 32; i++) acc[i] = fmaf(bn, xs[l][p0 + 2*i], acc[i]);
    }
    __syncthreads();
  }
  size_t base = ((size_t)bi)*HDIM*DSTATE;
  #pragma unroll
  for (int i = 0; i < 32; i++)
    states[base + (size_t)(p0 + 2*i)*DSTATE + n] = acc[i];
}

// ---------------- inter-chunk scan (in-place) ----------------
__global__ __launch_bounds__(256) void scan_kernel(float* __restrict__ states,
    const float* __restrict__ Acum){
  int idx = blockIdx.x*256 + threadIdx.x;  // b*h*p*n = 2^19
  int n = idx & 127; int p = (idx >> 7) & 63; int h = (idx >> 13) & 31; int b = idx >> 18;
  float R = 0.f;
  for (int c = 0; c < NCHUNK; c++){
    size_t o = (((size_t)((b*NCHUNK + c)*NHEADS + h))*HDIM + p)*DSTATE + n;
    float s = states[o];
    states[o] = R;
    float dA = expf(Acum[((size_t)(b*NHEADS + h)*NCHUNK + c)*CHUNK + CHUNK-1]);
    R = R*dA + s;
  }
}

// ---------------- scores[b,c,l,s] = sum_n C[l,n] B[s,n]  (lower triangle only) ----------------
__global__ __launch_bounds__(256) void scores_kernel(const float* __restrict__ Bm,
    const float* __restrict__ Cm, float* __restrict__ scores){
  int idx = blockIdx.x*256 + threadIdx.x;  // 2*16*256*256
  int s = idx & 255, l = (idx >> 8) & 255; int bc = idx >> 16;
  if (s > l) return;
  int b = bc >> 4, c = bc & 15;
  const float* Cp = Cm + (size_t)(b*SEQ + c*CHUNK + l)*DSTATE;
  const float* Bp = Bm + (size_t)(b*SEQ + c*CHUNK + s)*DSTATE;
  float acc = 0.f;
  #pragma unroll 4
  for (int n = 0; n < DSTATE; n += 4){
    float4 cv = *(const float4*)(Cp + n);
    float4 bv = *(const float4*)(Bp + n);
    acc += cv.x*bv.x + cv.y*bv.y + cv.z*bv.z + cv.w*bv.w;
  }
  scores[idx] = acc;
}

// ---------------- fused Y: diag + off + D*x, writes y (bf16) ----------------
__global__ __launch_bounds__(256) void ydiag_fused(const bf16* __restrict__ x,
    const float* __restrict__ dt, const float* __restrict__ Acum,
    const float* __restrict__ scores, const float* __restrict__ Cm,
    const float* __restrict__ states, const float* __restrict__ Dp,
    bf16* __restrict__ y){
  int bi = blockIdx.x;            // (b*NCHUNK+c)*NHEADS + h
  int h = bi & 31; int c = (bi >> 5) & 15; int b = bi >> 9;
  int bc = b*NCHUNK + c;
  int l = threadIdx.x;
  __shared__ float xdt[128][68];
  __shared__ float Ac[CHUNK];
  const float* AcBase = Acum + ((size_t)(b*NHEADS + h)*NCHUNK + c)*CHUNK;
  Ac[l] = AcBase[l];
  float acc[64];
  #pragma unroll
  for (int i = 0; i < 64; i++) acc[i] = 0.f;

  // phase 0: Y_off = exp(Ac[l]) * sum_n C[l,n] * S_in[p,n]
  {
    const float* src = states + (size_t)bi*HDIM*DSTATE;   // [p][n]
    #pragma unroll
    for (int i = 0; i < 32; i++){
      int idx = threadIdx.x + i*256;       // 8192 = 64p * 128n
      xdt[idx & 127][idx >> 7] = src[idx];
    }
  }
  __syncthreads();
  {
    float eAl = expf(Ac[l]);
    const float4* Cp = (const float4*)(Cm + (size_t)(b*SEQ + c*CHUNK + l)*DSTATE);
    for (int n4 = 0; n4 < 32; n4++){
      float4 cv = Cp[n4];
      float wv[4] = {cv.x*eAl, cv.y*eAl, cv.z*eAl, cv.w*eAl};
      #pragma unroll
      for (int j = 0; j < 4; j++){
        const float4* xr = (const float4*)xdt[n4*4 + j];
        #pragma unroll
        for (int i = 0; i < 16; i++){
          float4 v = xr[i];
          acc[4*i+0] = fmaf(wv[j], v.x, acc[4*i+0]);
          acc[4*i+1] = fmaf(wv[j], v.y, acc[4*i+1]);
          acc[4*i+2] = fmaf(wv[j], v.z, acc[4*i+2]);
          acc[4*i+3] = fmaf(wv[j], v.w, acc[4*i+3]);
        }
      }
    }
  }

  // phases 1,2: Y_diag over s in two halves of 128
  for (int st = 0; st < 2; st++){
    __syncthreads();
    #pragma unroll
    for (int i = 0; i < 32; i++){
      int idx = threadIdx.x + i*256;        // 8192 = 128r * 64c
      int r = idx >> 6, cc = idx & 63;
      int t = c*CHUNK + st*128 + r;
      xdt[r][cc] = b2f(x[(size_t)(b*SEQ + t)*INTER + h*HDIM + cc])
                 * dt[(size_t)(b*SEQ + t)*NHEADS + h];
    }
    __syncthreads();
    float Al = Ac[l];
    const float* scRow = scores + (size_t)bc*CHUNK*CHUNK + (size_t)l*CHUNK + st*128;
    for (int s2 = 0; s2 < 128; s2++){
      int s = st*128 + s2;
      if (s <= l){
        float wv = scRow[s2] * expf(Al - Ac[s]);
        const float4* xr = (const float4*)xdt[s2];
        #pragma unroll
        for (int i = 0; i < 16; i++){
          float4 v = xr[i];
          acc[4*i+0] = fmaf(wv, v.x, acc[4*i+0]);
          acc[4*i+1] = fmaf(wv, v.y, acc[4*i+1]);
          acc[4*i+2] = fmaf(wv, v.z, acc[4*i+2]);
          acc[4*i+3] = fmaf(wv, v.w, acc[4*i+3]);
        }
      }
    }
  }
  float D = Dp[h];
  size_t rowbase = (size_t)(b*SEQ + c*CHUNK + l)*INTER + h*HDIM;
  #pragma unroll
  for (int i = 0; i < 64; i++)
    y[rowbase + i] = f2b(acc[i] + D*b2f(x[rowbase + i]));
}

// ---------------- gate (y * silu(z)) + RMSNorm * norm_w, in place (bf16) ----------------
__global__ __launch_bounds__(256) void gatenorm_kernel(bf16* __restrict__ y,
    const bf16* __restrict__ z, const float* __restrict__ nw){
  int row = blockIdx.x;
  const bf16* zr = z + (size_t)row*INTER;
  bf16* yr = y + (size_t)row*INTER;
  int tid = threadIdx.x;
  float g[8]; float ss = 0.f;
  #pragma unroll
  for (int i = 0; i < 8; i++){
    int idx = tid + i*256;
    float zv = b2f(zr[idx]);
    float gv = b2f(yr[idx]) * zv * sigmoidf_(zv);
    g[i] = gv; ss += gv*gv;
  }
  #pragma unroll
  for (int off = 32; off > 0; off >>= 1) ss += __shfl_down(ss, off);
  __shared__ float red[4];
  __shared__ float stot;
  int lane = tid & 63, wid = tid >> 6;
  if (lane == 0) red[wid] = ss;
  __syncthreads();
  if (tid == 0) stot = rsqrtf((red[0]+red[1]+red[2]+red[3]) * (1.f/INTER) + 1e-5f);
  __syncthreads();
  float sc = stot;
  #pragma unroll
  for (int i = 0; i < 8; i++){
    int idx = tid + i*256;
    yr[idx] = f2b(g[i]*sc*nw[idx]);
  }
}

extern "C" void kernel_launch(void* const* d_in, const int* in_sizes, int n_in,
                              void* d_out, int out_size, void* d_ws, size_t ws_size,
                              hipStream_t stream){
  const float* u    = (const float*)d_in[0];
  const float* w_in = (const float*)d_in[1];
  const float* cw   = (const float*)d_in[2];
  const float* cb   = (const float*)d_in[3];
  const float* dtb  = (const float*)d_in[4];
  const float* Alog = (const float*)d_in[5];
  const float* Dp   = (const float*)d_in[6];
  const float* nw   = (const float*)d_in[7];
  const float* w_out= (const float*)d_in[8];
  float* out = (float*)d_out;
  char* ws = (char*)d_ws;

  // byte offsets (all 256B-aligned)
  const size_t OFF_Z      = 0;                       // bf16 [8192][2048]
  const size_t OFF_XBC    = 33554432;                // bf16 [8192][2304]; states f32 aliases after conv
  const size_t OFF_X      = 71303168;                // bf16 [8192][2048]
  const size_t OFF_Y      = 104857600;               // bf16 [8192][2048]; u_bf + w_inT alias before step 8
  const size_t OFF_BM     = 138412032;               // f32  [8192][128]
  const size_t OFF_CM     = 142606336;               // f32  [8192][128]
  const size_t OFF_DTRAW  = 146800640;               // f32  [8192][32]
  const size_t OFF_DT     = 147849216;               // f32  [8192][32]
  const size_t OFF_ACUM   = 148897792;               // f32  [2*32*16*256]
  const size_t OFF_SCORES = 149946368;               // f32  [32*256*256]; w_outT aliases after ydiag
  const size_t NEED       = 158334976;

  if (ws_size < NEED){
    zero_out_kernel<<<(out_size + 255)/256, 256, 0, stream>>>(out, out_size);
    return;
  }

  bf16*  z      = (bf16*)(ws + OFF_Z);
  bf16*  xbc    = (bf16*)(ws + OFF_XBC);
  float* states = (float*)(ws + OFF_XBC);   // alias: xBC dead after conv_kernel
  bf16*  x      = (bf16*)(ws + OFF_X);
  bf16*  y      = (bf16*)(ws + OFF_Y);
  bf16*  u_bf   = (bf16*)(ws + OFF_Y);                 // alias: dead once y is written
  bf16*  w_inT  = (bf16*)(ws + OFF_Y + 16777216);      // alias: dead once y is written
  float* Bm     = (float*)(ws + OFF_BM);
  float* Cm     = (float*)(ws + OFF_CM);
  float* dtraw  = (float*)(ws + OFF_DTRAW);
  float* dt     = (float*)(ws + OFF_DT);
  float* Acum   = (float*)(ws + OFF_ACUM);
  float* scores = (float*)(ws + OFF_SCORES);
  bf16*  w_outT = (bf16*)(ws + OFF_SCORES);            // alias: scores dead after ydiag_fused

  // 0) prep: u -> bf16; w_in[:, :4352] -> bf16 transposed [4352][1024]
  castu_kernel<<<(ROWS*DMODEL/4)/256, 256, 0, stream>>>(u, (unsigned short*)u_bf);
  transcast_kernel<<<dim3(NGEMM/64, DMODEL/64), 256, 0, stream>>>(w_in, w_inT, DMODEL, PROJDIM, 0);
  // 1a) z/xBC via bf16 MFMA GEMM
  gemm_mfma_inproj<<<dim3(NGEMM/128, ROWS/128), 256, 0, stream>>>(u_bf, w_inT, z, xbc);
  // 1b) dtraw via small fp32 GEMM (precision-critical path stays fp32)
  gemm_f32_dt<<<dim3(1, ROWS/64), 256, 0, stream>>>(u, w_in + NGEMM, dtraw, NHEADS, DMODEL, PROJDIM);
  // 2) conv + silu + split
  conv_kernel<<<ROWS*9, 256, 0, stream>>>(xbc, cw, cb, x, Bm, Cm);
  // 3) dt softplus
  dt_kernel<<<ROWS*NHEADS/256, 256, 0, stream>>>(dtraw, dtb, dt);
  // 4) per-chunk cumsum of dt*A
  acum_kernel<<<B_SZ*NHEADS*NCHUNK, 256, 0, stream>>>(dt, Alog, Acum);
  // 5) per-chunk states (overwrites xbc region)
  chunk_states_kernel<<<B_SZ*NCHUNK*NHEADS, 256, 0, stream>>>(x, Bm, dt, Acum, states);
  // 6) inter-chunk scan
  scan_kernel<<<(B_SZ*NHEADS*HDIM*DSTATE)/256, 256, 0, stream>>>(states, Acum);
  // 7) CB scores
  scores_kernel<<<(B_SZ*NCHUNK*CHUNK*CHUNK)/256, 256, 0, stream>>>(Bm, Cm, scores);
  // 8) fused Y_diag + Y_off + D*x -> y (overwrites u_bf/w_inT aliases)
  ydiag_fused<<<B_SZ*NCHUNK*NHEADS, 256, 0, stream>>>(x, dt, Acum, scores, Cm, states, Dp, y);
  // 8.5) prep out_proj weight: [2048][1024] -> bf16 transposed [1024][2048] (scores region)
  transcast_kernel<<<dim3(DMODEL/64, INTER/64), 256, 0, stream>>>(w_out, w_outT, INTER, DMODEL, 0);
  // 9) gate + RMSNorm (in place on y)
  gatenorm_kernel<<<ROWS, 256, 0, stream>>>(y, z, nw);
  // 10) out = y @ out_proj_w via bf16 MFMA
  gemm_mfma_outproj<<<dim3(DMODEL/128, ROWS/128), 256, 0, stream>>>(y, w_outT, out);
}

// Round 4
// 857.098 us; speedup vs baseline: 3.6018x; 1.4571x over previous
//
#include <hip/hip_runtime.h>
#include <hip/hip_bf16.h>

#define B_SZ 2
#define SEQ 4096
#define DMODEL 1024
#define INTER 2048
#define NHEADS 32
#define HDIM 64
#define DSTATE 128
#define DCONV 4
#define CONVDIM 2304
#define PROJDIM 4384
#define CHUNK 256
#define NCHUNK 16
#define ROWS (B_SZ*SEQ)   // 8192
#define NGEMM 4352        // z + xBC columns (34 tiles of 128)

typedef __hip_bfloat16 bf16;
typedef short bfx8 __attribute__((ext_vector_type(8)));
typedef float f32x4 __attribute__((ext_vector_type(4)));

__device__ __forceinline__ float sigmoidf_(float x){ return 1.f/(1.f+expf(-x)); }
__device__ __forceinline__ float b2f(bf16 v){ return __bfloat162float(v); }
__device__ __forceinline__ bf16 f2b(float v){ return __float2bfloat16(v); }
__device__ __forceinline__ float bits2f(unsigned short u){ return __uint_as_float(((unsigned)u) << 16); }
__device__ __forceinline__ unsigned short f2bits(float v){ bf16 t = __float2bfloat16(v); return *(unsigned short*)&t; }

#define MFMA16(a,b,c) __builtin_amdgcn_mfma_f32_16x16x32_bf16(a,b,c,0,0,0)

// ---------------- fallback: zero d_out (diagnostic path if ws too small) ----------------
__global__ void zero_out_kernel(float* o, int n){
  int i = blockIdx.x*256 + threadIdx.x;
  if (i < n) o[i] = 0.f;
}

// ---------------- cast u (f32) -> bf16, 4 elems/thread ----------------
__global__ __launch_bounds__(256) void castu_kernel(const float* __restrict__ in,
    unsigned short* __restrict__ o){
  int i = blockIdx.x*256 + threadIdx.x;
  float4 v = ((const float4*)in)[i];
  ushort4 w;
  w.x = f2bits(v.x); w.y = f2bits(v.y); w.z = f2bits(v.z); w.w = f2bits(v.w);
  ((ushort4*)o)[i] = w;
}

// ---------------- cast + transpose: in f32 [R][ld] (cols c0..) -> outT bf16 [C][R] ----------------
__global__ __launch_bounds__(256) void transcast_kernel(const float* __restrict__ in,
    bf16* __restrict__ outT, int R, int ld, int coff){
  __shared__ float t[64][65];
  int r0 = blockIdx.y*64, c0 = blockIdx.x*64;
  int tid = threadIdx.x;
  #pragma unroll
  for (int i = 0; i < 16; i++){
    int idx = tid + i*256;
    int r = idx >> 6, c = idx & 63;
    t[r][c] = in[(size_t)(r0+r)*ld + coff + c0 + c];
  }
  __syncthreads();
  #pragma unroll
  for (int i = 0; i < 16; i++){
    int idx = tid + i*256;
    int c = idx >> 6, r = idx & 63;
    outT[(size_t)(c0+c)*R + r0 + r] = f2b(t[r][c]);
  }
}

// ================= bf16 MFMA GEMM core (m97 structure) =================
#define MFMA_GEMM_BODY(K_, EPILOGUE)                                           \
  __shared__ unsigned short As[128*64];                                        \
  __shared__ unsigned short Bs[128*64];                                        \
  const int tid = threadIdx.x;                                                 \
  const int lane = tid & 63, wid = tid >> 6;                                   \
  const int wm = wid >> 1, wn = wid & 1;                                       \
  const int row0 = blockIdx.y*128, col0 = blockIdx.x*128;                      \
  f32x4 acc[4][4] = {};                                                        \
  const int rstg = wid*32 + ((lane>>3)&7);                                     \
  const int kstg = (lane&7)*8;                                                 \
  for (int k0 = 0; k0 < (K_); k0 += 64){                                       \
    _Pragma("unroll")                                                          \
    for (int j = 0; j < 4; j++){                                               \
      const bf16* gA = A + (size_t)(row0 + rstg + j*8)*(K_) + k0 + kstg;       \
      __builtin_amdgcn_global_load_lds(                                        \
        (const __attribute__((address_space(1))) void*)gA,                     \
        (__attribute__((address_space(3))) void*)(As + (wid*32 + j*8)*64),     \
        16, 0, 0);                                                             \
      const bf16* gB = Bt + (size_t)(col0 + rstg + j*8)*(K_) + k0 + kstg;      \
      __builtin_amdgcn_global_load_lds(                                        \
        (const __attribute__((address_space(1))) void*)gB,                     \
        (__attribute__((address_space(3))) void*)(Bs + (wid*32 + j*8)*64),     \
        16, 0, 0);                                                             \
    }                                                                          \
    __syncthreads();                                                           \
    _Pragma("unroll")                                                          \
    for (int kk = 0; kk < 2; kk++){                                            \
      bfx8 af[4], bfr[4];                                                      \
      _Pragma("unroll")                                                        \
      for (int m = 0; m < 4; m++)                                              \
        af[m] = *(const bfx8*)(As + (wm*64 + m*16 + (lane&15))*64              \
                               + kk*32 + (lane>>4)*8);                         \
      _Pragma("unroll")                                                        \
      for (int n = 0; n < 4; n++)                                              \
        bfr[n] = *(const bfx8*)(Bs + (wn*64 + n*16 + (lane&15))*64             \
                                + kk*32 + (lane>>4)*8);                        \
      _Pragma("unroll")                                                        \
      for (int m = 0; m < 4; m++)                                              \
        _Pragma("unroll")                                                      \
        for (int n = 0; n < 4; n++)                                            \
          acc[m][n] = MFMA16(af[m], bfr[n], acc[m][n]);                        \
    }                                                                          \
    __syncthreads();                                                           \
  }                                                                            \
  _Pragma("unroll")                                                            \
  for (int m = 0; m < 4; m++){                                                 \
    int row = row0 + wm*64 + m*16 + (lane>>4)*4;                               \
    _Pragma("unroll")                                                          \
    for (int n = 0; n < 4; n++){                                               \
      int col = col0 + wn*64 + n*16 + (lane&15);                               \
      _Pragma("unroll")                                                        \
      for (int r = 0; r < 4; r++){                                             \
        float v = acc[m][n][r];                                                \
        int rr = row + r;                                                      \
        EPILOGUE                                                               \
      }                                                                        \
    }                                                                          \
  }

__global__ __launch_bounds__(256) void gemm_mfma_inproj(const bf16* __restrict__ A,
    const bf16* __restrict__ Bt, bf16* __restrict__ z, bf16* __restrict__ xbc){
  MFMA_GEMM_BODY(DMODEL,
    if (col < INTER) z[(size_t)rr*INTER + col] = f2b(v);
    else             xbc[(size_t)rr*CONVDIM + (col - INTER)] = f2b(v);
  )
}

__global__ __launch_bounds__(256) void gemm_mfma_outproj(const bf16* __restrict__ A,
    const bf16* __restrict__ Bt, float* __restrict__ C){
  MFMA_GEMM_BODY(INTER,
    C[(size_t)rr*DMODEL + col] = v;
  )
}

// ---------------- small fp32 GEMM for dt columns (precision-critical) ----------------
__global__ __launch_bounds__(256) void gemm_f32_dt(const float* __restrict__ A,
    const float* __restrict__ B, float* __restrict__ C, int N, int K, int ldb){
  __shared__ float As[64][17];
  __shared__ float Bs[16][65];
  int tid = threadIdx.x, tx = tid & 15, ty = tid >> 4;
  int row0 = blockIdx.y*64, col0 = blockIdx.x*64;
  float acc[4][4] = {};
  for (int k0 = 0; k0 < K; k0 += 16){
    #pragma unroll
    for (int i = 0; i < 4; i++){
      int idx = tid + i*256;
      As[idx >> 4][idx & 15] = A[(size_t)(row0 + (idx >> 4))*K + k0 + (idx & 15)];
    }
    #pragma unroll
    for (int i = 0; i < 4; i++){
      int idx = tid + i*256;
      int col = col0 + (idx & 63);
      Bs[idx >> 6][idx & 63] = (col < N) ? B[(size_t)(k0 + (idx >> 6))*ldb + col] : 0.f;
    }
    __syncthreads();
    #pragma unroll
    for (int kk = 0; kk < 16; kk++){
      float a[4], bb[4];
      #pragma unroll
      for (int i = 0; i < 4; i++) a[i] = As[ty*4+i][kk];
      #pragma unroll
      for (int j = 0; j < 4; j++) bb[j] = Bs[kk][tx*4+j];
      #pragma unroll
      for (int i = 0; i < 4; i++)
        #pragma unroll
        for (int j = 0; j < 4; j++) acc[i][j] += a[i]*bb[j];
    }
    __syncthreads();
  }
  #pragma unroll
  for (int i = 0; i < 4; i++){
    int r = row0 + ty*4 + i;
    #pragma unroll
    for (int j = 0; j < 4; j++){
      int col = col0 + tx*4 + j;
      if (col < N) C[(size_t)r*N + col] = acc[i][j];
    }
  }
}

// ---------------- conv1d + silu + split (Bm/Cm now bf16) ----------------
__global__ __launch_bounds__(256) void conv_kernel(const bf16* __restrict__ xbc,
    const float* __restrict__ cw, const float* __restrict__ cb,
    bf16* __restrict__ x, bf16* __restrict__ Bm, bf16* __restrict__ Cm){
  int bt = blockIdx.x / 9;
  int ch = (blockIdx.x % 9)*256 + threadIdx.x;
  int t = bt & (SEQ-1);
  float acc = cb[ch];
  #pragma unroll
  for (int i = 0; i < 4; i++){
    int tt = t - 3 + i;
    if (tt >= 0)
      acc = fmaf(b2f(xbc[(size_t)(bt - t + tt)*CONVDIM + ch]), cw[ch*4+i], acc);
  }
  float v = acc * sigmoidf_(acc);
  if (ch < INTER)              x[(size_t)bt*INTER + ch] = f2b(v);
  else if (ch < INTER+DSTATE)  Bm[(size_t)bt*DSTATE + (ch-INTER)] = f2b(v);
  else                         Cm[(size_t)bt*DSTATE + (ch-INTER-DSTATE)] = f2b(v);
}

// ---------------- dt = softplus(dt_raw + bias) ----------------
__global__ __launch_bounds__(256) void dt_kernel(const float* __restrict__ dtraw,
    const float* __restrict__ dt_bias, float* __restrict__ dt){
  int idx = blockIdx.x*256 + threadIdx.x;
  int h = idx & 31;
  float v = dtraw[idx] + dt_bias[h];
  dt[idx] = (v > 20.f) ? v : log1pf(expf(v));
}

// ---------------- per-chunk inclusive cumsum of dt*A ----------------
__global__ __launch_bounds__(256) void acum_kernel(const float* __restrict__ dt,
    const float* __restrict__ A_log, float* __restrict__ Acum){
  int bi = blockIdx.x;            // (b*NHEADS+h)*NCHUNK + c
  int c = bi & 15; int h = (bi >> 4) & 31; int b = bi >> 9;
  int l = threadIdx.x;
  __shared__ float sbuf[CHUNK];
  float A = -expf(A_log[h]);
  int t = c*CHUNK + l;
  sbuf[l] = dt[(size_t)(b*SEQ + t)*NHEADS + h] * A;
  __syncthreads();
  for (int off = 1; off < CHUNK; off <<= 1){
    float add = (l >= off) ? sbuf[l-off] : 0.f;
    __syncthreads();
    sbuf[l] += add;
    __syncthreads();
  }
  Acum[(size_t)bi*CHUNK + l] = sbuf[l];
}

// ---------------- per-chunk states: states[b,c,h,p,n] (f32) ----------------
__global__ __launch_bounds__(256) void chunk_states_kernel(const bf16* __restrict__ x,
    const bf16* __restrict__ Bm, const float* __restrict__ dt,
    const float* __restrict__ Acum, float* __restrict__ states){
  int bi = blockIdx.x;            // (b*NCHUNK+c)*NHEADS + h
  int h = bi & 31; int c = (bi >> 5) & 15; int b = bi >> 9;
  int tid = threadIdx.x;
  __shared__ float w[CHUNK];
  __shared__ float Bsm[64][128];
  __shared__ float xs[64][64];
  const float* AcBase = Acum + ((size_t)(b*NHEADS + h)*NCHUNK + c)*CHUNK;
  float AcLast = AcBase[CHUNK-1];
  {
    int l = tid;
    int t = c*CHUNK + l;
    w[l] = expf(AcLast - AcBase[l]) * dt[(size_t)(b*SEQ + t)*NHEADS + h];
  }
  __syncthreads();
  float acc[32];
  #pragma unroll
  for (int i = 0; i < 32; i++) acc[i] = 0.f;
  int n = tid & 127;
  int p0 = tid >> 7;
  for (int lt = 0; lt < CHUNK; lt += 64){
    #pragma unroll
    for (int i = 0; i < 32; i++){
      int idx = tid + i*256;
      Bsm[idx >> 7][idx & 127] = b2f(Bm[(size_t)(b*SEQ + c*CHUNK + lt + (idx >> 7))*DSTATE + (idx & 127)]);
    }
    #pragma unroll
    for (int i = 0; i < 16; i++){
      int idx = tid + i*256;
      xs[idx >> 6][idx & 63] = b2f(x[(size_t)(b*SEQ + c*CHUNK + lt + (idx >> 6))*INTER + h*HDIM + (idx & 63)]);
    }
    __syncthreads();
    for (int l = 0; l < 64; l++){
      float bn = Bsm[l][n] * w[lt + l];
      #pragma unroll
      for (int i = 0; i < 32; i++) acc[i] = fmaf(bn, xs[l][p0 + 2*i], acc[i]);
    }
    __syncthreads();
  }
  size_t base = ((size_t)bi)*HDIM*DSTATE;
  #pragma unroll
  for (int i = 0; i < 32; i++)
    states[base + (size_t)(p0 + 2*i)*DSTATE + n] = acc[i];
}

// ---------------- inter-chunk scan (in-place) ----------------
__global__ __launch_bounds__(256) void scan_kernel(float* __restrict__ states,
    const float* __restrict__ Acum){
  int idx = blockIdx.x*256 + threadIdx.x;
  int n = idx & 127; int p = (idx >> 7) & 63; int h = (idx >> 13) & 31; int b = idx >> 18;
  float R = 0.f;
  for (int c = 0; c < NCHUNK; c++){
    size_t o = (((size_t)((b*NCHUNK + c)*NHEADS + h))*HDIM + p)*DSTATE + n;
    float s = states[o];
    states[o] = R;
    float dA = expf(Acum[((size_t)(b*NHEADS + h)*NCHUNK + c)*CHUNK + CHUNK-1]);
    R = R*dA + s;
  }
}

// ================= fused MFMA Y kernel: Y = (L∘(C·Bᵀ))·Xdt + exp(Ac)·C·statesᵀ, D·x on W-diag =================
// block = (b,c,h); 4 waves; wave w owns rows [w*64, w*64+64); stripes j<=w (triangular skip)
__global__ __launch_bounds__(256) void ydiag_mfma(
    const bf16* x, const float* __restrict__ dt,
    const float* __restrict__ Acum, const bf16* __restrict__ Bm,
    const bf16* __restrict__ Cm, const float* __restrict__ states,
    const float* __restrict__ Dp, bf16* y){
  int bi = blockIdx.x;            // (b*NCHUNK+c)*NHEADS + h
  int h = bi & 31; int c = (bi >> 5) & 15; int b = bi >> 9;
  int tid = threadIdx.x, lane = tid & 63, w = tid >> 6;

  __shared__ unsigned short XdtT[64*264];          // [p][s] pad 264
  __shared__ unsigned short pool[256*72];          // statesT(64x136) / Xrm(256x72) / W(4x64x64 swz)
  __shared__ float Acs[CHUNK];
  __shared__ float dts[CHUNK];

  const float* AcBase = Acum + ((size_t)(b*NHEADS + h)*NCHUNK + c)*CHUNK;
  // phase 0: stage statesT (bf16), Ac, dt
  Acs[tid] = AcBase[tid];
  dts[tid] = dt[(size_t)(b*SEQ + c*CHUNK + tid)*NHEADS + h];
  {
    const float* src = states + (size_t)bi*HDIM*DSTATE;   // [p][n]
    #pragma unroll
    for (int i = 0; i < 32; i++){
      int idx = tid + i*256;
      int p = idx >> 7, n = idx & 127;
      pool[p*136 + n] = f2bits(src[idx]);
    }
  }
  __syncthreads();

  const bf16* Crow = Cm + (size_t)(b*SEQ + c*CHUNK)*DSTATE;
  const bf16* Brow = Bm + (size_t)(b*SEQ + c*CHUNK)*DSTATE;

  // off-GEMM: accY = C @ statesT   (K = 128)
  f32x4 accY[4][4] = {};
  #pragma unroll
  for (int kk = 0; kk < 4; kk++){
    bfx8 af[4], bfr[4];
    #pragma unroll
    for (int m = 0; m < 4; m++)
      af[m] = *(const bfx8*)(Crow + (size_t)(w*64 + m*16 + (lane&15))*DSTATE + kk*32 + (lane>>4)*8);
    #pragma unroll
    for (int n = 0; n < 4; n++)
      bfr[n] = *(const bfx8*)(pool + (n*16 + (lane&15))*136 + kk*32 + (lane>>4)*8);
    #pragma unroll
    for (int m = 0; m < 4; m++)
      #pragma unroll
      for (int n = 0; n < 4; n++)
        accY[m][n] = MFMA16(af[m], bfr[n], accY[m][n]);
  }
  // scale by exp(Ac_l)
  {
    float eAl[4][4];
    #pragma unroll
    for (int m = 0; m < 4; m++)
      #pragma unroll
      for (int r = 0; r < 4; r++)
        eAl[m][r] = expf(Acs[w*64 + m*16 + (lane>>4)*4 + r]);
    #pragma unroll
    for (int m = 0; m < 4; m++)
      #pragma unroll
      for (int n = 0; n < 4; n++)
        #pragma unroll
        for (int r = 0; r < 4; r++)
          accY[m][n][r] *= eAl[m][r];
  }
  __syncthreads();   // statesT dead; pool -> Xrm

  // phase 1: Xrm = Xdt row-major [256 s][72-stride p]
  {
    const bf16* xg = x + (size_t)(b*SEQ + c*CHUNK)*INTER + h*HDIM;
    #pragma unroll
    for (int i = 0; i < 8; i++){
      int u = tid + i*256;
      int s = u >> 3, p0 = (u & 7)*8;
      bfx8 v = *(const bfx8*)(xg + (size_t)s*INTER + p0);
      float d = dts[s];
      bfx8 o;
      #pragma unroll
      for (int j = 0; j < 8; j++)
        o[j] = (short)f2bits(bits2f((unsigned short)v[j]) * d);
      *(bfx8*)(pool + s*72 + p0) = o;
    }
  }
  __syncthreads();
  // phase 2: transpose Xrm -> XdtT
  {
    int p = tid & 63, sb = tid >> 6;
    #pragma unroll
    for (int i = 0; i < 8; i++){
      int s0 = (sb + i*4)*8;
      bfx8 v;
      #pragma unroll
      for (int j = 0; j < 8; j++)
        v[j] = (short)pool[(s0 + j)*72 + p];
      *(bfx8*)(XdtT + p*264 + s0) = v;
    }
  }
  __syncthreads();   // XdtT ready; pool -> W (wave-local, no more block barriers)

  char* Wl = (char*)pool + w*8192;   // 64x64 bf16, swz: byte = l*128 + ((s*2)^((l&7)<<4))
  float Dh = Dp[h];

  for (int j = 0; j <= w; j++){
    int s0 = j*64;
    // S-GEMM: accS = C_rows @ B_stripe^T  (K = 128)
    f32x4 accS[4][4] = {};
    #pragma unroll
    for (int kk = 0; kk < 4; kk++){
      bfx8 af[4], bfr[4];
      #pragma unroll
      for (int m = 0; m < 4; m++)
        af[m] = *(const bfx8*)(Crow + (size_t)(w*64 + m*16 + (lane&15))*DSTATE + kk*32 + (lane>>4)*8);
      #pragma unroll
      for (int n = 0; n < 4; n++)
        bfr[n] = *(const bfx8*)(Brow + (size_t)(s0 + n*16 + (lane&15))*DSTATE + kk*32 + (lane>>4)*8);
      #pragma unroll
      for (int m = 0; m < 4; m++)
        #pragma unroll
        for (int n = 0; n < 4; n++)
          accS[m][n] = MFMA16(af[m], bfr[n], accS[m][n]);
    }
    // transform -> W (bf16, swizzled)
    if (j < w){
      float m_ = Acs[s0 + 63];
      float colf[4], rowf[4][4];
      #pragma unroll
      for (int n = 0; n < 4; n++) colf[n] = expf(m_ - Acs[s0 + n*16 + (lane&15)]);
      #pragma unroll
      for (int m = 0; m < 4; m++)
        #pragma unroll
        for (int r = 0; r < 4; r++)
          rowf[m][r] = expf(Acs[w*64 + m*16 + (lane>>4)*4 + r] - m_);
      #pragma unroll
      for (int m = 0; m < 4; m++)
        #pragma unroll
        for (int n = 0; n < 4; n++)
          #pragma unroll
          for (int r = 0; r < 4; r++){
            int ll = m*16 + (lane>>4)*4 + r;
            int sl = n*16 + (lane&15);
            *(unsigned short*)(Wl + ll*128 + ((sl*2) ^ ((ll&7)<<4)))
              = f2bits(accS[m][n][r] * rowf[m][r] * colf[n]);
          }
    } else {
      #pragma unroll
      for (int m = 0; m < 4; m++)
        #pragma unroll
        for (int n = 0; n < 4; n++)
          #pragma unroll
          for (int r = 0; r < 4; r++){
            int ll = m*16 + (lane>>4)*4 + r;
            int sl = n*16 + (lane&15);
            int lg = w*64 + ll, sg = s0 + sl;
            float wv;
            if (sg > lg)       wv = 0.f;
            else if (sg == lg) wv = accS[m][n][r] + Dh/dts[lg];
            else               wv = accS[m][n][r]*expf(Acs[lg] - Acs[sg]);
            *(unsigned short*)(Wl + ll*128 + ((sl*2) ^ ((ll&7)<<4))) = f2bits(wv);
          }
    }
    asm volatile("s_waitcnt lgkmcnt(0)" ::: "memory");
    __builtin_amdgcn_sched_barrier(0);
    // Y-GEMM: accY += W @ Xdt_stripe  (K = 64)
    #pragma unroll
    for (int kk = 0; kk < 2; kk++){
      bfx8 af[4], bfr[4];
      #pragma unroll
      for (int m = 0; m < 4; m++){
        int ll = m*16 + (lane&15);
        af[m] = *(const bfx8*)(Wl + ll*128 + (((kk*32 + (lane>>4)*8)*2) ^ ((ll&7)<<4)));
      }
      #pragma unroll
      for (int n = 0; n < 4; n++)
        bfr[n] = *(const bfx8*)(XdtT + (n*16 + (lane&15))*264 + s0 + kk*32 + (lane>>4)*8);
      #pragma unroll
      for (int m = 0; m < 4; m++)
        #pragma unroll
        for (int n = 0; n < 4; n++)
          accY[m][n] = MFMA16(af[m], bfr[n], accY[m][n]);
    }
  }
  // epilogue: write y (aliases x region; all x reads completed pre-barrier)
  bf16* yg = y + (size_t)(b*SEQ + c*CHUNK)*INTER + h*HDIM;
  #pragma unroll
  for (int m = 0; m < 4; m++)
    #pragma unroll
    for (int n = 0; n < 4; n++)
      #pragma unroll
      for (int r = 0; r < 4; r++)
        yg[(size_t)(w*64 + m*16 + (lane>>4)*4 + r)*INTER + n*16 + (lane&15)]
          = f2b(accY[m][n][r]);
}

// ---------------- gate (y * silu(z)) + RMSNorm * norm_w, in place (bf16) ----------------
__global__ __launch_bounds__(256) void gatenorm_kernel(bf16* __restrict__ y,
    const bf16* __restrict__ z, const float* __restrict__ nw){
  int row = blockIdx.x;
  const bf16* zr = z + (size_t)row*INTER;
  bf16* yr = y + (size_t)row*INTER;
  int tid = threadIdx.x;
  float g[8]; float ss = 0.f;
  #pragma unroll
  for (int i = 0; i < 8; i++){
    int idx = tid + i*256;
    float zv = b2f(zr[idx]);
    float gv = b2f(yr[idx]) * zv * sigmoidf_(zv);
    g[i] = gv; ss += gv*gv;
  }
  #pragma unroll
  for (int off = 32; off > 0; off >>= 1) ss += __shfl_down(ss, off);
  __shared__ float red[4];
  __shared__ float stot;
  int lane = tid & 63, wid = tid >> 6;
  if (lane == 0) red[wid] = ss;
  __syncthreads();
  if (tid == 0) stot = rsqrtf((red[0]+red[1]+red[2]+red[3]) * (1.f/INTER) + 1e-5f);
  __syncthreads();
  float sc = stot;
  #pragma unroll
  for (int i = 0; i < 8; i++){
    int idx = tid + i*256;
    yr[idx] = f2b(g[i]*sc*nw[idx]);
  }
}

extern "C" void kernel_launch(void* const* d_in, const int* in_sizes, int n_in,
                              void* d_out, int out_size, void* d_ws, size_t ws_size,
                              hipStream_t stream){
  const float* u    = (const float*)d_in[0];
  const float* w_in = (const float*)d_in[1];
  const float* cw   = (const float*)d_in[2];
  const float* cb   = (const float*)d_in[3];
  const float* dtb  = (const float*)d_in[4];
  const float* Alog = (const float*)d_in[5];
  const float* Dp   = (const float*)d_in[6];
  const float* nw   = (const float*)d_in[7];
  const float* w_out= (const float*)d_in[8];
  float* out = (float*)d_out;
  char* ws = (char*)d_ws;

  // layout (bytes)
  const size_t OFF_Z     = 0;              // bf16 [8192][2048]          33,554,432
  const size_t OFF_XBC   = 33554432;       // bf16 [8192][2304]; states f32 aliases after conv
  const size_t OFF_DT    = 67108864;       // f32 [8192][32] (XBC tail, valid after conv)
  const size_t OFF_ACUM  = 68157440;       // f32 [2*32*16*256] (XBC tail)
  const size_t OFF_X     = 71303168;       // bf16 [8192][2048]; y ALIASES here (ydiag reads-then-writes per-block slice)
  const size_t OFF_UBF   = 104857600;      // bf16 u [8192][1024] (dead after inproj)
  const size_t OFF_WINT  = 121634816;      // bf16 w_inT [4352][1024] (dead after inproj)
  const size_t OFF_BM    = 130547712;      // bf16 [8192][128]
  const size_t OFF_CM    = 132644864;      // bf16 [8192][128]
  const size_t OFF_DTRAW = 134742016;      // f32 [8192][32]
  const size_t OFF_WOUTT = 135790592;      // bf16 [1024][2048]
  const size_t NEED      = 139984896;

  if (ws_size < NEED){
    zero_out_kernel<<<(out_size + 255)/256, 256, 0, stream>>>(out, out_size);
    return;
  }

  bf16*  z      = (bf16*)(ws + OFF_Z);
  bf16*  xbc    = (bf16*)(ws + OFF_XBC);
  float* states = (float*)(ws + OFF_XBC);   // alias: xbc dead after conv
  float* dt     = (float*)(ws + OFF_DT);
  float* Acum   = (float*)(ws + OFF_ACUM);
  bf16*  x      = (bf16*)(ws + OFF_X);
  bf16*  y      = (bf16*)(ws + OFF_X);      // alias: per-block exclusive read-then-write in ydiag
  bf16*  u_bf   = (bf16*)(ws + OFF_UBF);
  bf16*  w_inT  = (bf16*)(ws + OFF_WINT);
  bf16*  Bm     = (bf16*)(ws + OFF_BM);
  bf16*  Cm     = (bf16*)(ws + OFF_CM);
  float* dtraw  = (float*)(ws + OFF_DTRAW);
  bf16*  w_outT = (bf16*)(ws + OFF_WOUTT);

  // 0) prep
  castu_kernel<<<(ROWS*DMODEL/4)/256, 256, 0, stream>>>(u, (unsigned short*)u_bf);
  transcast_kernel<<<dim3(NGEMM/64, DMODEL/64), 256, 0, stream>>>(w_in, w_inT, DMODEL, PROJDIM, 0);
  // 1a) z/xBC via bf16 MFMA GEMM
  gemm_mfma_inproj<<<dim3(NGEMM/128, ROWS/128), 256, 0, stream>>>(u_bf, w_inT, z, xbc);
  // 1b) dtraw via small fp32 GEMM
  gemm_f32_dt<<<dim3(1, ROWS/64), 256, 0, stream>>>(u, w_in + NGEMM, dtraw, NHEADS, DMODEL, PROJDIM);
  // 2) conv + silu + split
  conv_kernel<<<ROWS*9, 256, 0, stream>>>(xbc, cw, cb, x, Bm, Cm);
  // 3) dt softplus
  dt_kernel<<<ROWS*NHEADS/256, 256, 0, stream>>>(dtraw, dtb, dt);
  // 4) per-chunk cumsum of dt*A
  acum_kernel<<<B_SZ*NHEADS*NCHUNK, 256, 0, stream>>>(dt, Alog, Acum);
  // 5) per-chunk states (overwrites xbc region)
  chunk_states_kernel<<<B_SZ*NCHUNK*NHEADS, 256, 0, stream>>>(x, Bm, dt, Acum, states);
  // 6) inter-chunk scan
  scan_kernel<<<(B_SZ*NHEADS*HDIM*DSTATE)/256, 256, 0, stream>>>(states, Acum);
  // 7) fused MFMA Y (replaces scores + ydiag); y aliases x
  ydiag_mfma<<<B_SZ*NCHUNK*NHEADS, 256, 0, stream>>>(x, dt, Acum, Bm, Cm, states, Dp, y);
  // 7.5) prep out_proj weight
  transcast_kernel<<<dim3(DMODEL/64, INTER/64), 256, 0, stream>>>(w_out, w_outT, INTER, DMODEL, 0);
  // 8) gate + RMSNorm (in place on y)
  gatenorm_kernel<<<ROWS, 256, 0, stream>>>(y, z, nw);
  // 9) out = y @ out_proj_w via bf16 MFMA
  gemm_mfma_outproj<<<dim3(DMODEL/128, ROWS/128), 256, 0, stream>>>(y, w_outT, out);
}

// Round 5
// 566.744 us; speedup vs baseline: 5.4470x; 1.5123x over previous
//
#include <hip/hip_runtime.h>
#include <hip/hip_bf16.h>

#define B_SZ 2
#define SEQ 4096
#define DMODEL 1024
#define INTER 2048
#define NHEADS 32
#define HDIM 64
#define DSTATE 128
#define DCONV 4
#define CONVDIM 2304
#define PROJDIM 4384
#define CHUNK 256
#define NCHUNK 16
#define ROWS (B_SZ*SEQ)   // 8192
#define NGEMM 4352        // z + xBC columns (34 tiles of 128)

typedef __hip_bfloat16 bf16;
typedef short bfx8 __attribute__((ext_vector_type(8)));
typedef float f32x4 __attribute__((ext_vector_type(4)));

__device__ __forceinline__ float sigmoidf_(float x){ return 1.f/(1.f+expf(-x)); }
__device__ __forceinline__ float b2f(bf16 v){ return __bfloat162float(v); }
__device__ __forceinline__ bf16 f2b(float v){ return __float2bfloat16(v); }
__device__ __forceinline__ float bits2f(unsigned short u){ return __uint_as_float(((unsigned)u) << 16); }
__device__ __forceinline__ unsigned short f2bits(float v){ bf16 t = __float2bfloat16(v); return *(unsigned short*)&t; }

#define MFMA16(a,b,c) __builtin_amdgcn_mfma_f32_16x16x32_bf16(a,b,c,0,0,0)

// ---------------- fallback: zero d_out (diagnostic path if ws too small) ----------------
__global__ void zero_out_kernel(float* o, int n){
  int i = blockIdx.x*256 + threadIdx.x;
  if (i < n) o[i] = 0.f;
}

// ---------------- cast u (f32) -> bf16, 4 elems/thread ----------------
__global__ __launch_bounds__(256) void castu_kernel(const float* __restrict__ in,
    unsigned short* __restrict__ o){
  int i = blockIdx.x*256 + threadIdx.x;
  float4 v = ((const float4*)in)[i];
  ushort4 w;
  w.x = f2bits(v.x); w.y = f2bits(v.y); w.z = f2bits(v.z); w.w = f2bits(v.w);
  ((ushort4*)o)[i] = w;
}

// ---------------- cast + transpose: in f32 [R][ld] (cols c0..) -> outT bf16 [C][R] ----------------
__global__ __launch_bounds__(256) void transcast_kernel(const float* __restrict__ in,
    bf16* __restrict__ outT, int R, int ld, int coff){
  __shared__ float t[64][65];
  int r0 = blockIdx.y*64, c0 = blockIdx.x*64;
  int tid = threadIdx.x;
  #pragma unroll
  for (int i = 0; i < 16; i++){
    int idx = tid + i*256;
    int r = idx >> 6, c = idx & 63;
    t[r][c] = in[(size_t)(r0+r)*ld + coff + c0 + c];
  }
  __syncthreads();
  #pragma unroll
  for (int i = 0; i < 16; i++){
    int idx = tid + i*256;
    int c = idx >> 6, r = idx & 63;
    outT[(size_t)(c0+c)*R + r0 + r] = f2b(t[r][c]);
  }
}

// ================= bf16 MFMA GEMM core (m97 structure) =================
#define MFMA_GEMM_BODY(K_, EPILOGUE)                                           \
  __shared__ unsigned short As[128*64];                                        \
  __shared__ unsigned short Bs[128*64];                                        \
  const int tid = threadIdx.x;                                                 \
  const int lane = tid & 63, wid = tid >> 6;                                   \
  const int wm = wid >> 1, wn = wid & 1;                                       \
  const int row0 = blockIdx.y*128, col0 = blockIdx.x*128;                      \
  f32x4 acc[4][4] = {};                                                        \
  const int rstg = wid*32 + ((lane>>3)&7);                                     \
  const int kstg = (lane&7)*8;                                                 \
  for (int k0 = 0; k0 < (K_); k0 += 64){                                       \
    _Pragma("unroll")                                                          \
    for (int j = 0; j < 4; j++){                                               \
      const bf16* gA = A + (size_t)(row0 + rstg + j*8)*(K_) + k0 + kstg;       \
      __builtin_amdgcn_global_load_lds(                                        \
        (const __attribute__((address_space(1))) void*)gA,                     \
        (__attribute__((address_space(3))) void*)(As + (wid*32 + j*8)*64),     \
        16, 0, 0);                                                             \
      const bf16* gB = Bt + (size_t)(col0 + rstg + j*8)*(K_) + k0 + kstg;      \
      __builtin_amdgcn_global_load_lds(                                        \
        (const __attribute__((address_space(1))) void*)gB,                     \
        (__attribute__((address_space(3))) void*)(Bs + (wid*32 + j*8)*64),     \
        16, 0, 0);                                                             \
    }                                                                          \
    __syncthreads();                                                           \
    _Pragma("unroll")                                                          \
    for (int kk = 0; kk < 2; kk++){                                            \
      bfx8 af[4], bfr[4];                                                      \
      _Pragma("unroll")                                                        \
      for (int m = 0; m < 4; m++)                                              \
        af[m] = *(const bfx8*)(As + (wm*64 + m*16 + (lane&15))*64              \
                               + kk*32 + (lane>>4)*8);                         \
      _Pragma("unroll")                                                        \
      for (int n = 0; n < 4; n++)                                              \
        bfr[n] = *(const bfx8*)(Bs + (wn*64 + n*16 + (lane&15))*64             \
                                + kk*32 + (lane>>4)*8);                        \
      _Pragma("unroll")                                                        \
      for (int m = 0; m < 4; m++)                                              \
        _Pragma("unroll")                                                      \
        for (int n = 0; n < 4; n++)                                            \
          acc[m][n] = MFMA16(af[m], bfr[n], acc[m][n]);                        \
    }                                                                          \
    __syncthreads();                                                           \
  }                                                                            \
  _Pragma("unroll")                                                            \
  for (int m = 0; m < 4; m++){                                                 \
    int row = row0 + wm*64 + m*16 + (lane>>4)*4;                               \
    _Pragma("unroll")                                                          \
    for (int n = 0; n < 4; n++){                                               \
      int col = col0 + wn*64 + n*16 + (lane&15);                               \
      _Pragma("unroll")                                                        \
      for (int r = 0; r < 4; r++){                                             \
        float v = acc[m][n][r];                                                \
        int rr = row + r;                                                      \
        EPILOGUE                                                               \
      }                                                                        \
    }                                                                          \
  }

__global__ __launch_bounds__(256) void gemm_mfma_inproj(const bf16* __restrict__ A,
    const bf16* __restrict__ Bt, bf16* __restrict__ z, bf16* __restrict__ xbc){
  MFMA_GEMM_BODY(DMODEL,
    if (col < INTER) z[(size_t)rr*INTER + col] = f2b(v);
    else             xbc[(size_t)rr*CONVDIM + (col - INTER)] = f2b(v);
  )
}

__global__ __launch_bounds__(256) void gemm_mfma_outproj(const bf16* __restrict__ A,
    const bf16* __restrict__ Bt, float* __restrict__ C){
  MFMA_GEMM_BODY(INTER,
    C[(size_t)rr*DMODEL + col] = v;
  )
}

// ---------------- small fp32 GEMM for dt columns (precision-critical) ----------------
__global__ __launch_bounds__(256) void gemm_f32_dt(const float* __restrict__ A,
    const float* __restrict__ B, float* __restrict__ C, int N, int K, int ldb){
  __shared__ float As[64][17];
  __shared__ float Bs[16][65];
  int tid = threadIdx.x, tx = tid & 15, ty = tid >> 4;
  int row0 = blockIdx.y*64, col0 = blockIdx.x*64;
  float acc[4][4] = {};
  for (int k0 = 0; k0 < K; k0 += 16){
    #pragma unroll
    for (int i = 0; i < 4; i++){
      int idx = tid + i*256;
      As[idx >> 4][idx & 15] = A[(size_t)(row0 + (idx >> 4))*K + k0 + (idx & 15)];
    }
    #pragma unroll
    for (int i = 0; i < 4; i++){
      int idx = tid + i*256;
      int col = col0 + (idx & 63);
      Bs[idx >> 6][idx & 63] = (col < N) ? B[(size_t)(k0 + (idx >> 6))*ldb + col] : 0.f;
    }
    __syncthreads();
    #pragma unroll
    for (int kk = 0; kk < 16; kk++){
      float a[4], bb[4];
      #pragma unroll
      for (int i = 0; i < 4; i++) a[i] = As[ty*4+i][kk];
      #pragma unroll
      for (int j = 0; j < 4; j++) bb[j] = Bs[kk][tx*4+j];
      #pragma unroll
      for (int i = 0; i < 4; i++)
        #pragma unroll
        for (int j = 0; j < 4; j++) acc[i][j] += a[i]*bb[j];
    }
    __syncthreads();
  }
  #pragma unroll
  for (int i = 0; i < 4; i++){
    int r = row0 + ty*4 + i;
    #pragma unroll
    for (int j = 0; j < 4; j++){
      int col = col0 + tx*4 + j;
      if (col < N) C[(size_t)r*N + col] = acc[i][j];
    }
  }
}

// ---------------- conv1d + silu + split ----------------
__global__ __launch_bounds__(256) void conv_kernel(const bf16* __restrict__ xbc,
    const float* __restrict__ cw, const float* __restrict__ cb,
    bf16* __restrict__ x, bf16* __restrict__ Bm, bf16* __restrict__ Cm){
  int bt = blockIdx.x / 9;
  int ch = (blockIdx.x % 9)*256 + threadIdx.x;
  int t = bt & (SEQ-1);
  float acc = cb[ch];
  #pragma unroll
  for (int i = 0; i < 4; i++){
    int tt = t - 3 + i;
    if (tt >= 0)
      acc = fmaf(b2f(xbc[(size_t)(bt - t + tt)*CONVDIM + ch]), cw[ch*4+i], acc);
  }
  float v = acc * sigmoidf_(acc);
  if (ch < INTER)              x[(size_t)bt*INTER + ch] = f2b(v);
  else if (ch < INTER+DSTATE)  Bm[(size_t)bt*DSTATE + (ch-INTER)] = f2b(v);
  else                         Cm[(size_t)bt*DSTATE + (ch-INTER-DSTATE)] = f2b(v);
}

// ---------------- dt = softplus(dt_raw + bias) ----------------
__global__ __launch_bounds__(256) void dt_kernel(const float* __restrict__ dtraw,
    const float* __restrict__ dt_bias, float* __restrict__ dt){
  int idx = blockIdx.x*256 + threadIdx.x;
  int h = idx & 31;
  float v = dtraw[idx] + dt_bias[h];
  dt[idx] = (v > 20.f) ? v : log1pf(expf(v));
}

// ---------------- per-chunk inclusive cumsum of dt*A ----------------
__global__ __launch_bounds__(256) void acum_kernel(const float* __restrict__ dt,
    const float* __restrict__ A_log, float* __restrict__ Acum){
  int bi = blockIdx.x;            // (b*NHEADS+h)*NCHUNK + c
  int c = bi & 15; int h = (bi >> 4) & 31; int b = bi >> 9;
  int l = threadIdx.x;
  __shared__ float sbuf[CHUNK];
  float A = -expf(A_log[h]);
  int t = c*CHUNK + l;
  sbuf[l] = dt[(size_t)(b*SEQ + t)*NHEADS + h] * A;
  __syncthreads();
  for (int off = 1; off < CHUNK; off <<= 1){
    float add = (l >= off) ? sbuf[l-off] : 0.f;
    __syncthreads();
    sbuf[l] += add;
    __syncthreads();
  }
  Acum[(size_t)bi*CHUNK + l] = sbuf[l];
}

// ---------------- build XW_T [b][p=2048][t=4096] = x*dt*exp(AcLast-Ac), BT [b][n=128][t=4096] ----------------
// grid (34, 64, 2): tiles 0..31 -> x p-tiles (h = tile), 32..33 -> B n-tiles
__global__ __launch_bounds__(256) void xwt_kernel(const bf16* __restrict__ x,
    const bf16* __restrict__ Bm, const float* __restrict__ dt,
    const float* __restrict__ Acum, bf16* __restrict__ xwt, bf16* __restrict__ bt){
  int pt = blockIdx.x, tt = blockIdx.y, b = blockIdx.z;
  int tid = threadIdx.x;
  __shared__ unsigned short tile[64][72];
  __shared__ float wf[64];
  int t0 = tt*64;
  if (pt < 32){
    int h = pt, c = t0 >> 8;
    if (tid < 64){
      const float* AcB = Acum + ((size_t)(b*NHEADS + h)*NCHUNK + c)*CHUNK;
      int t = t0 + tid;
      wf[tid] = dt[(size_t)(b*SEQ + t)*NHEADS + h] * expf(AcB[255] - AcB[t & 255]);
    }
    __syncthreads();
    const bf16* src = x + (size_t)(b*SEQ + t0)*INTER + pt*64;
    #pragma unroll
    for (int i = 0; i < 2; i++){
      int u = tid + i*256;
      int r = u >> 3, po = (u & 7)*8;
      bfx8 v = *(const bfx8*)(src + (size_t)r*INTER + po);
      float d = wf[r];
      #pragma unroll
      for (int j = 0; j < 8; j++)
        tile[r][po + j] = f2bits(bits2f((unsigned short)v[j]) * d);
    }
    __syncthreads();
    bf16* dst = xwt + ((size_t)(b*INTER) + pt*64)*SEQ + t0;
    #pragma unroll
    for (int i = 0; i < 2; i++){
      int u = tid + i*256;
      int p = u >> 3, tc = (u & 7)*8;
      bfx8 v;
      #pragma unroll
      for (int j = 0; j < 8; j++) v[j] = (short)tile[tc + j][p];
      *(bfx8*)(dst + (size_t)p*SEQ + tc) = v;
    }
  } else {
    int n0 = (pt - 32)*64;
    const bf16* src = Bm + (size_t)(b*SEQ + t0)*DSTATE + n0;
    #pragma unroll
    for (int i = 0; i < 2; i++){
      int u = tid + i*256;
      int r = u >> 3, po = (u & 7)*8;
      bfx8 v = *(const bfx8*)(src + (size_t)r*DSTATE + po);
      *(bfx8*)&tile[r][po] = v;
    }
    __syncthreads();
    bf16* dst = bt + ((size_t)(b*DSTATE) + n0)*SEQ + t0;
    #pragma unroll
    for (int i = 0; i < 2; i++){
      int u = tid + i*256;
      int p = u >> 3, tc = (u & 7)*8;
      bfx8 v;
      #pragma unroll
      for (int j = 0; j < 8; j++) v[j] = (short)tile[tc + j][p];
      *(bfx8*)(dst + (size_t)p*SEQ + tc) = v;
    }
  }
}

// ---------------- MFMA chunk-states: states[b,c,h][p][n] = sum_l XW_T[p,l]*BT[n,l] ----------------
// block = (b,c,h), 4 waves 2x2, wave tile 32x64, K=256, operands direct from global
__global__ __launch_bounds__(256) void chunk_states_mfma(const bf16* __restrict__ xwt,
    const bf16* __restrict__ bt, float* __restrict__ states){
  int bi = blockIdx.x;            // (b*NCHUNK+c)*NHEADS + h
  int h = bi & 31; int c = (bi >> 5) & 15; int b = bi >> 9;
  int tid = threadIdx.x, lane = tid & 63, w = tid >> 6;
  int wm = w >> 1, wn = w & 1;
  const bf16* Arow = xwt + ((size_t)(b*INTER) + h*64)*SEQ + c*CHUNK;
  const bf16* Brow = bt + (size_t)(b*DSTATE)*SEQ + c*CHUNK;
  f32x4 acc[2][4] = {};
  #pragma unroll
  for (int kk = 0; kk < 8; kk++){
    bfx8 af[2], bfr[4];
    #pragma unroll
    for (int m = 0; m < 2; m++)
      af[m] = *(const bfx8*)(Arow + (size_t)(wm*32 + m*16 + (lane&15))*SEQ + kk*32 + (lane>>4)*8);
    #pragma unroll
    for (int n = 0; n < 4; n++)
      bfr[n] = *(const bfx8*)(Brow + (size_t)(wn*64 + n*16 + (lane&15))*SEQ + kk*32 + (lane>>4)*8);
    #pragma unroll
    for (int m = 0; m < 2; m++)
      #pragma unroll
      for (int n = 0; n < 4; n++)
        acc[m][n] = MFMA16(af[m], bfr[n], acc[m][n]);
  }
  float* dst = states + (size_t)bi*HDIM*DSTATE;
  #pragma unroll
  for (int m = 0; m < 2; m++)
    #pragma unroll
    for (int n = 0; n < 4; n++)
      #pragma unroll
      for (int r = 0; r < 4; r++){
        int p = wm*32 + m*16 + (lane>>4)*4 + r;
        int nn = wn*64 + n*16 + (lane&15);
        dst[(size_t)p*DSTATE + nn] = acc[m][n][r];
      }
}

// ---------------- inter-chunk scan (in-place) ----------------
__global__ __launch_bounds__(256) void scan_kernel(float* __restrict__ states,
    const float* __restrict__ Acum){
  int idx = blockIdx.x*256 + threadIdx.x;
  int n = idx & 127; int p = (idx >> 7) & 63; int h = (idx >> 13) & 31; int b = idx >> 18;
  float R = 0.f;
  for (int c = 0; c < NCHUNK; c++){
    size_t o = (((size_t)((b*NCHUNK + c)*NHEADS + h))*HDIM + p)*DSTATE + n;
    float s = states[o];
    states[o] = R;
    float dA = expf(Acum[((size_t)(b*NHEADS + h)*NCHUNK + c)*CHUNK + CHUNK-1]);
    R = R*dA + s;
  }
}

// ================= fused MFMA Y kernel =================
__global__ __launch_bounds__(256) void ydiag_mfma(
    const bf16* x, const float* __restrict__ dt,
    const float* __restrict__ Acum, const bf16* __restrict__ Bm,
    const bf16* __restrict__ Cm, const float* __restrict__ states,
    const float* __restrict__ Dp, bf16* y){
  int bi = blockIdx.x;            // (b*NCHUNK+c)*NHEADS + h
  int h = bi & 31; int c = (bi >> 5) & 15; int b = bi >> 9;
  int tid = threadIdx.x, lane = tid & 63, w = tid >> 6;

  __shared__ unsigned short XdtT[64*264];
  __shared__ unsigned short pool[256*72];
  __shared__ float Acs[CHUNK];
  __shared__ float dts[CHUNK];

  const float* AcBase = Acum + ((size_t)(b*NHEADS + h)*NCHUNK + c)*CHUNK;
  Acs[tid] = AcBase[tid];
  dts[tid] = dt[(size_t)(b*SEQ + c*CHUNK + tid)*NHEADS + h];
  {
    const float* src = states + (size_t)bi*HDIM*DSTATE;
    #pragma unroll
    for (int i = 0; i < 32; i++){
      int idx = tid + i*256;
      int p = idx >> 7, n = idx & 127;
      pool[p*136 + n] = f2bits(src[idx]);
    }
  }
  __syncthreads();

  const bf16* Crow = Cm + (size_t)(b*SEQ + c*CHUNK)*DSTATE;
  const bf16* Brow = Bm + (size_t)(b*SEQ + c*CHUNK)*DSTATE;

  f32x4 accY[4][4] = {};
  #pragma unroll
  for (int kk = 0; kk < 4; kk++){
    bfx8 af[4], bfr[4];
    #pragma unroll
    for (int m = 0; m < 4; m++)
      af[m] = *(const bfx8*)(Crow + (size_t)(w*64 + m*16 + (lane&15))*DSTATE + kk*32 + (lane>>4)*8);
    #pragma unroll
    for (int n = 0; n < 4; n++)
      bfr[n] = *(const bfx8*)(pool + (n*16 + (lane&15))*136 + kk*32 + (lane>>4)*8);
    #pragma unroll
    for (int m = 0; m < 4; m++)
      #pragma unroll
      for (int n = 0; n < 4; n++)
        accY[m][n] = MFMA16(af[m], bfr[n], accY[m][n]);
  }
  {
    float eAl[4][4];
    #pragma unroll
    for (int m = 0; m < 4; m++)
      #pragma unroll
      for (int r = 0; r < 4; r++)
        eAl[m][r] = expf(Acs[w*64 + m*16 + (lane>>4)*4 + r]);
    #pragma unroll
    for (int m = 0; m < 4; m++)
      #pragma unroll
      for (int n = 0; n < 4; n++)
        #pragma unroll
        for (int r = 0; r < 4; r++)
          accY[m][n][r] *= eAl[m][r];
  }
  __syncthreads();

  {
    const bf16* xg = x + (size_t)(b*SEQ + c*CHUNK)*INTER + h*HDIM;
    #pragma unroll
    for (int i = 0; i < 8; i++){
      int u = tid + i*256;
      int s = u >> 3, p0 = (u & 7)*8;
      bfx8 v = *(const bfx8*)(xg + (size_t)s*INTER + p0);
      float d = dts[s];
      bfx8 o;
      #pragma unroll
      for (int j = 0; j < 8; j++)
        o[j] = (short)f2bits(bits2f((unsigned short)v[j]) * d);
      *(bfx8*)(pool + s*72 + p0) = o;
    }
  }
  __syncthreads();
  {
    int p = tid & 63, sb = tid >> 6;
    #pragma unroll
    for (int i = 0; i < 8; i++){
      int s0 = (sb + i*4)*8;
      bfx8 v;
      #pragma unroll
      for (int j = 0; j < 8; j++)
        v[j] = (short)pool[(s0 + j)*72 + p];
      *(bfx8*)(XdtT + p*264 + s0) = v;
    }
  }
  __syncthreads();

  char* Wl = (char*)pool + w*8192;
  float Dh = Dp[h];

  for (int j = 0; j <= w; j++){
    int s0 = j*64;
    f32x4 accS[4][4] = {};
    #pragma unroll
    for (int kk = 0; kk < 4; kk++){
      bfx8 af[4], bfr[4];
      #pragma unroll
      for (int m = 0; m < 4; m++)
        af[m] = *(const bfx8*)(Crow + (size_t)(w*64 + m*16 + (lane&15))*DSTATE + kk*32 + (lane>>4)*8);
      #pragma unroll
      for (int n = 0; n < 4; n++)
        bfr[n] = *(const bfx8*)(Brow + (size_t)(s0 + n*16 + (lane&15))*DSTATE + kk*32 + (lane>>4)*8);
      #pragma unroll
      for (int m = 0; m < 4; m++)
        #pragma unroll
        for (int n = 0; n < 4; n++)
          accS[m][n] = MFMA16(af[m], bfr[n], accS[m][n]);
    }
    if (j < w){
      float m_ = Acs[s0 + 63];
      float colf[4], rowf[4][4];
      #pragma unroll
      for (int n = 0; n < 4; n++) colf[n] = expf(m_ - Acs[s0 + n*16 + (lane&15)]);
      #pragma unroll
      for (int m = 0; m < 4; m++)
        #pragma unroll
        for (int r = 0; r < 4; r++)
          rowf[m][r] = expf(Acs[w*64 + m*16 + (lane>>4)*4 + r] - m_);
      #pragma unroll
      for (int m = 0; m < 4; m++)
        #pragma unroll
        for (int n = 0; n < 4; n++)
          #pragma unroll
          for (int r = 0; r < 4; r++){
            int ll = m*16 + (lane>>4)*4 + r;
            int sl = n*16 + (lane&15);
            *(unsigned short*)(Wl + ll*128 + ((sl*2) ^ ((ll&7)<<4)))
              = f2bits(accS[m][n][r] * rowf[m][r] * colf[n]);
          }
    } else {
      #pragma unroll
      for (int m = 0; m < 4; m++)
        #pragma unroll
        for (int n = 0; n < 4; n++)
          #pragma unroll
          for (int r = 0; r < 4; r++){
            int ll = m*16 + (lane>>4)*4 + r;
            int sl = n*16 + (lane&15);
            int lg = w*64 + ll, sg = s0 + sl;
            float wv;
            if (sg > lg)       wv = 0.f;
            else if (sg == lg) wv = accS[m][n][r] + Dh/dts[lg];
            else               wv = accS[m][n][r]*expf(Acs[lg] - Acs[sg]);
            *(unsigned short*)(Wl + ll*128 + ((sl*2) ^ ((ll&7)<<4))) = f2bits(wv);
          }
    }
    asm volatile("s_waitcnt lgkmcnt(0)" ::: "memory");
    __builtin_amdgcn_sched_barrier(0);
    #pragma unroll
    for (int kk = 0; kk < 2; kk++){
      bfx8 af[4], bfr[4];
      #pragma unroll
      for (int m = 0; m < 4; m++){
        int ll = m*16 + (lane&15);
        af[m] = *(const bfx8*)(Wl + ll*128 + (((kk*32 + (lane>>4)*8)*2) ^ ((ll&7)<<4)));
      }
      #pragma unroll
      for (int n = 0; n < 4; n++)
        bfr[n] = *(const bfx8*)(XdtT + (n*16 + (lane&15))*264 + s0 + kk*32 + (lane>>4)*8);
      #pragma unroll
      for (int m = 0; m < 4; m++)
        #pragma unroll
        for (int n = 0; n < 4; n++)
          accY[m][n] = MFMA16(af[m], bfr[n], accY[m][n]);
    }
  }
  bf16* yg = y + (size_t)(b*SEQ + c*CHUNK)*INTER + h*HDIM;
  #pragma unroll
  for (int m = 0; m < 4; m++)
    #pragma unroll
    for (int n = 0; n < 4; n++)
      #pragma unroll
      for (int r = 0; r < 4; r++)
        yg[(size_t)(w*64 + m*16 + (lane>>4)*4 + r)*INTER + n*16 + (lane&15)]
          = f2b(accY[m][n][r]);
}

// ---------------- gate (y * silu(z)) + RMSNorm * norm_w, in place (bf16) ----------------
__global__ __launch_bounds__(256) void gatenorm_kernel(bf16* __restrict__ y,
    const bf16* __restrict__ z, const float* __restrict__ nw){
  int row = blockIdx.x;
  const bf16* zr = z + (size_t)row*INTER;
  bf16* yr = y + (size_t)row*INTER;
  int tid = threadIdx.x;
  float g[8]; float ss = 0.f;
  #pragma unroll
  for (int i = 0; i < 8; i++){
    int idx = tid + i*256;
    float zv = b2f(zr[idx]);
    float gv = b2f(yr[idx]) * zv * sigmoidf_(zv);
    g[i] = gv; ss += gv*gv;
  }
  #pragma unroll
  for (int off = 32; off > 0; off >>= 1) ss += __shfl_down(ss, off);
  __shared__ float red[4];
  __shared__ float stot;
  int lane = tid & 63, wid = tid >> 6;
  if (lane == 0) red[wid] = ss;
  __syncthreads();
  if (tid == 0) stot = rsqrtf((red[0]+red[1]+red[2]+red[3]) * (1.f/INTER) + 1e-5f);
  __syncthreads();
  float sc = stot;
  #pragma unroll
  for (int i = 0; i < 8; i++){
    int idx = tid + i*256;
    yr[idx] = f2b(g[i]*sc*nw[idx]);
  }
}

extern "C" void kernel_launch(void* const* d_in, const int* in_sizes, int n_in,
                              void* d_out, int out_size, void* d_ws, size_t ws_size,
                              hipStream_t stream){
  const float* u    = (const float*)d_in[0];
  const float* w_in = (const float*)d_in[1];
  const float* cw   = (const float*)d_in[2];
  const float* cb   = (const float*)d_in[3];
  const float* dtb  = (const float*)d_in[4];
  const float* Alog = (const float*)d_in[5];
  const float* Dp   = (const float*)d_in[6];
  const float* nw   = (const float*)d_in[7];
  const float* w_out= (const float*)d_in[8];
  float* out = (float*)d_out;
  char* ws = (char*)d_ws;

  // layout (bytes)
  const size_t OFF_Z     = 0;              // bf16 [8192][2048]
  const size_t OFF_XBC   = 33554432;       // bf16 [8192][2304]; states f32 aliases after conv
  const size_t OFF_DT    = 67108864;       // f32 [8192][32] (xbc tail, written after conv)
  const size_t OFF_ACUM  = 68157440;       // f32 [2*32*16*256] (xbc tail)
  const size_t OFF_X     = 71303168;       // bf16 [8192][2048]; y aliases
  const size_t OFF_UBF   = 104857600;      // bf16 u [8192][1024] (dead after inproj); XW_T aliases
  const size_t OFF_WINT  = 121634816;      // bf16 w_inT (dead after inproj)
  const size_t OFF_XWT   = 104857600;      // bf16 [2][2048][4096] = 33,554,432
  const size_t OFF_BM    = 138412032;      // bf16 [8192][128]
  const size_t OFF_CM    = 140509184;      // bf16 [8192][128]
  const size_t OFF_DTRAW = 142606336;      // f32 [8192][32]
  const size_t OFF_BT    = 143654912;      // bf16 [2][128][4096] = 2,097,152
  const size_t OFF_WOUTT = 145752064;      // bf16 [1024][2048]
  const size_t NEED      = 149946368;      // <= 158,334,976 proven in R2

  if (ws_size < NEED){
    zero_out_kernel<<<(out_size + 255)/256, 256, 0, stream>>>(out, out_size);
    return;
  }

  bf16*  z      = (bf16*)(ws + OFF_Z);
  bf16*  xbc    = (bf16*)(ws + OFF_XBC);
  float* states = (float*)(ws + OFF_XBC);
  float* dt     = (float*)(ws + OFF_DT);
  float* Acum   = (float*)(ws + OFF_ACUM);
  bf16*  x      = (bf16*)(ws + OFF_X);
  bf16*  y      = (bf16*)(ws + OFF_X);
  bf16*  u_bf   = (bf16*)(ws + OFF_UBF);
  bf16*  w_inT  = (bf16*)(ws + OFF_WINT);
  bf16*  xwt    = (bf16*)(ws + OFF_XWT);
  bf16*  Bm     = (bf16*)(ws + OFF_BM);
  bf16*  Cm     = (bf16*)(ws + OFF_CM);
  float* dtraw  = (float*)(ws + OFF_DTRAW);
  bf16*  bt     = (bf16*)(ws + OFF_BT);
  bf16*  w_outT = (bf16*)(ws + OFF_WOUTT);

  // 0) prep
  castu_kernel<<<(ROWS*DMODEL/4)/256, 256, 0, stream>>>(u, (unsigned short*)u_bf);
  transcast_kernel<<<dim3(NGEMM/64, DMODEL/64), 256, 0, stream>>>(w_in, w_inT, DMODEL, PROJDIM, 0);
  // 1) projections
  gemm_mfma_inproj<<<dim3(NGEMM/128, ROWS/128), 256, 0, stream>>>(u_bf, w_inT, z, xbc);
  gemm_f32_dt<<<dim3(1, ROWS/64), 256, 0, stream>>>(u, w_in + NGEMM, dtraw, NHEADS, DMODEL, PROJDIM);
  // 2) conv + silu + split
  conv_kernel<<<ROWS*9, 256, 0, stream>>>(xbc, cw, cb, x, Bm, Cm);
  // 3) dt softplus
  dt_kernel<<<ROWS*NHEADS/256, 256, 0, stream>>>(dtraw, dtb, dt);
  // 4) per-chunk cumsum of dt*A
  acum_kernel<<<B_SZ*NHEADS*NCHUNK, 256, 0, stream>>>(dt, Alog, Acum);
  // 4.5) weighted transpose XW_T + BT (overwrites u_bf/w_inT)
  xwt_kernel<<<dim3(34, 64, 2), 256, 0, stream>>>(x, Bm, dt, Acum, xwt, bt);
  // 5) MFMA chunk-states
  chunk_states_mfma<<<B_SZ*NCHUNK*NHEADS, 256, 0, stream>>>(xwt, bt, states);
  // 6) inter-chunk scan
  scan_kernel<<<(B_SZ*NHEADS*HDIM*DSTATE)/256, 256, 0, stream>>>(states, Acum);
  // 7) fused MFMA Y (y aliases x)
  ydiag_mfma<<<B_SZ*NCHUNK*NHEADS, 256, 0, stream>>>(x, dt, Acum, Bm, Cm, states, Dp, y);
  // 7.5) prep out_proj weight
  transcast_kernel<<<dim3(DMODEL/64, INTER/64), 256, 0, stream>>>(w_out, w_outT, INTER, DMODEL, 0);
  // 8) gate + RMSNorm
  gatenorm_kernel<<<ROWS, 256, 0, stream>>>(y, z, nw);
  // 9) out_proj
  gemm_mfma_outproj<<<dim3(DMODEL/128, ROWS/128), 256, 0, stream>>>(y, w_outT, out);
}

// Round 6
// 546.973 us; speedup vs baseline: 5.6439x; 1.0361x over previous
//
#include <hip/hip_runtime.h>
#include <hip/hip_bf16.h>

#define B_SZ 2
#define SEQ 4096
#define DMODEL 1024
#define INTER 2048
#define NHEADS 32
#define HDIM 64
#define DSTATE 128
#define DCONV 4
#define CONVDIM 2304
#define PROJDIM 4384
#define CHUNK 256
#define NCHUNK 16
#define ROWS (B_SZ*SEQ)   // 8192
#define NGEMM 4352        // z + xBC columns (17 tiles of 256)

typedef __hip_bfloat16 bf16;
typedef short bfx8 __attribute__((ext_vector_type(8)));
typedef float f32x4 __attribute__((ext_vector_type(4)));

__device__ __forceinline__ float sigmoidf_(float x){ return 1.f/(1.f+expf(-x)); }
__device__ __forceinline__ float b2f(bf16 v){ return __bfloat162float(v); }
__device__ __forceinline__ bf16 f2b(float v){ return __float2bfloat16(v); }
__device__ __forceinline__ float bits2f(unsigned short u){ return __uint_as_float(((unsigned)u) << 16); }
__device__ __forceinline__ unsigned short f2bits(float v){ bf16 t = __float2bfloat16(v); return *(unsigned short*)&t; }

#define MFMA16(a,b,c) __builtin_amdgcn_mfma_f32_16x16x32_bf16(a,b,c,0,0,0)

// ---------------- fallback: zero d_out ----------------
__global__ void zero_out_kernel(float* o, int n){
  int i = blockIdx.x*256 + threadIdx.x;
  if (i < n) o[i] = 0.f;
}

// ---------------- cast u (f32) -> bf16 ----------------
__global__ __launch_bounds__(256) void castu_kernel(const float* __restrict__ in,
    unsigned short* __restrict__ o){
  int i = blockIdx.x*256 + threadIdx.x;
  float4 v = ((const float4*)in)[i];
  ushort4 w;
  w.x = f2bits(v.x); w.y = f2bits(v.y); w.z = f2bits(v.z); w.w = f2bits(v.w);
  ((ushort4*)o)[i] = w;
}

// ---------------- cast + transpose ----------------
__global__ __launch_bounds__(256) void transcast_kernel(const float* __restrict__ in,
    bf16* __restrict__ outT, int R, int ld, int coff){
  __shared__ float t[64][65];
  int r0 = blockIdx.y*64, c0 = blockIdx.x*64;
  int tid = threadIdx.x;
  #pragma unroll
  for (int i = 0; i < 16; i++){
    int idx = tid + i*256;
    int r = idx >> 6, c = idx & 63;
    t[r][c] = in[(size_t)(r0+r)*ld + coff + c0 + c];
  }
  __syncthreads();
  #pragma unroll
  for (int i = 0; i < 16; i++){
    int idx = tid + i*256;
    int c = idx >> 6, r = idx & 63;
    outT[(size_t)(c0+c)*R + r0 + r] = f2b(t[r][c]);
  }
}

// ================= 8-phase 256x256 MFMA GEMM (m201 template, T2+T3+T4+T5) =================
// 512 thr / 8 waves (2x4). BK=64, 2 K-tiles/iter. LDS 128KB dynamic:
// buf0.A@0, buf0.B@32768, buf1.A@65536, buf1.B@98304 (bytes), each [256][64] bf16.
// Swizzle (T2, both sides): byte o within region -> o ^ ((row&7)<<4), row = o>>7.
__device__ __forceinline__ void stage8(const bf16* __restrict__ g, int Kdim,
    int tile0, int k0, char* region, int h, int tid){
  #pragma unroll
  for (int l = 0; l < 2; l++){
    int o  = h*16384 + (l*512 + tid)*16;          // linear dest byte (this thread's chunk)
    int os = o ^ (((o >> 7) & 7) << 4);            // pre-swizzled source position
    const bf16* src = g + (size_t)(tile0 + (os >> 7))*Kdim + k0 + ((os & 127) >> 1);
    __builtin_amdgcn_global_load_lds(
      (const __attribute__((address_space(1))) void*)src,
      (__attribute__((address_space(3))) void*)(region + h*16384 + (l*512 + (tid >> 6)*64)*16),
      16, 0, 0);
  }
}
__device__ __forceinline__ bfx8 fr8(const char* region, int row, int colbyte){
  int o = row*128 + colbyte;
  o ^= ((row & 7) << 4);
  return *(const bfx8*)(region + o);
}

#define LGKM0  asm volatile("s_waitcnt lgkmcnt(0)" ::: "memory"); __builtin_amdgcn_sched_barrier(0)
#define VM4    asm volatile("s_waitcnt vmcnt(4)" ::: "memory")
#define BAR    __builtin_amdgcn_s_barrier()
#define PRIO1  __builtin_amdgcn_s_setprio(1)
#define PRIO0  __builtin_amdgcn_s_setprio(0)

#define MFMA_QUAD(MH, NH, BARR)                                                \
  PRIO1;                                                                       \
  _Pragma("unroll") for (int m = 0; m < 4; m++)                                \
    _Pragma("unroll") for (int n = 0; n < 2; n++)                              \
      _Pragma("unroll") for (int kk = 0; kk < 2; kk++)                         \
        acc[(MH)+m][(NH)+n] = MFMA16(aF[m][kk], BARR[n][kk], acc[(MH)+m][(NH)+n]); \
  PRIO0

#define GEMM8_BODY(K_, NBX_, EPILOGUE)                                         \
  extern __shared__ char lds[];                                                \
  char* A0 = lds;          char* B0 = lds + 32768;                             \
  char* A1 = lds + 65536;  char* B1 = lds + 98304;                             \
  const int tid = threadIdx.x, lane = tid & 63, wid = tid >> 6;                \
  const int wm = wid >> 2, wn = wid & 3;                                       \
  int nb = (blockIdx.x & 7)*((int)gridDim.x >> 3) + (blockIdx.x >> 3);         \
  const int bx = nb % (NBX_), by = nb / (NBX_);                                \
  const int row0 = by*256, col0 = bx*256;                                      \
  f32x4 acc[8][4] = {};                                                        \
  bfx8 aF[4][2], b01[2][2], b23[2][2];                                         \
  const int frow = lane & 15;                                                  \
  const int fcb0 = (lane >> 4)*16;                                             \
  /* prologue: T0.Bh0,Bh1, T0.Ah0,Ah1 (k=0); T1.Bh0,Bh1 (k=64) */              \
  stage8(Bt, K_, col0, 0,  B0, 0, tid);                                        \
  stage8(Bt, K_, col0, 0,  B0, 1, tid);                                        \
  stage8(A,  K_, row0, 0,  A0, 0, tid);                                        \
  stage8(A,  K_, row0, 0,  A0, 1, tid);                                        \
  stage8(Bt, K_, col0, 64, B1, 0, tid);                                        \
  stage8(Bt, K_, col0, 64, B1, 1, tid);                                        \
  VM4;                                                                         \
  BAR;                                                                         \
  _Pragma("unroll 1")                                                          \
  for (int j = 0; j < (K_)/128; j++){                                          \
    const int kO  = j*128 + 64;                                                \
    const int kS1 = (j*128 + 128) & ((K_) - 1);                                \
    const int kS2 = (j*128 + 192) & ((K_) - 1);                                \
    /* ph1: stage buf1.Ah0<-T(2j+1); read buf0 A m0-3 + B n0-1; Q(0,0) */      \
    stage8(A, K_, row0, kO, A1, 0, tid);                                       \
    _Pragma("unroll") for (int m = 0; m < 4; m++)                              \
      _Pragma("unroll") for (int kk = 0; kk < 2; kk++)                         \
        aF[m][kk] = fr8(A0, wm*128 + m*16 + frow, kk*64 + fcb0);               \
    _Pragma("unroll") for (int n = 0; n < 2; n++)                              \
      _Pragma("unroll") for (int kk = 0; kk < 2; kk++)                         \
        b01[n][kk] = fr8(B0, wn*64 + n*16 + frow, kk*64 + fcb0);               \
    LGKM0;                                                                     \
    MFMA_QUAD(0, 0, b01);                                                      \
    BAR;                                                                       \
    /* ph2: stage buf1.Ah1; read buf0 B n2-3; Q(0,2) */                        \
    stage8(A, K_, row0, kO, A1, 1, tid);                                       \
    _Pragma("unroll") for (int n = 0; n < 2; n++)                              \
      _Pragma("unroll") for (int kk = 0; kk < 2; kk++)                         \
        b23[n][kk] = fr8(B0, wn*64 + (n+2)*16 + frow, kk*64 + fcb0);           \
    LGKM0;                                                                     \
    MFMA_QUAD(0, 2, b23);                                                      \
    BAR;                                                                       \
    /* ph3: stage buf0.Bh0<-T(2j+2); read buf0 A m4-7; Q(4,0) */               \
    stage8(Bt, K_, col0, kS1, B0, 0, tid);                                     \
    _Pragma("unroll") for (int m = 0; m < 4; m++)                              \
      _Pragma("unroll") for (int kk = 0; kk < 2; kk++)                         \
        aF[m][kk] = fr8(A0, wm*128 + (m+4)*16 + frow, kk*64 + fcb0);           \
    LGKM0;                                                                     \
    MFMA_QUAD(4, 0, b01);                                                      \
    BAR;                                                                       \
    /* ph4: stage buf0.Bh1; vmcnt(4) [T(2j+1) landed]; Q(4,2) */               \
    stage8(Bt, K_, col0, kS1, B0, 1, tid);                                     \
    VM4;                                                                       \
    MFMA_QUAD(4, 2, b23);                                                      \
    BAR;                                                                       \
    /* ph5: stage buf0.Ah0<-T(2j+2); read buf1 A m0-3 + B n0-1; Q'(0,0) */     \
    stage8(A, K_, row0, kS1, A0, 0, tid);                                      \
    _Pragma("unroll") for (int m = 0; m < 4; m++)                              \
      _Pragma("unroll") for (int kk = 0; kk < 2; kk++)                         \
        aF[m][kk] = fr8(A1, wm*128 + m*16 + frow, kk*64 + fcb0);               \
    _Pragma("unroll") for (int n = 0; n < 2; n++)                              \
      _Pragma("unroll") for (int kk = 0; kk < 2; kk++)                         \
        b01[n][kk] = fr8(B1, wn*64 + n*16 + frow, kk*64 + fcb0);               \
    LGKM0;                                                                     \
    MFMA_QUAD(0, 0, b01);                                                      \
    BAR;                                                                       \
    /* ph6: stage buf0.Ah1; read buf1 B n2-3; Q'(0,2) */                       \
    stage8(A, K_, row0, kS1, A0, 1, tid);                                      \
    _Pragma("unroll") for (int n = 0; n < 2; n++)                              \
      _Pragma("unroll") for (int kk = 0; kk < 2; kk++)                         \
        b23[n][kk] = fr8(B1, wn*64 + (n+2)*16 + frow, kk*64 + fcb0);           \
    LGKM0;                                                                     \
    MFMA_QUAD(0, 2, b23);                                                      \
    BAR;                                                                       \
    /* ph7: stage buf1.Bh0<-T(2j+3); read buf1 A m4-7; Q'(4,0) */              \
    stage8(Bt, K_, col0, kS2, B1, 0, tid);                                     \
    _Pragma("unroll") for (int m = 0; m < 4; m++)                              \
      _Pragma("unroll") for (int kk = 0; kk < 2; kk++)                         \
        aF[m][kk] = fr8(A1, wm*128 + (m+4)*16 + frow, kk*64 + fcb0);           \
    LGKM0;                                                                     \
    MFMA_QUAD(4, 0, b01);                                                      \
    BAR;                                                                       \
    /* ph8: stage buf1.Bh1; vmcnt(4) [T(2j+2) landed]; Q'(4,2) */              \
    stage8(Bt, K_, col0, kS2, B1, 1, tid);                                     \
    VM4;                                                                       \
    MFMA_QUAD(4, 2, b23);                                                      \
    BAR;                                                                       \
  }                                                                            \
  _Pragma("unroll") for (int m = 0; m < 8; m++){                               \
    int row = row0 + wm*128 + m*16 + (lane >> 4)*4;                            \
    _Pragma("unroll") for (int n = 0; n < 4; n++){                             \
      int col = col0 + wn*64 + n*16 + (lane & 15);                             \
      _Pragma("unroll") for (int r = 0; r < 4; r++){                           \
        float v = acc[m][n][r];                                                \
        int rr = row + r;                                                      \
        EPILOGUE                                                               \
      }                                                                        \
    }                                                                          \
  }

__global__ __launch_bounds__(512, 2) void gemm8_inproj(const bf16* __restrict__ A,
    const bf16* __restrict__ Bt, bf16* __restrict__ z, bf16* __restrict__ xbc){
  GEMM8_BODY(DMODEL, 17,
    if (col < INTER) z[(size_t)rr*INTER + col] = f2b(v);
    else             xbc[(size_t)rr*CONVDIM + (col - INTER)] = f2b(v);
  )
}
__global__ __launch_bounds__(512, 2) void gemm8_outproj(const bf16* __restrict__ A,
    const bf16* __restrict__ Bt, float* __restrict__ C){
  GEMM8_BODY(INTER, 4,
    C[(size_t)rr*DMODEL + col] = v;
  )
}

// ================= fallback m97-structure GEMMs (used if 128KB LDS opt-in fails) =================
#define MFMA_GEMM_BODY(K_, EPILOGUE)                                           \
  __shared__ unsigned short As[128*64];                                        \
  __shared__ unsigned short Bs[128*64];                                        \
  const int tid = threadIdx.x;                                                 \
  const int lane = tid & 63, wid = tid >> 6;                                   \
  const int wm = wid >> 1, wn = wid & 1;                                       \
  const int row0 = blockIdx.y*128, col0 = blockIdx.x*128;                      \
  f32x4 acc[4][4] = {};                                                        \
  const int rstg = wid*32 + ((lane>>3)&7);                                     \
  const int kstg = (lane&7)*8;                                                 \
  for (int k0 = 0; k0 < (K_); k0 += 64){                                       \
    _Pragma("unroll")                                                          \
    for (int j = 0; j < 4; j++){                                               \
      const bf16* gA = A + (size_t)(row0 + rstg + j*8)*(K_) + k0 + kstg;       \
      __builtin_amdgcn_global_load_lds(                                        \
        (const __attribute__((address_space(1))) void*)gA,                     \
        (__attribute__((address_space(3))) void*)(As + (wid*32 + j*8)*64),     \
        16, 0, 0);                                                             \
      const bf16* gB = Bt + (size_t)(col0 + rstg + j*8)*(K_) + k0 + kstg;      \
      __builtin_amdgcn_global_load_lds(                                        \
        (const __attribute__((address_space(1))) void*)gB,                     \
        (__attribute__((address_space(3))) void*)(Bs + (wid*32 + j*8)*64),     \
        16, 0, 0);                                                             \
    }                                                                          \
    __syncthreads();                                                           \
    _Pragma("unroll")                                                          \
    for (int kk = 0; kk < 2; kk++){                                            \
      bfx8 af[4], bfr[4];                                                      \
      _Pragma("unroll")                                                        \
      for (int m = 0; m < 4; m++)                                              \
        af[m] = *(const bfx8*)(As + (wm*64 + m*16 + (lane&15))*64              \
                               + kk*32 + (lane>>4)*8);                         \
      _Pragma("unroll")                                                        \
      for (int n = 0; n < 4; n++)                                              \
        bfr[n] = *(const bfx8*)(Bs + (wn*64 + n*16 + (lane&15))*64             \
                                + kk*32 + (lane>>4)*8);                        \
      _Pragma("unroll")                                                        \
      for (int m = 0; m < 4; m++)                                              \
        _Pragma("unroll")                                                      \
        for (int n = 0; n < 4; n++)                                            \
          acc[m][n] = MFMA16(af[m], bfr[n], acc[m][n]);                        \
    }                                                                          \
    __syncthreads();                                                           \
  }                                                                            \
  _Pragma("unroll")                                                            \
  for (int m = 0; m < 4; m++){                                                 \
    int row = row0 + wm*64 + m*16 + (lane>>4)*4;                               \
    _Pragma("unroll")                                                          \
    for (int n = 0; n < 4; n++){                                               \
      int col = col0 + wn*64 + n*16 + (lane&15);                               \
      _Pragma("unroll")                                                        \
      for (int r = 0; r < 4; r++){                                             \
        float v = acc[m][n][r];                                                \
        int rr = row + r;                                                      \
        EPILOGUE                                                               \
      }                                                                        \
    }                                                                          \
  }

__global__ __launch_bounds__(256) void gemm_mfma_inproj(const bf16* __restrict__ A,
    const bf16* __restrict__ Bt, bf16* __restrict__ z, bf16* __restrict__ xbc){
  MFMA_GEMM_BODY(DMODEL,
    if (col < INTER) z[(size_t)rr*INTER + col] = f2b(v);
    else             xbc[(size_t)rr*CONVDIM + (col - INTER)] = f2b(v);
  )
}
__global__ __launch_bounds__(256) void gemm_mfma_outproj(const bf16* __restrict__ A,
    const bf16* __restrict__ Bt, float* __restrict__ C){
  MFMA_GEMM_BODY(INTER,
    C[(size_t)rr*DMODEL + col] = v;
  )
}

// ---------------- small fp32 GEMM for dt columns ----------------
__global__ __launch_bounds__(256) void gemm_f32_dt(const float* __restrict__ A,
    const float* __restrict__ B, float* __restrict__ C, int N, int K, int ldb){
  __shared__ float As[64][17];
  __shared__ float Bs[16][65];
  int tid = threadIdx.x, tx = tid & 15, ty = tid >> 4;
  int row0 = blockIdx.y*64, col0 = blockIdx.x*64;
  float acc[4][4] = {};
  for (int k0 = 0; k0 < K; k0 += 16){
    #pragma unroll
    for (int i = 0; i < 4; i++){
      int idx = tid + i*256;
      As[idx >> 4][idx & 15] = A[(size_t)(row0 + (idx >> 4))*K + k0 + (idx & 15)];
    }
    #pragma unroll
    for (int i = 0; i < 4; i++){
      int idx = tid + i*256;
      int col = col0 + (idx & 63);
      Bs[idx >> 6][idx & 63] = (col < N) ? B[(size_t)(k0 + (idx >> 6))*ldb + col] : 0.f;
    }
    __syncthreads();
    #pragma unroll
    for (int kk = 0; kk < 16; kk++){
      float a[4], bb[4];
      #pragma unroll
      for (int i = 0; i < 4; i++) a[i] = As[ty*4+i][kk];
      #pragma unroll
      for (int j = 0; j < 4; j++) bb[j] = Bs[kk][tx*4+j];
      #pragma unroll
      for (int i = 0; i < 4; i++)
        #pragma unroll
        for (int j = 0; j < 4; j++) acc[i][j] += a[i]*bb[j];
    }
    __syncthreads();
  }
  #pragma unroll
  for (int i = 0; i < 4; i++){
    int r = row0 + ty*4 + i;
    #pragma unroll
    for (int j = 0; j < 4; j++){
      int col = col0 + tx*4 + j;
      if (col < N) C[(size_t)r*N + col] = acc[i][j];
    }
  }
}

// ---------------- conv1d + silu + split ----------------
__global__ __launch_bounds__(256) void conv_kernel(const bf16* __restrict__ xbc,
    const float* __restrict__ cw, const float* __restrict__ cb,
    bf16* __restrict__ x, bf16* __restrict__ Bm, bf16* __restrict__ Cm){
  int bt = blockIdx.x / 9;
  int ch = (blockIdx.x % 9)*256 + threadIdx.x;
  int t = bt & (SEQ-1);
  float acc = cb[ch];
  #pragma unroll
  for (int i = 0; i < 4; i++){
    int tt = t - 3 + i;
    if (tt >= 0)
      acc = fmaf(b2f(xbc[(size_t)(bt - t + tt)*CONVDIM + ch]), cw[ch*4+i], acc);
  }
  float v = acc * sigmoidf_(acc);
  if (ch < INTER)              x[(size_t)bt*INTER + ch] = f2b(v);
  else if (ch < INTER+DSTATE)  Bm[(size_t)bt*DSTATE + (ch-INTER)] = f2b(v);
  else                         Cm[(size_t)bt*DSTATE + (ch-INTER-DSTATE)] = f2b(v);
}

// ---------------- dt = softplus(dt_raw + bias) ----------------
__global__ __launch_bounds__(256) void dt_kernel(const float* __restrict__ dtraw,
    const float* __restrict__ dt_bias, float* __restrict__ dt){
  int idx = blockIdx.x*256 + threadIdx.x;
  int h = idx & 31;
  float v = dtraw[idx] + dt_bias[h];
  dt[idx] = (v > 20.f) ? v : log1pf(expf(v));
}

// ---------------- per-chunk inclusive cumsum of dt*A ----------------
__global__ __launch_bounds__(256) void acum_kernel(const float* __restrict__ dt,
    const float* __restrict__ A_log, float* __restrict__ Acum){
  int bi = blockIdx.x;            // (b*NHEADS+h)*NCHUNK + c
  int c = bi & 15; int h = (bi >> 4) & 31; int b = bi >> 9;
  int l = threadIdx.x;
  __shared__ float sbuf[CHUNK];
  float A = -expf(A_log[h]);
  int t = c*CHUNK + l;
  sbuf[l] = dt[(size_t)(b*SEQ + t)*NHEADS + h] * A;
  __syncthreads();
  for (int off = 1; off < CHUNK; off <<= 1){
    float add = (l >= off) ? sbuf[l-off] : 0.f;
    __syncthreads();
    sbuf[l] += add;
    __syncthreads();
  }
  Acum[(size_t)bi*CHUNK + l] = sbuf[l];
}

// ---------------- build XW_T + BT ----------------
__global__ __launch_bounds__(256) void xwt_kernel(const bf16* __restrict__ x,
    const bf16* __restrict__ Bm, const float* __restrict__ dt,
    const float* __restrict__ Acum, bf16* __restrict__ xwt, bf16* __restrict__ bt){
  int pt = blockIdx.x, tt = blockIdx.y, b = blockIdx.z;
  int tid = threadIdx.x;
  __shared__ unsigned short tile[64][72];
  __shared__ float wf[64];
  int t0 = tt*64;
  if (pt < 32){
    int h = pt, c = t0 >> 8;
    if (tid < 64){
      const float* AcB = Acum + ((size_t)(b*NHEADS + h)*NCHUNK + c)*CHUNK;
      int t = t0 + tid;
      wf[tid] = dt[(size_t)(b*SEQ + t)*NHEADS + h] * expf(AcB[255] - AcB[t & 255]);
    }
    __syncthreads();
    const bf16* src = x + (size_t)(b*SEQ + t0)*INTER + pt*64;
    #pragma unroll
    for (int i = 0; i < 2; i++){
      int u = tid + i*256;
      int r = u >> 3, po = (u & 7)*8;
      bfx8 v = *(const bfx8*)(src + (size_t)r*INTER + po);
      float d = wf[r];
      #pragma unroll
      for (int j = 0; j < 8; j++)
        tile[r][po + j] = f2bits(bits2f((unsigned short)v[j]) * d);
    }
    __syncthreads();
    bf16* dst = xwt + ((size_t)(b*INTER) + pt*64)*SEQ + t0;
    #pragma unroll
    for (int i = 0; i < 2; i++){
      int u = tid + i*256;
      int p = u >> 3, tc = (u & 7)*8;
      bfx8 v;
      #pragma unroll
      for (int j = 0; j < 8; j++) v[j] = (short)tile[tc + j][p];
      *(bfx8*)(dst + (size_t)p*SEQ + tc) = v;
    }
  } else {
    int n0 = (pt - 32)*64;
    const bf16* src = Bm + (size_t)(b*SEQ + t0)*DSTATE + n0;
    #pragma unroll
    for (int i = 0; i < 2; i++){
      int u = tid + i*256;
      int r = u >> 3, po = (u & 7)*8;
      bfx8 v = *(const bfx8*)(src + (size_t)r*DSTATE + po);
      *(bfx8*)&tile[r][po] = v;
    }
    __syncthreads();
    bf16* dst = bt + ((size_t)(b*DSTATE) + n0)*SEQ + t0;
    #pragma unroll
    for (int i = 0; i < 2; i++){
      int u = tid + i*256;
      int p = u >> 3, tc = (u & 7)*8;
      bfx8 v;
      #pragma unroll
      for (int j = 0; j < 8; j++) v[j] = (short)tile[tc + j][p];
      *(bfx8*)(dst + (size_t)p*SEQ + tc) = v;
    }
  }
}

// ---------------- MFMA chunk-states ----------------
__global__ __launch_bounds__(256) void chunk_states_mfma(const bf16* __restrict__ xwt,
    const bf16* __restrict__ bt, float* __restrict__ states){
  int bi = blockIdx.x;            // (b*NCHUNK+c)*NHEADS + h
  int h = bi & 31; int c = (bi >> 5) & 15; int b = bi >> 9;
  int tid = threadIdx.x, lane = tid & 63, w = tid >> 6;
  int wm = w >> 1, wn = w & 1;
  const bf16* Arow = xwt + ((size_t)(b*INTER) + h*64)*SEQ + c*CHUNK;
  const bf16* Brow = bt + (size_t)(b*DSTATE)*SEQ + c*CHUNK;
  f32x4 acc[2][4] = {};
  #pragma unroll
  for (int kk = 0; kk < 8; kk++){
    bfx8 af[2], bfr[4];
    #pragma unroll
    for (int m = 0; m < 2; m++)
      af[m] = *(const bfx8*)(Arow + (size_t)(wm*32 + m*16 + (lane&15))*SEQ + kk*32 + (lane>>4)*8);
    #pragma unroll
    for (int n = 0; n < 4; n++)
      bfr[n] = *(const bfx8*)(Brow + (size_t)(wn*64 + n*16 + (lane&15))*SEQ + kk*32 + (lane>>4)*8);
    #pragma unroll
    for (int m = 0; m < 2; m++)
      #pragma unroll
      for (int n = 0; n < 4; n++)
        acc[m][n] = MFMA16(af[m], bfr[n], acc[m][n]);
  }
  float* dst = states + (size_t)bi*HDIM*DSTATE;
  #pragma unroll
  for (int m = 0; m < 2; m++)
    #pragma unroll
    for (int n = 0; n < 4; n++)
      #pragma unroll
      for (int r = 0; r < 4; r++){
        int p = wm*32 + m*16 + (lane>>4)*4 + r;
        int nn = wn*64 + n*16 + (lane&15);
        dst[(size_t)p*DSTATE + nn] = acc[m][n][r];
      }
}

// ---------------- inter-chunk scan ----------------
__global__ __launch_bounds__(256) void scan_kernel(float* __restrict__ states,
    const float* __restrict__ Acum){
  int idx = blockIdx.x*256 + threadIdx.x;
  int n = idx & 127; int p = (idx >> 7) & 63; int h = (idx >> 13) & 31; int b = idx >> 18;
  float R = 0.f;
  for (int c = 0; c < NCHUNK; c++){
    size_t o = (((size_t)((b*NCHUNK + c)*NHEADS + h))*HDIM + p)*DSTATE + n;
    float s = states[o];
    states[o] = R;
    float dA = expf(Acum[((size_t)(b*NHEADS + h)*NCHUNK + c)*CHUNK + CHUNK-1]);
    R = R*dA + s;
  }
}

// ================= fused MFMA Y kernel =================
__global__ __launch_bounds__(256) void ydiag_mfma(
    const bf16* x, const float* __restrict__ dt,
    const float* __restrict__ Acum, const bf16* __restrict__ Bm,
    const bf16* __restrict__ Cm, const float* __restrict__ states,
    const float* __restrict__ Dp, bf16* y){
  int bi = blockIdx.x;            // (b*NCHUNK+c)*NHEADS + h
  int h = bi & 31; int c = (bi >> 5) & 15; int b = bi >> 9;
  int tid = threadIdx.x, lane = tid & 63, w = tid >> 6;

  __shared__ unsigned short XdtT[64*264];
  __shared__ unsigned short pool[256*72];
  __shared__ float Acs[CHUNK];
  __shared__ float dts[CHUNK];

  const float* AcBase = Acum + ((size_t)(b*NHEADS + h)*NCHUNK + c)*CHUNK;
  Acs[tid] = AcBase[tid];
  dts[tid] = dt[(size_t)(b*SEQ + c*CHUNK + tid)*NHEADS + h];
  {
    const float* src = states + (size_t)bi*HDIM*DSTATE;
    #pragma unroll
    for (int i = 0; i < 32; i++){
      int idx = tid + i*256;
      int p = idx >> 7, n = idx & 127;
      pool[p*136 + n] = f2bits(src[idx]);
    }
  }
  __syncthreads();

  const bf16* Crow = Cm + (size_t)(b*SEQ + c*CHUNK)*DSTATE;
  const bf16* Brow = Bm + (size_t)(b*SEQ + c*CHUNK)*DSTATE;

  f32x4 accY[4][4] = {};
  #pragma unroll
  for (int kk = 0; kk < 4; kk++){
    bfx8 af[4], bfr[4];
    #pragma unroll
    for (int m = 0; m < 4; m++)
      af[m] = *(const bfx8*)(Crow + (size_t)(w*64 + m*16 + (lane&15))*DSTATE + kk*32 + (lane>>4)*8);
    #pragma unroll
    for (int n = 0; n < 4; n++)
      bfr[n] = *(const bfx8*)(pool + (n*16 + (lane&15))*136 + kk*32 + (lane>>4)*8);
    #pragma unroll
    for (int m = 0; m < 4; m++)
      #pragma unroll
      for (int n = 0; n < 4; n++)
        accY[m][n] = MFMA16(af[m], bfr[n], accY[m][n]);
  }
  {
    float eAl[4][4];
    #pragma unroll
    for (int m = 0; m < 4; m++)
      #pragma unroll
      for (int r = 0; r < 4; r++)
        eAl[m][r] = expf(Acs[w*64 + m*16 + (lane>>4)*4 + r]);
    #pragma unroll
    for (int m = 0; m < 4; m++)
      #pragma unroll
      for (int n = 0; n < 4; n++)
        #pragma unroll
        for (int r = 0; r < 4; r++)
          accY[m][n][r] *= eAl[m][r];
  }
  __syncthreads();

  {
    const bf16* xg = x + (size_t)(b*SEQ + c*CHUNK)*INTER + h*HDIM;
    #pragma unroll
    for (int i = 0; i < 8; i++){
      int u = tid + i*256;
      int s = u >> 3, p0 = (u & 7)*8;
      bfx8 v = *(const bfx8*)(xg + (size_t)s*INTER + p0);
      float d = dts[s];
      bfx8 o;
      #pragma unroll
      for (int j = 0; j < 8; j++)
        o[j] = (short)f2bits(bits2f((unsigned short)v[j]) * d);
      *(bfx8*)(pool + s*72 + p0) = o;
    }
  }
  __syncthreads();
  {
    int p = tid & 63, sb = tid >> 6;
    #pragma unroll
    for (int i = 0; i < 8; i++){
      int s0 = (sb + i*4)*8;
      bfx8 v;
      #pragma unroll
      for (int j = 0; j < 8; j++)
        v[j] = (short)pool[(s0 + j)*72 + p];
      *(bfx8*)(XdtT + p*264 + s0) = v;
    }
  }
  __syncthreads();

  char* Wl = (char*)pool + w*8192;
  float Dh = Dp[h];

  for (int j = 0; j <= w; j++){
    int s0 = j*64;
    f32x4 accS[4][4] = {};
    #pragma unroll
    for (int kk = 0; kk < 4; kk++){
      bfx8 af[4], bfr[4];
      #pragma unroll
      for (int m = 0; m < 4; m++)
        af[m] = *(const bfx8*)(Crow + (size_t)(w*64 + m*16 + (lane&15))*DSTATE + kk*32 + (lane>>4)*8);
      #pragma unroll
      for (int n = 0; n < 4; n++)
        bfr[n] = *(const bfx8*)(Brow + (size_t)(s0 + n*16 + (lane&15))*DSTATE + kk*32 + (lane>>4)*8);
      #pragma unroll
      for (int m = 0; m < 4; m++)
        #pragma unroll
        for (int n = 0; n < 4; n++)
          accS[m][n] = MFMA16(af[m], bfr[n], accS[m][n]);
    }
    if (j < w){
      float m_ = Acs[s0 + 63];
      float colf[4], rowf[4][4];
      #pragma unroll
      for (int n = 0; n < 4; n++) colf[n] = expf(m_ - Acs[s0 + n*16 + (lane&15)]);
      #pragma unroll
      for (int m = 0; m < 4; m++)
        #pragma unroll
        for (int r = 0; r < 4; r++)
          rowf[m][r] = expf(Acs[w*64 + m*16 + (lane>>4)*4 + r] - m_);
      #pragma unroll
      for (int m = 0; m < 4; m++)
        #pragma unroll
        for (int n = 0; n < 4; n++)
          #pragma unroll
          for (int r = 0; r < 4; r++){
            int ll = m*16 + (lane>>4)*4 + r;
            int sl = n*16 + (lane&15);
            *(unsigned short*)(Wl + ll*128 + ((sl*2) ^ ((ll&7)<<4)))
              = f2bits(accS[m][n][r] * rowf[m][r] * colf[n]);
          }
    } else {
      #pragma unroll
      for (int m = 0; m < 4; m++)
        #pragma unroll
        for (int n = 0; n < 4; n++)
          #pragma unroll
          for (int r = 0; r < 4; r++){
            int ll = m*16 + (lane>>4)*4 + r;
            int sl = n*16 + (lane&15);
            int lg = w*64 + ll, sg = s0 + sl;
            float wv;
            if (sg > lg)       wv = 0.f;
            else if (sg == lg) wv = accS[m][n][r] + Dh/dts[lg];
            else               wv = accS[m][n][r]*expf(Acs[lg] - Acs[sg]);
            *(unsigned short*)(Wl + ll*128 + ((sl*2) ^ ((ll&7)<<4))) = f2bits(wv);
          }
    }
    asm volatile("s_waitcnt lgkmcnt(0)" ::: "memory");
    __builtin_amdgcn_sched_barrier(0);
    #pragma unroll
    for (int kk = 0; kk < 2; kk++){
      bfx8 af[4], bfr[4];
      #pragma unroll
      for (int m = 0; m < 4; m++){
        int ll = m*16 + (lane&15);
        af[m] = *(const bfx8*)(Wl + ll*128 + (((kk*32 + (lane>>4)*8)*2) ^ ((ll&7)<<4)));
      }
      #pragma unroll
      for (int n = 0; n < 4; n++)
        bfr[n] = *(const bfx8*)(XdtT + (n*16 + (lane&15))*264 + s0 + kk*32 + (lane>>4)*8);
      #pragma unroll
      for (int m = 0; m < 4; m++)
        #pragma unroll
        for (int n = 0; n < 4; n++)
          accY[m][n] = MFMA16(af[m], bfr[n], accY[m][n]);
    }
  }
  bf16* yg = y + (size_t)(b*SEQ + c*CHUNK)*INTER + h*HDIM;
  #pragma unroll
  for (int m = 0; m < 4; m++)
    #pragma unroll
    for (int n = 0; n < 4; n++)
      #pragma unroll
      for (int r = 0; r < 4; r++)
        yg[(size_t)(w*64 + m*16 + (lane>>4)*4 + r)*INTER + n*16 + (lane&15)]
          = f2b(accY[m][n][r]);
}

// ---------------- gate + RMSNorm ----------------
__global__ __launch_bounds__(256) void gatenorm_kernel(bf16* __restrict__ y,
    const bf16* __restrict__ z, const float* __restrict__ nw){
  int row = blockIdx.x;
  const bf16* zr = z + (size_t)row*INTER;
  bf16* yr = y + (size_t)row*INTER;
  int tid = threadIdx.x;
  float g[8]; float ss = 0.f;
  #pragma unroll
  for (int i = 0; i < 8; i++){
    int idx = tid + i*256;
    float zv = b2f(zr[idx]);
    float gv = b2f(yr[idx]) * zv * sigmoidf_(zv);
    g[i] = gv; ss += gv*gv;
  }
  #pragma unroll
  for (int off = 32; off > 0; off >>= 1) ss += __shfl_down(ss, off);
  __shared__ float red[4];
  __shared__ float stot;
  int lane = tid & 63, wid = tid >> 6;
  if (lane == 0) red[wid] = ss;
  __syncthreads();
  if (tid == 0) stot = rsqrtf((red[0]+red[1]+red[2]+red[3]) * (1.f/INTER) + 1e-5f);
  __syncthreads();
  float sc = stot;
  #pragma unroll
  for (int i = 0; i < 8; i++){
    int idx = tid + i*256;
    yr[idx] = f2b(g[i]*sc*nw[idx]);
  }
}

extern "C" void kernel_launch(void* const* d_in, const int* in_sizes, int n_in,
                              void* d_out, int out_size, void* d_ws, size_t ws_size,
                              hipStream_t stream){
  const float* u    = (const float*)d_in[0];
  const float* w_in = (const float*)d_in[1];
  const float* cw   = (const float*)d_in[2];
  const float* cb   = (const float*)d_in[3];
  const float* dtb  = (const float*)d_in[4];
  const float* Alog = (const float*)d_in[5];
  const float* Dp   = (const float*)d_in[6];
  const float* nw   = (const float*)d_in[7];
  const float* w_out= (const float*)d_in[8];
  float* out = (float*)d_out;
  char* ws = (char*)d_ws;

  // layout (bytes)
  const size_t OFF_Z     = 0;              // bf16 [8192][2048]
  const size_t OFF_XBC   = 33554432;       // bf16 [8192][2304]; states f32 aliases after conv
  const size_t OFF_DT    = 67108864;       // f32 [8192][32]
  const size_t OFF_ACUM  = 68157440;       // f32 [2*32*16*256]
  const size_t OFF_X     = 71303168;       // bf16 [8192][2048]; y aliases
  const size_t OFF_UBF   = 104857600;      // bf16 u; XW_T aliases after inproj
  const size_t OFF_WINT  = 121634816;      // bf16 w_inT
  const size_t OFF_XWT   = 104857600;      // bf16 [2][2048][4096]
  const size_t OFF_BM    = 138412032;      // bf16 [8192][128]
  const size_t OFF_CM    = 140509184;      // bf16 [8192][128]
  const size_t OFF_DTRAW = 142606336;      // f32 [8192][32]
  const size_t OFF_BT    = 143654912;      // bf16 [2][128][4096]
  const size_t OFF_WOUTT = 145752064;      // bf16 [1024][2048]
  const size_t NEED      = 149946368;

  if (ws_size < NEED){
    zero_out_kernel<<<(out_size + 255)/256, 256, 0, stream>>>(out, out_size);
    return;
  }

  bf16*  z      = (bf16*)(ws + OFF_Z);
  bf16*  xbc    = (bf16*)(ws + OFF_XBC);
  float* states = (float*)(ws + OFF_XBC);
  float* dt     = (float*)(ws + OFF_DT);
  float* Acum   = (float*)(ws + OFF_ACUM);
  bf16*  x      = (bf16*)(ws + OFF_X);
  bf16*  y      = (bf16*)(ws + OFF_X);
  bf16*  u_bf   = (bf16*)(ws + OFF_UBF);
  bf16*  w_inT  = (bf16*)(ws + OFF_WINT);
  bf16*  xwt    = (bf16*)(ws + OFF_XWT);
  bf16*  Bm     = (bf16*)(ws + OFF_BM);
  bf16*  Cm     = (bf16*)(ws + OFF_CM);
  float* dtraw  = (float*)(ws + OFF_DTRAW);
  bf16*  bt     = (bf16*)(ws + OFF_BT);
  bf16*  w_outT = (bf16*)(ws + OFF_WOUTT);

  // opt-in to 128KB dynamic LDS for the 8-phase GEMMs (fallback to m97 kernels if refused)
  bool use8 = true;
  if (hipFuncSetAttribute((const void*)gemm8_inproj,
        hipFuncAttributeMaxDynamicSharedMemorySize, 131072) != hipSuccess) use8 = false;
  if (hipFuncSetAttribute((const void*)gemm8_outproj,
        hipFuncAttributeMaxDynamicSharedMemorySize, 131072) != hipSuccess) use8 = false;

  // 0) prep
  castu_kernel<<<(ROWS*DMODEL/4)/256, 256, 0, stream>>>(u, (unsigned short*)u_bf);
  transcast_kernel<<<dim3(NGEMM/64, DMODEL/64), 256, 0, stream>>>(w_in, w_inT, DMODEL, PROJDIM, 0);
  // 1) projections
  if (use8)
    gemm8_inproj<<<544, 512, 131072, stream>>>(u_bf, w_inT, z, xbc);
  else
    gemm_mfma_inproj<<<dim3(NGEMM/128, ROWS/128), 256, 0, stream>>>(u_bf, w_inT, z, xbc);
  gemm_f32_dt<<<dim3(1, ROWS/64), 256, 0, stream>>>(u, w_in + NGEMM, dtraw, NHEADS, DMODEL, PROJDIM);
  // 2) conv + silu + split
  conv_kernel<<<ROWS*9, 256, 0, stream>>>(xbc, cw, cb, x, Bm, Cm);
  // 3) dt softplus
  dt_kernel<<<ROWS*NHEADS/256, 256, 0, stream>>>(dtraw, dtb, dt);
  // 4) per-chunk cumsum of dt*A
  acum_kernel<<<B_SZ*NHEADS*NCHUNK, 256, 0, stream>>>(dt, Alog, Acum);
  // 4.5) weighted transpose XW_T + BT
  xwt_kernel<<<dim3(34, 64, 2), 256, 0, stream>>>(x, Bm, dt, Acum, xwt, bt);
  // 5) MFMA chunk-states
  chunk_states_mfma<<<B_SZ*NCHUNK*NHEADS, 256, 0, stream>>>(xwt, bt, states);
  // 6) inter-chunk scan
  scan_kernel<<<(B_SZ*NHEADS*HDIM*DSTATE)/256, 256, 0, stream>>>(states, Acum);
  // 7) fused MFMA Y (y aliases x)
  ydiag_mfma<<<B_SZ*NCHUNK*NHEADS, 256, 0, stream>>>(x, dt, Acum, Bm, Cm, states, Dp, y);
  // 7.5) prep out_proj weight
  transcast_kernel<<<dim3(DMODEL/64, INTER/64), 256, 0, stream>>>(w_out, w_outT, INTER, DMODEL, 0);
  // 8) gate + RMSNorm
  gatenorm_kernel<<<ROWS, 256, 0, stream>>>(y, z, nw);
  // 9) out_proj
  if (use8)
    gemm8_outproj<<<128, 512, 131072, stream>>>(y, w_outT, out);
  else
    gemm_mfma_outproj<<<dim3(DMODEL/128, ROWS/128), 256, 0, stream>>>(y, w_outT, out);
}

// Round 7
// 477.625 us; speedup vs baseline: 6.4634x; 1.1452x over previous
//
#include <hip/hip_runtime.h>
#include <hip/hip_bf16.h>

#define B_SZ 2
#define SEQ 4096
#define DMODEL 1024
#define INTER 2048
#define NHEADS 32
#define HDIM 64
#define DSTATE 128
#define DCONV 4
#define CONVDIM 2304
#define PROJDIM 4384
#define CHUNK 256
#define NCHUNK 16
#define ROWS (B_SZ*SEQ)   // 8192
#define NGEMM 4352        // z + xBC columns (17 tiles of 256)

typedef __hip_bfloat16 bf16;
typedef short bfx8 __attribute__((ext_vector_type(8)));
typedef float f32x4 __attribute__((ext_vector_type(4)));

__device__ __forceinline__ float sigmoidf_(float x){ return 1.f/(1.f+expf(-x)); }
__device__ __forceinline__ float b2f(bf16 v){ return __bfloat162float(v); }
__device__ __forceinline__ bf16 f2b(float v){ return __float2bfloat16(v); }
__device__ __forceinline__ float bits2f(unsigned short u){ return __uint_as_float(((unsigned)u) << 16); }
__device__ __forceinline__ unsigned short f2bits(float v){ bf16 t = __float2bfloat16(v); return *(unsigned short*)&t; }

#define MFMA16(a,b,c) __builtin_amdgcn_mfma_f32_16x16x32_bf16(a,b,c,0,0,0)

// ---------------- fallback: zero d_out ----------------
__global__ void zero_out_kernel(float* o, int n){
  int i = blockIdx.x*256 + threadIdx.x;
  if (i < n) o[i] = 0.f;
}

// ---------------- cast u (f32) -> bf16 ----------------
__global__ __launch_bounds__(256) void castu_kernel(const float* __restrict__ in,
    unsigned short* __restrict__ o){
  int i = blockIdx.x*256 + threadIdx.x;
  float4 v = ((const float4*)in)[i];
  ushort4 w;
  w.x = f2bits(v.x); w.y = f2bits(v.y); w.z = f2bits(v.z); w.w = f2bits(v.w);
  ((ushort4*)o)[i] = w;
}

// ---------------- cast + transpose ----------------
__global__ __launch_bounds__(256) void transcast_kernel(const float* __restrict__ in,
    bf16* __restrict__ outT, int R, int ld, int coff){
  __shared__ float t[64][65];
  int r0 = blockIdx.y*64, c0 = blockIdx.x*64;
  int tid = threadIdx.x;
  #pragma unroll
  for (int i = 0; i < 16; i++){
    int idx = tid + i*256;
    int r = idx >> 6, c = idx & 63;
    t[r][c] = in[(size_t)(r0+r)*ld + coff + c0 + c];
  }
  __syncthreads();
  #pragma unroll
  for (int i = 0; i < 16; i++){
    int idx = tid + i*256;
    int c = idx >> 6, r = idx & 63;
    outT[(size_t)(c0+c)*R + r0 + r] = f2b(t[r][c]);
  }
}

// ================= 8-phase 256x256 MFMA GEMM (m201 template, T2+T3+T4+T5) =================
__device__ __forceinline__ void stage8(const bf16* __restrict__ g, int Kdim,
    int tile0, int k0, char* region, int h, int tid){
  #pragma unroll
  for (int l = 0; l < 2; l++){
    int o  = h*16384 + (l*512 + tid)*16;
    int os = o ^ (((o >> 7) & 7) << 4);
    const bf16* src = g + (size_t)(tile0 + (os >> 7))*Kdim + k0 + ((os & 127) >> 1);
    __builtin_amdgcn_global_load_lds(
      (const __attribute__((address_space(1))) void*)src,
      (__attribute__((address_space(3))) void*)(region + h*16384 + (l*512 + (tid >> 6)*64)*16),
      16, 0, 0);
  }
}
__device__ __forceinline__ bfx8 fr8(const char* region, int row, int colbyte){
  int o = row*128 + colbyte;
  o ^= ((row & 7) << 4);
  return *(const bfx8*)(region + o);
}

#define LGKM0  asm volatile("s_waitcnt lgkmcnt(0)" ::: "memory"); __builtin_amdgcn_sched_barrier(0)
#define VM4    asm volatile("s_waitcnt vmcnt(4)" ::: "memory")
#define BAR    __builtin_amdgcn_s_barrier()
#define PRIO1  __builtin_amdgcn_s_setprio(1)
#define PRIO0  __builtin_amdgcn_s_setprio(0)

#define MFMA_QUAD(MH, NH, BARR)                                                \
  PRIO1;                                                                       \
  _Pragma("unroll") for (int m = 0; m < 4; m++)                                \
    _Pragma("unroll") for (int n = 0; n < 2; n++)                              \
      _Pragma("unroll") for (int kk = 0; kk < 2; kk++)                         \
        acc[(MH)+m][(NH)+n] = MFMA16(aF[m][kk], BARR[n][kk], acc[(MH)+m][(NH)+n]); \
  PRIO0

#define GEMM8_BODY(K_, NBX_, EPILOGUE)                                         \
  extern __shared__ char lds[];                                                \
  char* A0 = lds;          char* B0 = lds + 32768;                             \
  char* A1 = lds + 65536;  char* B1 = lds + 98304;                             \
  const int tid = threadIdx.x, lane = tid & 63, wid = tid >> 6;                \
  const int wm = wid >> 2, wn = wid & 3;                                       \
  int nb = (blockIdx.x & 7)*((int)gridDim.x >> 3) + (blockIdx.x >> 3);         \
  const int bx = nb % (NBX_), by = nb / (NBX_);                                \
  const int row0 = by*256, col0 = bx*256;                                      \
  f32x4 acc[8][4] = {};                                                        \
  bfx8 aF[4][2], b01[2][2], b23[2][2];                                         \
  const int frow = lane & 15;                                                  \
  const int fcb0 = (lane >> 4)*16;                                             \
  stage8(Bt, K_, col0, 0,  B0, 0, tid);                                        \
  stage8(Bt, K_, col0, 0,  B0, 1, tid);                                        \
  stage8(A,  K_, row0, 0,  A0, 0, tid);                                        \
  stage8(A,  K_, row0, 0,  A0, 1, tid);                                        \
  stage8(Bt, K_, col0, 64, B1, 0, tid);                                        \
  stage8(Bt, K_, col0, 64, B1, 1, tid);                                        \
  VM4;                                                                         \
  BAR;                                                                         \
  _Pragma("unroll 1")                                                          \
  for (int j = 0; j < (K_)/128; j++){                                          \
    const int kO  = j*128 + 64;                                                \
    const int kS1 = (j*128 + 128) & ((K_) - 1);                                \
    const int kS2 = (j*128 + 192) & ((K_) - 1);                                \
    stage8(A, K_, row0, kO, A1, 0, tid);                                       \
    _Pragma("unroll") for (int m = 0; m < 4; m++)                              \
      _Pragma("unroll") for (int kk = 0; kk < 2; kk++)                         \
        aF[m][kk] = fr8(A0, wm*128 + m*16 + frow, kk*64 + fcb0);               \
    _Pragma("unroll") for (int n = 0; n < 2; n++)                              \
      _Pragma("unroll") for (int kk = 0; kk < 2; kk++)                         \
        b01[n][kk] = fr8(B0, wn*64 + n*16 + frow, kk*64 + fcb0);               \
    LGKM0;                                                                     \
    MFMA_QUAD(0, 0, b01);                                                      \
    BAR;                                                                       \
    stage8(A, K_, row0, kO, A1, 1, tid);                                       \
    _Pragma("unroll") for (int n = 0; n < 2; n++)                              \
      _Pragma("unroll") for (int kk = 0; kk < 2; kk++)                         \
        b23[n][kk] = fr8(B0, wn*64 + (n+2)*16 + frow, kk*64 + fcb0);           \
    LGKM0;                                                                     \
    MFMA_QUAD(0, 2, b23);                                                      \
    BAR;                                                                       \
    stage8(Bt, K_, col0, kS1, B0, 0, tid);                                     \
    _Pragma("unroll") for (int m = 0; m < 4; m++)                              \
      _Pragma("unroll") for (int kk = 0; kk < 2; kk++)                         \
        aF[m][kk] = fr8(A0, wm*128 + (m+4)*16 + frow, kk*64 + fcb0);           \
    LGKM0;                                                                     \
    MFMA_QUAD(4, 0, b01);                                                      \
    BAR;                                                                       \
    stage8(Bt, K_, col0, kS1, B0, 1, tid);                                     \
    VM4;                                                                       \
    MFMA_QUAD(4, 2, b23);                                                      \
    BAR;                                                                       \
    stage8(A, K_, row0, kS1, A0, 0, tid);                                      \
    _Pragma("unroll") for (int m = 0; m < 4; m++)                              \
      _Pragma("unroll") for (int kk = 0; kk < 2; kk++)                         \
        aF[m][kk] = fr8(A1, wm*128 + m*16 + frow, kk*64 + fcb0);               \
    _Pragma("unroll") for (int n = 0; n < 2; n++)                              \
      _Pragma("unroll") for (int kk = 0; kk < 2; kk++)                         \
        b01[n][kk] = fr8(B1, wn*64 + n*16 + frow, kk*64 + fcb0);               \
    LGKM0;                                                                     \
    MFMA_QUAD(0, 0, b01);                                                      \
    BAR;                                                                       \
    stage8(A, K_, row0, kS1, A0, 1, tid);                                      \
    _Pragma("unroll") for (int n = 0; n < 2; n++)                              \
      _Pragma("unroll") for (int kk = 0; kk < 2; kk++)                         \
        b23[n][kk] = fr8(B1, wn*64 + (n+2)*16 + frow, kk*64 + fcb0);           \
    LGKM0;                                                                     \
    MFMA_QUAD(0, 2, b23);                                                      \
    BAR;                                                                       \
    stage8(Bt, K_, col0, kS2, B1, 0, tid);                                     \
    _Pragma("unroll") for (int m = 0; m < 4; m++)                              \
      _Pragma("unroll") for (int kk = 0; kk < 2; kk++)                         \
        aF[m][kk] = fr8(A1, wm*128 + (m+4)*16 + frow, kk*64 + fcb0);           \
    LGKM0;                                                                     \
    MFMA_QUAD(4, 0, b01);                                                      \
    BAR;                                                                       \
    stage8(Bt, K_, col0, kS2, B1, 1, tid);                                     \
    VM4;                                                                       \
    MFMA_QUAD(4, 2, b23);                                                      \
    BAR;                                                                       \
  }                                                                            \
  _Pragma("unroll") for (int m = 0; m < 8; m++){                               \
    int row = row0 + wm*128 + m*16 + (lane >> 4)*4;                            \
    _Pragma("unroll") for (int n = 0; n < 4; n++){                             \
      int col = col0 + wn*64 + n*16 + (lane & 15);                             \
      _Pragma("unroll") for (int r = 0; r < 4; r++){                           \
        float v = acc[m][n][r];                                                \
        int rr = row + r;                                                      \
        EPILOGUE                                                               \
      }                                                                        \
    }                                                                          \
  }

__global__ __launch_bounds__(512, 2) void gemm8_inproj(const bf16* __restrict__ A,
    const bf16* __restrict__ Bt, bf16* __restrict__ z, bf16* __restrict__ xbc){
  GEMM8_BODY(DMODEL, 17,
    if (col < INTER) z[(size_t)rr*INTER + col] = f2b(v);
    else             xbc[(size_t)rr*CONVDIM + (col - INTER)] = f2b(v);
  )
}
__global__ __launch_bounds__(512, 2) void gemm8_outproj(const bf16* __restrict__ A,
    const bf16* __restrict__ Bt, float* __restrict__ C){
  GEMM8_BODY(INTER, 4,
    C[(size_t)rr*DMODEL + col] = v;
  )
}

// ================= fallback m97-structure GEMMs =================
#define MFMA_GEMM_BODY(K_, EPILOGUE)                                           \
  __shared__ unsigned short As[128*64];                                        \
  __shared__ unsigned short Bs[128*64];                                        \
  const int tid = threadIdx.x;                                                 \
  const int lane = tid & 63, wid = tid >> 6;                                   \
  const int wm = wid >> 1, wn = wid & 1;                                       \
  const int row0 = blockIdx.y*128, col0 = blockIdx.x*128;                      \
  f32x4 acc[4][4] = {};                                                        \
  const int rstg = wid*32 + ((lane>>3)&7);                                     \
  const int kstg = (lane&7)*8;                                                 \
  for (int k0 = 0; k0 < (K_); k0 += 64){                                       \
    _Pragma("unroll")                                                          \
    for (int j = 0; j < 4; j++){                                               \
      const bf16* gA = A + (size_t)(row0 + rstg + j*8)*(K_) + k0 + kstg;       \
      __builtin_amdgcn_global_load_lds(                                        \
        (const __attribute__((address_space(1))) void*)gA,                     \
        (__attribute__((address_space(3))) void*)(As + (wid*32 + j*8)*64),     \
        16, 0, 0);                                                             \
      const bf16* gB = Bt + (size_t)(col0 + rstg + j*8)*(K_) + k0 + kstg;      \
      __builtin_amdgcn_global_load_lds(                                        \
        (const __attribute__((address_space(1))) void*)gB,                     \
        (__attribute__((address_space(3))) void*)(Bs + (wid*32 + j*8)*64),     \
        16, 0, 0);                                                             \
    }                                                                          \
    __syncthreads();                                                           \
    _Pragma("unroll")                                                          \
    for (int kk = 0; kk < 2; kk++){                                            \
      bfx8 af[4], bfr[4];                                                      \
      _Pragma("unroll")                                                        \
      for (int m = 0; m < 4; m++)                                              \
        af[m] = *(const bfx8*)(As + (wm*64 + m*16 + (lane&15))*64              \
                               + kk*32 + (lane>>4)*8);                         \
      _Pragma("unroll")                                                        \
      for (int n = 0; n < 4; n++)                                              \
        bfr[n] = *(const bfx8*)(Bs + (wn*64 + n*16 + (lane&15))*64             \
                                + kk*32 + (lane>>4)*8);                        \
      _Pragma("unroll")                                                        \
      for (int m = 0; m < 4; m++)                                              \
        _Pragma("unroll")                                                      \
        for (int n = 0; n < 4; n++)                                            \
          acc[m][n] = MFMA16(af[m], bfr[n], acc[m][n]);                        \
    }                                                                          \
    __syncthreads();                                                           \
  }                                                                            \
  _Pragma("unroll")                                                            \
  for (int m = 0; m < 4; m++){                                                 \
    int row = row0 + wm*64 + m*16 + (lane>>4)*4;                               \
    _Pragma("unroll")                                                          \
    for (int n = 0; n < 4; n++){                                               \
      int col = col0 + wn*64 + n*16 + (lane&15);                               \
      _Pragma("unroll")                                                        \
      for (int r = 0; r < 4; r++){                                             \
        float v = acc[m][n][r];                                                \
        int rr = row + r;                                                      \
        EPILOGUE                                                               \
      }                                                                        \
    }                                                                          \
  }

__global__ __launch_bounds__(256) void gemm_mfma_inproj(const bf16* __restrict__ A,
    const bf16* __restrict__ Bt, bf16* __restrict__ z, bf16* __restrict__ xbc){
  MFMA_GEMM_BODY(DMODEL,
    if (col < INTER) z[(size_t)rr*INTER + col] = f2b(v);
    else             xbc[(size_t)rr*CONVDIM + (col - INTER)] = f2b(v);
  )
}
__global__ __launch_bounds__(256) void gemm_mfma_outproj(const bf16* __restrict__ A,
    const bf16* __restrict__ Bt, float* __restrict__ C){
  MFMA_GEMM_BODY(INTER,
    C[(size_t)rr*DMODEL + col] = v;
  )
}

// ---------------- split-K fp32 dt GEMM: partial[ks][row][col] ----------------
// grid (8, 128): ks = K-split (128 each), 64 rows/block. 256 thr.
__global__ __launch_bounds__(256) void dt_partial(const float* __restrict__ u,
    const float* __restrict__ w_in, float* __restrict__ partial){
  __shared__ float wsm[128][33];
  __shared__ float us[64][133];
  int ks = blockIdx.x, row0 = blockIdx.y*64;
  int k0 = ks*128;
  int tid = threadIdx.x;
  // stage w slice [128 k][32 col]
  #pragma unroll
  for (int i = 0; i < 16; i++){
    int idx = tid + i*256;
    int r = idx >> 5, c = idx & 31;
    wsm[r][c] = w_in[(size_t)(k0 + r)*PROJDIM + NGEMM + c];
  }
  // stage u [64 rows][128 k] via float4
  #pragma unroll
  for (int i = 0; i < 8; i++){
    int idx = tid + i*256;
    int r = idx >> 5, c4 = idx & 31;
    float4 v = *(const float4*)(u + (size_t)(row0 + r)*DMODEL + k0 + c4*4);
    us[r][c4*4+0] = v.x; us[r][c4*4+1] = v.y; us[r][c4*4+2] = v.z; us[r][c4*4+3] = v.w;
  }
  __syncthreads();
  int col = tid & 31, r0 = tid >> 5;   // r0 in 0..7
  float acc[8] = {};
  #pragma unroll 4
  for (int kk4 = 0; kk4 < 32; kk4++){
    float4 uv[8];
    #pragma unroll
    for (int i = 0; i < 8; i++)
      uv[i] = *(const float4*)&us[r0 + i*8][kk4*4];
    #pragma unroll
    for (int j = 0; j < 4; j++){
      float wv = wsm[kk4*4 + j][col];
      #pragma unroll
      for (int i = 0; i < 8; i++){
        float uvj = (j == 0) ? uv[i].x : (j == 1) ? uv[i].y : (j == 2) ? uv[i].z : uv[i].w;
        acc[i] = fmaf(uvj, wv, acc[i]);
      }
    }
  }
  #pragma unroll
  for (int i = 0; i < 8; i++)
    partial[((size_t)ks*ROWS + row0 + r0 + i*8)*NHEADS + col] = acc[i];
}

// ---------------- reduce 8 partials -> dtraw ----------------
__global__ __launch_bounds__(256) void dt_reduce(const float* __restrict__ partial,
    float* __restrict__ dtraw){
  int idx = blockIdx.x*256 + threadIdx.x;   // ROWS*NHEADS = 262144
  float s = 0.f;
  #pragma unroll
  for (int ks = 0; ks < 8; ks++)
    s += partial[(size_t)ks*ROWS*NHEADS + idx];
  dtraw[idx] = s;
}

// ---------------- conv1d + silu + split ----------------
__global__ __launch_bounds__(256) void conv_kernel(const bf16* __restrict__ xbc,
    const float* __restrict__ cw, const float* __restrict__ cb,
    bf16* __restrict__ x, bf16* __restrict__ Bm, bf16* __restrict__ Cm){
  int bt = blockIdx.x / 9;
  int ch = (blockIdx.x % 9)*256 + threadIdx.x;
  int t = bt & (SEQ-1);
  float acc = cb[ch];
  #pragma unroll
  for (int i = 0; i < 4; i++){
    int tt = t - 3 + i;
    if (tt >= 0)
      acc = fmaf(b2f(xbc[(size_t)(bt - t + tt)*CONVDIM + ch]), cw[ch*4+i], acc);
  }
  float v = acc * sigmoidf_(acc);
  if (ch < INTER)              x[(size_t)bt*INTER + ch] = f2b(v);
  else if (ch < INTER+DSTATE)  Bm[(size_t)bt*DSTATE + (ch-INTER)] = f2b(v);
  else                         Cm[(size_t)bt*DSTATE + (ch-INTER-DSTATE)] = f2b(v);
}

// ---------------- dt = softplus(dt_raw + bias) ----------------
__global__ __launch_bounds__(256) void dt_kernel(const float* __restrict__ dtraw,
    const float* __restrict__ dt_bias, float* __restrict__ dt){
  int idx = blockIdx.x*256 + threadIdx.x;
  int h = idx & 31;
  float v = dtraw[idx] + dt_bias[h];
  dt[idx] = (v > 20.f) ? v : log1pf(expf(v));
}

// ---------------- per-chunk inclusive cumsum of dt*A ----------------
__global__ __launch_bounds__(256) void acum_kernel(const float* __restrict__ dt,
    const float* __restrict__ A_log, float* __restrict__ Acum){
  int bi = blockIdx.x;            // (b*NHEADS+h)*NCHUNK + c
  int c = bi & 15; int h = (bi >> 4) & 31; int b = bi >> 9;
  int l = threadIdx.x;
  __shared__ float sbuf[CHUNK];
  float A = -expf(A_log[h]);
  int t = c*CHUNK + l;
  sbuf[l] = dt[(size_t)(b*SEQ + t)*NHEADS + h] * A;
  __syncthreads();
  for (int off = 1; off < CHUNK; off <<= 1){
    float add = (l >= off) ? sbuf[l-off] : 0.f;
    __syncthreads();
    sbuf[l] += add;
    __syncthreads();
  }
  Acum[(size_t)bi*CHUNK + l] = sbuf[l];
}

// ---------------- build XW_T + BT ----------------
__global__ __launch_bounds__(256) void xwt_kernel(const bf16* __restrict__ x,
    const bf16* __restrict__ Bm, const float* __restrict__ dt,
    const float* __restrict__ Acum, bf16* __restrict__ xwt, bf16* __restrict__ bt){
  int pt = blockIdx.x, tt = blockIdx.y, b = blockIdx.z;
  int tid = threadIdx.x;
  __shared__ unsigned short tile[64][72];
  __shared__ float wf[64];
  int t0 = tt*64;
  if (pt < 32){
    int h = pt, c = t0 >> 8;
    if (tid < 64){
      const float* AcB = Acum + ((size_t)(b*NHEADS + h)*NCHUNK + c)*CHUNK;
      int t = t0 + tid;
      wf[tid] = dt[(size_t)(b*SEQ + t)*NHEADS + h] * expf(AcB[255] - AcB[t & 255]);
    }
    __syncthreads();
    const bf16* src = x + (size_t)(b*SEQ + t0)*INTER + pt*64;
    #pragma unroll
    for (int i = 0; i < 2; i++){
      int u = tid + i*256;
      int r = u >> 3, po = (u & 7)*8;
      bfx8 v = *(const bfx8*)(src + (size_t)r*INTER + po);
      float d = wf[r];
      #pragma unroll
      for (int j = 0; j < 8; j++)
        tile[r][po + j] = f2bits(bits2f((unsigned short)v[j]) * d);
    }
    __syncthreads();
    bf16* dst = xwt + ((size_t)(b*INTER) + pt*64)*SEQ + t0;
    #pragma unroll
    for (int i = 0; i < 2; i++){
      int u = tid + i*256;
      int p = u >> 3, tc = (u & 7)*8;
      bfx8 v;
      #pragma unroll
      for (int j = 0; j < 8; j++) v[j] = (short)tile[tc + j][p];
      *(bfx8*)(dst + (size_t)p*SEQ + tc) = v;
    }
  } else {
    int n0 = (pt - 32)*64;
    const bf16* src = Bm + (size_t)(b*SEQ + t0)*DSTATE + n0;
    #pragma unroll
    for (int i = 0; i < 2; i++){
      int u = tid + i*256;
      int r = u >> 3, po = (u & 7)*8;
      bfx8 v = *(const bfx8*)(src + (size_t)r*DSTATE + po);
      *(bfx8*)&tile[r][po] = v;
    }
    __syncthreads();
    bf16* dst = bt + ((size_t)(b*DSTATE) + n0)*SEQ + t0;
    #pragma unroll
    for (int i = 0; i < 2; i++){
      int u = tid + i*256;
      int p = u >> 3, tc = (u & 7)*8;
      bfx8 v;
      #pragma unroll
      for (int j = 0; j < 8; j++) v[j] = (short)tile[tc + j][p];
      *(bfx8*)(dst + (size_t)p*SEQ + tc) = v;
    }
  }
}

// ---------------- MFMA chunk-states ----------------
__global__ __launch_bounds__(256) void chunk_states_mfma(const bf16* __restrict__ xwt,
    const bf16* __restrict__ bt, float* __restrict__ states){
  int bi = blockIdx.x;            // (b*NCHUNK+c)*NHEADS + h
  int h = bi & 31; int c = (bi >> 5) & 15; int b = bi >> 9;
  int tid = threadIdx.x, lane = tid & 63, w = tid >> 6;
  int wm = w >> 1, wn = w & 1;
  const bf16* Arow = xwt + ((size_t)(b*INTER) + h*64)*SEQ + c*CHUNK;
  const bf16* Brow = bt + (size_t)(b*DSTATE)*SEQ + c*CHUNK;
  f32x4 acc[2][4] = {};
  #pragma unroll
  for (int kk = 0; kk < 8; kk++){
    bfx8 af[2], bfr[4];
    #pragma unroll
    for (int m = 0; m < 2; m++)
      af[m] = *(const bfx8*)(Arow + (size_t)(wm*32 + m*16 + (lane&15))*SEQ + kk*32 + (lane>>4)*8);
    #pragma unroll
    for (int n = 0; n < 4; n++)
      bfr[n] = *(const bfx8*)(Brow + (size_t)(wn*64 + n*16 + (lane&15))*SEQ + kk*32 + (lane>>4)*8);
    #pragma unroll
    for (int m = 0; m < 2; m++)
      #pragma unroll
      for (int n = 0; n < 4; n++)
        acc[m][n] = MFMA16(af[m], bfr[n], acc[m][n]);
  }
  float* dst = states + (size_t)bi*HDIM*DSTATE;
  #pragma unroll
  for (int m = 0; m < 2; m++)
    #pragma unroll
    for (int n = 0; n < 4; n++)
      #pragma unroll
      for (int r = 0; r < 4; r++){
        int p = wm*32 + m*16 + (lane>>4)*4 + r;
        int nn = wn*64 + n*16 + (lane&15);
        dst[(size_t)p*DSTATE + nn] = acc[m][n][r];
      }
}

// ---------------- inter-chunk scan ----------------
__global__ __launch_bounds__(256) void scan_kernel(float* __restrict__ states,
    const float* __restrict__ Acum){
  int idx = blockIdx.x*256 + threadIdx.x;
  int n = idx & 127; int p = (idx >> 7) & 63; int h = (idx >> 13) & 31; int b = idx >> 18;
  float R = 0.f;
  for (int c = 0; c < NCHUNK; c++){
    size_t o = (((size_t)((b*NCHUNK + c)*NHEADS + h))*HDIM + p)*DSTATE + n;
    float s = states[o];
    states[o] = R;
    float dA = expf(Acum[((size_t)(b*NHEADS + h)*NCHUNK + c)*CHUNK + CHUNK-1]);
    R = R*dA + s;
  }
}

// ================= fused MFMA Y kernel =================
__global__ __launch_bounds__(256) void ydiag_mfma(
    const bf16* x, const float* __restrict__ dt,
    const float* __restrict__ Acum, const bf16* __restrict__ Bm,
    const bf16* __restrict__ Cm, const float* __restrict__ states,
    const float* __restrict__ Dp, bf16* y){
  int bi = blockIdx.x;            // (b*NCHUNK+c)*NHEADS + h
  int h = bi & 31; int c = (bi >> 5) & 15; int b = bi >> 9;
  int tid = threadIdx.x, lane = tid & 63, w = tid >> 6;

  __shared__ unsigned short XdtT[64*264];
  __shared__ unsigned short pool[256*72];
  __shared__ float Acs[CHUNK];
  __shared__ float dts[CHUNK];

  const float* AcBase = Acum + ((size_t)(b*NHEADS + h)*NCHUNK + c)*CHUNK;
  Acs[tid] = AcBase[tid];
  dts[tid] = dt[(size_t)(b*SEQ + c*CHUNK + tid)*NHEADS + h];
  {
    const float* src = states + (size_t)bi*HDIM*DSTATE;
    #pragma unroll
    for (int i = 0; i < 32; i++){
      int idx = tid + i*256;
      int p = idx >> 7, n = idx & 127;
      pool[p*136 + n] = f2bits(src[idx]);
    }
  }
  __syncthreads();

  const bf16* Crow = Cm + (size_t)(b*SEQ + c*CHUNK)*DSTATE;
  const bf16* Brow = Bm + (size_t)(b*SEQ + c*CHUNK)*DSTATE;

  f32x4 accY[4][4] = {};
  #pragma unroll
  for (int kk = 0; kk < 4; kk++){
    bfx8 af[4], bfr[4];
    #pragma unroll
    for (int m = 0; m < 4; m++)
      af[m] = *(const bfx8*)(Crow + (size_t)(w*64 + m*16 + (lane&15))*DSTATE + kk*32 + (lane>>4)*8);
    #pragma unroll
    for (int n = 0; n < 4; n++)
      bfr[n] = *(const bfx8*)(pool + (n*16 + (lane&15))*136 + kk*32 + (lane>>4)*8);
    #pragma unroll
    for (int m = 0; m < 4; m++)
      #pragma unroll
      for (int n = 0; n < 4; n++)
        accY[m][n] = MFMA16(af[m], bfr[n], accY[m][n]);
  }
  {
    float eAl[4][4];
    #pragma unroll
    for (int m = 0; m < 4; m++)
      #pragma unroll
      for (int r = 0; r < 4; r++)
        eAl[m][r] = expf(Acs[w*64 + m*16 + (lane>>4)*4 + r]);
    #pragma unroll
    for (int m = 0; m < 4; m++)
      #pragma unroll
      for (int n = 0; n < 4; n++)
        #pragma unroll
        for (int r = 0; r < 4; r++)
          accY[m][n][r] *= eAl[m][r];
  }
  __syncthreads();

  {
    const bf16* xg = x + (size_t)(b*SEQ + c*CHUNK)*INTER + h*HDIM;
    #pragma unroll
    for (int i = 0; i < 8; i++){
      int u = tid + i*256;
      int s = u >> 3, p0 = (u & 7)*8;
      bfx8 v = *(const bfx8*)(xg + (size_t)s*INTER + p0);
      float d = dts[s];
      bfx8 o;
      #pragma unroll
      for (int j = 0; j < 8; j++)
        o[j] = (short)f2bits(bits2f((unsigned short)v[j]) * d);
      *(bfx8*)(pool + s*72 + p0) = o;
    }
  }
  __syncthreads();
  {
    int p = tid & 63, sb = tid >> 6;
    #pragma unroll
    for (int i = 0; i < 8; i++){
      int s0 = (sb + i*4)*8;
      bfx8 v;
      #pragma unroll
      for (int j = 0; j < 8; j++)
        v[j] = (short)pool[(s0 + j)*72 + p];
      *(bfx8*)(XdtT + p*264 + s0) = v;
    }
  }
  __syncthreads();

  char* Wl = (char*)pool + w*8192;
  float Dh = Dp[h];

  for (int j = 0; j <= w; j++){
    int s0 = j*64;
    f32x4 accS[4][4] = {};
    #pragma unroll
    for (int kk = 0; kk < 4; kk++){
      bfx8 af[4], bfr[4];
      #pragma unroll
      for (int m = 0; m < 4; m++)
        af[m] = *(const bfx8*)(Crow + (size_t)(w*64 + m*16 + (lane&15))*DSTATE + kk*32 + (lane>>4)*8);
      #pragma unroll
      for (int n = 0; n < 4; n++)
        bfr[n] = *(const bfx8*)(Brow + (size_t)(s0 + n*16 + (lane&15))*DSTATE + kk*32 + (lane>>4)*8);
      #pragma unroll
      for (int m = 0; m < 4; m++)
        #pragma unroll
        for (int n = 0; n < 4; n++)
          accS[m][n] = MFMA16(af[m], bfr[n], accS[m][n]);
    }
    if (j < w){
      float m_ = Acs[s0 + 63];
      float colf[4], rowf[4][4];
      #pragma unroll
      for (int n = 0; n < 4; n++) colf[n] = expf(m_ - Acs[s0 + n*16 + (lane&15)]);
      #pragma unroll
      for (int m = 0; m < 4; m++)
        #pragma unroll
        for (int r = 0; r < 4; r++)
          rowf[m][r] = expf(Acs[w*64 + m*16 + (lane>>4)*4 + r] - m_);
      #pragma unroll
      for (int m = 0; m < 4; m++)
        #pragma unroll
        for (int n = 0; n < 4; n++)
          #pragma unroll
          for (int r = 0; r < 4; r++){
            int ll = m*16 + (lane>>4)*4 + r;
            int sl = n*16 + (lane&15);
            *(unsigned short*)(Wl + ll*128 + ((sl*2) ^ ((ll&7)<<4)))
              = f2bits(accS[m][n][r] * rowf[m][r] * colf[n]);
          }
    } else {
      #pragma unroll
      for (int m = 0; m < 4; m++)
        #pragma unroll
        for (int n = 0; n < 4; n++)
          #pragma unroll
          for (int r = 0; r < 4; r++){
            int ll = m*16 + (lane>>4)*4 + r;
            int sl = n*16 + (lane&15);
            int lg = w*64 + ll, sg = s0 + sl;
            float wv;
            if (sg > lg)       wv = 0.f;
            else if (sg == lg) wv = accS[m][n][r] + Dh/dts[lg];
            else               wv = accS[m][n][r]*expf(Acs[lg] - Acs[sg]);
            *(unsigned short*)(Wl + ll*128 + ((sl*2) ^ ((ll&7)<<4))) = f2bits(wv);
          }
    }
    asm volatile("s_waitcnt lgkmcnt(0)" ::: "memory");
    __builtin_amdgcn_sched_barrier(0);
    #pragma unroll
    for (int kk = 0; kk < 2; kk++){
      bfx8 af[4], bfr[4];
      #pragma unroll
      for (int m = 0; m < 4; m++){
        int ll = m*16 + (lane&15);
        af[m] = *(const bfx8*)(Wl + ll*128 + (((kk*32 + (lane>>4)*8)*2) ^ ((ll&7)<<4)));
      }
      #pragma unroll
      for (int n = 0; n < 4; n++)
        bfr[n] = *(const bfx8*)(XdtT + (n*16 + (lane&15))*264 + s0 + kk*32 + (lane>>4)*8);
      #pragma unroll
      for (int m = 0; m < 4; m++)
        #pragma unroll
        for (int n = 0; n < 4; n++)
          accY[m][n] = MFMA16(af[m], bfr[n], accY[m][n]);
    }
  }
  bf16* yg = y + (size_t)(b*SEQ + c*CHUNK)*INTER + h*HDIM;
  #pragma unroll
  for (int m = 0; m < 4; m++)
    #pragma unroll
    for (int n = 0; n < 4; n++)
      #pragma unroll
      for (int r = 0; r < 4; r++)
        yg[(size_t)(w*64 + m*16 + (lane>>4)*4 + r)*INTER + n*16 + (lane&15)]
          = f2b(accY[m][n][r]);
}

// ---------------- gate + RMSNorm ----------------
__global__ __launch_bounds__(256) void gatenorm_kernel(bf16* __restrict__ y,
    const bf16* __restrict__ z, const float* __restrict__ nw){
  int row = blockIdx.x;
  const bf16* zr = z + (size_t)row*INTER;
  bf16* yr = y + (size_t)row*INTER;
  int tid = threadIdx.x;
  float g[8]; float ss = 0.f;
  #pragma unroll
  for (int i = 0; i < 8; i++){
    int idx = tid + i*256;
    float zv = b2f(zr[idx]);
    float gv = b2f(yr[idx]) * zv * sigmoidf_(zv);
    g[i] = gv; ss += gv*gv;
  }
  #pragma unroll
  for (int off = 32; off > 0; off >>= 1) ss += __shfl_down(ss, off);
  __shared__ float red[4];
  __shared__ float stot;
  int lane = tid & 63, wid = tid >> 6;
  if (lane == 0) red[wid] = ss;
  __syncthreads();
  if (tid == 0) stot = rsqrtf((red[0]+red[1]+red[2]+red[3]) * (1.f/INTER) + 1e-5f);
  __syncthreads();
  float sc = stot;
  #pragma unroll
  for (int i = 0; i < 8; i++){
    int idx = tid + i*256;
    yr[idx] = f2b(g[i]*sc*nw[idx]);
  }
}

extern "C" void kernel_launch(void* const* d_in, const int* in_sizes, int n_in,
                              void* d_out, int out_size, void* d_ws, size_t ws_size,
                              hipStream_t stream){
  const float* u    = (const float*)d_in[0];
  const float* w_in = (const float*)d_in[1];
  const float* cw   = (const float*)d_in[2];
  const float* cb   = (const float*)d_in[3];
  const float* dtb  = (const float*)d_in[4];
  const float* Alog = (const float*)d_in[5];
  const float* Dp   = (const float*)d_in[6];
  const float* nw   = (const float*)d_in[7];
  const float* w_out= (const float*)d_in[8];
  float* out = (float*)d_out;
  char* ws = (char*)d_ws;

  // layout (bytes)
  const size_t OFF_Z     = 0;              // bf16 [8192][2048]
  const size_t OFF_XBC   = 33554432;       // bf16 [8192][2304]; states f32 aliases after conv
  const size_t OFF_DT    = 67108864;       // f32 [8192][32]
  const size_t OFF_ACUM  = 68157440;       // f32 [2*32*16*256]
  const size_t OFF_X     = 71303168;       // bf16 [8192][2048]; y aliases
  const size_t OFF_UBF   = 104857600;      // bf16 u; XW_T aliases after inproj
  const size_t OFF_WINT  = 121634816;      // bf16 w_inT
  const size_t OFF_XWT   = 104857600;      // bf16 [2][2048][4096]
  const size_t OFF_BM    = 138412032;      // bf16 [8192][128]
  const size_t OFF_CM    = 140509184;      // bf16 [8192][128]
  const size_t OFF_DTRAW = 142606336;      // f32 [8192][32]
  const size_t OFF_BT    = 143654912;      // bf16 [2][128][4096]
  const size_t OFF_WOUTT = 145752064;      // bf16 [1024][2048]
  const size_t OFF_PART  = 149946368;      // f32 [8][8192][32] = 8,388,608
  const size_t NEED      = 158334976;      // == R2-proven size

  if (ws_size < NEED){
    zero_out_kernel<<<(out_size + 255)/256, 256, 0, stream>>>(out, out_size);
    return;
  }

  bf16*  z      = (bf16*)(ws + OFF_Z);
  bf16*  xbc    = (bf16*)(ws + OFF_XBC);
  float* states = (float*)(ws + OFF_XBC);
  float* dt     = (float*)(ws + OFF_DT);
  float* Acum   = (float*)(ws + OFF_ACUM);
  bf16*  x      = (bf16*)(ws + OFF_X);
  bf16*  y      = (bf16*)(ws + OFF_X);
  bf16*  u_bf   = (bf16*)(ws + OFF_UBF);
  bf16*  w_inT  = (bf16*)(ws + OFF_WINT);
  bf16*  xwt    = (bf16*)(ws + OFF_XWT);
  bf16*  Bm     = (bf16*)(ws + OFF_BM);
  bf16*  Cm     = (bf16*)(ws + OFF_CM);
  float* dtraw  = (float*)(ws + OFF_DTRAW);
  bf16*  bt     = (bf16*)(ws + OFF_BT);
  bf16*  w_outT = (bf16*)(ws + OFF_WOUTT);
  float* part   = (float*)(ws + OFF_PART);

  bool use8 = true;
  if (hipFuncSetAttribute((const void*)gemm8_inproj,
        hipFuncAttributeMaxDynamicSharedMemorySize, 131072) != hipSuccess) use8 = false;
  if (hipFuncSetAttribute((const void*)gemm8_outproj,
        hipFuncAttributeMaxDynamicSharedMemorySize, 131072) != hipSuccess) use8 = false;

  // 0) prep
  castu_kernel<<<(ROWS*DMODEL/4)/256, 256, 0, stream>>>(u, (unsigned short*)u_bf);
  transcast_kernel<<<dim3(NGEMM/64, DMODEL/64), 256, 0, stream>>>(w_in, w_inT, DMODEL, PROJDIM, 0);
  // 1) projections
  if (use8)
    gemm8_inproj<<<544, 512, 131072, stream>>>(u_bf, w_inT, z, xbc);
  else
    gemm_mfma_inproj<<<dim3(NGEMM/128, ROWS/128), 256, 0, stream>>>(u_bf, w_inT, z, xbc);
  // 1b) dtraw via split-K fp32 (precision-critical path stays fp32)
  dt_partial<<<dim3(8, ROWS/64), 256, 0, stream>>>(u, w_in, part);
  dt_reduce<<<(ROWS*NHEADS)/256, 256, 0, stream>>>(part, dtraw);
  // 2) conv + silu + split
  conv_kernel<<<ROWS*9, 256, 0, stream>>>(xbc, cw, cb, x, Bm, Cm);
  // 3) dt softplus
  dt_kernel<<<ROWS*NHEADS/256, 256, 0, stream>>>(dtraw, dtb, dt);
  // 4) per-chunk cumsum of dt*A
  acum_kernel<<<B_SZ*NHEADS*NCHUNK, 256, 0, stream>>>(dt, Alog, Acum);
  // 4.5) weighted transpose XW_T + BT
  xwt_kernel<<<dim3(34, 64, 2), 256, 0, stream>>>(x, Bm, dt, Acum, xwt, bt);
  // 5) MFMA chunk-states
  chunk_states_mfma<<<B_SZ*NCHUNK*NHEADS, 256, 0, stream>>>(xwt, bt, states);
  // 6) inter-chunk scan
  scan_kernel<<<(B_SZ*NHEADS*HDIM*DSTATE)/256, 256, 0, stream>>>(states, Acum);
  // 7) fused MFMA Y (y aliases x)
  ydiag_mfma<<<B_SZ*NCHUNK*NHEADS, 256, 0, stream>>>(x, dt, Acum, Bm, Cm, states, Dp, y);
  // 7.5) prep out_proj weight
  transcast_kernel<<<dim3(DMODEL/64, INTER/64), 256, 0, stream>>>(w_out, w_outT, INTER, DMODEL, 0);
  // 8) gate + RMSNorm
  gatenorm_kernel<<<ROWS, 256, 0, stream>>>(y, z, nw);
  // 9) out_proj
  if (use8)
    gemm8_outproj<<<128, 512, 131072, stream>>>(y, w_outT, out);
  else
    gemm_mfma_outproj<<<dim3(DMODEL/128, ROWS/128), 256, 0, stream>>>(y, w_outT, out);
}

// Round 8
// 425.344 us; speedup vs baseline: 7.2578x; 1.1229x over previous
//
#include <hip/hip_runtime.h>
#include <hip/hip_bf16.h>

#define B_SZ 2
#define SEQ 4096
#define DMODEL 1024
#define INTER 2048
#define NHEADS 32
#define HDIM 64
#define DSTATE 128
#define DCONV 4
#define CONVDIM 2304
#define PROJDIM 4384
#define CHUNK 256
#define NCHUNK 16
#define ROWS (B_SZ*SEQ)   // 8192
#define NGEMM 4352        // z + xBC columns (17 tiles of 256)

typedef __hip_bfloat16 bf16;
typedef short bfx8 __attribute__((ext_vector_type(8)));
typedef float f32x4 __attribute__((ext_vector_type(4)));

__device__ __forceinline__ float sigmoidf_(float x){ return 1.f/(1.f+expf(-x)); }
__device__ __forceinline__ float b2f(bf16 v){ return __bfloat162float(v); }
__device__ __forceinline__ bf16 f2b(float v){ return __float2bfloat16(v); }
__device__ __forceinline__ float bits2f(unsigned short u){ return __uint_as_float(((unsigned)u) << 16); }
__device__ __forceinline__ unsigned short f2bits(float v){ bf16 t = __float2bfloat16(v); return *(unsigned short*)&t; }

#define MFMA16(a,b,c) __builtin_amdgcn_mfma_f32_16x16x32_bf16(a,b,c,0,0,0)

// ---------------- fallback: zero d_out ----------------
__global__ void zero_out_kernel(float* o, int n){
  int i = blockIdx.x*256 + threadIdx.x;
  if (i < n) o[i] = 0.f;
}

// ---------------- cast u (f32) -> bf16 ----------------
__global__ __launch_bounds__(256) void castu_kernel(const float* __restrict__ in,
    unsigned short* __restrict__ o){
  int i = blockIdx.x*256 + threadIdx.x;
  float4 v = ((const float4*)in)[i];
  ushort4 w;
  w.x = f2bits(v.x); w.y = f2bits(v.y); w.z = f2bits(v.z); w.w = f2bits(v.w);
  ((ushort4*)o)[i] = w;
}

// ---------------- cast + transpose ----------------
__global__ __launch_bounds__(256) void transcast_kernel(const float* __restrict__ in,
    bf16* __restrict__ outT, int R, int ld, int coff){
  __shared__ float t[64][65];
  int r0 = blockIdx.y*64, c0 = blockIdx.x*64;
  int tid = threadIdx.x;
  #pragma unroll
  for (int i = 0; i < 16; i++){
    int idx = tid + i*256;
    int r = idx >> 6, c = idx & 63;
    t[r][c] = in[(size_t)(r0+r)*ld + coff + c0 + c];
  }
  __syncthreads();
  #pragma unroll
  for (int i = 0; i < 16; i++){
    int idx = tid + i*256;
    int c = idx >> 6, r = idx & 63;
    outT[(size_t)(c0+c)*R + r0 + r] = f2b(t[r][c]);
  }
}

// ================= 8-phase 256x256 MFMA GEMM (m201 template, T2+T3+T4+T5) =================
__device__ __forceinline__ void stage8(const bf16* __restrict__ g, int Kdim,
    int tile0, int k0, char* region, int h, int tid){
  #pragma unroll
  for (int l = 0; l < 2; l++){
    int o  = h*16384 + (l*512 + tid)*16;
    int os = o ^ (((o >> 7) & 7) << 4);
    const bf16* src = g + (size_t)(tile0 + (os >> 7))*Kdim + k0 + ((os & 127) >> 1);
    __builtin_amdgcn_global_load_lds(
      (const __attribute__((address_space(1))) void*)src,
      (__attribute__((address_space(3))) void*)(region + h*16384 + (l*512 + (tid >> 6)*64)*16),
      16, 0, 0);
  }
}
__device__ __forceinline__ bfx8 fr8(const char* region, int row, int colbyte){
  int o = row*128 + colbyte;
  o ^= ((row & 7) << 4);
  return *(const bfx8*)(region + o);
}

#define LGKM0  asm volatile("s_waitcnt lgkmcnt(0)" ::: "memory"); __builtin_amdgcn_sched_barrier(0)
#define VM4    asm volatile("s_waitcnt vmcnt(4)" ::: "memory")
#define BAR    __builtin_amdgcn_s_barrier()
#define PRIO1  __builtin_amdgcn_s_setprio(1)
#define PRIO0  __builtin_amdgcn_s_setprio(0)

#define MFMA_QUAD(MH, NH, BARR)                                                \
  PRIO1;                                                                       \
  _Pragma("unroll") for (int m = 0; m < 4; m++)                                \
    _Pragma("unroll") for (int n = 0; n < 2; n++)                              \
      _Pragma("unroll") for (int kk = 0; kk < 2; kk++)                         \
        acc[(MH)+m][(NH)+n] = MFMA16(aF[m][kk], BARR[n][kk], acc[(MH)+m][(NH)+n]); \
  PRIO0

#define GEMM8_BODY(K_, NBX_, EPILOGUE)                                         \
  extern __shared__ char lds[];                                                \
  char* A0 = lds;          char* B0 = lds + 32768;                             \
  char* A1 = lds + 65536;  char* B1 = lds + 98304;                             \
  const int tid = threadIdx.x, lane = tid & 63, wid = tid >> 6;                \
  const int wm = wid >> 2, wn = wid & 3;                                       \
  int nb = (blockIdx.x & 7)*((int)gridDim.x >> 3) + (blockIdx.x >> 3);         \
  const int bx = nb % (NBX_), by = nb / (NBX_);                                \
  const int row0 = by*256, col0 = bx*256;                                      \
  f32x4 acc[8][4] = {};                                                        \
  bfx8 aF[4][2], b01[2][2], b23[2][2];                                         \
  const int frow = lane & 15;                                                  \
  const int fcb0 = (lane >> 4)*16;                                             \
  stage8(Bt, K_, col0, 0,  B0, 0, tid);                                        \
  stage8(Bt, K_, col0, 0,  B0, 1, tid);                                        \
  stage8(A,  K_, row0, 0,  A0, 0, tid);                                        \
  stage8(A,  K_, row0, 0,  A0, 1, tid);                                        \
  stage8(Bt, K_, col0, 64, B1, 0, tid);                                        \
  stage8(Bt, K_, col0, 64, B1, 1, tid);                                        \
  VM4;                                                                         \
  BAR;                                                                         \
  _Pragma("unroll 1")                                                          \
  for (int j = 0; j < (K_)/128; j++){                                          \
    const int kO  = j*128 + 64;                                                \
    const int kS1 = (j*128 + 128) & ((K_) - 1);                                \
    const int kS2 = (j*128 + 192) & ((K_) - 1);                                \
    stage8(A, K_, row0, kO, A1, 0, tid);                                       \
    _Pragma("unroll") for (int m = 0; m < 4; m++)                              \
      _Pragma("unroll") for (int kk = 0; kk < 2; kk++)                         \
        aF[m][kk] = fr8(A0, wm*128 + m*16 + frow, kk*64 + fcb0);               \
    _Pragma("unroll") for (int n = 0; n < 2; n++)                              \
      _Pragma("unroll") for (int kk = 0; kk < 2; kk++)                         \
        b01[n][kk] = fr8(B0, wn*64 + n*16 + frow, kk*64 + fcb0);               \
    LGKM0;                                                                     \
    MFMA_QUAD(0, 0, b01);                                                      \
    BAR;                                                                       \
    stage8(A, K_, row0, kO, A1, 1, tid);                                       \
    _Pragma("unroll") for (int n = 0; n < 2; n++)                              \
      _Pragma("unroll") for (int kk = 0; kk < 2; kk++)                         \
        b23[n][kk] = fr8(B0, wn*64 + (n+2)*16 + frow, kk*64 + fcb0);           \
    LGKM0;                                                                     \
    MFMA_QUAD(0, 2, b23);                                                      \
    BAR;                                                                       \
    stage8(Bt, K_, col0, kS1, B0, 0, tid);                                     \
    _Pragma("unroll") for (int m = 0; m < 4; m++)                              \
      _Pragma("unroll") for (int kk = 0; kk < 2; kk++)                         \
        aF[m][kk] = fr8(A0, wm*128 + (m+4)*16 + frow, kk*64 + fcb0);           \
    LGKM0;                                                                     \
    MFMA_QUAD(4, 0, b01);                                                      \
    BAR;                                                                       \
    stage8(Bt, K_, col0, kS1, B0, 1, tid);                                     \
    VM4;                                                                       \
    MFMA_QUAD(4, 2, b23);                                                      \
    BAR;                                                                       \
    stage8(A, K_, row0, kS1, A0, 0, tid);                                      \
    _Pragma("unroll") for (int m = 0; m < 4; m++)                              \
      _Pragma("unroll") for (int kk = 0; kk < 2; kk++)                         \
        aF[m][kk] = fr8(A1, wm*128 + m*16 + frow, kk*64 + fcb0);               \
    _Pragma("unroll") for (int n = 0; n < 2; n++)                              \
      _Pragma("unroll") for (int kk = 0; kk < 2; kk++)                         \
        b01[n][kk] = fr8(B1, wn*64 + n*16 + frow, kk*64 + fcb0);               \
    LGKM0;                                                                     \
    MFMA_QUAD(0, 0, b01);                                                      \
    BAR;                                                                       \
    stage8(A, K_, row0, kS1, A0, 1, tid);                                      \
    _Pragma("unroll") for (int n = 0; n < 2; n++)                              \
      _Pragma("unroll") for (int kk = 0; kk < 2; kk++)                         \
        b23[n][kk] = fr8(B1, wn*64 + (n+2)*16 + frow, kk*64 + fcb0);           \
    LGKM0;                                                                     \
    MFMA_QUAD(0, 2, b23);                                                      \
    BAR;                                                                       \
    stage8(Bt, K_, col0, kS2, B1, 0, tid);                                     \
    _Pragma("unroll") for (int m = 0; m < 4; m++)                              \
      _Pragma("unroll") for (int kk = 0; kk < 2; kk++)                         \
        aF[m][kk] = fr8(A1, wm*128 + (m+4)*16 + frow, kk*64 + fcb0);           \
    LGKM0;                                                                     \
    MFMA_QUAD(4, 0, b01);                                                      \
    BAR;                                                                       \
    stage8(Bt, K_, col0, kS2, B1, 1, tid);                                     \
    VM4;                                                                       \
    MFMA_QUAD(4, 2, b23);                                                      \
    BAR;                                                                       \
  }                                                                            \
  _Pragma("unroll") for (int m = 0; m < 8; m++){                               \
    int row = row0 + wm*128 + m*16 + (lane >> 4)*4;                            \
    _Pragma("unroll") for (int n = 0; n < 4; n++){                             \
      int col = col0 + wn*64 + n*16 + (lane & 15);                             \
      _Pragma("unroll") for (int r = 0; r < 4; r++){                           \
        float v = acc[m][n][r];                                                \
        int rr = row + r;                                                      \
        EPILOGUE                                                               \
      }                                                                        \
    }                                                                          \
  }

__global__ __launch_bounds__(512, 2) void gemm8_inproj(const bf16* __restrict__ A,
    const bf16* __restrict__ Bt, bf16* __restrict__ z, bf16* __restrict__ xbc){
  GEMM8_BODY(DMODEL, 17,
    if (col < INTER) z[(size_t)rr*INTER + col] = f2b(v);
    else             xbc[(size_t)rr*CONVDIM + (col - INTER)] = f2b(v);
  )
}
__global__ __launch_bounds__(512, 2) void gemm8_outproj(const bf16* __restrict__ A,
    const bf16* __restrict__ Bt, float* __restrict__ C){
  GEMM8_BODY(INTER, 4,
    C[(size_t)rr*DMODEL + col] = v;
  )
}

// ================= fallback m97-structure GEMMs =================
#define MFMA_GEMM_BODY(K_, EPILOGUE)                                           \
  __shared__ unsigned short As[128*64];                                        \
  __shared__ unsigned short Bs[128*64];                                        \
  const int tid = threadIdx.x;                                                 \
  const int lane = tid & 63, wid = tid >> 6;                                   \
  const int wm = wid >> 1, wn = wid & 1;                                       \
  const int row0 = blockIdx.y*128, col0 = blockIdx.x*128;                      \
  f32x4 acc[4][4] = {};                                                        \
  const int rstg = wid*32 + ((lane>>3)&7);                                     \
  const int kstg = (lane&7)*8;                                                 \
  for (int k0 = 0; k0 < (K_); k0 += 64){                                       \
    _Pragma("unroll")                                                          \
    for (int j = 0; j < 4; j++){                                               \
      const bf16* gA = A + (size_t)(row0 + rstg + j*8)*(K_) + k0 + kstg;       \
      __builtin_amdgcn_global_load_lds(                                        \
        (const __attribute__((address_space(1))) void*)gA,                     \
        (__attribute__((address_space(3))) void*)(As + (wid*32 + j*8)*64),     \
        16, 0, 0);                                                             \
      const bf16* gB = Bt + (size_t)(col0 + rstg + j*8)*(K_) + k0 + kstg;      \
      __builtin_amdgcn_global_load_lds(                                        \
        (const __attribute__((address_space(1))) void*)gB,                     \
        (__attribute__((address_space(3))) void*)(Bs + (wid*32 + j*8)*64),     \
        16, 0, 0);                                                             \
    }                                                                          \
    __syncthreads();                                                           \
    _Pragma("unroll")                                                          \
    for (int kk = 0; kk < 2; kk++){                                            \
      bfx8 af[4], bfr[4];                                                      \
      _Pragma("unroll")                                                        \
      for (int m = 0; m < 4; m++)                                              \
        af[m] = *(const bfx8*)(As + (wm*64 + m*16 + (lane&15))*64              \
                               + kk*32 + (lane>>4)*8);                         \
      _Pragma("unroll")                                                        \
      for (int n = 0; n < 4; n++)                                              \
        bfr[n] = *(const bfx8*)(Bs + (wn*64 + n*16 + (lane&15))*64             \
                                + kk*32 + (lane>>4)*8);                        \
      _Pragma("unroll")                                                        \
      for (int m = 0; m < 4; m++)                                              \
        _Pragma("unroll")                                                      \
        for (int n = 0; n < 4; n++)                                            \
          acc[m][n] = MFMA16(af[m], bfr[n], acc[m][n]);                        \
    }                                                                          \
    __syncthreads();                                                           \
  }                                                                            \
  _Pragma("unroll")                                                            \
  for (int m = 0; m < 4; m++){                                                 \
    int row = row0 + wm*64 + m*16 + (lane>>4)*4;                               \
    _Pragma("unroll")                                                          \
    for (int n = 0; n < 4; n++){                                               \
      int col = col0 + wn*64 + n*16 + (lane&15);                               \
      _Pragma("unroll")                                                        \
      for (int r = 0; r < 4; r++){                                             \
        float v = acc[m][n][r];                                                \
        int rr = row + r;                                                      \
        EPILOGUE                                                               \
      }                                                                        \
    }                                                                          \
  }

__global__ __launch_bounds__(256) void gemm_mfma_inproj(const bf16* __restrict__ A,
    const bf16* __restrict__ Bt, bf16* __restrict__ z, bf16* __restrict__ xbc){
  MFMA_GEMM_BODY(DMODEL,
    if (col < INTER) z[(size_t)rr*INTER + col] = f2b(v);
    else             xbc[(size_t)rr*CONVDIM + (col - INTER)] = f2b(v);
  )
}
__global__ __launch_bounds__(256) void gemm_mfma_outproj(const bf16* __restrict__ A,
    const bf16* __restrict__ Bt, float* __restrict__ C){
  MFMA_GEMM_BODY(INTER,
    C[(size_t)rr*DMODEL + col] = v;
  )
}

// ---------------- split-K fp32 dt GEMM ----------------
__global__ __launch_bounds__(256) void dt_partial(const float* __restrict__ u,
    const float* __restrict__ w_in, float* __restrict__ partial){
  __shared__ float wsm[128][33];
  __shared__ float us[64][133];
  int ks = blockIdx.x, row0 = blockIdx.y*64;
  int k0 = ks*128;
  int tid = threadIdx.x;
  #pragma unroll
  for (int i = 0; i < 16; i++){
    int idx = tid + i*256;
    int r = idx >> 5, c = idx & 31;
    wsm[r][c] = w_in[(size_t)(k0 + r)*PROJDIM + NGEMM + c];
  }
  #pragma unroll
  for (int i = 0; i < 8; i++){
    int idx = tid + i*256;
    int r = idx >> 5, c4 = idx & 31;
    float4 v = *(const float4*)(u + (size_t)(row0 + r)*DMODEL + k0 + c4*4);
    us[r][c4*4+0] = v.x; us[r][c4*4+1] = v.y; us[r][c4*4+2] = v.z; us[r][c4*4+3] = v.w;
  }
  __syncthreads();
  int col = tid & 31, r0 = tid >> 5;
  float acc[8] = {};
  #pragma unroll 4
  for (int kk4 = 0; kk4 < 32; kk4++){
    float4 uv[8];
    #pragma unroll
    for (int i = 0; i < 8; i++)
      uv[i] = *(const float4*)&us[r0 + i*8][kk4*4];
    #pragma unroll
    for (int j = 0; j < 4; j++){
      float wv = wsm[kk4*4 + j][col];
      #pragma unroll
      for (int i = 0; i < 8; i++){
        float uvj = (j == 0) ? uv[i].x : (j == 1) ? uv[i].y : (j == 2) ? uv[i].z : uv[i].w;
        acc[i] = fmaf(uvj, wv, acc[i]);
      }
    }
  }
  #pragma unroll
  for (int i = 0; i < 8; i++)
    partial[((size_t)ks*ROWS + row0 + r0 + i*8)*NHEADS + col] = acc[i];
}

__global__ __launch_bounds__(256) void dt_reduce(const float* __restrict__ partial,
    float* __restrict__ dtraw){
  int idx = blockIdx.x*256 + threadIdx.x;
  float s = 0.f;
  #pragma unroll
  for (int ks = 0; ks < 8; ks++)
    s += partial[(size_t)ks*ROWS*NHEADS + idx];
  dtraw[idx] = s;
}

// ---------------- conv1d + silu + split ----------------
__global__ __launch_bounds__(256) void conv_kernel(const bf16* __restrict__ xbc,
    const float* __restrict__ cw, const float* __restrict__ cb,
    bf16* __restrict__ x, bf16* __restrict__ Bm, bf16* __restrict__ Cm){
  int bt = blockIdx.x / 9;
  int ch = (blockIdx.x % 9)*256 + threadIdx.x;
  int t = bt & (SEQ-1);
  float acc = cb[ch];
  #pragma unroll
  for (int i = 0; i < 4; i++){
    int tt = t - 3 + i;
    if (tt >= 0)
      acc = fmaf(b2f(xbc[(size_t)(bt - t + tt)*CONVDIM + ch]), cw[ch*4+i], acc);
  }
  float v = acc * sigmoidf_(acc);
  if (ch < INTER)              x[(size_t)bt*INTER + ch] = f2b(v);
  else if (ch < INTER+DSTATE)  Bm[(size_t)bt*DSTATE + (ch-INTER)] = f2b(v);
  else                         Cm[(size_t)bt*DSTATE + (ch-INTER-DSTATE)] = f2b(v);
}

// ---------------- dt = softplus(dt_raw + bias) ----------------
__global__ __launch_bounds__(256) void dt_kernel(const float* __restrict__ dtraw,
    const float* __restrict__ dt_bias, float* __restrict__ dt){
  int idx = blockIdx.x*256 + threadIdx.x;
  int h = idx & 31;
  float v = dtraw[idx] + dt_bias[h];
  dt[idx] = (v > 20.f) ? v : log1pf(expf(v));
}

// ---------------- per-chunk inclusive cumsum of dt*A ----------------
__global__ __launch_bounds__(256) void acum_kernel(const float* __restrict__ dt,
    const float* __restrict__ A_log, float* __restrict__ Acum){
  int bi = blockIdx.x;            // (b*NHEADS+h)*NCHUNK + c
  int c = bi & 15; int h = (bi >> 4) & 31; int b = bi >> 9;
  int l = threadIdx.x;
  __shared__ float sbuf[CHUNK];
  float A = -expf(A_log[h]);
  int t = c*CHUNK + l;
  sbuf[l] = dt[(size_t)(b*SEQ + t)*NHEADS + h] * A;
  __syncthreads();
  for (int off = 1; off < CHUNK; off <<= 1){
    float add = (l >= off) ? sbuf[l-off] : 0.f;
    __syncthreads();
    sbuf[l] += add;
    __syncthreads();
  }
  Acum[(size_t)bi*CHUNK + l] = sbuf[l];
}

// ---------------- head-shared scores: S[bc][l][s] = C·B^T (lower stripes), bf16 ----------------
// grid (32, 4): block (bc, rb); wave k computes stripe k (k <= rb)
__global__ __launch_bounds__(256) void scores_mfma(const bf16* __restrict__ Bm,
    const bf16* __restrict__ Cm, bf16* __restrict__ S){
  int bc = blockIdx.x;           // b*NCHUNK + c
  int rb = blockIdx.y;           // row-block 0..3
  int b = bc >> 4, c = bc & 15;
  int tid = threadIdx.x, lane = tid & 63, k = tid >> 6;
  if (k > rb) return;
  const bf16* Crow = Cm + (size_t)(b*SEQ + c*CHUNK)*DSTATE;
  const bf16* Brow = Bm + (size_t)(b*SEQ + c*CHUNK)*DSTATE;
  f32x4 acc[4][4] = {};
  #pragma unroll
  for (int kk = 0; kk < 4; kk++){
    bfx8 af[4], bfr[4];
    #pragma unroll
    for (int m = 0; m < 4; m++)
      af[m] = *(const bfx8*)(Crow + (size_t)(rb*64 + m*16 + (lane&15))*DSTATE + kk*32 + (lane>>4)*8);
    #pragma unroll
    for (int n = 0; n < 4; n++)
      bfr[n] = *(const bfx8*)(Brow + (size_t)(k*64 + n*16 + (lane&15))*DSTATE + kk*32 + (lane>>4)*8);
    #pragma unroll
    for (int m = 0; m < 4; m++)
      #pragma unroll
      for (int n = 0; n < 4; n++)
        acc[m][n] = MFMA16(af[m], bfr[n], acc[m][n]);
  }
  bf16* dst = S + (size_t)bc*CHUNK*CHUNK;
  #pragma unroll
  for (int m = 0; m < 4; m++)
    #pragma unroll
    for (int n = 0; n < 4; n++)
      #pragma unroll
      for (int r = 0; r < 4; r++)
        dst[(size_t)(rb*64 + m*16 + (lane>>4)*4 + r)*CHUNK + k*64 + n*16 + (lane&15)]
          = f2b(acc[m][n][r]);
}

// ---------------- build XW_T + BT ----------------
__global__ __launch_bounds__(256) void xwt_kernel(const bf16* __restrict__ x,
    const bf16* __restrict__ Bm, const float* __restrict__ dt,
    const float* __restrict__ Acum, bf16* __restrict__ xwt, bf16* __restrict__ bt){
  int pt = blockIdx.x, tt = blockIdx.y, b = blockIdx.z;
  int tid = threadIdx.x;
  __shared__ unsigned short tile[64][72];
  __shared__ float wf[64];
  int t0 = tt*64;
  if (pt < 32){
    int h = pt, c = t0 >> 8;
    if (tid < 64){
      const float* AcB = Acum + ((size_t)(b*NHEADS + h)*NCHUNK + c)*CHUNK;
      int t = t0 + tid;
      wf[tid] = dt[(size_t)(b*SEQ + t)*NHEADS + h] * expf(AcB[255] - AcB[t & 255]);
    }
    __syncthreads();
    const bf16* src = x + (size_t)(b*SEQ + t0)*INTER + pt*64;
    #pragma unroll
    for (int i = 0; i < 2; i++){
      int u = tid + i*256;
      int r = u >> 3, po = (u & 7)*8;
      bfx8 v = *(const bfx8*)(src + (size_t)r*INTER + po);
      float d = wf[r];
      #pragma unroll
      for (int j = 0; j < 8; j++)
        tile[r][po + j] = f2bits(bits2f((unsigned short)v[j]) * d);
    }
    __syncthreads();
    bf16* dst = xwt + ((size_t)(b*INTER) + pt*64)*SEQ + t0;
    #pragma unroll
    for (int i = 0; i < 2; i++){
      int u = tid + i*256;
      int p = u >> 3, tc = (u & 7)*8;
      bfx8 v;
      #pragma unroll
      for (int j = 0; j < 8; j++) v[j] = (short)tile[tc + j][p];
      *(bfx8*)(dst + (size_t)p*SEQ + tc) = v;
    }
  } else {
    int n0 = (pt - 32)*64;
    const bf16* src = Bm + (size_t)(b*SEQ + t0)*DSTATE + n0;
    #pragma unroll
    for (int i = 0; i < 2; i++){
      int u = tid + i*256;
      int r = u >> 3, po = (u & 7)*8;
      bfx8 v = *(const bfx8*)(src + (size_t)r*DSTATE + po);
      *(bfx8*)&tile[r][po] = v;
    }
    __syncthreads();
    bf16* dst = bt + ((size_t)(b*DSTATE) + n0)*SEQ + t0;
    #pragma unroll
    for (int i = 0; i < 2; i++){
      int u = tid + i*256;
      int p = u >> 3, tc = (u & 7)*8;
      bfx8 v;
      #pragma unroll
      for (int j = 0; j < 8; j++) v[j] = (short)tile[tc + j][p];
      *(bfx8*)(dst + (size_t)p*SEQ + tc) = v;
    }
  }
}

// ---------------- MFMA chunk-states ----------------
__global__ __launch_bounds__(256) void chunk_states_mfma(const bf16* __restrict__ xwt,
    const bf16* __restrict__ bt, float* __restrict__ states){
  int bi = blockIdx.x;            // (b*NCHUNK+c)*NHEADS + h
  int h = bi & 31; int c = (bi >> 5) & 15; int b = bi >> 9;
  int tid = threadIdx.x, lane = tid & 63, w = tid >> 6;
  int wm = w >> 1, wn = w & 1;
  const bf16* Arow = xwt + ((size_t)(b*INTER) + h*64)*SEQ + c*CHUNK;
  const bf16* Brow = bt + (size_t)(b*DSTATE)*SEQ + c*CHUNK;
  f32x4 acc[2][4] = {};
  #pragma unroll
  for (int kk = 0; kk < 8; kk++){
    bfx8 af[2], bfr[4];
    #pragma unroll
    for (int m = 0; m < 2; m++)
      af[m] = *(const bfx8*)(Arow + (size_t)(wm*32 + m*16 + (lane&15))*SEQ + kk*32 + (lane>>4)*8);
    #pragma unroll
    for (int n = 0; n < 4; n++)
      bfr[n] = *(const bfx8*)(Brow + (size_t)(wn*64 + n*16 + (lane&15))*SEQ + kk*32 + (lane>>4)*8);
    #pragma unroll
    for (int m = 0; m < 2; m++)
      #pragma unroll
      for (int n = 0; n < 4; n++)
        acc[m][n] = MFMA16(af[m], bfr[n], acc[m][n]);
  }
  float* dst = states + (size_t)bi*HDIM*DSTATE;
  #pragma unroll
  for (int m = 0; m < 2; m++)
    #pragma unroll
    for (int n = 0; n < 4; n++)
      #pragma unroll
      for (int r = 0; r < 4; r++){
        int p = wm*32 + m*16 + (lane>>4)*4 + r;
        int nn = wn*64 + n*16 + (lane&15);
        dst[(size_t)p*DSTATE + nn] = acc[m][n][r];
      }
}

// ---------------- inter-chunk scan ----------------
__global__ __launch_bounds__(256) void scan_kernel(float* __restrict__ states,
    const float* __restrict__ Acum){
  int idx = blockIdx.x*256 + threadIdx.x;
  int n = idx & 127; int p = (idx >> 7) & 63; int h = (idx >> 13) & 31; int b = idx >> 18;
  float R = 0.f;
  for (int c = 0; c < NCHUNK; c++){
    size_t o = (((size_t)((b*NCHUNK + c)*NHEADS + h))*HDIM + p)*DSTATE + n;
    float s = states[o];
    states[o] = R;
    float dA = expf(Acum[((size_t)(b*NHEADS + h)*NCHUNK + c)*CHUNK + CHUNK-1]);
    R = R*dA + s;
  }
}

// ================= fused MFMA Y kernel (S from global, in-register transform) =================
// block = (b,c,h); 4 waves; wave w owns rows [w*64, w*64+64); stripes j<=w
__global__ __launch_bounds__(256, 3) void ydiag_mfma(
    const bf16* x, const float* __restrict__ dt,
    const float* __restrict__ Acum, const bf16* __restrict__ Sg,
    const bf16* __restrict__ Cm, const float* __restrict__ states,
    const float* __restrict__ Dp, bf16* y){
  int bi = blockIdx.x;            // (b*NCHUNK+c)*NHEADS + h
  int h = bi & 31; int c = (bi >> 5) & 15; int b = bi >> 9;
  int bc = b*NCHUNK + c;
  int tid = threadIdx.x, lane = tid & 63, w = tid >> 6;

  __shared__ unsigned short XdtT[64*264];   // [p][s] stride 264 (33,792 B)
  __shared__ unsigned short pool[128*72];   // statesT (64x136) / Xrm half (128x72) (18,432 B)
  __shared__ float Acs[CHUNK];
  __shared__ float dts[CHUNK];

  const float* AcBase = Acum + ((size_t)(b*NHEADS + h)*NCHUNK + c)*CHUNK;
  Acs[tid] = AcBase[tid];
  dts[tid] = dt[(size_t)(b*SEQ + c*CHUNK + tid)*NHEADS + h];
  // stage statesT (bf16) into pool [p][136]
  {
    const float* src = states + (size_t)bi*HDIM*DSTATE;
    #pragma unroll
    for (int i = 0; i < 32; i++){
      int idx = tid + i*256;
      int p = idx >> 7, n = idx & 127;
      pool[p*136 + n] = f2bits(src[idx]);
    }
  }
  __syncthreads();

  const bf16* Crow = Cm + (size_t)(b*SEQ + c*CHUNK)*DSTATE;

  // off-GEMM: accY = C @ statesT (K = 128), scaled by exp(Ac_l)
  f32x4 accY[4][4] = {};
  #pragma unroll
  for (int kk = 0; kk < 4; kk++){
    bfx8 af[4], bfr[4];
    #pragma unroll
    for (int m = 0; m < 4; m++)
      af[m] = *(const bfx8*)(Crow + (size_t)(w*64 + m*16 + (lane&15))*DSTATE + kk*32 + (lane>>4)*8);
    #pragma unroll
    for (int n = 0; n < 4; n++)
      bfr[n] = *(const bfx8*)(pool + (n*16 + (lane&15))*136 + kk*32 + (lane>>4)*8);
    #pragma unroll
    for (int m = 0; m < 4; m++)
      #pragma unroll
      for (int n = 0; n < 4; n++)
        accY[m][n] = MFMA16(af[m], bfr[n], accY[m][n]);
  }
  {
    float eAl[4][4];
    #pragma unroll
    for (int m = 0; m < 4; m++)
      #pragma unroll
      for (int r = 0; r < 4; r++)
        eAl[m][r] = expf(Acs[w*64 + m*16 + (lane>>4)*4 + r]);
    #pragma unroll
    for (int m = 0; m < 4; m++)
      #pragma unroll
      for (int n = 0; n < 4; n++)
        #pragma unroll
        for (int r = 0; r < 4; r++)
          accY[m][n][r] *= eAl[m][r];
  }
  __syncthreads();   // statesT reads done; pool reused for Xrm halves

  // build XdtT in two s-halves (Xrm staging fits 128x72)
  #pragma unroll 1
  for (int q = 0; q < 2; q++){
    const bf16* xg = x + (size_t)(b*SEQ + c*CHUNK + q*128)*INTER + h*HDIM;
    #pragma unroll
    for (int i = 0; i < 4; i++){
      int u = tid + i*256;
      int s = u >> 3, p0 = (u & 7)*8;     // s in 0..127
      bfx8 v = *(const bfx8*)(xg + (size_t)s*INTER + p0);
      float d = dts[q*128 + s];
      bfx8 o;
      #pragma unroll
      for (int j = 0; j < 8; j++)
        o[j] = (short)f2bits(bits2f((unsigned short)v[j]) * d);
      *(bfx8*)(pool + s*72 + p0) = o;
    }
    __syncthreads();
    {
      int p = tid & 63, sb = tid >> 6;
      #pragma unroll
      for (int i = 0; i < 4; i++){
        int s0 = (sb + i*4)*8;            // 0..120
        bfx8 v;
        #pragma unroll
        for (int j = 0; j < 8; j++)
          v[j] = (short)pool[(s0 + j)*72 + p];
        *(bfx8*)(XdtT + p*264 + q*128 + s0) = v;
      }
    }
    __syncthreads();
  }

  // stripe loop: W fragments built in registers from global S
  const bf16* Srow = Sg + (size_t)bc*CHUNK*CHUNK + (size_t)(w*64)*CHUNK;
  float Dh = Dp[h];
  for (int j = 0; j <= w; j++){
    int s0 = j*64;
    bfx8 wfr[4][2];
    if (j < w){
      float m_ = Acs[s0 + 63];
      float rowf[4];
      #pragma unroll
      for (int m = 0; m < 4; m++)
        rowf[m] = expf(Acs[w*64 + m*16 + (lane&15)] - m_);
      #pragma unroll
      for (int kk = 0; kk < 2; kk++){
        float colf[8];
        #pragma unroll
        for (int t = 0; t < 8; t++)
          colf[t] = expf(m_ - Acs[s0 + kk*32 + (lane>>4)*8 + t]);
        #pragma unroll
        for (int m = 0; m < 4; m++){
          bfx8 raw = *(const bfx8*)(Srow + (size_t)(m*16 + (lane&15))*CHUNK + s0 + kk*32 + (lane>>4)*8);
          bfx8 o;
          #pragma unroll
          for (int t = 0; t < 8; t++)
            o[t] = (short)f2bits(bits2f((unsigned short)raw[t]) * rowf[m] * colf[t]);
          wfr[m][kk] = o;
        }
      }
    } else {
      // diagonal stripe: per-element exp (rowf would overflow), zero upper, +D/dt on diag
      #pragma unroll
      for (int kk = 0; kk < 2; kk++)
        #pragma unroll
        for (int m = 0; m < 4; m++){
          int lg = w*64 + m*16 + (lane&15);
          float Al = Acs[lg];
          bfx8 raw = *(const bfx8*)(Srow + (size_t)(m*16 + (lane&15))*CHUNK + s0 + kk*32 + (lane>>4)*8);
          bfx8 o;
          #pragma unroll
          for (int t = 0; t < 8; t++){
            int sg = s0 + kk*32 + (lane>>4)*8 + t;
            float v;
            if (sg > lg)       v = 0.f;
            else if (sg == lg) v = bits2f((unsigned short)raw[t]) + Dh/dts[lg];
            else               v = bits2f((unsigned short)raw[t]) * expf(Al - Acs[sg]);
            o[t] = (short)f2bits(v);
          }
          wfr[m][kk] = o;
        }
    }
    #pragma unroll
    for (int kk = 0; kk < 2; kk++){
      bfx8 bfr[4];
      #pragma unroll
      for (int n = 0; n < 4; n++)
        bfr[n] = *(const bfx8*)(XdtT + (n*16 + (lane&15))*264 + s0 + kk*32 + (lane>>4)*8);
      #pragma unroll
      for (int m = 0; m < 4; m++)
        #pragma unroll
        for (int n = 0; n < 4; n++)
          accY[m][n] = MFMA16(wfr[m][kk], bfr[n], accY[m][n]);
    }
  }
  // epilogue (y aliases x; all x reads completed before)
  bf16* yg = y + (size_t)(b*SEQ + c*CHUNK)*INTER + h*HDIM;
  #pragma unroll
  for (int m = 0; m < 4; m++)
    #pragma unroll
    for (int n = 0; n < 4; n++)
      #pragma unroll
      for (int r = 0; r < 4; r++)
        yg[(size_t)(w*64 + m*16 + (lane>>4)*4 + r)*INTER + n*16 + (lane&15)]
          = f2b(accY[m][n][r]);
}

// ---------------- gate + RMSNorm ----------------
__global__ __launch_bounds__(256) void gatenorm_kernel(bf16* __restrict__ y,
    const bf16* __restrict__ z, const float* __restrict__ nw){
  int row = blockIdx.x;
  const bf16* zr = z + (size_t)row*INTER;
  bf16* yr = y + (size_t)row*INTER;
  int tid = threadIdx.x;
  float g[8]; float ss = 0.f;
  #pragma unroll
  for (int i = 0; i < 8; i++){
    int idx = tid + i*256;
    float zv = b2f(zr[idx]);
    float gv = b2f(yr[idx]) * zv * sigmoidf_(zv);
    g[i] = gv; ss += gv*gv;
  }
  #pragma unroll
  for (int off = 32; off > 0; off >>= 1) ss += __shfl_down(ss, off);
  __shared__ float red[4];
  __shared__ float stot;
  int lane = tid & 63, wid = tid >> 6;
  if (lane == 0) red[wid] = ss;
  __syncthreads();
  if (tid == 0) stot = rsqrtf((red[0]+red[1]+red[2]+red[3]) * (1.f/INTER) + 1e-5f);
  __syncthreads();
  float sc = stot;
  #pragma unroll
  for (int i = 0; i < 8; i++){
    int idx = tid + i*256;
    yr[idx] = f2b(g[i]*sc*nw[idx]);
  }
}

extern "C" void kernel_launch(void* const* d_in, const int* in_sizes, int n_in,
                              void* d_out, int out_size, void* d_ws, size_t ws_size,
                              hipStream_t stream){
  const float* u    = (const float*)d_in[0];
  const float* w_in = (const float*)d_in[1];
  const float* cw   = (const float*)d_in[2];
  const float* cb   = (const float*)d_in[3];
  const float* dtb  = (const float*)d_in[4];
  const float* Alog = (const float*)d_in[5];
  const float* Dp   = (const float*)d_in[6];
  const float* nw   = (const float*)d_in[7];
  const float* w_out= (const float*)d_in[8];
  float* out = (float*)d_out;
  char* ws = (char*)d_ws;

  // layout (bytes)
  const size_t OFF_Z     = 0;              // bf16 [8192][2048]
  const size_t OFF_XBC   = 33554432;       // bf16 [8192][2304]; states f32 aliases after conv
  const size_t OFF_DT    = 67108864;       // f32 [8192][32]
  const size_t OFF_ACUM  = 68157440;       // f32 [2*32*16*256]
  const size_t OFF_X     = 71303168;       // bf16 [8192][2048]; y aliases
  const size_t OFF_UBF   = 104857600;      // bf16 u; XW_T aliases after inproj
  const size_t OFF_WINT  = 121634816;      // bf16 w_inT
  const size_t OFF_XWT   = 104857600;      // bf16 [2][2048][4096]
  const size_t OFF_BM    = 138412032;      // bf16 [8192][128]
  const size_t OFF_CM    = 140509184;      // bf16 [8192][128]
  const size_t OFF_DTRAW = 142606336;      // f32 [8192][32]
  const size_t OFF_BT    = 143654912;      // bf16 [2][128][4096]
  const size_t OFF_WOUTT = 145752064;      // bf16 [1024][2048]
  const size_t OFF_PART  = 149946368;      // f32 [8][8192][32]; S (bf16 [32][256][256]) aliases after dt_reduce
  const size_t NEED      = 158334976;

  if (ws_size < NEED){
    zero_out_kernel<<<(out_size + 255)/256, 256, 0, stream>>>(out, out_size);
    return;
  }

  bf16*  z      = (bf16*)(ws + OFF_Z);
  bf16*  xbc    = (bf16*)(ws + OFF_XBC);
  float* states = (float*)(ws + OFF_XBC);
  float* dt     = (float*)(ws + OFF_DT);
  float* Acum   = (float*)(ws + OFF_ACUM);
  bf16*  x      = (bf16*)(ws + OFF_X);
  bf16*  y      = (bf16*)(ws + OFF_X);
  bf16*  u_bf   = (bf16*)(ws + OFF_UBF);
  bf16*  w_inT  = (bf16*)(ws + OFF_WINT);
  bf16*  xwt    = (bf16*)(ws + OFF_XWT);
  bf16*  Bm     = (bf16*)(ws + OFF_BM);
  bf16*  Cm     = (bf16*)(ws + OFF_CM);
  float* dtraw  = (float*)(ws + OFF_DTRAW);
  bf16*  bt     = (bf16*)(ws + OFF_BT);
  bf16*  w_outT = (bf16*)(ws + OFF_WOUTT);
  float* part   = (float*)(ws + OFF_PART);
  bf16*  S      = (bf16*)(ws + OFF_PART);   // alias: part dead after dt_reduce

  bool use8 = true;
  if (hipFuncSetAttribute((const void*)gemm8_inproj,
        hipFuncAttributeMaxDynamicSharedMemorySize, 131072) != hipSuccess) use8 = false;
  if (hipFuncSetAttribute((const void*)gemm8_outproj,
        hipFuncAttributeMaxDynamicSharedMemorySize, 131072) != hipSuccess) use8 = false;

  // 0) prep
  castu_kernel<<<(ROWS*DMODEL/4)/256, 256, 0, stream>>>(u, (unsigned short*)u_bf);
  transcast_kernel<<<dim3(NGEMM/64, DMODEL/64), 256, 0, stream>>>(w_in, w_inT, DMODEL, PROJDIM, 0);
  // 1) projections
  if (use8)
    gemm8_inproj<<<544, 512, 131072, stream>>>(u_bf, w_inT, z, xbc);
  else
    gemm_mfma_inproj<<<dim3(NGEMM/128, ROWS/128), 256, 0, stream>>>(u_bf, w_inT, z, xbc);
  // 1b) dtraw via split-K fp32
  dt_partial<<<dim3(8, ROWS/64), 256, 0, stream>>>(u, w_in, part);
  dt_reduce<<<(ROWS*NHEADS)/256, 256, 0, stream>>>(part, dtraw);
  // 2) conv + silu + split
  conv_kernel<<<ROWS*9, 256, 0, stream>>>(xbc, cw, cb, x, Bm, Cm);
  // 2.5) head-shared scores (S overwrites part region)
  scores_mfma<<<dim3(B_SZ*NCHUNK, 4), 256, 0, stream>>>(Bm, Cm, S);
  // 3) dt softplus
  dt_kernel<<<ROWS*NHEADS/256, 256, 0, stream>>>(dtraw, dtb, dt);
  // 4) per-chunk cumsum of dt*A
  acum_kernel<<<B_SZ*NHEADS*NCHUNK, 256, 0, stream>>>(dt, Alog, Acum);
  // 4.5) weighted transpose XW_T + BT
  xwt_kernel<<<dim3(34, 64, 2), 256, 0, stream>>>(x, Bm, dt, Acum, xwt, bt);
  // 5) MFMA chunk-states
  chunk_states_mfma<<<B_SZ*NCHUNK*NHEADS, 256, 0, stream>>>(xwt, bt, states);
  // 6) inter-chunk scan
  scan_kernel<<<(B_SZ*NHEADS*HDIM*DSTATE)/256, 256, 0, stream>>>(states, Acum);
  // 7) fused MFMA Y (y aliases x; S from global)
  ydiag_mfma<<<B_SZ*NCHUNK*NHEADS, 256, 0, stream>>>(x, dt, Acum, S, Cm, states, Dp, y);
  // 7.5) prep out_proj weight
  transcast_kernel<<<dim3(DMODEL/64, INTER/64), 256, 0, stream>>>(w_out, w_outT, INTER, DMODEL, 0);
  // 8) gate + RMSNorm
  gatenorm_kernel<<<ROWS, 256, 0, stream>>>(y, z, nw);
  // 9) out_proj
  if (use8)
    gemm8_outproj<<<128, 512, 131072, stream>>>(y, w_outT, out);
  else
    gemm_mfma_outproj<<<dim3(DMODEL/128, ROWS/128), 256, 0, stream>>>(y, w_outT, out);
}

// Round 10
// 419.489 us; speedup vs baseline: 7.3591x; 1.0140x over previous
//
#include <hip/hip_runtime.h>
#include <hip/hip_bf16.h>

#define B_SZ 2
#define SEQ 4096
#define DMODEL 1024
#define INTER 2048
#define NHEADS 32
#define HDIM 64
#define DSTATE 128
#define DCONV 4
#define CONVDIM 2304
#define PROJDIM 4384
#define CHUNK 256
#define NCHUNK 16
#define ROWS (B_SZ*SEQ)   // 8192
#define NGEMM 4352        // z + xBC columns (17 tiles of 256)

typedef __hip_bfloat16 bf16;
typedef short bfx8 __attribute__((ext_vector_type(8)));
typedef float f32x4 __attribute__((ext_vector_type(4)));

__device__ __forceinline__ float sigmoidf_(float x){ return 1.f/(1.f+expf(-x)); }
__device__ __forceinline__ float b2f(bf16 v){ return __bfloat162float(v); }
__device__ __forceinline__ bf16 f2b(float v){ return __float2bfloat16(v); }
__device__ __forceinline__ float bits2f(unsigned short u){ return __uint_as_float(((unsigned)u) << 16); }
__device__ __forceinline__ unsigned short f2bits(float v){ bf16 t = __float2bfloat16(v); return *(unsigned short*)&t; }

#define MFMA16(a,b,c) __builtin_amdgcn_mfma_f32_16x16x32_bf16(a,b,c,0,0,0)

// ---------------- fallback: zero d_out ----------------
__global__ void zero_out_kernel(float* o, int n){
  int i = blockIdx.x*256 + threadIdx.x;
  if (i < n) o[i] = 0.f;
}

// ---------------- cast + transpose ----------------
__global__ __launch_bounds__(256) void transcast_kernel(const float* __restrict__ in,
    bf16* __restrict__ outT, int R, int ld, int coff){
  __shared__ float t[64][65];
  int r0 = blockIdx.y*64, c0 = blockIdx.x*64;
  int tid = threadIdx.x;
  #pragma unroll
  for (int i = 0; i < 16; i++){
    int idx = tid + i*256;
    int r = idx >> 6, c = idx & 63;
    t[r][c] = in[(size_t)(r0+r)*ld + coff + c0 + c];
  }
  __syncthreads();
  #pragma unroll
  for (int i = 0; i < 16; i++){
    int idx = tid + i*256;
    int c = idx >> 6, r = idx & 63;
    outT[(size_t)(c0+c)*R + r0 + r] = f2b(t[r][c]);
  }
}

// ================= 8-phase 256x256 MFMA GEMM (m201 template, T2+T3+T4+T5) =================
__device__ __forceinline__ void stage8(const bf16* __restrict__ g, int Kdim,
    int tile0, int k0, char* region, int h, int tid){
  #pragma unroll
  for (int l = 0; l < 2; l++){
    int o  = h*16384 + (l*512 + tid)*16;
    int os = o ^ (((o >> 7) & 7) << 4);
    const bf16* src = g + (size_t)(tile0 + (os >> 7))*Kdim + k0 + ((os & 127) >> 1);
    __builtin_amdgcn_global_load_lds(
      (const __attribute__((address_space(1))) void*)src,
      (__attribute__((address_space(3))) void*)(region + h*16384 + (l*512 + (tid >> 6)*64)*16),
      16, 0, 0);
  }
}
__device__ __forceinline__ bfx8 fr8(const char* region, int row, int colbyte){
  int o = row*128 + colbyte;
  o ^= ((row & 7) << 4);
  return *(const bfx8*)(region + o);
}

#define LGKM0  asm volatile("s_waitcnt lgkmcnt(0)" ::: "memory"); __builtin_amdgcn_sched_barrier(0)
#define VM4    asm volatile("s_waitcnt vmcnt(4)" ::: "memory")
#define VM0    asm volatile("s_waitcnt vmcnt(0)" ::: "memory")
#define BAR    __builtin_amdgcn_s_barrier()
#define PRIO1  __builtin_amdgcn_s_setprio(1)
#define PRIO0  __builtin_amdgcn_s_setprio(0)

#define MFMA_QUAD(MH, NH, BARR)                                                \
  PRIO1;                                                                       \
  _Pragma("unroll") for (int m = 0; m < 4; m++)                                \
    _Pragma("unroll") for (int n = 0; n < 2; n++)                              \
      _Pragma("unroll") for (int kk = 0; kk < 2; kk++)                         \
        acc[(MH)+m][(NH)+n] = MFMA16(aF[m][kk], BARR[n][kk], acc[(MH)+m][(NH)+n]); \
  PRIO0

// body ends after loop-final BAR with acc[8][4] ready; kernels append epilogues.
// last-iteration prefetches (dead wrapped tiles) are skipped; ph4 drains vmcnt(0)
// so LDS can be reused by the epilogue.
#define GEMM8_BODY(K_, NBX_)                                                   \
  extern __shared__ char lds[];                                                \
  char* A0 = lds;          char* B0 = lds + 32768;                             \
  char* A1 = lds + 65536;  char* B1 = lds + 98304;                             \
  const int tid = threadIdx.x, lane = tid & 63, wid = tid >> 6;                \
  const int wm = wid >> 2, wn = wid & 3;                                       \
  int nb = (blockIdx.x & 7)*((int)gridDim.x >> 3) + (blockIdx.x >> 3);         \
  const int bx = nb % (NBX_), by = nb / (NBX_);                                \
  const int row0 = by*256, col0 = bx*256;                                      \
  f32x4 acc[8][4] = {};                                                        \
  bfx8 aF[4][2], b01[2][2], b23[2][2];                                         \
  const int frow = lane & 15;                                                  \
  const int fcb0 = (lane >> 4)*16;                                             \
  const int JLAST = (K_)/128 - 1;                                              \
  stage8(Bt, K_, col0, 0,  B0, 0, tid);                                        \
  stage8(Bt, K_, col0, 0,  B0, 1, tid);                                        \
  stage8(A,  K_, row0, 0,  A0, 0, tid);                                        \
  stage8(A,  K_, row0, 0,  A0, 1, tid);                                        \
  stage8(Bt, K_, col0, 64, B1, 0, tid);                                        \
  stage8(Bt, K_, col0, 64, B1, 1, tid);                                        \
  VM4;                                                                         \
  BAR;                                                                         \
  _Pragma("unroll 1")                                                          \
  for (int j = 0; j <= JLAST; j++){                                            \
    const int kO  = j*128 + 64;                                                \
    const int kS1 = (j*128 + 128) & ((K_) - 1);                                \
    const int kS2 = (j*128 + 192) & ((K_) - 1);                                \
    stage8(A, K_, row0, kO, A1, 0, tid);                                       \
    _Pragma("unroll") for (int m = 0; m < 4; m++)                              \
      _Pragma("unroll") for (int kk = 0; kk < 2; kk++)                         \
        aF[m][kk] = fr8(A0, wm*128 + m*16 + frow, kk*64 + fcb0);               \
    _Pragma("unroll") for (int n = 0; n < 2; n++)                              \
      _Pragma("unroll") for (int kk = 0; kk < 2; kk++)                         \
        b01[n][kk] = fr8(B0, wn*64 + n*16 + frow, kk*64 + fcb0);               \
    LGKM0;                                                                     \
    MFMA_QUAD(0, 0, b01);                                                      \
    BAR;                                                                       \
    stage8(A, K_, row0, kO, A1, 1, tid);                                       \
    _Pragma("unroll") for (int n = 0; n < 2; n++)                              \
      _Pragma("unroll") for (int kk = 0; kk < 2; kk++)                         \
        b23[n][kk] = fr8(B0, wn*64 + (n+2)*16 + frow, kk*64 + fcb0);           \
    LGKM0;                                                                     \
    MFMA_QUAD(0, 2, b23);                                                      \
    BAR;                                                                       \
    if (j < JLAST) stage8(Bt, K_, col0, kS1, B0, 0, tid);                      \
    _Pragma("unroll") for (int m = 0; m < 4; m++)                              \
      _Pragma("unroll") for (int kk = 0; kk < 2; kk++)                         \
        aF[m][kk] = fr8(A0, wm*128 + (m+4)*16 + frow, kk*64 + fcb0);           \
    LGKM0;                                                                     \
    MFMA_QUAD(4, 0, b01);                                                      \
    BAR;                                                                       \
    if (j < JLAST){ stage8(Bt, K_, col0, kS1, B0, 1, tid); VM4; }              \
    else { VM0; }                                                              \
    MFMA_QUAD(4, 2, b23);                                                      \
    BAR;                                                                       \
    if (j < JLAST) stage8(A, K_, row0, kS1, A0, 0, tid);                       \
    _Pragma("unroll") for (int m = 0; m < 4; m++)                              \
      _Pragma("unroll") for (int kk = 0; kk < 2; kk++)                         \
        aF[m][kk] = fr8(A1, wm*128 + m*16 + frow, kk*64 + fcb0);               \
    _Pragma("unroll") for (int n = 0; n < 2; n++)                              \
      _Pragma("unroll") for (int kk = 0; kk < 2; kk++)                         \
        b01[n][kk] = fr8(B1, wn*64 + n*16 + frow, kk*64 + fcb0);               \
    LGKM0;                                                                     \
    MFMA_QUAD(0, 0, b01);                                                      \
    BAR;                                                                       \
    if (j < JLAST) stage8(A, K_, row0, kS1, A0, 1, tid);                       \
    _Pragma("unroll") for (int n = 0; n < 2; n++)                              \
      _Pragma("unroll") for (int kk = 0; kk < 2; kk++)                         \
        b23[n][kk] = fr8(B1, wn*64 + (n+2)*16 + frow, kk*64 + fcb0);           \
    LGKM0;                                                                     \
    MFMA_QUAD(0, 2, b23);                                                      \
    BAR;                                                                       \
    if (j < JLAST) stage8(Bt, K_, col0, kS2, B1, 0, tid);                      \
    _Pragma("unroll") for (int m = 0; m < 4; m++)                              \
      _Pragma("unroll") for (int kk = 0; kk < 2; kk++)                         \
        aF[m][kk] = fr8(A1, wm*128 + (m+4)*16 + frow, kk*64 + fcb0);           \
    LGKM0;                                                                     \
    MFMA_QUAD(4, 0, b01);                                                      \
    BAR;                                                                       \
    if (j < JLAST) stage8(Bt, K_, col0, kS2, B1, 1, tid);                      \
    VM4;                                                                       \
    MFMA_QUAD(4, 2, b23);                                                      \
    BAR;                                                                       \
  }

#define SST_STRIDE 280   // bf16 elems; 16B-aligned rows, 2-way LDS write alias (free)

__global__ __launch_bounds__(512, 2) void gemm8_inproj(const bf16* __restrict__ A,
    const bf16* __restrict__ Bt, bf16* __restrict__ z, bf16* __restrict__ xbc){
  GEMM8_BODY(DMODEL, 17)
  // LDS-staged coalesced epilogue: two half-tiles of 128 rows
  unsigned short* sst = (unsigned short*)lds;
  #pragma unroll 1
  for (int half = 0; half < 2; half++){
    if (wm == half){
      #pragma unroll
      for (int m = 0; m < 8; m++)
        #pragma unroll
        for (int n = 0; n < 4; n++)
          #pragma unroll
          for (int r = 0; r < 4; r++){
            int rl = m*16 + (lane>>4)*4 + r;          // 0..127
            sst[rl*SST_STRIDE + wn*64 + n*16 + (lane&15)] = f2bits(acc[m][n][r]);
          }
    }
    BAR;
    #pragma unroll
    for (int i = 0; i < 8; i++){
      int q = tid + i*512;                            // 4096 chunks of 8 elems
      int rl = q >> 5, c8 = (q & 31)*8;
      bfx8 v = *(const bfx8*)(sst + rl*SST_STRIDE + c8);
      int gr = row0 + half*128 + rl, gc = col0 + c8;
      if (gc < INTER) *(bfx8*)(z + (size_t)gr*INTER + gc) = v;
      else            *(bfx8*)(xbc + (size_t)gr*CONVDIM + (gc - INTER)) = v;
    }
    BAR;
  }
}
__global__ __launch_bounds__(512, 2) void gemm8_outproj(const bf16* __restrict__ A,
    const bf16* __restrict__ Bt, float* __restrict__ C){
  GEMM8_BODY(INTER, 4)
  #pragma unroll
  for (int m = 0; m < 8; m++){
    int row = row0 + wm*128 + m*16 + (lane >> 4)*4;
    #pragma unroll
    for (int n = 0; n < 4; n++){
      int col = col0 + wn*64 + n*16 + (lane & 15);
      #pragma unroll
      for (int r = 0; r < 4; r++)
        C[(size_t)(row + r)*DMODEL + col] = acc[m][n][r];
    }
  }
}

// ================= fallback m97-structure GEMMs =================
#define MFMA_GEMM_BODY(K_, EPILOGUE)                                           \
  __shared__ unsigned short As[128*64];                                        \
  __shared__ unsigned short Bs[128*64];                                        \
  const int tid = threadIdx.x;                                                 \
  const int lane = tid & 63, wid = tid >> 6;                                   \
  const int wm = wid >> 1, wn = wid & 1;                                       \
  const int row0 = blockIdx.y*128, col0 = blockIdx.x*128;                      \
  f32x4 acc[4][4] = {};                                                        \
  const int rstg = wid*32 + ((lane>>3)&7);                                     \
  const int kstg = (lane&7)*8;                                                 \
  for (int k0 = 0; k0 < (K_); k0 += 64){                                       \
    _Pragma("unroll")                                                          \
    for (int j = 0; j < 4; j++){                                               \
      const bf16* gA = A + (size_t)(row0 + rstg + j*8)*(K_) + k0 + kstg;       \
      __builtin_amdgcn_global_load_lds(                                        \
        (const __attribute__((address_space(1))) void*)gA,                     \
        (__attribute__((address_space(3))) void*)(As + (wid*32 + j*8)*64),     \
        16, 0, 0);                                                             \
      const bf16* gB = Bt + (size_t)(col0 + rstg + j*8)*(K_) + k0 + kstg;      \
      __builtin_amdgcn_global_load_lds(                                        \
        (const __attribute__((address_space(1))) void*)gB,                     \
        (__attribute__((address_space(3))) void*)(Bs + (wid*32 + j*8)*64),     \
        16, 0, 0);                                                             \
    }                                                                          \
    __syncthreads();                                                           \
    _Pragma("unroll")                                                          \
    for (int kk = 0; kk < 2; kk++){                                            \
      bfx8 af[4], bfr[4];                                                      \
      _Pragma("unroll")                                                        \
      for (int m = 0; m < 4; m++)                                              \
        af[m] = *(const bfx8*)(As + (wm*64 + m*16 + (lane&15))*64              \
                               + kk*32 + (lane>>4)*8);                         \
      _Pragma("unroll")                                                        \
      for (int n = 0; n < 4; n++)                                              \
        bfr[n] = *(const bfx8*)(Bs + (wn*64 + n*16 + (lane&15))*64             \
                                + kk*32 + (lane>>4)*8);                        \
      _Pragma("unroll")                                                        \
      for (int m = 0; m < 4; m++)                                              \
        _Pragma("unroll")                                                      \
        for (int n = 0; n < 4; n++)                                            \
          acc[m][n] = MFMA16(af[m], bfr[n], acc[m][n]);                        \
    }                                                                          \
    __syncthreads();                                                           \
  }                                                                            \
  _Pragma("unroll")                                                            \
  for (int m = 0; m < 4; m++){                                                 \
    int row = row0 + wm*64 + m*16 + (lane>>4)*4;                               \
    _Pragma("unroll")                                                          \
    for (int n = 0; n < 4; n++){                                               \
      int col = col0 + wn*64 + n*16 + (lane&15);                               \
      _Pragma("unroll")                                                        \
      for (int r = 0; r < 4; r++){                                             \
        float v = acc[m][n][r];                                                \
        int rr = row + r;                                                      \
        EPILOGUE                                                               \
      }                                                                        \
    }                                                                          \
  }

__global__ __launch_bounds__(256) void gemm_mfma_inproj(const bf16* __restrict__ A,
    const bf16* __restrict__ Bt, bf16* __restrict__ z, bf16* __restrict__ xbc){
  MFMA_GEMM_BODY(DMODEL,
    if (col < INTER) z[(size_t)rr*INTER + col] = f2b(v);
    else             xbc[(size_t)rr*CONVDIM + (col - INTER)] = f2b(v);
  )
}
__global__ __launch_bounds__(256) void gemm_mfma_outproj(const bf16* __restrict__ A,
    const bf16* __restrict__ Bt, float* __restrict__ C){
  MFMA_GEMM_BODY(INTER,
    C[(size_t)rr*DMODEL + col] = v;
  )
}

// ---------------- split-K fp32 dt GEMM + fused u->bf16 cast ----------------
__global__ __launch_bounds__(256) void dt_partial(const float* __restrict__ u,
    const float* __restrict__ w_in, float* __restrict__ partial,
    unsigned short* __restrict__ u_bf){
  __shared__ float wsm[128][33];
  __shared__ float us[64][133];
  int ks = blockIdx.x, row0 = blockIdx.y*64;
  int k0 = ks*128;
  int tid = threadIdx.x;
  #pragma unroll
  for (int i = 0; i < 16; i++){
    int idx = tid + i*256;
    int r = idx >> 5, c = idx & 31;
    wsm[r][c] = w_in[(size_t)(k0 + r)*PROJDIM + NGEMM + c];
  }
  #pragma unroll
  for (int i = 0; i < 8; i++){
    int idx = tid + i*256;
    int r = idx >> 5, c4 = idx & 31;
    float4 v = *(const float4*)(u + (size_t)(row0 + r)*DMODEL + k0 + c4*4);
    us[r][c4*4+0] = v.x; us[r][c4*4+1] = v.y; us[r][c4*4+2] = v.z; us[r][c4*4+3] = v.w;
    ushort4 w;
    w.x = f2bits(v.x); w.y = f2bits(v.y); w.z = f2bits(v.z); w.w = f2bits(v.w);
    *(ushort4*)(u_bf + (size_t)(row0 + r)*DMODEL + k0 + c4*4) = w;
  }
  __syncthreads();
  int col = tid & 31, r0 = tid >> 5;
  float acc[8] = {};
  #pragma unroll 4
  for (int kk4 = 0; kk4 < 32; kk4++){
    float4 uv[8];
    #pragma unroll
    for (int i = 0; i < 8; i++)
      uv[i] = *(const float4*)&us[r0 + i*8][kk4*4];
    #pragma unroll
    for (int j = 0; j < 4; j++){
      float wv = wsm[kk4*4 + j][col];
      #pragma unroll
      for (int i = 0; i < 8; i++){
        float uvj = (j == 0) ? uv[i].x : (j == 1) ? uv[i].y : (j == 2) ? uv[i].z : uv[i].w;
        acc[i] = fmaf(uvj, wv, acc[i]);
      }
    }
  }
  #pragma unroll
  for (int i = 0; i < 8; i++)
    partial[((size_t)ks*ROWS + row0 + r0 + i*8)*NHEADS + col] = acc[i];
}

// ---------------- conv1d + silu + split ----------------
__global__ __launch_bounds__(256) void conv_kernel(const bf16* __restrict__ xbc,
    const float* __restrict__ cw, const float* __restrict__ cb,
    bf16* __restrict__ x, bf16* __restrict__ Bm, bf16* __restrict__ Cm){
  int bt = blockIdx.x / 9;
  int ch = (blockIdx.x % 9)*256 + threadIdx.x;
  int t = bt & (SEQ-1);
  float acc = cb[ch];
  #pragma unroll
  for (int i = 0; i < 4; i++){
    int tt = t - 3 + i;
    if (tt >= 0)
      acc = fmaf(b2f(xbc[(size_t)(bt - t + tt)*CONVDIM + ch]), cw[ch*4+i], acc);
  }
  float v = acc * sigmoidf_(acc);
  if (ch < INTER)              x[(size_t)bt*INTER + ch] = f2b(v);
  else if (ch < INTER+DSTATE)  Bm[(size_t)bt*DSTATE + (ch-INTER)] = f2b(v);
  else                         Cm[(size_t)bt*DSTATE + (ch-INTER-DSTATE)] = f2b(v);
}

// ---------------- fused: 8-way reduce + bias + softplus -> dt; cumsum(dt*A) -> Acum ----------------
// NOTE: dt/Acum alias the xbc TAIL — this kernel MUST launch after conv_kernel.
__global__ __launch_bounds__(256) void acum_fused(const float* __restrict__ partial,
    const float* __restrict__ dt_bias, const float* __restrict__ A_log,
    float* __restrict__ dt, float* __restrict__ Acum){
  int bi = blockIdx.x;            // (b*NHEADS+h)*NCHUNK + c
  int c = bi & 15; int h = (bi >> 4) & 31; int b = bi >> 9;
  int l = threadIdx.x;
  __shared__ float sbuf[CHUNK];
  int t = c*CHUNK + l;
  size_t idx = (size_t)(b*SEQ + t)*NHEADS + h;
  float s = dt_bias[h];
  #pragma unroll
  for (int ks = 0; ks < 8; ks++)
    s += partial[(size_t)ks*ROWS*NHEADS + idx];
  float v = (s > 20.f) ? s : log1pf(expf(s));
  dt[idx] = v;
  float A = -expf(A_log[h]);
  sbuf[l] = v * A;
  __syncthreads();
  for (int off = 1; off < CHUNK; off <<= 1){
    float add = (l >= off) ? sbuf[l-off] : 0.f;
    __syncthreads();
    sbuf[l] += add;
    __syncthreads();
  }
  Acum[(size_t)bi*CHUNK + l] = sbuf[l];
}

// ---------------- head-shared scores (dense task list): S[bc][l][s] = C·B^T ----------------
__global__ __launch_bounds__(256) void scores_mfma(const bf16* __restrict__ Bm,
    const bf16* __restrict__ Cm, bf16* __restrict__ S){
  int bc = blockIdx.x;
  int b = bc >> 4, c = bc & 15;
  int tid = threadIdx.x, lane = tid & 63;
  int task = blockIdx.y*4 + (tid >> 6);
  if (task >= 10) return;
  int rb = (task >= 6) ? 3 : (task >= 3) ? 2 : (task >= 1) ? 1 : 0;
  int j = task - rb*(rb+1)/2;
  const bf16* Crow = Cm + (size_t)(b*SEQ + c*CHUNK)*DSTATE;
  const bf16* Brow = Bm + (size_t)(b*SEQ + c*CHUNK)*DSTATE;
  f32x4 acc[4][4] = {};
  #pragma unroll
  for (int kk = 0; kk < 4; kk++){
    bfx8 af[4], bfr[4];
    #pragma unroll
    for (int m = 0; m < 4; m++)
      af[m] = *(const bfx8*)(Crow + (size_t)(rb*64 + m*16 + (lane&15))*DSTATE + kk*32 + (lane>>4)*8);
    #pragma unroll
    for (int n = 0; n < 4; n++)
      bfr[n] = *(const bfx8*)(Brow + (size_t)(j*64 + n*16 + (lane&15))*DSTATE + kk*32 + (lane>>4)*8);
    #pragma unroll
    for (int m = 0; m < 4; m++)
      #pragma unroll
      for (int n = 0; n < 4; n++)
        acc[m][n] = MFMA16(af[m], bfr[n], acc[m][n]);
  }
  bf16* dst = S + (size_t)bc*CHUNK*CHUNK;
  #pragma unroll
  for (int m = 0; m < 4; m++)
    #pragma unroll
    for (int n = 0; n < 4; n++)
      #pragma unroll
      for (int r = 0; r < 4; r++)
        dst[(size_t)(rb*64 + m*16 + (lane>>4)*4 + r)*CHUNK + j*64 + n*16 + (lane&15)]
          = f2b(acc[m][n][r]);
}

// ---------------- build XW_T + BT ----------------
__global__ __launch_bounds__(256) void xwt_kernel(const bf16* __restrict__ x,
    const bf16* __restrict__ Bm, const float* __restrict__ dt,
    const float* __restrict__ Acum, bf16* __restrict__ xwt, bf16* __restrict__ bt){
  int pt = blockIdx.x, tt = blockIdx.y, b = blockIdx.z;
  int tid = threadIdx.x;
  __shared__ unsigned short tile[64][72];
  __shared__ float wf[64];
  int t0 = tt*64;
  if (pt < 32){
    int h = pt, c = t0 >> 8;
    if (tid < 64){
      const float* AcB = Acum + ((size_t)(b*NHEADS + h)*NCHUNK + c)*CHUNK;
      int t = t0 + tid;
      wf[tid] = dt[(size_t)(b*SEQ + t)*NHEADS + h] * expf(AcB[255] - AcB[t & 255]);
    }
    __syncthreads();
    const bf16* src = x + (size_t)(b*SEQ + t0)*INTER + pt*64;
    #pragma unroll
    for (int i = 0; i < 2; i++){
      int u = tid + i*256;
      int r = u >> 3, po = (u & 7)*8;
      bfx8 v = *(const bfx8*)(src + (size_t)r*INTER + po);
      float d = wf[r];
      #pragma unroll
      for (int j = 0; j < 8; j++)
        tile[r][po + j] = f2bits(bits2f((unsigned short)v[j]) * d);
    }
    __syncthreads();
    bf16* dst = xwt + ((size_t)(b*INTER) + pt*64)*SEQ + t0;
    #pragma unroll
    for (int i = 0; i < 2; i++){
      int u = tid + i*256;
      int p = u >> 3, tc = (u & 7)*8;
      bfx8 v;
      #pragma unroll
      for (int j = 0; j < 8; j++) v[j] = (short)tile[tc + j][p];
      *(bfx8*)(dst + (size_t)p*SEQ + tc) = v;
    }
  } else {
    int n0 = (pt - 32)*64;
    const bf16* src = Bm + (size_t)(b*SEQ + t0)*DSTATE + n0;
    #pragma unroll
    for (int i = 0; i < 2; i++){
      int u = tid + i*256;
      int r = u >> 3, po = (u & 7)*8;
      bfx8 v = *(const bfx8*)(src + (size_t)r*DSTATE + po);
      *(bfx8*)&tile[r][po] = v;
    }
    __syncthreads();
    bf16* dst = bt + ((size_t)(b*DSTATE) + n0)*SEQ + t0;
    #pragma unroll
    for (int i = 0; i < 2; i++){
      int u = tid + i*256;
      int p = u >> 3, tc = (u & 7)*8;
      bfx8 v;
      #pragma unroll
      for (int j = 0; j < 8; j++) v[j] = (short)tile[tc + j][p];
      *(bfx8*)(dst + (size_t)p*SEQ + tc) = v;
    }
  }
}

// ---------------- MFMA chunk-states ----------------
__global__ __launch_bounds__(256) void chunk_states_mfma(const bf16* __restrict__ xwt,
    const bf16* __restrict__ bt, float* __restrict__ states){
  int bi = blockIdx.x;            // (b*NCHUNK+c)*NHEADS + h
  int h = bi & 31; int c = (bi >> 5) & 15; int b = bi >> 9;
  int tid = threadIdx.x, lane = tid & 63, w = tid >> 6;
  int wm = w >> 1, wn = w & 1;
  const bf16* Arow = xwt + ((size_t)(b*INTER) + h*64)*SEQ + c*CHUNK;
  const bf16* Brow = bt + (size_t)(b*DSTATE)*SEQ + c*CHUNK;
  f32x4 acc[2][4] = {};
  #pragma unroll
  for (int kk = 0; kk < 8; kk++){
    bfx8 af[2], bfr[4];
    #pragma unroll
    for (int m = 0; m < 2; m++)
      af[m] = *(const bfx8*)(Arow + (size_t)(wm*32 + m*16 + (lane&15))*SEQ + kk*32 + (lane>>4)*8);
    #pragma unroll
    for (int n = 0; n < 4; n++)
      bfr[n] = *(const bfx8*)(Brow + (size_t)(wn*64 + n*16 + (lane&15))*SEQ + kk*32 + (lane>>4)*8);
    #pragma unroll
    for (int m = 0; m < 2; m++)
      #pragma unroll
      for (int n = 0; n < 4; n++)
        acc[m][n] = MFMA16(af[m], bfr[n], acc[m][n]);
  }
  float* dst = states + (size_t)bi*HDIM*DSTATE;
  #pragma unroll
  for (int m = 0; m < 2; m++)
    #pragma unroll
    for (int n = 0; n < 4; n++)
      #pragma unroll
      for (int r = 0; r < 4; r++){
        int p = wm*32 + m*16 + (lane>>4)*4 + r;
        int nn = wn*64 + n*16 + (lane&15);
        dst[(size_t)p*DSTATE + nn] = acc[m][n][r];
      }
}

// ---------------- inter-chunk scan ----------------
__global__ __launch_bounds__(256) void scan_kernel(float* __restrict__ states,
    const float* __restrict__ Acum){
  int idx = blockIdx.x*256 + threadIdx.x;
  int n = idx & 127; int p = (idx >> 7) & 63; int h = (idx >> 13) & 31; int b = idx >> 18;
  float R = 0.f;
  for (int c = 0; c < NCHUNK; c++){
    size_t o = (((size_t)((b*NCHUNK + c)*NHEADS + h))*HDIM + p)*DSTATE + n;
    float s = states[o];
    states[o] = R;
    float dA = expf(Acum[((size_t)(b*NHEADS + h)*NCHUNK + c)*CHUNK + CHUNK-1]);
    R = R*dA + s;
  }
}

// ================= fused MFMA Y kernel (S from global, in-register transform) =================
__global__ __launch_bounds__(256, 3) void ydiag_mfma(
    const bf16* x, const float* __restrict__ dt,
    const float* __restrict__ Acum, const bf16* __restrict__ Sg,
    const bf16* __restrict__ Cm, const float* __restrict__ states,
    const float* __restrict__ Dp, bf16* y){
  int bi = blockIdx.x;            // (b*NCHUNK+c)*NHEADS + h
  int h = bi & 31; int c = (bi >> 5) & 15; int b = bi >> 9;
  int bc = b*NCHUNK + c;
  int tid = threadIdx.x, lane = tid & 63, w = tid >> 6;

  __shared__ unsigned short XdtT[64*264];
  __shared__ unsigned short pool[128*72];
  __shared__ float Acs[CHUNK];
  __shared__ float dts[CHUNK];

  const float* AcBase = Acum + ((size_t)(b*NHEADS + h)*NCHUNK + c)*CHUNK;
  Acs[tid] = AcBase[tid];
  dts[tid] = dt[(size_t)(b*SEQ + c*CHUNK + tid)*NHEADS + h];
  {
    const float* src = states + (size_t)bi*HDIM*DSTATE;
    #pragma unroll
    for (int i = 0; i < 32; i++){
      int idx = tid + i*256;
      int p = idx >> 7, n = idx & 127;
      pool[p*136 + n] = f2bits(src[idx]);
    }
  }
  __syncthreads();

  const bf16* Crow = Cm + (size_t)(b*SEQ + c*CHUNK)*DSTATE;

  f32x4 accY[4][4] = {};
  #pragma unroll
  for (int kk = 0; kk < 4; kk++){
    bfx8 af[4], bfr[4];
    #pragma unroll
    for (int m = 0; m < 4; m++)
      af[m] = *(const bfx8*)(Crow + (size_t)(w*64 + m*16 + (lane&15))*DSTATE + kk*32 + (lane>>4)*8);
    #pragma unroll
    for (int n = 0; n < 4; n++)
      bfr[n] = *(const bfx8*)(pool + (n*16 + (lane&15))*136 + kk*32 + (lane>>4)*8);
    #pragma unroll
    for (int m = 0; m < 4; m++)
      #pragma unroll
      for (int n = 0; n < 4; n++)
        accY[m][n] = MFMA16(af[m], bfr[n], accY[m][n]);
  }
  {
    float eAl[4][4];
    #pragma unroll
    for (int m = 0; m < 4; m++)
      #pragma unroll
      for (int r = 0; r < 4; r++)
        eAl[m][r] = expf(Acs[w*64 + m*16 + (lane>>4)*4 + r]);
    #pragma unroll
    for (int m = 0; m < 4; m++)
      #pragma unroll
      for (int n = 0; n < 4; n++)
        #pragma unroll
        for (int r = 0; r < 4; r++)
          accY[m][n][r] *= eAl[m][r];
  }
  __syncthreads();

  #pragma unroll 1
  for (int q = 0; q < 2; q++){
    const bf16* xg = x + (size_t)(b*SEQ + c*CHUNK + q*128)*INTER + h*HDIM;
    #pragma unroll
    for (int i = 0; i < 4; i++){
      int u = tid + i*256;
      int s = u >> 3, p0 = (u & 7)*8;
      bfx8 v = *(const bfx8*)(xg + (size_t)s*INTER + p0);
      float d = dts[q*128 + s];
      bfx8 o;
      #pragma unroll
      for (int j = 0; j < 8; j++)
        o[j] = (short)f2bits(bits2f((unsigned short)v[j]) * d);
      *(bfx8*)(pool + s*72 + p0) = o;
    }
    __syncthreads();
    {
      int p = tid & 63, sb = tid >> 6;
      #pragma unroll
      for (int i = 0; i < 4; i++){
        int s0 = (sb + i*4)*8;
        bfx8 v;
        #pragma unroll
        for (int j = 0; j < 8; j++)
          v[j] = (short)pool[(s0 + j)*72 + p];
        *(bfx8*)(XdtT + p*264 + q*128 + s0) = v;
      }
    }
    __syncthreads();
  }

  const bf16* Srow = Sg + (size_t)bc*CHUNK*CHUNK + (size_t)(w*64)*CHUNK;
  float Dh = Dp[h];
  for (int j = 0; j <= w; j++){
    int s0 = j*64;
    bfx8 wfr[4][2];
    if (j < w){
      float m_ = Acs[s0 + 63];
      float rowf[4];
      #pragma unroll
      for (int m = 0; m < 4; m++)
        rowf[m] = expf(Acs[w*64 + m*16 + (lane&15)] - m_);
      #pragma unroll
      for (int kk = 0; kk < 2; kk++){
        float colf[8];
        #pragma unroll
        for (int t = 0; t < 8; t++)
          colf[t] = expf(m_ - Acs[s0 + kk*32 + (lane>>4)*8 + t]);
        #pragma unroll
        for (int m = 0; m < 4; m++){
          bfx8 raw = *(const bfx8*)(Srow + (size_t)(m*16 + (lane&15))*CHUNK + s0 + kk*32 + (lane>>4)*8);
          bfx8 o;
          #pragma unroll
          for (int t = 0; t < 8; t++)
            o[t] = (short)f2bits(bits2f((unsigned short)raw[t]) * rowf[m] * colf[t]);
          wfr[m][kk] = o;
        }
      }
    } else {
      #pragma unroll
      for (int kk = 0; kk < 2; kk++)
        #pragma unroll
        for (int m = 0; m < 4; m++){
          int lg = w*64 + m*16 + (lane&15);
          float Al = Acs[lg];
          bfx8 raw = *(const bfx8*)(Srow + (size_t)(m*16 + (lane&15))*CHUNK + s0 + kk*32 + (lane>>4)*8);
          bfx8 o;
          #pragma unroll
          for (int t = 0; t < 8; t++){
            int sg = s0 + kk*32 + (lane>>4)*8 + t;
            float v;
            if (sg > lg)       v = 0.f;
            else if (sg == lg) v = bits2f((unsigned short)raw[t]) + Dh/dts[lg];
            else               v = bits2f((unsigned short)raw[t]) * expf(Al - Acs[sg]);
            o[t] = (short)f2bits(v);
          }
          wfr[m][kk] = o;
        }
    }
    #pragma unroll
    for (int kk = 0; kk < 2; kk++){
      bfx8 bfr[4];
      #pragma unroll
      for (int n = 0; n < 4; n++)
        bfr[n] = *(const bfx8*)(XdtT + (n*16 + (lane&15))*264 + s0 + kk*32 + (lane>>4)*8);
      #pragma unroll
      for (int m = 0; m < 4; m++)
        #pragma unroll
        for (int n = 0; n < 4; n++)
          accY[m][n] = MFMA16(wfr[m][kk], bfr[n], accY[m][n]);
    }
  }
  bf16* yg = y + (size_t)(b*SEQ + c*CHUNK)*INTER + h*HDIM;
  #pragma unroll
  for (int m = 0; m < 4; m++)
    #pragma unroll
    for (int n = 0; n < 4; n++)
      #pragma unroll
      for (int r = 0; r < 4; r++)
        yg[(size_t)(w*64 + m*16 + (lane>>4)*4 + r)*INTER + n*16 + (lane&15)]
          = f2b(accY[m][n][r]);
}

// ---------------- gate + RMSNorm ----------------
__global__ __launch_bounds__(256) void gatenorm_kernel(bf16* __restrict__ y,
    const bf16* __restrict__ z, const float* __restrict__ nw){
  int row = blockIdx.x;
  const bf16* zr = z + (size_t)row*INTER;
  bf16* yr = y + (size_t)row*INTER;
  int tid = threadIdx.x;
  float g[8]; float ss = 0.f;
  #pragma unroll
  for (int i = 0; i < 8; i++){
    int idx = tid + i*256;
    float zv = b2f(zr[idx]);
    float gv = b2f(yr[idx]) * zv * sigmoidf_(zv);
    g[i] = gv; ss += gv*gv;
  }
  #pragma unroll
  for (int off = 32; off > 0; off >>= 1) ss += __shfl_down(ss, off);
  __shared__ float red[4];
  __shared__ float stot;
  int lane = tid & 63, wid = tid >> 6;
  if (lane == 0) red[wid] = ss;
  __syncthreads();
  if (tid == 0) stot = rsqrtf((red[0]+red[1]+red[2]+red[3]) * (1.f/INTER) + 1e-5f);
  __syncthreads();
  float sc = stot;
  #pragma unroll
  for (int i = 0; i < 8; i++){
    int idx = tid + i*256;
    yr[idx] = f2b(g[i]*sc*nw[idx]);
  }
}

extern "C" void kernel_launch(void* const* d_in, const int* in_sizes, int n_in,
                              void* d_out, int out_size, void* d_ws, size_t ws_size,
                              hipStream_t stream){
  const float* u    = (const float*)d_in[0];
  const float* w_in = (const float*)d_in[1];
  const float* cw   = (const float*)d_in[2];
  const float* cb   = (const float*)d_in[3];
  const float* dtb  = (const float*)d_in[4];
  const float* Alog = (const float*)d_in[5];
  const float* Dp   = (const float*)d_in[6];
  const float* nw   = (const float*)d_in[7];
  const float* w_out= (const float*)d_in[8];
  float* out = (float*)d_out;
  char* ws = (char*)d_ws;

  // layout (bytes)
  const size_t OFF_Z     = 0;              // bf16 [8192][2048]
  const size_t OFF_XBC   = 33554432;       // bf16 [8192][2304]; states f32 aliases after conv
  const size_t OFF_DT    = 67108864;       // f32 [8192][32]  (xbc TAIL — write only after conv!)
  const size_t OFF_ACUM  = 68157440;       // f32 [2*32*16*256] (xbc TAIL — write only after conv!)
  const size_t OFF_X     = 71303168;       // bf16 [8192][2048]; y aliases
  const size_t OFF_UBF   = 104857600;      // bf16 u; XW_T aliases after inproj
  const size_t OFF_WINT  = 121634816;      // bf16 w_inT
  const size_t OFF_XWT   = 104857600;      // bf16 [2][2048][4096]
  const size_t OFF_BM    = 138412032;      // bf16 [8192][128]
  const size_t OFF_CM    = 140509184;      // bf16 [8192][128]
  const size_t OFF_BT    = 143654912;      // bf16 [2][128][4096]
  const size_t OFF_WOUTT = 145752064;      // bf16 [1024][2048]
  const size_t OFF_PART  = 149946368;      // f32 [8][8192][32]; S (bf16 [32][256][256]) aliases after acum_fused
  const size_t NEED      = 158334976;

  if (ws_size < NEED){
    zero_out_kernel<<<(out_size + 255)/256, 256, 0, stream>>>(out, out_size);
    return;
  }

  bf16*  z      = (bf16*)(ws + OFF_Z);
  bf16*  xbc    = (bf16*)(ws + OFF_XBC);
  float* states = (float*)(ws + OFF_XBC);
  float* dt     = (float*)(ws + OFF_DT);
  float* Acum   = (float*)(ws + OFF_ACUM);
  bf16*  x      = (bf16*)(ws + OFF_X);
  bf16*  y      = (bf16*)(ws + OFF_X);
  bf16*  u_bf   = (bf16*)(ws + OFF_UBF);
  bf16*  w_inT  = (bf16*)(ws + OFF_WINT);
  bf16*  xwt    = (bf16*)(ws + OFF_XWT);
  bf16*  Bm     = (bf16*)(ws + OFF_BM);
  bf16*  Cm     = (bf16*)(ws + OFF_CM);
  bf16*  bt     = (bf16*)(ws + OFF_BT);
  bf16*  w_outT = (bf16*)(ws + OFF_WOUTT);
  float* part   = (float*)(ws + OFF_PART);
  bf16*  S      = (bf16*)(ws + OFF_PART);   // alias: part dead after acum_fused

  bool use8 = true;
  if (hipFuncSetAttribute((const void*)gemm8_inproj,
        hipFuncAttributeMaxDynamicSharedMemorySize, 131072) != hipSuccess) use8 = false;
  if (hipFuncSetAttribute((const void*)gemm8_outproj,
        hipFuncAttributeMaxDynamicSharedMemorySize, 131072) != hipSuccess) use8 = false;

  // 1) split-K dt partials + fused u->bf16 cast
  dt_partial<<<dim3(8, ROWS/64), 256, 0, stream>>>(u, w_in, part, (unsigned short*)u_bf);
  // 2) w_in transpose/cast
  transcast_kernel<<<dim3(NGEMM/64, DMODEL/64), 256, 0, stream>>>(w_in, w_inT, DMODEL, PROJDIM, 0);
  // 3) inproj GEMM
  if (use8)
    gemm8_inproj<<<544, 512, 131072, stream>>>(u_bf, w_inT, z, xbc);
  else
    gemm_mfma_inproj<<<dim3(NGEMM/128, ROWS/128), 256, 0, stream>>>(u_bf, w_inT, z, xbc);
  // 4) conv + silu + split  (MUST precede acum_fused: dt/Acum alias the xbc tail)
  conv_kernel<<<ROWS*9, 256, 0, stream>>>(xbc, cw, cb, x, Bm, Cm);
  // 5) fused reduce+softplus -> dt, cumsum -> Acum (xbc now dead)
  acum_fused<<<B_SZ*NHEADS*NCHUNK, 256, 0, stream>>>(part, dtb, Alog, dt, Acum);
  // 6) head-shared scores (S overwrites part region)
  scores_mfma<<<dim3(B_SZ*NCHUNK, 3), 256, 0, stream>>>(Bm, Cm, S);
  // 7) weighted transpose XW_T + BT
  xwt_kernel<<<dim3(34, 64, 2), 256, 0, stream>>>(x, Bm, dt, Acum, xwt, bt);
  // 8) MFMA chunk-states
  chunk_states_mfma<<<B_SZ*NCHUNK*NHEADS, 256, 0, stream>>>(xwt, bt, states);
  // 9) inter-chunk scan
  scan_kernel<<<(B_SZ*NHEADS*HDIM*DSTATE)/256, 256, 0, stream>>>(states, Acum);
  // 10) fused MFMA Y (y aliases x; S from global)
  ydiag_mfma<<<B_SZ*NCHUNK*NHEADS, 256, 0, stream>>>(x, dt, Acum, S, Cm, states, Dp, y);
  // 11) prep out_proj weight
  transcast_kernel<<<dim3(DMODEL/64, INTER/64), 256, 0, stream>>>(w_out, w_outT, INTER, DMODEL, 0);
  // 12) gate + RMSNorm
  gatenorm_kernel<<<ROWS, 256, 0, stream>>>(y, z, nw);
  // 13) out_proj
  if (use8)
    gemm8_outproj<<<128, 512, 131072, stream>>>(y, w_outT, out);
  else
    gemm_mfma_outproj<<<dim3(DMODEL/128, ROWS/128), 256, 0, stream>>>(y, w_outT, out);
}

// Round 11
// 410.352 us; speedup vs baseline: 7.5230x; 1.0223x over previous
//
#include <hip/hip_runtime.h>
#include <hip/hip_bf16.h>

#define B_SZ 2
#define SEQ 4096
#define DMODEL 1024
#define INTER 2048
#define NHEADS 32
#define HDIM 64
#define DSTATE 128
#define DCONV 4
#define CONVDIM 2304
#define PROJDIM 4384
#define CHUNK 256
#define NCHUNK 16
#define ROWS (B_SZ*SEQ)   // 8192
#define NGEMM 4352        // z + xBC columns (17 tiles of 256)

typedef __hip_bfloat16 bf16;
typedef short bfx8 __attribute__((ext_vector_type(8)));
typedef float f32x4 __attribute__((ext_vector_type(4)));

__device__ __forceinline__ float sigmoidf_(float x){ return 1.f/(1.f+expf(-x)); }
__device__ __forceinline__ float b2f(bf16 v){ return __bfloat162float(v); }
__device__ __forceinline__ bf16 f2b(float v){ return __float2bfloat16(v); }
__device__ __forceinline__ float bits2f(unsigned short u){ return __uint_as_float(((unsigned)u) << 16); }
__device__ __forceinline__ unsigned short f2bits(float v){ bf16 t = __float2bfloat16(v); return *(unsigned short*)&t; }

#define MFMA16(a,b,c) __builtin_amdgcn_mfma_f32_16x16x32_bf16(a,b,c,0,0,0)

// ---------------- fallback: zero d_out ----------------
__global__ void zero_out_kernel(float* o, int n){
  int i = blockIdx.x*256 + threadIdx.x;
  if (i < n) o[i] = 0.f;
}

// ---------------- cast + transpose ----------------
__global__ __launch_bounds__(256) void transcast_kernel(const float* __restrict__ in,
    bf16* __restrict__ outT, int R, int ld, int coff){
  __shared__ float t[64][65];
  int r0 = blockIdx.y*64, c0 = blockIdx.x*64;
  int tid = threadIdx.x;
  #pragma unroll
  for (int i = 0; i < 16; i++){
    int idx = tid + i*256;
    int r = idx >> 6, c = idx & 63;
    t[r][c] = in[(size_t)(r0+r)*ld + coff + c0 + c];
  }
  __syncthreads();
  #pragma unroll
  for (int i = 0; i < 16; i++){
    int idx = tid + i*256;
    int c = idx >> 6, r = idx & 63;
    outT[(size_t)(c0+c)*R + r0 + r] = f2b(t[r][c]);
  }
}

// ================= 8-phase 256x256 MFMA GEMM (m201 template, T2+T3+T4+T5) =================
__device__ __forceinline__ void stage8(const bf16* __restrict__ g, int Kdim,
    int tile0, int k0, char* region, int h, int tid){
  #pragma unroll
  for (int l = 0; l < 2; l++){
    int o  = h*16384 + (l*512 + tid)*16;
    int os = o ^ (((o >> 7) & 7) << 4);
    const bf16* src = g + (size_t)(tile0 + (os >> 7))*Kdim + k0 + ((os & 127) >> 1);
    __builtin_amdgcn_global_load_lds(
      (const __attribute__((address_space(1))) void*)src,
      (__attribute__((address_space(3))) void*)(region + h*16384 + (l*512 + (tid >> 6)*64)*16),
      16, 0, 0);
  }
}
__device__ __forceinline__ bfx8 fr8(const char* region, int row, int colbyte){
  int o = row*128 + colbyte;
  o ^= ((row & 7) << 4);
  return *(const bfx8*)(region + o);
}

#define LGKM0  asm volatile("s_waitcnt lgkmcnt(0)" ::: "memory"); __builtin_amdgcn_sched_barrier(0)
#define VM4    asm volatile("s_waitcnt vmcnt(4)" ::: "memory")
#define VM0    asm volatile("s_waitcnt vmcnt(0)" ::: "memory")
#define BAR    __builtin_amdgcn_s_barrier()
#define PRIO1  __builtin_amdgcn_s_setprio(1)
#define PRIO0  __builtin_amdgcn_s_setprio(0)

#define MFMA_QUAD(MH, NH, BARR)                                                \
  PRIO1;                                                                       \
  _Pragma("unroll") for (int m = 0; m < 4; m++)                                \
    _Pragma("unroll") for (int n = 0; n < 2; n++)                              \
      _Pragma("unroll") for (int kk = 0; kk < 2; kk++)                         \
        acc[(MH)+m][(NH)+n] = MFMA16(aF[m][kk], BARR[n][kk], acc[(MH)+m][(NH)+n]); \
  PRIO0

// tile->block mapping: per-XCD COLUMN-MAJOR (t = xcd*perXcd + i; by = t%NBY, bx = t/NBY)
// so each XCD's B-tile footprint is 2-3 column tiles (~1.2 MB, L2-resident).
#define GEMM8_BODY(K_, NBY_)                                                   \
  extern __shared__ char lds[];                                                \
  char* A0 = lds;          char* B0 = lds + 32768;                             \
  char* A1 = lds + 65536;  char* B1 = lds + 98304;                             \
  const int tid = threadIdx.x, lane = tid & 63, wid = tid >> 6;                \
  const int wm = wid >> 2, wn = wid & 3;                                       \
  int nb = (blockIdx.x & 7)*((int)gridDim.x >> 3) + (blockIdx.x >> 3);         \
  const int by = nb % (NBY_), bx = nb / (NBY_);                                \
  const int row0 = by*256, col0 = bx*256;                                      \
  f32x4 acc[8][4] = {};                                                        \
  bfx8 aF[4][2], b01[2][2], b23[2][2];                                         \
  const int frow = lane & 15;                                                  \
  const int fcb0 = (lane >> 4)*16;                                             \
  const int JLAST = (K_)/128 - 1;                                              \
  stage8(Bt, K_, col0, 0,  B0, 0, tid);                                        \
  stage8(Bt, K_, col0, 0,  B0, 1, tid);                                        \
  stage8(A,  K_, row0, 0,  A0, 0, tid);                                        \
  stage8(A,  K_, row0, 0,  A0, 1, tid);                                        \
  stage8(Bt, K_, col0, 64, B1, 0, tid);                                        \
  stage8(Bt, K_, col0, 64, B1, 1, tid);                                        \
  VM4;                                                                         \
  BAR;                                                                         \
  _Pragma("unroll 1")                                                          \
  for (int j = 0; j <= JLAST; j++){                                            \
    const int kO  = j*128 + 64;                                                \
    const int kS1 = (j*128 + 128) & ((K_) - 1);                                \
    const int kS2 = (j*128 + 192) & ((K_) - 1);                                \
    stage8(A, K_, row0, kO, A1, 0, tid);                                       \
    _Pragma("unroll") for (int m = 0; m < 4; m++)                              \
      _Pragma("unroll") for (int kk = 0; kk < 2; kk++)                         \
        aF[m][kk] = fr8(A0, wm*128 + m*16 + frow, kk*64 + fcb0);               \
    _Pragma("unroll") for (int n = 0; n < 2; n++)                              \
      _Pragma("unroll") for (int kk = 0; kk < 2; kk++)                         \
        b01[n][kk] = fr8(B0, wn*64 + n*16 + frow, kk*64 + fcb0);               \
    LGKM0;                                                                     \
    MFMA_QUAD(0, 0, b01);                                                      \
    BAR;                                                                       \
    stage8(A, K_, row0, kO, A1, 1, tid);                                       \
    _Pragma("unroll") for (int n = 0; n < 2; n++)                              \
      _Pragma("unroll") for (int kk = 0; kk < 2; kk++)                         \
        b23[n][kk] = fr8(B0, wn*64 + (n+2)*16 + frow, kk*64 + fcb0);           \
    LGKM0;                                                                     \
    MFMA_QUAD(0, 2, b23);                                                      \
    BAR;                                                                       \
    if (j < JLAST) stage8(Bt, K_, col0, kS1, B0, 0, tid);                      \
    _Pragma("unroll") for (int m = 0; m < 4; m++)                              \
      _Pragma("unroll") for (int kk = 0; kk < 2; kk++)                         \
        aF[m][kk] = fr8(A0, wm*128 + (m+4)*16 + frow, kk*64 + fcb0);           \
    LGKM0;                                                                     \
    MFMA_QUAD(4, 0, b01);                                                      \
    BAR;                                                                       \
    if (j < JLAST){ stage8(Bt, K_, col0, kS1, B0, 1, tid); VM4; }              \
    else { VM0; }                                                              \
    MFMA_QUAD(4, 2, b23);                                                      \
    BAR;                                                                       \
    if (j < JLAST) stage8(A, K_, row0, kS1, A0, 0, tid);                       \
    _Pragma("unroll") for (int m = 0; m < 4; m++)                              \
      _Pragma("unroll") for (int kk = 0; kk < 2; kk++)                         \
        aF[m][kk] = fr8(A1, wm*128 + m*16 + frow, kk*64 + fcb0);               \
    _Pragma("unroll") for (int n = 0; n < 2; n++)                              \
      _Pragma("unroll") for (int kk = 0; kk < 2; kk++)                         \
        b01[n][kk] = fr8(B1, wn*64 + n*16 + frow, kk*64 + fcb0);               \
    LGKM0;                                                                     \
    MFMA_QUAD(0, 0, b01);                                                      \
    BAR;                                                                       \
    if (j < JLAST) stage8(A, K_, row0, kS1, A0, 1, tid);                       \
    _Pragma("unroll") for (int n = 0; n < 2; n++)                              \
      _Pragma("unroll") for (int kk = 0; kk < 2; kk++)                         \
        b23[n][kk] = fr8(B1, wn*64 + (n+2)*16 + frow, kk*64 + fcb0);           \
    LGKM0;                                                                     \
    MFMA_QUAD(0, 2, b23);                                                      \
    BAR;                                                                       \
    if (j < JLAST) stage8(Bt, K_, col0, kS2, B1, 0, tid);                      \
    _Pragma("unroll") for (int m = 0; m < 4; m++)                              \
      _Pragma("unroll") for (int kk = 0; kk < 2; kk++)                         \
        aF[m][kk] = fr8(A1, wm*128 + (m+4)*16 + frow, kk*64 + fcb0);           \
    LGKM0;                                                                     \
    MFMA_QUAD(4, 0, b01);                                                      \
    BAR;                                                                       \
    if (j < JLAST) stage8(Bt, K_, col0, kS2, B1, 1, tid);                      \
    VM4;                                                                       \
    MFMA_QUAD(4, 2, b23);                                                      \
    BAR;                                                                       \
  }

#define SST_STRIDE 280   // bf16 elems; 16B-aligned rows, 2-way LDS write alias (free)

__global__ __launch_bounds__(512, 2) void gemm8_inproj(const bf16* __restrict__ A,
    const bf16* __restrict__ Bt, bf16* __restrict__ z, bf16* __restrict__ xbc){
  GEMM8_BODY(DMODEL, 32)
  // LDS-staged coalesced epilogue: two half-tiles of 128 rows
  unsigned short* sst = (unsigned short*)lds;
  #pragma unroll 1
  for (int half = 0; half < 2; half++){
    if (wm == half){
      #pragma unroll
      for (int m = 0; m < 8; m++)
        #pragma unroll
        for (int n = 0; n < 4; n++)
          #pragma unroll
          for (int r = 0; r < 4; r++){
            int rl = m*16 + (lane>>4)*4 + r;          // 0..127
            sst[rl*SST_STRIDE + wn*64 + n*16 + (lane&15)] = f2bits(acc[m][n][r]);
          }
    }
    BAR;
    #pragma unroll
    for (int i = 0; i < 8; i++){
      int q = tid + i*512;                            // 4096 chunks of 8 elems
      int rl = q >> 5, c8 = (q & 31)*8;
      bfx8 v = *(const bfx8*)(sst + rl*SST_STRIDE + c8);
      int gr = row0 + half*128 + rl, gc = col0 + c8;
      if (gc < INTER) *(bfx8*)(z + (size_t)gr*INTER + gc) = v;
      else            *(bfx8*)(xbc + (size_t)gr*CONVDIM + (gc - INTER)) = v;
    }
    BAR;
  }
}

// ================= m97-structure GEMMs (128^2 tile; outproj production path) =================
#define MFMA_GEMM_BODY(K_, EPILOGUE)                                           \
  __shared__ unsigned short As[128*64];                                        \
  __shared__ unsigned short Bs[128*64];                                        \
  const int tid = threadIdx.x;                                                 \
  const int lane = tid & 63, wid = tid >> 6;                                   \
  const int wm = wid >> 1, wn = wid & 1;                                       \
  const int row0 = blockIdx.y*128, col0 = blockIdx.x*128;                      \
  f32x4 acc[4][4] = {};                                                        \
  const int rstg = wid*32 + ((lane>>3)&7);                                     \
  const int kstg = (lane&7)*8;                                                 \
  for (int k0 = 0; k0 < (K_); k0 += 64){                                       \
    _Pragma("unroll")                                                          \
    for (int j = 0; j < 4; j++){                                               \
      const bf16* gA = A + (size_t)(row0 + rstg + j*8)*(K_) + k0 + kstg;       \
      __builtin_amdgcn_global_load_lds(                                        \
        (const __attribute__((address_space(1))) void*)gA,                     \
        (__attribute__((address_space(3))) void*)(As + (wid*32 + j*8)*64),     \
        16, 0, 0);                                                             \
      const bf16* gB = Bt + (size_t)(col0 + rstg + j*8)*(K_) + k0 + kstg;      \
      __builtin_amdgcn_global_load_lds(                                        \
        (const __attribute__((address_space(1))) void*)gB,                     \
        (__attribute__((address_space(3))) void*)(Bs + (wid*32 + j*8)*64),     \
        16, 0, 0);                                                             \
    }                                                                          \
    __syncthreads();                                                           \
    _Pragma("unroll")                                                          \
    for (int kk = 0; kk < 2; kk++){                                            \
      bfx8 af[4], bfr[4];                                                      \
      _Pragma("unroll")                                                        \
      for (int m = 0; m < 4; m++)                                              \
        af[m] = *(const bfx8*)(As + (wm*64 + m*16 + (lane&15))*64              \
                               + kk*32 + (lane>>4)*8);                         \
      _Pragma("unroll")                                                        \
      for (int n = 0; n < 4; n++)                                              \
        bfr[n] = *(const bfx8*)(Bs + (wn*64 + n*16 + (lane&15))*64             \
                                + kk*32 + (lane>>4)*8);                        \
      _Pragma("unroll")                                                        \
      for (int m = 0; m < 4; m++)                                              \
        _Pragma("unroll")                                                      \
        for (int n = 0; n < 4; n++)                                            \
          acc[m][n] = MFMA16(af[m], bfr[n], acc[m][n]);                        \
    }                                                                          \
    __syncthreads();                                                           \
  }                                                                            \
  _Pragma("unroll")                                                            \
  for (int m = 0; m < 4; m++){                                                 \
    int row = row0 + wm*64 + m*16 + (lane>>4)*4;                               \
    _Pragma("unroll")                                                          \
    for (int n = 0; n < 4; n++){                                               \
      int col = col0 + wn*64 + n*16 + (lane&15);                               \
      _Pragma("unroll")                                                        \
      for (int r = 0; r < 4; r++){                                             \
        float v = acc[m][n][r];                                                \
        int rr = row + r;                                                      \
        EPILOGUE                                                               \
      }                                                                        \
    }                                                                          \
  }

__global__ __launch_bounds__(256) void gemm_mfma_inproj(const bf16* __restrict__ A,
    const bf16* __restrict__ Bt, bf16* __restrict__ z, bf16* __restrict__ xbc){
  MFMA_GEMM_BODY(DMODEL,
    if (col < INTER) z[(size_t)rr*INTER + col] = f2b(v);
    else             xbc[(size_t)rr*CONVDIM + (col - INTER)] = f2b(v);
  )
}
__global__ __launch_bounds__(256) void gemm_mfma_outproj(const bf16* __restrict__ A,
    const bf16* __restrict__ Bt, float* __restrict__ C){
  MFMA_GEMM_BODY(INTER,
    C[(size_t)rr*DMODEL + col] = v;
  )
}

// ---------------- split-K fp32 dt GEMM + fused u->bf16 cast ----------------
__global__ __launch_bounds__(256) void dt_partial(const float* __restrict__ u,
    const float* __restrict__ w_in, float* __restrict__ partial,
    unsigned short* __restrict__ u_bf){
  __shared__ float wsm[128][33];
  __shared__ float us[64][133];
  int ks = blockIdx.x, row0 = blockIdx.y*64;
  int k0 = ks*128;
  int tid = threadIdx.x;
  #pragma unroll
  for (int i = 0; i < 16; i++){
    int idx = tid + i*256;
    int r = idx >> 5, c = idx & 31;
    wsm[r][c] = w_in[(size_t)(k0 + r)*PROJDIM + NGEMM + c];
  }
  #pragma unroll
  for (int i = 0; i < 8; i++){
    int idx = tid + i*256;
    int r = idx >> 5, c4 = idx & 31;
    float4 v = *(const float4*)(u + (size_t)(row0 + r)*DMODEL + k0 + c4*4);
    us[r][c4*4+0] = v.x; us[r][c4*4+1] = v.y; us[r][c4*4+2] = v.z; us[r][c4*4+3] = v.w;
    ushort4 w;
    w.x = f2bits(v.x); w.y = f2bits(v.y); w.z = f2bits(v.z); w.w = f2bits(v.w);
    *(ushort4*)(u_bf + (size_t)(row0 + r)*DMODEL + k0 + c4*4) = w;
  }
  __syncthreads();
  int col = tid & 31, r0 = tid >> 5;
  float acc[8] = {};
  #pragma unroll 4
  for (int kk4 = 0; kk4 < 32; kk4++){
    float4 uv[8];
    #pragma unroll
    for (int i = 0; i < 8; i++)
      uv[i] = *(const float4*)&us[r0 + i*8][kk4*4];
    #pragma unroll
    for (int j = 0; j < 4; j++){
      float wv = wsm[kk4*4 + j][col];
      #pragma unroll
      for (int i = 0; i < 8; i++){
        float uvj = (j == 0) ? uv[i].x : (j == 1) ? uv[i].y : (j == 2) ? uv[i].z : uv[i].w;
        acc[i] = fmaf(uvj, wv, acc[i]);
      }
    }
  }
  #pragma unroll
  for (int i = 0; i < 8; i++)
    partial[((size_t)ks*ROWS + row0 + r0 + i*8)*NHEADS + col] = acc[i];
}

// ---------------- conv1d + silu + split ----------------
__global__ __launch_bounds__(256) void conv_kernel(const bf16* __restrict__ xbc,
    const float* __restrict__ cw, const float* __restrict__ cb,
    bf16* __restrict__ x, bf16* __restrict__ Bm, bf16* __restrict__ Cm){
  int bt = blockIdx.x / 9;
  int ch = (blockIdx.x % 9)*256 + threadIdx.x;
  int t = bt & (SEQ-1);
  float acc = cb[ch];
  #pragma unroll
  for (int i = 0; i < 4; i++){
    int tt = t - 3 + i;
    if (tt >= 0)
      acc = fmaf(b2f(xbc[(size_t)(bt - t + tt)*CONVDIM + ch]), cw[ch*4+i], acc);
  }
  float v = acc * sigmoidf_(acc);
  if (ch < INTER)              x[(size_t)bt*INTER + ch] = f2b(v);
  else if (ch < INTER+DSTATE)  Bm[(size_t)bt*DSTATE + (ch-INTER)] = f2b(v);
  else                         Cm[(size_t)bt*DSTATE + (ch-INTER-DSTATE)] = f2b(v);
}

// ---------------- fused: 8-way reduce + bias + softplus -> dt; cumsum(dt*A) -> Acum ----------------
// NOTE: dt/Acum alias the xbc TAIL — this kernel MUST launch after conv_kernel.
__global__ __launch_bounds__(256) void acum_fused(const float* __restrict__ partial,
    const float* __restrict__ dt_bias, const float* __restrict__ A_log,
    float* __restrict__ dt, float* __restrict__ Acum){
  int bi = blockIdx.x;            // (b*NHEADS+h)*NCHUNK + c
  int c = bi & 15; int h = (bi >> 4) & 31; int b = bi >> 9;
  int l = threadIdx.x;
  __shared__ float sbuf[CHUNK];
  int t = c*CHUNK + l;
  size_t idx = (size_t)(b*SEQ + t)*NHEADS + h;
  float s = dt_bias[h];
  #pragma unroll
  for (int ks = 0; ks < 8; ks++)
    s += partial[(size_t)ks*ROWS*NHEADS + idx];
  float v = (s > 20.f) ? s : log1pf(expf(s));
  dt[idx] = v;
  float A = -expf(A_log[h]);
  sbuf[l] = v * A;
  __syncthreads();
  for (int off = 1; off < CHUNK; off <<= 1){
    float add = (l >= off) ? sbuf[l-off] : 0.f;
    __syncthreads();
    sbuf[l] += add;
    __syncthreads();
  }
  Acum[(size_t)bi*CHUNK + l] = sbuf[l];
}

// ---------------- head-shared scores (dense task list): S[bc][l][s] = C·B^T ----------------
__global__ __launch_bounds__(256) void scores_mfma(const bf16* __restrict__ Bm,
    const bf16* __restrict__ Cm, bf16* __restrict__ S){
  int bc = blockIdx.x;
  int b = bc >> 4, c = bc & 15;
  int tid = threadIdx.x, lane = tid & 63;
  int task = blockIdx.y*4 + (tid >> 6);
  if (task >= 10) return;
  int rb = (task >= 6) ? 3 : (task >= 3) ? 2 : (task >= 1) ? 1 : 0;
  int j = task - rb*(rb+1)/2;
  const bf16* Crow = Cm + (size_t)(b*SEQ + c*CHUNK)*DSTATE;
  const bf16* Brow = Bm + (size_t)(b*SEQ + c*CHUNK)*DSTATE;
  f32x4 acc[4][4] = {};
  #pragma unroll
  for (int kk = 0; kk < 4; kk++){
    bfx8 af[4], bfr[4];
    #pragma unroll
    for (int m = 0; m < 4; m++)
      af[m] = *(const bfx8*)(Crow + (size_t)(rb*64 + m*16 + (lane&15))*DSTATE + kk*32 + (lane>>4)*8);
    #pragma unroll
    for (int n = 0; n < 4; n++)
      bfr[n] = *(const bfx8*)(Brow + (size_t)(j*64 + n*16 + (lane&15))*DSTATE + kk*32 + (lane>>4)*8);
    #pragma unroll
    for (int m = 0; m < 4; m++)
      #pragma unroll
      for (int n = 0; n < 4; n++)
        acc[m][n] = MFMA16(af[m], bfr[n], acc[m][n]);
  }
  bf16* dst = S + (size_t)bc*CHUNK*CHUNK;
  #pragma unroll
  for (int m = 0; m < 4; m++)
    #pragma unroll
    for (int n = 0; n < 4; n++)
      #pragma unroll
      for (int r = 0; r < 4; r++)
        dst[(size_t)(rb*64 + m*16 + (lane>>4)*4 + r)*CHUNK + j*64 + n*16 + (lane&15)]
          = f2b(acc[m][n][r]);
}

// ---------------- build XW_T + BT ----------------
__global__ __launch_bounds__(256) void xwt_kernel(const bf16* __restrict__ x,
    const bf16* __restrict__ Bm, const float* __restrict__ dt,
    const float* __restrict__ Acum, bf16* __restrict__ xwt, bf16* __restrict__ bt){
  int pt = blockIdx.x, tt = blockIdx.y, b = blockIdx.z;
  int tid = threadIdx.x;
  __shared__ unsigned short tile[64][72];
  __shared__ float wf[64];
  int t0 = tt*64;
  if (pt < 32){
    int h = pt, c = t0 >> 8;
    if (tid < 64){
      const float* AcB = Acum + ((size_t)(b*NHEADS + h)*NCHUNK + c)*CHUNK;
      int t = t0 + tid;
      wf[tid] = dt[(size_t)(b*SEQ + t)*NHEADS + h] * expf(AcB[255] - AcB[t & 255]);
    }
    __syncthreads();
    const bf16* src = x + (size_t)(b*SEQ + t0)*INTER + pt*64;
    #pragma unroll
    for (int i = 0; i < 2; i++){
      int u = tid + i*256;
      int r = u >> 3, po = (u & 7)*8;
      bfx8 v = *(const bfx8*)(src + (size_t)r*INTER + po);
      float d = wf[r];
      #pragma unroll
      for (int j = 0; j < 8; j++)
        tile[r][po + j] = f2bits(bits2f((unsigned short)v[j]) * d);
    }
    __syncthreads();
    bf16* dst = xwt + ((size_t)(b*INTER) + pt*64)*SEQ + t0;
    #pragma unroll
    for (int i = 0; i < 2; i++){
      int u = tid + i*256;
      int p = u >> 3, tc = (u & 7)*8;
      bfx8 v;
      #pragma unroll
      for (int j = 0; j < 8; j++) v[j] = (short)tile[tc + j][p];
      *(bfx8*)(dst + (size_t)p*SEQ + tc) = v;
    }
  } else {
    int n0 = (pt - 32)*64;
    const bf16* src = Bm + (size_t)(b*SEQ + t0)*DSTATE + n0;
    #pragma unroll
    for (int i = 0; i < 2; i++){
      int u = tid + i*256;
      int r = u >> 3, po = (u & 7)*8;
      bfx8 v = *(const bfx8*)(src + (size_t)r*DSTATE + po);
      *(bfx8*)&tile[r][po] = v;
    }
    __syncthreads();
    bf16* dst = bt + ((size_t)(b*DSTATE) + n0)*SEQ + t0;
    #pragma unroll
    for (int i = 0; i < 2; i++){
      int u = tid + i*256;
      int p = u >> 3, tc = (u & 7)*8;
      bfx8 v;
      #pragma unroll
      for (int j = 0; j < 8; j++) v[j] = (short)tile[tc + j][p];
      *(bfx8*)(dst + (size_t)p*SEQ + tc) = v;
    }
  }
}

// ---------------- MFMA chunk-states ----------------
__global__ __launch_bounds__(256) void chunk_states_mfma(const bf16* __restrict__ xwt,
    const bf16* __restrict__ bt, float* __restrict__ states){
  int bi = blockIdx.x;            // (b*NCHUNK+c)*NHEADS + h
  int h = bi & 31; int c = (bi >> 5) & 15; int b = bi >> 9;
  int tid = threadIdx.x, lane = tid & 63, w = tid >> 6;
  int wm = w >> 1, wn = w & 1;
  const bf16* Arow = xwt + ((size_t)(b*INTER) + h*64)*SEQ + c*CHUNK;
  const bf16* Brow = bt + (size_t)(b*DSTATE)*SEQ + c*CHUNK;
  f32x4 acc[2][4] = {};
  #pragma unroll
  for (int kk = 0; kk < 8; kk++){
    bfx8 af[2], bfr[4];
    #pragma unroll
    for (int m = 0; m < 2; m++)
      af[m] = *(const bfx8*)(Arow + (size_t)(wm*32 + m*16 + (lane&15))*SEQ + kk*32 + (lane>>4)*8);
    #pragma unroll
    for (int n = 0; n < 4; n++)
      bfr[n] = *(const bfx8*)(Brow + (size_t)(wn*64 + n*16 + (lane&15))*SEQ + kk*32 + (lane>>4)*8);
    #pragma unroll
    for (int m = 0; m < 2; m++)
      #pragma unroll
      for (int n = 0; n < 4; n++)
        acc[m][n] = MFMA16(af[m], bfr[n], acc[m][n]);
  }
  float* dst = states + (size_t)bi*HDIM*DSTATE;
  #pragma unroll
  for (int m = 0; m < 2; m++)
    #pragma unroll
    for (int n = 0; n < 4; n++)
      #pragma unroll
      for (int r = 0; r < 4; r++){
        int p = wm*32 + m*16 + (lane>>4)*4 + r;
        int nn = wn*64 + n*16 + (lane&15);
        dst[(size_t)p*DSTATE + nn] = acc[m][n][r];
      }
}

// ---------------- inter-chunk scan ----------------
__global__ __launch_bounds__(256) void scan_kernel(float* __restrict__ states,
    const float* __restrict__ Acum){
  int idx = blockIdx.x*256 + threadIdx.x;
  int n = idx & 127; int p = (idx >> 7) & 63; int h = (idx >> 13) & 31; int b = idx >> 18;
  float R = 0.f;
  for (int c = 0; c < NCHUNK; c++){
    size_t o = (((size_t)((b*NCHUNK + c)*NHEADS + h))*HDIM + p)*DSTATE + n;
    float s = states[o];
    states[o] = R;
    float dA = expf(Acum[((size_t)(b*NHEADS + h)*NCHUNK + c)*CHUNK + CHUNK-1]);
    R = R*dA + s;
  }
}

// ================= fused MFMA Y kernel (S from global, in-register transform) =================
__global__ __launch_bounds__(256, 3) void ydiag_mfma(
    const bf16* x, const float* __restrict__ dt,
    const float* __restrict__ Acum, const bf16* __restrict__ Sg,
    const bf16* __restrict__ Cm, const float* __restrict__ states,
    const float* __restrict__ Dp, bf16* y){
  int bi = blockIdx.x;            // (b*NCHUNK+c)*NHEADS + h
  int h = bi & 31; int c = (bi >> 5) & 15; int b = bi >> 9;
  int bc = b*NCHUNK + c;
  int tid = threadIdx.x, lane = tid & 63, w = tid >> 6;

  __shared__ unsigned short XdtT[64*264];
  __shared__ unsigned short pool[128*72];
  __shared__ float Acs[CHUNK];
  __shared__ float dts[CHUNK];

  const float* AcBase = Acum + ((size_t)(b*NHEADS + h)*NCHUNK + c)*CHUNK;
  Acs[tid] = AcBase[tid];
  dts[tid] = dt[(size_t)(b*SEQ + c*CHUNK + tid)*NHEADS + h];
  {
    const float* src = states + (size_t)bi*HDIM*DSTATE;
    #pragma unroll
    for (int i = 0; i < 32; i++){
      int idx = tid + i*256;
      int p = idx >> 7, n = idx & 127;
      pool[p*136 + n] = f2bits(src[idx]);
    }
  }
  __syncthreads();

  const bf16* Crow = Cm + (size_t)(b*SEQ + c*CHUNK)*DSTATE;

  f32x4 accY[4][4] = {};
  #pragma unroll
  for (int kk = 0; kk < 4; kk++){
    bfx8 af[4], bfr[4];
    #pragma unroll
    for (int m = 0; m < 4; m++)
      af[m] = *(const bfx8*)(Crow + (size_t)(w*64 + m*16 + (lane&15))*DSTATE + kk*32 + (lane>>4)*8);
    #pragma unroll
    for (int n = 0; n < 4; n++)
      bfr[n] = *(const bfx8*)(pool + (n*16 + (lane&15))*136 + kk*32 + (lane>>4)*8);
    #pragma unroll
    for (int m = 0; m < 4; m++)
      #pragma unroll
      for (int n = 0; n < 4; n++)
        accY[m][n] = MFMA16(af[m], bfr[n], accY[m][n]);
  }
  {
    float eAl[4][4];
    #pragma unroll
    for (int m = 0; m < 4; m++)
      #pragma unroll
      for (int r = 0; r < 4; r++)
        eAl[m][r] = expf(Acs[w*64 + m*16 + (lane>>4)*4 + r]);
    #pragma unroll
    for (int m = 0; m < 4; m++)
      #pragma unroll
      for (int n = 0; n < 4; n++)
        #pragma unroll
        for (int r = 0; r < 4; r++)
          accY[m][n][r] *= eAl[m][r];
  }
  __syncthreads();

  #pragma unroll 1
  for (int q = 0; q < 2; q++){
    const bf16* xg = x + (size_t)(b*SEQ + c*CHUNK + q*128)*INTER + h*HDIM;
    #pragma unroll
    for (int i = 0; i < 4; i++){
      int u = tid + i*256;
      int s = u >> 3, p0 = (u & 7)*8;
      bfx8 v = *(const bfx8*)(xg + (size_t)s*INTER + p0);
      float d = dts[q*128 + s];
      bfx8 o;
      #pragma unroll
      for (int j = 0; j < 8; j++)
        o[j] = (short)f2bits(bits2f((unsigned short)v[j]) * d);
      *(bfx8*)(pool + s*72 + p0) = o;
    }
    __syncthreads();
    {
      int p = tid & 63, sb = tid >> 6;
      #pragma unroll
      for (int i = 0; i < 4; i++){
        int s0 = (sb + i*4)*8;
        bfx8 v;
        #pragma unroll
        for (int j = 0; j < 8; j++)
          v[j] = (short)pool[(s0 + j)*72 + p];
        *(bfx8*)(XdtT + p*264 + q*128 + s0) = v;
      }
    }
    __syncthreads();
  }

  const bf16* Srow = Sg + (size_t)bc*CHUNK*CHUNK + (size_t)(w*64)*CHUNK;
  float Dh = Dp[h];
  for (int j = 0; j <= w; j++){
    int s0 = j*64;
    bfx8 wfr[4][2];
    if (j < w){
      float m_ = Acs[s0 + 63];
      float rowf[4];
      #pragma unroll
      for (int m = 0; m < 4; m++)
        rowf[m] = expf(Acs[w*64 + m*16 + (lane&15)] - m_);
      #pragma unroll
      for (int kk = 0; kk < 2; kk++){
        float colf[8];
        #pragma unroll
        for (int t = 0; t < 8; t++)
          colf[t] = expf(m_ - Acs[s0 + kk*32 + (lane>>4)*8 + t]);
        #pragma unroll
        for (int m = 0; m < 4; m++){
          bfx8 raw = *(const bfx8*)(Srow + (size_t)(m*16 + (lane&15))*CHUNK + s0 + kk*32 + (lane>>4)*8);
          bfx8 o;
          #pragma unroll
          for (int t = 0; t < 8; t++)
            o[t] = (short)f2bits(bits2f((unsigned short)raw[t]) * rowf[m] * colf[t]);
          wfr[m][kk] = o;
        }
      }
    } else {
      #pragma unroll
      for (int kk = 0; kk < 2; kk++)
        #pragma unroll
        for (int m = 0; m < 4; m++){
          int lg = w*64 + m*16 + (lane&15);
          float Al = Acs[lg];
          bfx8 raw = *(const bfx8*)(Srow + (size_t)(m*16 + (lane&15))*CHUNK + s0 + kk*32 + (lane>>4)*8);
          bfx8 o;
          #pragma unroll
          for (int t = 0; t < 8; t++){
            int sg = s0 + kk*32 + (lane>>4)*8 + t;
            float v;
            if (sg > lg)       v = 0.f;
            else if (sg == lg) v = bits2f((unsigned short)raw[t]) + Dh/dts[lg];
            else               v = bits2f((unsigned short)raw[t]) * expf(Al - Acs[sg]);
            o[t] = (short)f2bits(v);
          }
          wfr[m][kk] = o;
        }
    }
    #pragma unroll
    for (int kk = 0; kk < 2; kk++){
      bfx8 bfr[4];
      #pragma unroll
      for (int n = 0; n < 4; n++)
        bfr[n] = *(const bfx8*)(XdtT + (n*16 + (lane&15))*264 + s0 + kk*32 + (lane>>4)*8);
      #pragma unroll
      for (int m = 0; m < 4; m++)
        #pragma unroll
        for (int n = 0; n < 4; n++)
          accY[m][n] = MFMA16(wfr[m][kk], bfr[n], accY[m][n]);
    }
  }
  bf16* yg = y + (size_t)(b*SEQ + c*CHUNK)*INTER + h*HDIM;
  #pragma unroll
  for (int m = 0; m < 4; m++)
    #pragma unroll
    for (int n = 0; n < 4; n++)
      #pragma unroll
      for (int r = 0; r < 4; r++)
        yg[(size_t)(w*64 + m*16 + (lane>>4)*4 + r)*INTER + n*16 + (lane&15)]
          = f2b(accY[m][n][r]);
}

// ---------------- gate + RMSNorm ----------------
__global__ __launch_bounds__(256) void gatenorm_kernel(bf16* __restrict__ y,
    const bf16* __restrict__ z, const float* __restrict__ nw){
  int row = blockIdx.x;
  const bf16* zr = z + (size_t)row*INTER;
  bf16* yr = y + (size_t)row*INTER;
  int tid = threadIdx.x;
  float g[8]; float ss = 0.f;
  #pragma unroll
  for (int i = 0; i < 8; i++){
    int idx = tid + i*256;
    float zv = b2f(zr[idx]);
    float gv = b2f(yr[idx]) * zv * sigmoidf_(zv);
    g[i] = gv; ss += gv*gv;
  }
  #pragma unroll
  for (int off = 32; off > 0; off >>= 1) ss += __shfl_down(ss, off);
  __shared__ float red[4];
  __shared__ float stot;
  int lane = tid & 63, wid = tid >> 6;
  if (lane == 0) red[wid] = ss;
  __syncthreads();
  if (tid == 0) stot = rsqrtf((red[0]+red[1]+red[2]+red[3]) * (1.f/INTER) + 1e-5f);
  __syncthreads();
  float sc = stot;
  #pragma unroll
  for (int i = 0; i < 8; i++){
    int idx = tid + i*256;
    yr[idx] = f2b(g[i]*sc*nw[idx]);
  }
}

extern "C" void kernel_launch(void* const* d_in, const int* in_sizes, int n_in,
                              void* d_out, int out_size, void* d_ws, size_t ws_size,
                              hipStream_t stream){
  const float* u    = (const float*)d_in[0];
  const float* w_in = (const float*)d_in[1];
  const float* cw   = (const float*)d_in[2];
  const float* cb   = (const float*)d_in[3];
  const float* dtb  = (const float*)d_in[4];
  const float* Alog = (const float*)d_in[5];
  const float* Dp   = (const float*)d_in[6];
  const float* nw   = (const float*)d_in[7];
  const float* w_out= (const float*)d_in[8];
  float* out = (float*)d_out;
  char* ws = (char*)d_ws;

  // layout (bytes)
  const size_t OFF_Z     = 0;              // bf16 [8192][2048]
  const size_t OFF_XBC   = 33554432;       // bf16 [8192][2304]; states f32 aliases after conv
  const size_t OFF_DT    = 67108864;       // f32 [8192][32]  (xbc TAIL — write only after conv!)
  const size_t OFF_ACUM  = 68157440;       // f32 [2*32*16*256] (xbc TAIL — write only after conv!)
  const size_t OFF_X     = 71303168;       // bf16 [8192][2048]; y aliases
  const size_t OFF_UBF   = 104857600;      // bf16 u; XW_T aliases after inproj
  const size_t OFF_WINT  = 121634816;      // bf16 w_inT
  const size_t OFF_XWT   = 104857600;      // bf16 [2][2048][4096]
  const size_t OFF_BM    = 138412032;      // bf16 [8192][128]
  const size_t OFF_CM    = 140509184;      // bf16 [8192][128]
  const size_t OFF_BT    = 143654912;      // bf16 [2][128][4096]
  const size_t OFF_WOUTT = 145752064;      // bf16 [1024][2048]
  const size_t OFF_PART  = 149946368;      // f32 [8][8192][32]; S (bf16 [32][256][256]) aliases after acum_fused
  const size_t NEED      = 158334976;

  if (ws_size < NEED){
    zero_out_kernel<<<(out_size + 255)/256, 256, 0, stream>>>(out, out_size);
    return;
  }

  bf16*  z      = (bf16*)(ws + OFF_Z);
  bf16*  xbc    = (bf16*)(ws + OFF_XBC);
  float* states = (float*)(ws + OFF_XBC);
  float* dt     = (float*)(ws + OFF_DT);
  float* Acum   = (float*)(ws + OFF_ACUM);
  bf16*  x      = (bf16*)(ws + OFF_X);
  bf16*  y      = (bf16*)(ws + OFF_X);
  bf16*  u_bf   = (bf16*)(ws + OFF_UBF);
  bf16*  w_inT  = (bf16*)(ws + OFF_WINT);
  bf16*  xwt    = (bf16*)(ws + OFF_XWT);
  bf16*  Bm     = (bf16*)(ws + OFF_BM);
  bf16*  Cm     = (bf16*)(ws + OFF_CM);
  bf16*  bt     = (bf16*)(ws + OFF_BT);
  bf16*  w_outT = (bf16*)(ws + OFF_WOUTT);
  float* part   = (float*)(ws + OFF_PART);
  bf16*  S      = (bf16*)(ws + OFF_PART);   // alias: part dead after acum_fused

  bool use8 = true;
  if (hipFuncSetAttribute((const void*)gemm8_inproj,
        hipFuncAttributeMaxDynamicSharedMemorySize, 131072) != hipSuccess) use8 = false;

  // 1) split-K dt partials + fused u->bf16 cast
  dt_partial<<<dim3(8, ROWS/64), 256, 0, stream>>>(u, w_in, part, (unsigned short*)u_bf);
  // 2) w_in transpose/cast
  transcast_kernel<<<dim3(NGEMM/64, DMODEL/64), 256, 0, stream>>>(w_in, w_inT, DMODEL, PROJDIM, 0);
  // 3) inproj GEMM (per-XCD col-major tile map for w_inT L2 residency)
  if (use8)
    gemm8_inproj<<<544, 512, 131072, stream>>>(u_bf, w_inT, z, xbc);
  else
    gemm_mfma_inproj<<<dim3(NGEMM/128, ROWS/128), 256, 0, stream>>>(u_bf, w_inT, z, xbc);
  // 4) conv + silu + split  (MUST precede acum_fused: dt/Acum alias the xbc tail)
  conv_kernel<<<ROWS*9, 256, 0, stream>>>(xbc, cw, cb, x, Bm, Cm);
  // 5) fused reduce+softplus -> dt, cumsum -> Acum (xbc now dead)
  acum_fused<<<B_SZ*NHEADS*NCHUNK, 256, 0, stream>>>(part, dtb, Alog, dt, Acum);
  // 6) head-shared scores (S overwrites part region)
  scores_mfma<<<dim3(B_SZ*NCHUNK, 3), 256, 0, stream>>>(Bm, Cm, S);
  // 7) weighted transpose XW_T + BT
  xwt_kernel<<<dim3(34, 64, 2), 256, 0, stream>>>(x, Bm, dt, Acum, xwt, bt);
  // 8) MFMA chunk-states
  chunk_states_mfma<<<B_SZ*NCHUNK*NHEADS, 256, 0, stream>>>(xwt, bt, states);
  // 9) inter-chunk scan
  scan_kernel<<<(B_SZ*NHEADS*HDIM*DSTATE)/256, 256, 0, stream>>>(states, Acum);
  // 10) fused MFMA Y (y aliases x; S from global)
  ydiag_mfma<<<B_SZ*NCHUNK*NHEADS, 256, 0, stream>>>(x, dt, Acum, S, Cm, states, Dp, y);
  // 11) prep out_proj weight
  transcast_kernel<<<dim3(DMODEL/64, INTER/64), 256, 0, stream>>>(w_out, w_outT, INTER, DMODEL, 0);
  // 12) gate + RMSNorm
  gatenorm_kernel<<<ROWS, 256, 0, stream>>>(y, z, nw);
  // 13) out_proj — m97 128^2 kernel: 512 blocks (~3/CU) vs 8-phase's 128 blocks (half chip idle)
  gemm_mfma_outproj<<<dim3(DMODEL/128, ROWS/128), 256, 0, stream>>>(y, w_outT, out);
}

// Round 12
// 351.804 us; speedup vs baseline: 8.7750x; 1.1664x over previous
//
#include <hip/hip_runtime.h>
#include <hip/hip_bf16.h>

#define B_SZ 2
#define SEQ 4096
#define DMODEL 1024
#define INTER 2048
#define NHEADS 32
#define HDIM 64
#define DSTATE 128
#define DCONV 4
#define CONVDIM 2304
#define PROJDIM 4384
#define CHUNK 256
#define NCHUNK 16
#define ROWS (B_SZ*SEQ)   // 8192
#define NGEMM 4352        // z + xBC columns (17 tiles of 256)

typedef __hip_bfloat16 bf16;
typedef short bfx8 __attribute__((ext_vector_type(8)));
typedef float f32x4 __attribute__((ext_vector_type(4)));

__device__ __forceinline__ float sigmoidf_(float x){ return 1.f/(1.f+expf(-x)); }
__device__ __forceinline__ float b2f(bf16 v){ return __bfloat162float(v); }
__device__ __forceinline__ bf16 f2b(float v){ return __float2bfloat16(v); }
__device__ __forceinline__ float bits2f(unsigned short u){ return __uint_as_float(((unsigned)u) << 16); }
__device__ __forceinline__ unsigned short f2bits(float v){ bf16 t = __float2bfloat16(v); return *(unsigned short*)&t; }

#define MFMA16(a,b,c) __builtin_amdgcn_mfma_f32_16x16x32_bf16(a,b,c,0,0,0)

// ---------------- fallback: zero d_out ----------------
__global__ void zero_out_kernel(float* o, int n){
  int i = blockIdx.x*256 + threadIdx.x;
  if (i < n) o[i] = 0.f;
}

// ---------------- cast + transpose ----------------
__global__ __launch_bounds__(256) void transcast_kernel(const float* __restrict__ in,
    bf16* __restrict__ outT, int R, int ld, int coff){
  __shared__ float t[64][65];
  int r0 = blockIdx.y*64, c0 = blockIdx.x*64;
  int tid = threadIdx.x;
  #pragma unroll
  for (int i = 0; i < 16; i++){
    int idx = tid + i*256;
    int r = idx >> 6, c = idx & 63;
    t[r][c] = in[(size_t)(r0+r)*ld + coff + c0 + c];
  }
  __syncthreads();
  #pragma unroll
  for (int i = 0; i < 16; i++){
    int idx = tid + i*256;
    int c = idx >> 6, r = idx & 63;
    outT[(size_t)(c0+c)*R + r0 + r] = f2b(t[r][c]);
  }
}

// ================= 8-phase 256x256 MFMA GEMM (m201 template, T2+T3+T4+T5) =================
__device__ __forceinline__ void stage8(const bf16* __restrict__ g, int Kdim,
    int tile0, int k0, char* region, int h, int tid){
  #pragma unroll
  for (int l = 0; l < 2; l++){
    int o  = h*16384 + (l*512 + tid)*16;
    int os = o ^ (((o >> 7) & 7) << 4);
    const bf16* src = g + (size_t)(tile0 + (os >> 7))*Kdim + k0 + ((os & 127) >> 1);
    __builtin_amdgcn_global_load_lds(
      (const __attribute__((address_space(1))) void*)src,
      (__attribute__((address_space(3))) void*)(region + h*16384 + (l*512 + (tid >> 6)*64)*16),
      16, 0, 0);
  }
}
__device__ __forceinline__ bfx8 fr8(const char* region, int row, int colbyte){
  int o = row*128 + colbyte;
  o ^= ((row & 7) << 4);
  return *(const bfx8*)(region + o);
}

#define LGKM0  asm volatile("s_waitcnt lgkmcnt(0)" ::: "memory"); __builtin_amdgcn_sched_barrier(0)
#define VM4    asm volatile("s_waitcnt vmcnt(4)" ::: "memory")
#define VM0    asm volatile("s_waitcnt vmcnt(0)" ::: "memory")
#define BAR    __builtin_amdgcn_s_barrier()
#define PRIO1  __builtin_amdgcn_s_setprio(1)
#define PRIO0  __builtin_amdgcn_s_setprio(0)

#define MFMA_QUAD(MH, NH, BARR)                                                \
  PRIO1;                                                                       \
  _Pragma("unroll") for (int m = 0; m < 4; m++)                                \
    _Pragma("unroll") for (int n = 0; n < 2; n++)                              \
      _Pragma("unroll") for (int kk = 0; kk < 2; kk++)                         \
        acc[(MH)+m][(NH)+n] = MFMA16(aF[m][kk], BARR[n][kk], acc[(MH)+m][(NH)+n]); \
  PRIO0

// tile->block mapping: per-XCD contiguous, row-major (R9 form — lowest measured FETCH)
#define GEMM8_BODY(K_, NBX_)                                                   \
  extern __shared__ char lds[];                                                \
  char* A0 = lds;          char* B0 = lds + 32768;                             \
  char* A1 = lds + 65536;  char* B1 = lds + 98304;                             \
  const int tid = threadIdx.x, lane = tid & 63, wid = tid >> 6;                \
  const int wm = wid >> 2, wn = wid & 3;                                       \
  int nb = (blockIdx.x & 7)*((int)gridDim.x >> 3) + (blockIdx.x >> 3);         \
  const int bx = nb % (NBX_), by = nb / (NBX_);                                \
  const int row0 = by*256, col0 = bx*256;                                      \
  f32x4 acc[8][4] = {};                                                        \
  bfx8 aF[4][2], b01[2][2], b23[2][2];                                         \
  const int frow = lane & 15;                                                  \
  const int fcb0 = (lane >> 4)*16;                                             \
  const int JLAST = (K_)/128 - 1;                                              \
  stage8(Bt, K_, col0, 0,  B0, 0, tid);                                        \
  stage8(Bt, K_, col0, 0,  B0, 1, tid);                                        \
  stage8(A,  K_, row0, 0,  A0, 0, tid);                                        \
  stage8(A,  K_, row0, 0,  A0, 1, tid);                                        \
  stage8(Bt, K_, col0, 64, B1, 0, tid);                                        \
  stage8(Bt, K_, col0, 64, B1, 1, tid);                                        \
  VM4;                                                                         \
  BAR;                                                                         \
  _Pragma("unroll 1")                                                          \
  for (int j = 0; j <= JLAST; j++){                                            \
    const int kO  = j*128 + 64;                                                \
    const int kS1 = (j*128 + 128) & ((K_) - 1);                                \
    const int kS2 = (j*128 + 192) & ((K_) - 1);                                \
    stage8(A, K_, row0, kO, A1, 0, tid);                                       \
    _Pragma("unroll") for (int m = 0; m < 4; m++)                              \
      _Pragma("unroll") for (int kk = 0; kk < 2; kk++)                         \
        aF[m][kk] = fr8(A0, wm*128 + m*16 + frow, kk*64 + fcb0);               \
    _Pragma("unroll") for (int n = 0; n < 2; n++)                              \
      _Pragma("unroll") for (int kk = 0; kk < 2; kk++)                         \
        b01[n][kk] = fr8(B0, wn*64 + n*16 + frow, kk*64 + fcb0);               \
    LGKM0;                                                                     \
    MFMA_QUAD(0, 0, b01);                                                      \
    BAR;                                                                       \
    stage8(A, K_, row0, kO, A1, 1, tid);                                       \
    _Pragma("unroll") for (int n = 0; n < 2; n++)                              \
      _Pragma("unroll") for (int kk = 0; kk < 2; kk++)                         \
        b23[n][kk] = fr8(B0, wn*64 + (n+2)*16 + frow, kk*64 + fcb0);           \
    LGKM0;                                                                     \
    MFMA_QUAD(0, 2, b23);                                                      \
    BAR;                                                                       \
    if (j < JLAST) stage8(Bt, K_, col0, kS1, B0, 0, tid);                      \
    _Pragma("unroll") for (int m = 0; m < 4; m++)                              \
      _Pragma("unroll") for (int kk = 0; kk < 2; kk++)                         \
        aF[m][kk] = fr8(A0, wm*128 + (m+4)*16 + frow, kk*64 + fcb0);           \
    LGKM0;                                                                     \
    MFMA_QUAD(4, 0, b01);                                                      \
    BAR;                                                                       \
    if (j < JLAST){ stage8(Bt, K_, col0, kS1, B0, 1, tid); VM4; }              \
    else { VM0; }                                                              \
    MFMA_QUAD(4, 2, b23);                                                      \
    BAR;                                                                       \
    if (j < JLAST) stage8(A, K_, row0, kS1, A0, 0, tid);                       \
    _Pragma("unroll") for (int m = 0; m < 4; m++)                              \
      _Pragma("unroll") for (int kk = 0; kk < 2; kk++)                         \
        aF[m][kk] = fr8(A1, wm*128 + m*16 + frow, kk*64 + fcb0);               \
    _Pragma("unroll") for (int n = 0; n < 2; n++)                              \
      _Pragma("unroll") for (int kk = 0; kk < 2; kk++)                         \
        b01[n][kk] = fr8(B1, wn*64 + n*16 + frow, kk*64 + fcb0);               \
    LGKM0;                                                                     \
    MFMA_QUAD(0, 0, b01);                                                      \
    BAR;                                                                       \
    if (j < JLAST) stage8(A, K_, row0, kS1, A0, 1, tid);                       \
    _Pragma("unroll") for (int n = 0; n < 2; n++)                              \
      _Pragma("unroll") for (int kk = 0; kk < 2; kk++)                         \
        b23[n][kk] = fr8(B1, wn*64 + (n+2)*16 + frow, kk*64 + fcb0);           \
    LGKM0;                                                                     \
    MFMA_QUAD(0, 2, b23);                                                      \
    BAR;                                                                       \
    if (j < JLAST) stage8(Bt, K_, col0, kS2, B1, 0, tid);                      \
    _Pragma("unroll") for (int m = 0; m < 4; m++)                              \
      _Pragma("unroll") for (int kk = 0; kk < 2; kk++)                         \
        aF[m][kk] = fr8(A1, wm*128 + (m+4)*16 + frow, kk*64 + fcb0);           \
    LGKM0;                                                                     \
    MFMA_QUAD(4, 0, b01);                                                      \
    BAR;                                                                       \
    if (j < JLAST) stage8(Bt, K_, col0, kS2, B1, 1, tid);                      \
    VM4;                                                                       \
    MFMA_QUAD(4, 2, b23);                                                      \
    BAR;                                                                       \
  }

#define SST_STRIDE 280   // bf16 elems; 16B-aligned rows, 2-way LDS write alias (free)

__global__ __launch_bounds__(512, 2) void gemm8_inproj(const bf16* __restrict__ A,
    const bf16* __restrict__ Bt, bf16* __restrict__ z, bf16* __restrict__ xbc){
  GEMM8_BODY(DMODEL, 17)
  // LDS-staged coalesced epilogue: two half-tiles of 128 rows
  unsigned short* sst = (unsigned short*)lds;
  #pragma unroll 1
  for (int half = 0; half < 2; half++){
    if (wm == half){
      #pragma unroll
      for (int m = 0; m < 8; m++)
        #pragma unroll
        for (int n = 0; n < 4; n++)
          #pragma unroll
          for (int r = 0; r < 4; r++){
            int rl = m*16 + (lane>>4)*4 + r;          // 0..127
            sst[rl*SST_STRIDE + wn*64 + n*16 + (lane&15)] = f2bits(acc[m][n][r]);
          }
    }
    BAR;
    #pragma unroll
    for (int i = 0; i < 8; i++){
      int q = tid + i*512;                            // 4096 chunks of 8 elems
      int rl = q >> 5, c8 = (q & 31)*8;
      bfx8 v = *(const bfx8*)(sst + rl*SST_STRIDE + c8);
      int gr = row0 + half*128 + rl, gc = col0 + c8;
      if (gc < INTER) *(bfx8*)(z + (size_t)gr*INTER + gc) = v;
      else            *(bfx8*)(xbc + (size_t)gr*CONVDIM + (gc - INTER)) = v;
    }
    BAR;
  }
}

// ================= m97-structure GEMMs (128^2 tile; outproj production path) =================
#define MFMA_GEMM_BODY(K_, EPILOGUE)                                           \
  __shared__ unsigned short As[128*64];                                        \
  __shared__ unsigned short Bs[128*64];                                        \
  const int tid = threadIdx.x;                                                 \
  const int lane = tid & 63, wid = tid >> 6;                                   \
  const int wm = wid >> 1, wn = wid & 1;                                       \
  const int row0 = blockIdx.y*128, col0 = blockIdx.x*128;                      \
  f32x4 acc[4][4] = {};                                                        \
  const int rstg = wid*32 + ((lane>>3)&7);                                     \
  const int kstg = (lane&7)*8;                                                 \
  for (int k0 = 0; k0 < (K_); k0 += 64){                                       \
    _Pragma("unroll")                                                          \
    for (int j = 0; j < 4; j++){                                               \
      const bf16* gA = A + (size_t)(row0 + rstg + j*8)*(K_) + k0 + kstg;       \
      __builtin_amdgcn_global_load_lds(                                        \
        (const __attribute__((address_space(1))) void*)gA,                     \
        (__attribute__((address_space(3))) void*)(As + (wid*32 + j*8)*64),     \
        16, 0, 0);                                                             \
      const bf16* gB = Bt + (size_t)(col0 + rstg + j*8)*(K_) + k0 + kstg;      \
      __builtin_amdgcn_global_load_lds(                                        \
        (const __attribute__((address_space(1))) void*)gB,                     \
        (__attribute__((address_space(3))) void*)(Bs + (wid*32 + j*8)*64),     \
        16, 0, 0);                                                             \
    }                                                                          \
    __syncthreads();                                                           \
    _Pragma("unroll")                                                          \
    for (int kk = 0; kk < 2; kk++){                                            \
      bfx8 af[4], bfr[4];                                                      \
      _Pragma("unroll")                                                        \
      for (int m = 0; m < 4; m++)                                              \
        af[m] = *(const bfx8*)(As + (wm*64 + m*16 + (lane&15))*64              \
                               + kk*32 + (lane>>4)*8);                         \
      _Pragma("unroll")                                                        \
      for (int n = 0; n < 4; n++)                                              \
        bfr[n] = *(const bfx8*)(Bs + (wn*64 + n*16 + (lane&15))*64             \
                                + kk*32 + (lane>>4)*8);                        \
      _Pragma("unroll")                                                        \
      for (int m = 0; m < 4; m++)                                              \
        _Pragma("unroll")                                                      \
        for (int n = 0; n < 4; n++)                                            \
          acc[m][n] = MFMA16(af[m], bfr[n], acc[m][n]);                        \
    }                                                                          \
    __syncthreads();                                                           \
  }                                                                            \
  _Pragma("unroll")                                                            \
  for (int m = 0; m < 4; m++){                                                 \
    int row = row0 + wm*64 + m*16 + (lane>>4)*4;                               \
    _Pragma("unroll")                                                          \
    for (int n = 0; n < 4; n++){                                               \
      int col = col0 + wn*64 + n*16 + (lane&15);                               \
      _Pragma("unroll")                                                        \
      for (int r = 0; r < 4; r++){                                             \
        float v = acc[m][n][r];                                                \
        int rr = row + r;                                                      \
        EPILOGUE                                                               \
      }                                                                        \
    }                                                                          \
  }

__global__ __launch_bounds__(256) void gemm_mfma_inproj(const bf16* __restrict__ A,
    const bf16* __restrict__ Bt, bf16* __restrict__ z, bf16* __restrict__ xbc){
  MFMA_GEMM_BODY(DMODEL,
    if (col < INTER) z[(size_t)rr*INTER + col] = f2b(v);
    else             xbc[(size_t)rr*CONVDIM + (col - INTER)] = f2b(v);
  )
}
__global__ __launch_bounds__(256) void gemm_mfma_outproj(const bf16* __restrict__ A,
    const bf16* __restrict__ Bt, float* __restrict__ C){
  MFMA_GEMM_BODY(INTER,
    C[(size_t)rr*DMODEL + col] = v;
  )
}

// ---------------- split-K fp32 dt GEMM + fused u->bf16 cast ----------------
__global__ __launch_bounds__(256) void dt_partial(const float* __restrict__ u,
    const float* __restrict__ w_in, float* __restrict__ partial,
    unsigned short* __restrict__ u_bf){
  __shared__ float wsm[128][33];
  __shared__ float us[64][133];
  int ks = blockIdx.x, row0 = blockIdx.y*64;
  int k0 = ks*128;
  int tid = threadIdx.x;
  #pragma unroll
  for (int i = 0; i < 16; i++){
    int idx = tid + i*256;
    int r = idx >> 5, c = idx & 31;
    wsm[r][c] = w_in[(size_t)(k0 + r)*PROJDIM + NGEMM + c];
  }
  #pragma unroll
  for (int i = 0; i < 8; i++){
    int idx = tid + i*256;
    int r = idx >> 5, c4 = idx & 31;
    float4 v = *(const float4*)(u + (size_t)(row0 + r)*DMODEL + k0 + c4*4);
    us[r][c4*4+0] = v.x; us[r][c4*4+1] = v.y; us[r][c4*4+2] = v.z; us[r][c4*4+3] = v.w;
    ushort4 w;
    w.x = f2bits(v.x); w.y = f2bits(v.y); w.z = f2bits(v.z); w.w = f2bits(v.w);
    *(ushort4*)(u_bf + (size_t)(row0 + r)*DMODEL + k0 + c4*4) = w;
  }
  __syncthreads();
  int col = tid & 31, r0 = tid >> 5;
  float acc[8] = {};
  #pragma unroll 4
  for (int kk4 = 0; kk4 < 32; kk4++){
    float4 uv[8];
    #pragma unroll
    for (int i = 0; i < 8; i++)
      uv[i] = *(const float4*)&us[r0 + i*8][kk4*4];
    #pragma unroll
    for (int j = 0; j < 4; j++){
      float wv = wsm[kk4*4 + j][col];
      #pragma unroll
      for (int i = 0; i < 8; i++){
        float uvj = (j == 0) ? uv[i].x : (j == 1) ? uv[i].y : (j == 2) ? uv[i].z : uv[i].w;
        acc[i] = fmaf(uvj, wv, acc[i]);
      }
    }
  }
  #pragma unroll
  for (int i = 0; i < 8; i++)
    partial[((size_t)ks*ROWS + row0 + r0 + i*8)*NHEADS + col] = acc[i];
}

// ---------------- conv1d + silu + split (sliding-window, re-read factor ~1.05) ----------------
// grid (9 ch-slices, 64 t-slices, B); thread owns one channel, walks 64 timesteps.
__global__ __launch_bounds__(256) void conv_kernel(const bf16* __restrict__ xbc,
    const float* __restrict__ cw, const float* __restrict__ cb,
    bf16* __restrict__ x, bf16* __restrict__ Bm, bf16* __restrict__ Cm){
  int ch = blockIdx.x*256 + threadIdx.x;     // 0..2303
  int t0 = blockIdx.y*64;
  int b  = blockIdx.z;
  float w0 = cw[ch*4+0], w1 = cw[ch*4+1], w2 = cw[ch*4+2], w3 = cw[ch*4+3];
  float bia = cb[ch];
  const bf16* src = xbc + (size_t)(b*SEQ)*CONVDIM + ch;
  float xm3 = 0.f, xm2 = 0.f, xm1 = 0.f;
  if (t0 > 0){
    xm3 = b2f(src[(size_t)(t0-3)*CONVDIM]);
    xm2 = b2f(src[(size_t)(t0-2)*CONVDIM]);
    xm1 = b2f(src[(size_t)(t0-1)*CONVDIM]);
  }
  bf16* dst; size_t dstride;
  if (ch < INTER)             { dst = x  + (size_t)(b*SEQ + t0)*INTER  + ch;                 dstride = INTER; }
  else if (ch < INTER+DSTATE) { dst = Bm + (size_t)(b*SEQ + t0)*DSTATE + (ch-INTER);         dstride = DSTATE; }
  else                        { dst = Cm + (size_t)(b*SEQ + t0)*DSTATE + (ch-INTER-DSTATE);  dstride = DSTATE; }
  #pragma unroll 4
  for (int i = 0; i < 64; i++){
    float xc = b2f(src[(size_t)(t0+i)*CONVDIM]);
    float acc = bia;
    acc = fmaf(xm3, w0, acc);
    acc = fmaf(xm2, w1, acc);
    acc = fmaf(xm1, w2, acc);
    acc = fmaf(xc,  w3, acc);
    float v = acc * sigmoidf_(acc);
    dst[(size_t)i*dstride] = f2b(v);
    xm3 = xm2; xm2 = xm1; xm1 = xc;
  }
}

// ---------------- fused: 8-way reduce + bias + softplus -> dt; cumsum(dt*A) -> Acum ----------------
// NOTE: dt/Acum alias the xbc TAIL — this kernel MUST launch after conv_kernel.
__global__ __launch_bounds__(256) void acum_fused(const float* __restrict__ partial,
    const float* __restrict__ dt_bias, const float* __restrict__ A_log,
    float* __restrict__ dt, float* __restrict__ Acum){
  int bi = blockIdx.x;            // (b*NHEADS+h)*NCHUNK + c
  int c = bi & 15; int h = (bi >> 4) & 31; int b = bi >> 9;
  int l = threadIdx.x;
  __shared__ float sbuf[CHUNK];
  int t = c*CHUNK + l;
  size_t idx = (size_t)(b*SEQ + t)*NHEADS + h;
  float s = dt_bias[h];
  #pragma unroll
  for (int ks = 0; ks < 8; ks++)
    s += partial[(size_t)ks*ROWS*NHEADS + idx];
  float v = (s > 20.f) ? s : log1pf(expf(s));
  dt[idx] = v;
  float A = -expf(A_log[h]);
  sbuf[l] = v * A;
  __syncthreads();
  for (int off = 1; off < CHUNK; off <<= 1){
    float add = (l >= off) ? sbuf[l-off] : 0.f;
    __syncthreads();
    sbuf[l] += add;
    __syncthreads();
  }
  Acum[(size_t)bi*CHUNK + l] = sbuf[l];
}

// ---------------- head-shared scores (dense task list): S[bc][l][s] = C·B^T ----------------
__global__ __launch_bounds__(256) void scores_mfma(const bf16* __restrict__ Bm,
    const bf16* __restrict__ Cm, bf16* __restrict__ S){
  int bc = blockIdx.x;
  int b = bc >> 4, c = bc & 15;
  int tid = threadIdx.x, lane = tid & 63;
  int task = blockIdx.y*4 + (tid >> 6);
  if (task >= 10) return;
  int rb = (task >= 6) ? 3 : (task >= 3) ? 2 : (task >= 1) ? 1 : 0;
  int j = task - rb*(rb+1)/2;
  const bf16* Crow = Cm + (size_t)(b*SEQ + c*CHUNK)*DSTATE;
  const bf16* Brow = Bm + (size_t)(b*SEQ + c*CHUNK)*DSTATE;
  f32x4 acc[4][4] = {};
  #pragma unroll
  for (int kk = 0; kk < 4; kk++){
    bfx8 af[4], bfr[4];
    #pragma unroll
    for (int m = 0; m < 4; m++)
      af[m] = *(const bfx8*)(Crow + (size_t)(rb*64 + m*16 + (lane&15))*DSTATE + kk*32 + (lane>>4)*8);
    #pragma unroll
    for (int n = 0; n < 4; n++)
      bfr[n] = *(const bfx8*)(Brow + (size_t)(j*64 + n*16 + (lane&15))*DSTATE + kk*32 + (lane>>4)*8);
    #pragma unroll
    for (int m = 0; m < 4; m++)
      #pragma unroll
      for (int n = 0; n < 4; n++)
        acc[m][n] = MFMA16(af[m], bfr[n], acc[m][n]);
  }
  bf16* dst = S + (size_t)bc*CHUNK*CHUNK;
  #pragma unroll
  for (int m = 0; m < 4; m++)
    #pragma unroll
    for (int n = 0; n < 4; n++)
      #pragma unroll
      for (int r = 0; r < 4; r++)
        dst[(size_t)(rb*64 + m*16 + (lane>>4)*4 + r)*CHUNK + j*64 + n*16 + (lane&15)]
          = f2b(acc[m][n][r]);
}

// ---------------- build XW_T + BT ----------------
__global__ __launch_bounds__(256) void xwt_kernel(const bf16* __restrict__ x,
    const bf16* __restrict__ Bm, const float* __restrict__ dt,
    const float* __restrict__ Acum, bf16* __restrict__ xwt, bf16* __restrict__ bt){
  int pt = blockIdx.x, tt = blockIdx.y, b = blockIdx.z;
  int tid = threadIdx.x;
  __shared__ unsigned short tile[64][72];
  __shared__ float wf[64];
  int t0 = tt*64;
  if (pt < 32){
    int h = pt, c = t0 >> 8;
    if (tid < 64){
      const float* AcB = Acum + ((size_t)(b*NHEADS + h)*NCHUNK + c)*CHUNK;
      int t = t0 + tid;
      wf[tid] = dt[(size_t)(b*SEQ + t)*NHEADS + h] * expf(AcB[255] - AcB[t & 255]);
    }
    __syncthreads();
    const bf16* src = x + (size_t)(b*SEQ + t0)*INTER + pt*64;
    #pragma unroll
    for (int i = 0; i < 2; i++){
      int u = tid + i*256;
      int r = u >> 3, po = (u & 7)*8;
      bfx8 v = *(const bfx8*)(src + (size_t)r*INTER + po);
      float d = wf[r];
      #pragma unroll
      for (int j = 0; j < 8; j++)
        tile[r][po + j] = f2bits(bits2f((unsigned short)v[j]) * d);
    }
    __syncthreads();
    bf16* dst = xwt + ((size_t)(b*INTER) + pt*64)*SEQ + t0;
    #pragma unroll
    for (int i = 0; i < 2; i++){
      int u = tid + i*256;
      int p = u >> 3, tc = (u & 7)*8;
      bfx8 v;
      #pragma unroll
      for (int j = 0; j < 8; j++) v[j] = (short)tile[tc + j][p];
      *(bfx8*)(dst + (size_t)p*SEQ + tc) = v;
    }
  } else {
    int n0 = (pt - 32)*64;
    const bf16* src = Bm + (size_t)(b*SEQ + t0)*DSTATE + n0;
    #pragma unroll
    for (int i = 0; i < 2; i++){
      int u = tid + i*256;
      int r = u >> 3, po = (u & 7)*8;
      bfx8 v = *(const bfx8*)(src + (size_t)r*DSTATE + po);
      *(bfx8*)&tile[r][po] = v;
    }
    __syncthreads();
    bf16* dst = bt + ((size_t)(b*DSTATE) + n0)*SEQ + t0;
    #pragma unroll
    for (int i = 0; i < 2; i++){
      int u = tid + i*256;
      int p = u >> 3, tc = (u & 7)*8;
      bfx8 v;
      #pragma unroll
      for (int j = 0; j < 8; j++) v[j] = (short)tile[tc + j][p];
      *(bfx8*)(dst + (size_t)p*SEQ + tc) = v;
    }
  }
}

// ---------------- MFMA chunk-states ----------------
__global__ __launch_bounds__(256) void chunk_states_mfma(const bf16* __restrict__ xwt,
    const bf16* __restrict__ bt, float* __restrict__ states){
  int bi = blockIdx.x;            // (b*NCHUNK+c)*NHEADS + h
  int h = bi & 31; int c = (bi >> 5) & 15; int b = bi >> 9;
  int tid = threadIdx.x, lane = tid & 63, w = tid >> 6;
  int wm = w >> 1, wn = w & 1;
  const bf16* Arow = xwt + ((size_t)(b*INTER) + h*64)*SEQ + c*CHUNK;
  const bf16* Brow = bt + (size_t)(b*DSTATE)*SEQ + c*CHUNK;
  f32x4 acc[2][4] = {};
  #pragma unroll
  for (int kk = 0; kk < 8; kk++){
    bfx8 af[2], bfr[4];
    #pragma unroll
    for (int m = 0; m < 2; m++)
      af[m] = *(const bfx8*)(Arow + (size_t)(wm*32 + m*16 + (lane&15))*SEQ + kk*32 + (lane>>4)*8);
    #pragma unroll
    for (int n = 0; n < 4; n++)
      bfr[n] = *(const bfx8*)(Brow + (size_t)(wn*64 + n*16 + (lane&15))*SEQ + kk*32 + (lane>>4)*8);
    #pragma unroll
    for (int m = 0; m < 2; m++)
      #pragma unroll
      for (int n = 0; n < 4; n++)
        acc[m][n] = MFMA16(af[m], bfr[n], acc[m][n]);
  }
  float* dst = states + (size_t)bi*HDIM*DSTATE;
  #pragma unroll
  for (int m = 0; m < 2; m++)
    #pragma unroll
    for (int n = 0; n < 4; n++)
      #pragma unroll
      for (int r = 0; r < 4; r++){
        int p = wm*32 + m*16 + (lane>>4)*4 + r;
        int nn = wn*64 + n*16 + (lane&15);
        dst[(size_t)p*DSTATE + nn] = acc[m][n][r];
      }
}

// ---------------- inter-chunk scan ----------------
__global__ __launch_bounds__(256) void scan_kernel(float* __restrict__ states,
    const float* __restrict__ Acum){
  int idx = blockIdx.x*256 + threadIdx.x;
  int n = idx & 127; int p = (idx >> 7) & 63; int h = (idx >> 13) & 31; int b = idx >> 18;
  float R = 0.f;
  for (int c = 0; c < NCHUNK; c++){
    size_t o = (((size_t)((b*NCHUNK + c)*NHEADS + h))*HDIM + p)*DSTATE + n;
    float s = states[o];
    states[o] = R;
    float dA = expf(Acum[((size_t)(b*NHEADS + h)*NCHUNK + c)*CHUNK + CHUNK-1]);
    R = R*dA + s;
  }
}

// ================= fused MFMA Y kernel (S from global, in-register transform) =================
__global__ __launch_bounds__(256, 3) void ydiag_mfma(
    const bf16* x, const float* __restrict__ dt,
    const float* __restrict__ Acum, const bf16* __restrict__ Sg,
    const bf16* __restrict__ Cm, const float* __restrict__ states,
    const float* __restrict__ Dp, bf16* y){
  int bi = blockIdx.x;            // (b*NCHUNK+c)*NHEADS + h
  int h = bi & 31; int c = (bi >> 5) & 15; int b = bi >> 9;
  int bc = b*NCHUNK + c;
  int tid = threadIdx.x, lane = tid & 63, w = tid >> 6;

  __shared__ unsigned short XdtT[64*264];
  __shared__ unsigned short pool[128*72];
  __shared__ float Acs[CHUNK];
  __shared__ float dts[CHUNK];

  const float* AcBase = Acum + ((size_t)(b*NHEADS + h)*NCHUNK + c)*CHUNK;
  Acs[tid] = AcBase[tid];
  dts[tid] = dt[(size_t)(b*SEQ + c*CHUNK + tid)*NHEADS + h];
  {
    const float* src = states + (size_t)bi*HDIM*DSTATE;
    #pragma unroll
    for (int i = 0; i < 32; i++){
      int idx = tid + i*256;
      int p = idx >> 7, n = idx & 127;
      pool[p*136 + n] = f2bits(src[idx]);
    }
  }
  __syncthreads();

  const bf16* Crow = Cm + (size_t)(b*SEQ + c*CHUNK)*DSTATE;

  f32x4 accY[4][4] = {};
  #pragma unroll
  for (int kk = 0; kk < 4; kk++){
    bfx8 af[4], bfr[4];
    #pragma unroll
    for (int m = 0; m < 4; m++)
      af[m] = *(const bfx8*)(Crow + (size_t)(w*64 + m*16 + (lane&15))*DSTATE + kk*32 + (lane>>4)*8);
    #pragma unroll
    for (int n = 0; n < 4; n++)
      bfr[n] = *(const bfx8*)(pool + (n*16 + (lane&15))*136 + kk*32 + (lane>>4)*8);
    #pragma unroll
    for (int m = 0; m < 4; m++)
      #pragma unroll
      for (int n = 0; n < 4; n++)
        accY[m][n] = MFMA16(af[m], bfr[n], accY[m][n]);
  }
  {
    float eAl[4][4];
    #pragma unroll
    for (int m = 0; m < 4; m++)
      #pragma unroll
      for (int r = 0; r < 4; r++)
        eAl[m][r] = expf(Acs[w*64 + m*16 + (lane>>4)*4 + r]);
    #pragma unroll
    for (int m = 0; m < 4; m++)
      #pragma unroll
      for (int n = 0; n < 4; n++)
        #pragma unroll
        for (int r = 0; r < 4; r++)
          accY[m][n][r] *= eAl[m][r];
  }
  __syncthreads();

  #pragma unroll 1
  for (int q = 0; q < 2; q++){
    const bf16* xg = x + (size_t)(b*SEQ + c*CHUNK + q*128)*INTER + h*HDIM;
    #pragma unroll
    for (int i = 0; i < 4; i++){
      int u = tid + i*256;
      int s = u >> 3, p0 = (u & 7)*8;
      bfx8 v = *(const bfx8*)(xg + (size_t)s*INTER + p0);
      float d = dts[q*128 + s];
      bfx8 o;
      #pragma unroll
      for (int j = 0; j < 8; j++)
        o[j] = (short)f2bits(bits2f((unsigned short)v[j]) * d);
      *(bfx8*)(pool + s*72 + p0) = o;
    }
    __syncthreads();
    {
      int p = tid & 63, sb = tid >> 6;
      #pragma unroll
      for (int i = 0; i < 4; i++){
        int s0 = (sb + i*4)*8;
        bfx8 v;
        #pragma unroll
        for (int j = 0; j < 8; j++)
          v[j] = (short)pool[(s0 + j)*72 + p];
        *(bfx8*)(XdtT + p*264 + q*128 + s0) = v;
      }
    }
    __syncthreads();
  }

  const bf16* Srow = Sg + (size_t)bc*CHUNK*CHUNK + (size_t)(w*64)*CHUNK;
  float Dh = Dp[h];
  for (int j = 0; j <= w; j++){
    int s0 = j*64;
    bfx8 wfr[4][2];
    if (j < w){
      float m_ = Acs[s0 + 63];
      float rowf[4];
      #pragma unroll
      for (int m = 0; m < 4; m++)
        rowf[m] = expf(Acs[w*64 + m*16 + (lane&15)] - m_);
      #pragma unroll
      for (int kk = 0; kk < 2; kk++){
        float colf[8];
        #pragma unroll
        for (int t = 0; t < 8; t++)
          colf[t] = expf(m_ - Acs[s0 + kk*32 + (lane>>4)*8 + t]);
        #pragma unroll
        for (int m = 0; m < 4; m++){
          bfx8 raw = *(const bfx8*)(Srow + (size_t)(m*16 + (lane&15))*CHUNK + s0 + kk*32 + (lane>>4)*8);
          bfx8 o;
          #pragma unroll
          for (int t = 0; t < 8; t++)
            o[t] = (short)f2bits(bits2f((unsigned short)raw[t]) * rowf[m] * colf[t]);
          wfr[m][kk] = o;
        }
      }
    } else {
      #pragma unroll
      for (int kk = 0; kk < 2; kk++)
        #pragma unroll
        for (int m = 0; m < 4; m++){
          int lg = w*64 + m*16 + (lane&15);
          float Al = Acs[lg];
          bfx8 raw = *(const bfx8*)(Srow + (size_t)(m*16 + (lane&15))*CHUNK + s0 + kk*32 + (lane>>4)*8);
          bfx8 o;
          #pragma unroll
          for (int t = 0; t < 8; t++){
            int sg = s0 + kk*32 + (lane>>4)*8 + t;
            float v;
            if (sg > lg)       v = 0.f;
            else if (sg == lg) v = bits2f((unsigned short)raw[t]) + Dh/dts[lg];
            else               v = bits2f((unsigned short)raw[t]) * expf(Al - Acs[sg]);
            o[t] = (short)f2bits(v);
          }
          wfr[m][kk] = o;
        }
    }
    #pragma unroll
    for (int kk = 0; kk < 2; kk++){
      bfx8 bfr[4];
      #pragma unroll
      for (int n = 0; n < 4; n++)
        bfr[n] = *(const bfx8*)(XdtT + (n*16 + (lane&15))*264 + s0 + kk*32 + (lane>>4)*8);
      #pragma unroll
      for (int m = 0; m < 4; m++)
        #pragma unroll
        for (int n = 0; n < 4; n++)
          accY[m][n] = MFMA16(wfr[m][kk], bfr[n], accY[m][n]);
    }
  }
  bf16* yg = y + (size_t)(b*SEQ + c*CHUNK)*INTER + h*HDIM;
  #pragma unroll
  for (int m = 0; m < 4; m++)
    #pragma unroll
    for (int n = 0; n < 4; n++)
      #pragma unroll
      for (int r = 0; r < 4; r++)
        yg[(size_t)(w*64 + m*16 + (lane>>4)*4 + r)*INTER + n*16 + (lane&15)]
          = f2b(accY[m][n][r]);
}

// ---------------- gate + RMSNorm (vectorized bfx8 loads/stores) ----------------
__global__ __launch_bounds__(256) void gatenorm_kernel(bf16* __restrict__ y,
    const bf16* __restrict__ z, const float* __restrict__ nw){
  int row = blockIdx.x;
  const bf16* zr = z + (size_t)row*INTER;
  bf16* yr = y + (size_t)row*INTER;
  int tid = threadIdx.x;
  bfx8 zv = *(const bfx8*)(zr + tid*8);
  bfx8 yv = *(const bfx8*)(yr + tid*8);
  float g[8]; float ss = 0.f;
  #pragma unroll
  for (int j = 0; j < 8; j++){
    float zf = bits2f((unsigned short)zv[j]);
    float gv = bits2f((unsigned short)yv[j]) * zf * sigmoidf_(zf);
    g[j] = gv; ss += gv*gv;
  }
  #pragma unroll
  for (int off = 32; off > 0; off >>= 1) ss += __shfl_down(ss, off);
  __shared__ float red[4];
  __shared__ float stot;
  int lane = tid & 63, wid = tid >> 6;
  if (lane == 0) red[wid] = ss;
  __syncthreads();
  if (tid == 0) stot = rsqrtf((red[0]+red[1]+red[2]+red[3]) * (1.f/INTER) + 1e-5f);
  __syncthreads();
  float sc = stot;
  float4 nw0 = *(const float4*)(nw + tid*8);
  float4 nw1 = *(const float4*)(nw + tid*8 + 4);
  bfx8 o;
  o[0] = (short)f2bits(g[0]*sc*nw0.x);
  o[1] = (short)f2bits(g[1]*sc*nw0.y);
  o[2] = (short)f2bits(g[2]*sc*nw0.z);
  o[3] = (short)f2bits(g[3]*sc*nw0.w);
  o[4] = (short)f2bits(g[4]*sc*nw1.x);
  o[5] = (short)f2bits(g[5]*sc*nw1.y);
  o[6] = (short)f2bits(g[6]*sc*nw1.z);
  o[7] = (short)f2bits(g[7]*sc*nw1.w);
  *(bfx8*)(yr + tid*8) = o;
}

extern "C" void kernel_launch(void* const* d_in, const int* in_sizes, int n_in,
                              void* d_out, int out_size, void* d_ws, size_t ws_size,
                              hipStream_t stream){
  const float* u    = (const float*)d_in[0];
  const float* w_in = (const float*)d_in[1];
  const float* cw   = (const float*)d_in[2];
  const float* cb   = (const float*)d_in[3];
  const float* dtb  = (const float*)d_in[4];
  const float* Alog = (const float*)d_in[5];
  const float* Dp   = (const float*)d_in[6];
  const float* nw   = (const float*)d_in[7];
  const float* w_out= (const float*)d_in[8];
  float* out = (float*)d_out;
  char* ws = (char*)d_ws;

  // layout (bytes)
  const size_t OFF_Z     = 0;              // bf16 [8192][2048]
  const size_t OFF_XBC   = 33554432;       // bf16 [8192][2304]; states f32 aliases after conv
  const size_t OFF_DT    = 67108864;       // f32 [8192][32]  (xbc TAIL — write only after conv!)
  const size_t OFF_ACUM  = 68157440;       // f32 [2*32*16*256] (xbc TAIL — write only after conv!)
  const size_t OFF_X     = 71303168;       // bf16 [8192][2048]; y aliases
  const size_t OFF_UBF   = 104857600;      // bf16 u; XW_T aliases after inproj
  const size_t OFF_WINT  = 121634816;      // bf16 w_inT
  const size_t OFF_XWT   = 104857600;      // bf16 [2][2048][4096]
  const size_t OFF_BM    = 138412032;      // bf16 [8192][128]
  const size_t OFF_CM    = 140509184;      // bf16 [8192][128]
  const size_t OFF_BT    = 143654912;      // bf16 [2][128][4096]
  const size_t OFF_WOUTT = 145752064;      // bf16 [1024][2048]
  const size_t OFF_PART  = 149946368;      // f32 [8][8192][32]; S (bf16 [32][256][256]) aliases after acum_fused
  const size_t NEED      = 158334976;

  if (ws_size < NEED){
    zero_out_kernel<<<(out_size + 255)/256, 256, 0, stream>>>(out, out_size);
    return;
  }

  bf16*  z      = (bf16*)(ws + OFF_Z);
  bf16*  xbc    = (bf16*)(ws + OFF_XBC);
  float* states = (float*)(ws + OFF_XBC);
  float* dt     = (float*)(ws + OFF_DT);
  float* Acum   = (float*)(ws + OFF_ACUM);
  bf16*  x      = (bf16*)(ws + OFF_X);
  bf16*  y      = (bf16*)(ws + OFF_X);
  bf16*  u_bf   = (bf16*)(ws + OFF_UBF);
  bf16*  w_inT  = (bf16*)(ws + OFF_WINT);
  bf16*  xwt    = (bf16*)(ws + OFF_XWT);
  bf16*  Bm     = (bf16*)(ws + OFF_BM);
  bf16*  Cm     = (bf16*)(ws + OFF_CM);
  bf16*  bt     = (bf16*)(ws + OFF_BT);
  bf16*  w_outT = (bf16*)(ws + OFF_WOUTT);
  float* part   = (float*)(ws + OFF_PART);
  bf16*  S      = (bf16*)(ws + OFF_PART);   // alias: part dead after acum_fused

  bool use8 = true;
  if (hipFuncSetAttribute((const void*)gemm8_inproj,
        hipFuncAttributeMaxDynamicSharedMemorySize, 131072) != hipSuccess) use8 = false;

  // 1) split-K dt partials + fused u->bf16 cast
  dt_partial<<<dim3(8, ROWS/64), 256, 0, stream>>>(u, w_in, part, (unsigned short*)u_bf);
  // 2) w_in transpose/cast
  transcast_kernel<<<dim3(NGEMM/64, DMODEL/64), 256, 0, stream>>>(w_in, w_inT, DMODEL, PROJDIM, 0);
  // 3) inproj GEMM
  if (use8)
    gemm8_inproj<<<544, 512, 131072, stream>>>(u_bf, w_inT, z, xbc);
  else
    gemm_mfma_inproj<<<dim3(NGEMM/128, ROWS/128), 256, 0, stream>>>(u_bf, w_inT, z, xbc);
  // 4) conv + silu + split (sliding window; MUST precede acum_fused: dt/Acum alias xbc tail)
  conv_kernel<<<dim3(9, SEQ/64, B_SZ), 256, 0, stream>>>(xbc, cw, cb, x, Bm, Cm);
  // 5) fused reduce+softplus -> dt, cumsum -> Acum (xbc now dead)
  acum_fused<<<B_SZ*NHEADS*NCHUNK, 256, 0, stream>>>(part, dtb, Alog, dt, Acum);
  // 6) head-shared scores (S overwrites part region)
  scores_mfma<<<dim3(B_SZ*NCHUNK, 3), 256, 0, stream>>>(Bm, Cm, S);
  // 7) weighted transpose XW_T + BT
  xwt_kernel<<<dim3(34, 64, 2), 256, 0, stream>>>(x, Bm, dt, Acum, xwt, bt);
  // 8) MFMA chunk-states
  chunk_states_mfma<<<B_SZ*NCHUNK*NHEADS, 256, 0, stream>>>(xwt, bt, states);
  // 9) inter-chunk scan
  scan_kernel<<<(B_SZ*NHEADS*HDIM*DSTATE)/256, 256, 0, stream>>>(states, Acum);
  // 10) fused MFMA Y (y aliases x; S from global)
  ydiag_mfma<<<B_SZ*NCHUNK*NHEADS, 256, 0, stream>>>(x, dt, Acum, S, Cm, states, Dp, y);
  // 11) prep out_proj weight
  transcast_kernel<<<dim3(DMODEL/64, INTER/64), 256, 0, stream>>>(w_out, w_outT, INTER, DMODEL, 0);
  // 12) gate + RMSNorm
  gatenorm_kernel<<<ROWS, 256, 0, stream>>>(y, z, nw);
  // 13) out_proj — m97 128^2 kernel (512 blocks, ~3/CU)
  gemm_mfma_outproj<<<dim3(DMODEL/128, ROWS/128), 256, 0, stream>>>(y, w_outT, out);
}

// Round 13
// 344.851 us; speedup vs baseline: 8.9519x; 1.0202x over previous
//
#include <hip/hip_runtime.h>
#include <hip/hip_bf16.h>

#define B_SZ 2
#define SEQ 4096
#define DMODEL 1024
#define INTER 2048
#define NHEADS 32
#define HDIM 64
#define DSTATE 128
#define DCONV 4
#define CONVDIM 2304
#define PROJDIM 4384
#define CHUNK 256
#define NCHUNK 16
#define ROWS (B_SZ*SEQ)   // 8192
#define NGEMM 4352        // z + xBC columns
#define NMAIN 4096        // main 8-phase kernel cols (16 tiles of 256; grid 512 = 2 clean rounds)

typedef __hip_bfloat16 bf16;
typedef short bfx8 __attribute__((ext_vector_type(8)));
typedef float f32x4 __attribute__((ext_vector_type(4)));

__device__ __forceinline__ float sigmoidf_(float x){ return 1.f/(1.f+expf(-x)); }
__device__ __forceinline__ float b2f(bf16 v){ return __bfloat162float(v); }
__device__ __forceinline__ bf16 f2b(float v){ return __float2bfloat16(v); }
__device__ __forceinline__ float bits2f(unsigned short u){ return __uint_as_float(((unsigned)u) << 16); }
__device__ __forceinline__ unsigned short f2bits(float v){ bf16 t = __float2bfloat16(v); return *(unsigned short*)&t; }

#define MFMA16(a,b,c) __builtin_amdgcn_mfma_f32_16x16x32_bf16(a,b,c,0,0,0)

// ---------------- fallback: zero d_out ----------------
__global__ void zero_out_kernel(float* o, int n){
  int i = blockIdx.x*256 + threadIdx.x;
  if (i < n) o[i] = 0.f;
}

// ---------------- cast + transpose ----------------
__global__ __launch_bounds__(256) void transcast_kernel(const float* __restrict__ in,
    bf16* __restrict__ outT, int R, int ld, int coff){
  __shared__ float t[64][65];
  int r0 = blockIdx.y*64, c0 = blockIdx.x*64;
  int tid = threadIdx.x;
  #pragma unroll
  for (int i = 0; i < 16; i++){
    int idx = tid + i*256;
    int r = idx >> 6, c = idx & 63;
    t[r][c] = in[(size_t)(r0+r)*ld + coff + c0 + c];
  }
  __syncthreads();
  #pragma unroll
  for (int i = 0; i < 16; i++){
    int idx = tid + i*256;
    int c = idx >> 6, r = idx & 63;
    outT[(size_t)(c0+c)*R + r0 + r] = f2b(t[r][c]);
  }
}

// ================= 8-phase 256x256 MFMA GEMM (m201 template, T2+T3+T4+T5) =================
__device__ __forceinline__ void stage8(const bf16* __restrict__ g, int Kdim,
    int tile0, int k0, char* region, int h, int tid){
  #pragma unroll
  for (int l = 0; l < 2; l++){
    int o  = h*16384 + (l*512 + tid)*16;
    int os = o ^ (((o >> 7) & 7) << 4);
    const bf16* src = g + (size_t)(tile0 + (os >> 7))*Kdim + k0 + ((os & 127) >> 1);
    __builtin_amdgcn_global_load_lds(
      (const __attribute__((address_space(1))) void*)src,
      (__attribute__((address_space(3))) void*)(region + h*16384 + (l*512 + (tid >> 6)*64)*16),
      16, 0, 0);
  }
}
__device__ __forceinline__ bfx8 fr8(const char* region, int row, int colbyte){
  int o = row*128 + colbyte;
  o ^= ((row & 7) << 4);
  return *(const bfx8*)(region + o);
}

#define LGKM0  asm volatile("s_waitcnt lgkmcnt(0)" ::: "memory"); __builtin_amdgcn_sched_barrier(0)
#define VM4    asm volatile("s_waitcnt vmcnt(4)" ::: "memory")
#define VM0    asm volatile("s_waitcnt vmcnt(0)" ::: "memory")
#define BAR    __builtin_amdgcn_s_barrier()
#define PRIO1  __builtin_amdgcn_s_setprio(1)
#define PRIO0  __builtin_amdgcn_s_setprio(0)

#define MFMA_QUAD(MH, NH, BARR)                                                \
  PRIO1;                                                                       \
  _Pragma("unroll") for (int m = 0; m < 4; m++)                                \
    _Pragma("unroll") for (int n = 0; n < 2; n++)                              \
      _Pragma("unroll") for (int kk = 0; kk < 2; kk++)                         \
        acc[(MH)+m][(NH)+n] = MFMA16(aF[m][kk], BARR[n][kk], acc[(MH)+m][(NH)+n]); \
  PRIO0

#define GEMM8_BODY(K_, NBX_)                                                   \
  extern __shared__ char lds[];                                                \
  char* A0 = lds;          char* B0 = lds + 32768;                             \
  char* A1 = lds + 65536;  char* B1 = lds + 98304;                             \
  const int tid = threadIdx.x, lane = tid & 63, wid = tid >> 6;                \
  const int wm = wid >> 2, wn = wid & 3;                                       \
  int nb = (blockIdx.x & 7)*((int)gridDim.x >> 3) + (blockIdx.x >> 3);         \
  const int bx = nb % (NBX_), by = nb / (NBX_);                                \
  const int row0 = by*256, col0 = bx*256;                                      \
  f32x4 acc[8][4] = {};                                                        \
  bfx8 aF[4][2], b01[2][2], b23[2][2];                                         \
  const int frow = lane & 15;                                                  \
  const int fcb0 = (lane >> 4)*16;                                             \
  const int JLAST = (K_)/128 - 1;                                              \
  stage8(Bt, K_, col0, 0,  B0, 0, tid);                                        \
  stage8(Bt, K_, col0, 0,  B0, 1, tid);                                        \
  stage8(A,  K_, row0, 0,  A0, 0, tid);                                        \
  stage8(A,  K_, row0, 0,  A0, 1, tid);                                        \
  stage8(Bt, K_, col0, 64, B1, 0, tid);                                        \
  stage8(Bt, K_, col0, 64, B1, 1, tid);                                        \
  VM4;                                                                         \
  BAR;                                                                         \
  _Pragma("unroll 1")                                                          \
  for (int j = 0; j <= JLAST; j++){                                            \
    const int kO  = j*128 + 64;                                                \
    const int kS1 = (j*128 + 128) & ((K_) - 1);                                \
    const int kS2 = (j*128 + 192) & ((K_) - 1);                                \
    stage8(A, K_, row0, kO, A1, 0, tid);                                       \
    _Pragma("unroll") for (int m = 0; m < 4; m++)                              \
      _Pragma("unroll") for (int kk = 0; kk < 2; kk++)                         \
        aF[m][kk] = fr8(A0, wm*128 + m*16 + frow, kk*64 + fcb0);               \
    _Pragma("unroll") for (int n = 0; n < 2; n++)                              \
      _Pragma("unroll") for (int kk = 0; kk < 2; kk++)                         \
        b01[n][kk] = fr8(B0, wn*64 + n*16 + frow, kk*64 + fcb0);               \
    LGKM0;                                                                     \
    MFMA_QUAD(0, 0, b01);                                                      \
    BAR;                                                                       \
    stage8(A, K_, row0, kO, A1, 1, tid);                                       \
    _Pragma("unroll") for (int n = 0; n < 2; n++)                              \
      _Pragma("unroll") for (int kk = 0; kk < 2; kk++)                         \
        b23[n][kk] = fr8(B0, wn*64 + (n+2)*16 + frow, kk*64 + fcb0);           \
    LGKM0;                                                                     \
    MFMA_QUAD(0, 2, b23);                                                      \
    BAR;                                                                       \
    if (j < JLAST) stage8(Bt, K_, col0, kS1, B0, 0, tid);                      \
    _Pragma("unroll") for (int m = 0; m < 4; m++)                              \
      _Pragma("unroll") for (int kk = 0; kk < 2; kk++)                         \
        aF[m][kk] = fr8(A0, wm*128 + (m+4)*16 + frow, kk*64 + fcb0);           \
    LGKM0;                                                                     \
    MFMA_QUAD(4, 0, b01);                                                      \
    BAR;                                                                       \
    if (j < JLAST){ stage8(Bt, K_, col0, kS1, B0, 1, tid); VM4; }              \
    else { VM0; }                                                              \
    MFMA_QUAD(4, 2, b23);                                                      \
    BAR;                                                                       \
    if (j < JLAST) stage8(A, K_, row0, kS1, A0, 0, tid);                       \
    _Pragma("unroll") for (int m = 0; m < 4; m++)                              \
      _Pragma("unroll") for (int kk = 0; kk < 2; kk++)                         \
        aF[m][kk] = fr8(A1, wm*128 + m*16 + frow, kk*64 + fcb0);               \
    _Pragma("unroll") for (int n = 0; n < 2; n++)                              \
      _Pragma("unroll") for (int kk = 0; kk < 2; kk++)                         \
        b01[n][kk] = fr8(B1, wn*64 + n*16 + frow, kk*64 + fcb0);               \
    LGKM0;                                                                     \
    MFMA_QUAD(0, 0, b01);                                                      \
    BAR;                                                                       \
    if (j < JLAST) stage8(A, K_, row0, kS1, A0, 1, tid);                       \
    _Pragma("unroll") for (int n = 0; n < 2; n++)                              \
      _Pragma("unroll") for (int kk = 0; kk < 2; kk++)                         \
        b23[n][kk] = fr8(B1, wn*64 + (n+2)*16 + frow, kk*64 + fcb0);           \
    LGKM0;                                                                     \
    MFMA_QUAD(0, 2, b23);                                                      \
    BAR;                                                                       \
    if (j < JLAST) stage8(Bt, K_, col0, kS2, B1, 0, tid);                      \
    _Pragma("unroll") for (int m = 0; m < 4; m++)                              \
      _Pragma("unroll") for (int kk = 0; kk < 2; kk++)                         \
        aF[m][kk] = fr8(A1, wm*128 + (m+4)*16 + frow, kk*64 + fcb0);           \
    LGKM0;                                                                     \
    MFMA_QUAD(4, 0, b01);                                                      \
    BAR;                                                                       \
    if (j < JLAST) stage8(Bt, K_, col0, kS2, B1, 1, tid);                      \
    VM4;                                                                       \
    MFMA_QUAD(4, 2, b23);                                                      \
    BAR;                                                                       \
  }

#define SST_STRIDE 280   // bf16 elems; 16B-aligned rows, 2-way LDS write alias (free)

// main inproj: cols 0..4095 only (16 tiles -> grid 512 = 2 exact occupancy rounds)
__global__ __launch_bounds__(512, 2) void gemm8_inproj(const bf16* __restrict__ A,
    const bf16* __restrict__ Bt, bf16* __restrict__ z, bf16* __restrict__ xbc){
  GEMM8_BODY(DMODEL, 16)
  // LDS-staged coalesced epilogue: two half-tiles of 128 rows
  unsigned short* sst = (unsigned short*)lds;
  #pragma unroll 1
  for (int half = 0; half < 2; half++){
    if (wm == half){
      #pragma unroll
      for (int m = 0; m < 8; m++)
        #pragma unroll
        for (int n = 0; n < 4; n++)
          #pragma unroll
          for (int r = 0; r < 4; r++){
            int rl = m*16 + (lane>>4)*4 + r;          // 0..127
            sst[rl*SST_STRIDE + wn*64 + n*16 + (lane&15)] = f2bits(acc[m][n][r]);
          }
    }
    BAR;
    #pragma unroll
    for (int i = 0; i < 8; i++){
      int q = tid + i*512;                            // 4096 chunks of 8 elems
      int rl = q >> 5, c8 = (q & 31)*8;
      bfx8 v = *(const bfx8*)(sst + rl*SST_STRIDE + c8);
      int gr = row0 + half*128 + rl, gc = col0 + c8;
      if (gc < INTER) *(bfx8*)(z + (size_t)gr*INTER + gc) = v;
      else            *(bfx8*)(xbc + (size_t)gr*CONVDIM + (gc - INTER)) = v;
    }
    BAR;
  }
}

// ================= m97-structure GEMMs (128^2 tile) =================
#define MFMA_GEMM_BODY(K_, EPILOGUE)                                           \
  __shared__ unsigned short As[128*64];                                        \
  __shared__ unsigned short Bs[128*64];                                        \
  const int tid = threadIdx.x;                                                 \
  const int lane = tid & 63, wid = tid >> 6;                                   \
  const int wm = wid >> 1, wn = wid & 1;                                       \
  const int row0 = blockIdx.y*128, col0 = blockIdx.x*128;                      \
  f32x4 acc[4][4] = {};                                                        \
  const int rstg = wid*32 + ((lane>>3)&7);                                     \
  const int kstg = (lane&7)*8;                                                 \
  for (int k0 = 0; k0 < (K_); k0 += 64){                                       \
    _Pragma("unroll")                                                          \
    for (int j = 0; j < 4; j++){                                               \
      const bf16* gA = A + (size_t)(row0 + rstg + j*8)*(K_) + k0 + kstg;       \
      __builtin_amdgcn_global_load_lds(                                        \
        (const __attribute__((address_space(1))) void*)gA,                     \
        (__attribute__((address_space(3))) void*)(As + (wid*32 + j*8)*64),     \
        16, 0, 0);                                                             \
      const bf16* gB = Bt + (size_t)(col0 + rstg + j*8)*(K_) + k0 + kstg;      \
      __builtin_amdgcn_global_load_lds(                                        \
        (const __attribute__((address_space(1))) void*)gB,                     \
        (__attribute__((address_space(3))) void*)(Bs + (wid*32 + j*8)*64),     \
        16, 0, 0);                                                             \
    }                                                                          \
    __syncthreads();                                                           \
    _Pragma("unroll")                                                          \
    for (int kk = 0; kk < 2; kk++){                                            \
      bfx8 af[4], bfr[4];                                                      \
      _Pragma("unroll")                                                        \
      for (int m = 0; m < 4; m++)                                              \
        af[m] = *(const bfx8*)(As + (wm*64 + m*16 + (lane&15))*64              \
                               + kk*32 + (lane>>4)*8);                         \
      _Pragma("unroll")                                                        \
      for (int n = 0; n < 4; n++)                                              \
        bfr[n] = *(const bfx8*)(Bs + (wn*64 + n*16 + (lane&15))*64             \
                                + kk*32 + (lane>>4)*8);                        \
      _Pragma("unroll")                                                        \
      for (int m = 0; m < 4; m++)                                              \
        _Pragma("unroll")                                                      \
        for (int n = 0; n < 4; n++)                                            \
          acc[m][n] = MFMA16(af[m], bfr[n], acc[m][n]);                        \
    }                                                                          \
    __syncthreads();                                                           \
  }                                                                            \
  _Pragma("unroll")                                                            \
  for (int m = 0; m < 4; m++){                                                 \
    int row = row0 + wm*64 + m*16 + (lane>>4)*4;                               \
    _Pragma("unroll")                                                          \
    for (int n = 0; n < 4; n++){                                               \
      int col = col0 + wn*64 + n*16 + (lane&15);                               \
      _Pragma("unroll")                                                        \
      for (int r = 0; r < 4; r++){                                             \
        float v = acc[m][n][r];                                                \
        int rr = row + r;                                                      \
        EPILOGUE                                                               \
      }                                                                        \
    }                                                                          \
  }

__global__ __launch_bounds__(256) void gemm_mfma_inproj(const bf16* __restrict__ A,
    const bf16* __restrict__ Bt, bf16* __restrict__ z, bf16* __restrict__ xbc){
  MFMA_GEMM_BODY(DMODEL,
    if (col < INTER) z[(size_t)rr*INTER + col] = f2b(v);
    else             xbc[(size_t)rr*CONVDIM + (col - INTER)] = f2b(v);
  )
}
// strip: inproj cols 4096..4351 (xbc cols 2048..2303); Bt pre-offset by caller
__global__ __launch_bounds__(256) void gemm_mfma_strip(const bf16* __restrict__ A,
    const bf16* __restrict__ Bt, bf16* __restrict__ xbc){
  MFMA_GEMM_BODY(DMODEL,
    xbc[(size_t)rr*CONVDIM + 2048 + col] = f2b(v);
  )
}
__global__ __launch_bounds__(256) void gemm_mfma_outproj(const bf16* __restrict__ A,
    const bf16* __restrict__ Bt, float* __restrict__ C){
  MFMA_GEMM_BODY(INTER,
    C[(size_t)rr*DMODEL + col] = v;
  )
}

// ---------------- split-K fp32 dt GEMM + fused u->bf16 cast ----------------
__global__ __launch_bounds__(256) void dt_partial(const float* __restrict__ u,
    const float* __restrict__ w_in, float* __restrict__ partial,
    unsigned short* __restrict__ u_bf){
  __shared__ float wsm[128][33];
  __shared__ float us[64][133];
  int ks = blockIdx.x, row0 = blockIdx.y*64;
  int k0 = ks*128;
  int tid = threadIdx.x;
  #pragma unroll
  for (int i = 0; i < 16; i++){
    int idx = tid + i*256;
    int r = idx >> 5, c = idx & 31;
    wsm[r][c] = w_in[(size_t)(k0 + r)*PROJDIM + NGEMM + c];
  }
  #pragma unroll
  for (int i = 0; i < 8; i++){
    int idx = tid + i*256;
    int r = idx >> 5, c4 = idx & 31;
    float4 v = *(const float4*)(u + (size_t)(row0 + r)*DMODEL + k0 + c4*4);
    us[r][c4*4+0] = v.x; us[r][c4*4+1] = v.y; us[r][c4*4+2] = v.z; us[r][c4*4+3] = v.w;
    ushort4 w;
    w.x = f2bits(v.x); w.y = f2bits(v.y); w.z = f2bits(v.z); w.w = f2bits(v.w);
    *(ushort4*)(u_bf + (size_t)(row0 + r)*DMODEL + k0 + c4*4) = w;
  }
  __syncthreads();
  int col = tid & 31, r0 = tid >> 5;
  float acc[8] = {};
  #pragma unroll 4
  for (int kk4 = 0; kk4 < 32; kk4++){
    float4 uv[8];
    #pragma unroll
    for (int i = 0; i < 8; i++)
      uv[i] = *(const float4*)&us[r0 + i*8][kk4*4];
    #pragma unroll
    for (int j = 0; j < 4; j++){
      float wv = wsm[kk4*4 + j][col];
      #pragma unroll
      for (int i = 0; i < 8; i++){
        float uvj = (j == 0) ? uv[i].x : (j == 1) ? uv[i].y : (j == 2) ? uv[i].z : uv[i].w;
        acc[i] = fmaf(uvj, wv, acc[i]);
      }
    }
  }
  #pragma unroll
  for (int i = 0; i < 8; i++)
    partial[((size_t)ks*ROWS + row0 + r0 + i*8)*NHEADS + col] = acc[i];
}

// ---------------- conv1d + silu + split (sliding-window) ----------------
__global__ __launch_bounds__(256) void conv_kernel(const bf16* __restrict__ xbc,
    const float* __restrict__ cw, const float* __restrict__ cb,
    bf16* __restrict__ x, bf16* __restrict__ Bm, bf16* __restrict__ Cm){
  int ch = blockIdx.x*256 + threadIdx.x;     // 0..2303
  int t0 = blockIdx.y*64;
  int b  = blockIdx.z;
  float w0 = cw[ch*4+0], w1 = cw[ch*4+1], w2 = cw[ch*4+2], w3 = cw[ch*4+3];
  float bia = cb[ch];
  const bf16* src = xbc + (size_t)(b*SEQ)*CONVDIM + ch;
  float xm3 = 0.f, xm2 = 0.f, xm1 = 0.f;
  if (t0 > 0){
    xm3 = b2f(src[(size_t)(t0-3)*CONVDIM]);
    xm2 = b2f(src[(size_t)(t0-2)*CONVDIM]);
    xm1 = b2f(src[(size_t)(t0-1)*CONVDIM]);
  }
  bf16* dst; size_t dstride;
  if (ch < INTER)             { dst = x  + (size_t)(b*SEQ + t0)*INTER  + ch;                 dstride = INTER; }
  else if (ch < INTER+DSTATE) { dst = Bm + (size_t)(b*SEQ + t0)*DSTATE + (ch-INTER);         dstride = DSTATE; }
  else                        { dst = Cm + (size_t)(b*SEQ + t0)*DSTATE + (ch-INTER-DSTATE);  dstride = DSTATE; }
  #pragma unroll 4
  for (int i = 0; i < 64; i++){
    float xc = b2f(src[(size_t)(t0+i)*CONVDIM]);
    float acc = bia;
    acc = fmaf(xm3, w0, acc);
    acc = fmaf(xm2, w1, acc);
    acc = fmaf(xm1, w2, acc);
    acc = fmaf(xc,  w3, acc);
    float v = acc * sigmoidf_(acc);
    dst[(size_t)i*dstride] = f2b(v);
    xm3 = xm2; xm2 = xm1; xm1 = xc;
  }
}

// ---------------- fused: 8-way reduce + bias + softplus -> dt; cumsum(dt*A) -> Acum ----------------
// NOTE: dt/Acum alias the xbc TAIL — this kernel MUST launch after conv_kernel.
__global__ __launch_bounds__(256) void acum_fused(const float* __restrict__ partial,
    const float* __restrict__ dt_bias, const float* __restrict__ A_log,
    float* __restrict__ dt, float* __restrict__ Acum){
  int bi = blockIdx.x;            // (b*NHEADS+h)*NCHUNK + c
  int c = bi & 15; int h = (bi >> 4) & 31; int b = bi >> 9;
  int l = threadIdx.x;
  __shared__ float sbuf[CHUNK];
  int t = c*CHUNK + l;
  size_t idx = (size_t)(b*SEQ + t)*NHEADS + h;
  float s = dt_bias[h];
  #pragma unroll
  for (int ks = 0; ks < 8; ks++)
    s += partial[(size_t)ks*ROWS*NHEADS + idx];
  float v = (s > 20.f) ? s : log1pf(expf(s));
  dt[idx] = v;
  float A = -expf(A_log[h]);
  sbuf[l] = v * A;
  __syncthreads();
  for (int off = 1; off < CHUNK; off <<= 1){
    float add = (l >= off) ? sbuf[l-off] : 0.f;
    __syncthreads();
    sbuf[l] += add;
    __syncthreads();
  }
  Acum[(size_t)bi*CHUNK + l] = sbuf[l];
}

// ---------------- head-shared scores (dense task list): S[bc][l][s] = C·B^T ----------------
__global__ __launch_bounds__(256) void scores_mfma(const bf16* __restrict__ Bm,
    const bf16* __restrict__ Cm, bf16* __restrict__ S){
  int bc = blockIdx.x;
  int b = bc >> 4, c = bc & 15;
  int tid = threadIdx.x, lane = tid & 63;
  int task = blockIdx.y*4 + (tid >> 6);
  if (task >= 10) return;
  int rb = (task >= 6) ? 3 : (task >= 3) ? 2 : (task >= 1) ? 1 : 0;
  int j = task - rb*(rb+1)/2;
  const bf16* Crow = Cm + (size_t)(b*SEQ + c*CHUNK)*DSTATE;
  const bf16* Brow = Bm + (size_t)(b*SEQ + c*CHUNK)*DSTATE;
  f32x4 acc[4][4] = {};
  #pragma unroll
  for (int kk = 0; kk < 4; kk++){
    bfx8 af[4], bfr[4];
    #pragma unroll
    for (int m = 0; m < 4; m++)
      af[m] = *(const bfx8*)(Crow + (size_t)(rb*64 + m*16 + (lane&15))*DSTATE + kk*32 + (lane>>4)*8);
    #pragma unroll
    for (int n = 0; n < 4; n++)
      bfr[n] = *(const bfx8*)(Brow + (size_t)(j*64 + n*16 + (lane&15))*DSTATE + kk*32 + (lane>>4)*8);
    #pragma unroll
    for (int m = 0; m < 4; m++)
      #pragma unroll
      for (int n = 0; n < 4; n++)
        acc[m][n] = MFMA16(af[m], bfr[n], acc[m][n]);
  }
  bf16* dst = S + (size_t)bc*CHUNK*CHUNK;
  #pragma unroll
  for (int m = 0; m < 4; m++)
    #pragma unroll
    for (int n = 0; n < 4; n++)
      #pragma unroll
      for (int r = 0; r < 4; r++)
        dst[(size_t)(rb*64 + m*16 + (lane>>4)*4 + r)*CHUNK + j*64 + n*16 + (lane&15)]
          = f2b(acc[m][n][r]);
}

// ---------------- build XW_T + BT ----------------
__global__ __launch_bounds__(256) void xwt_kernel(const bf16* __restrict__ x,
    const bf16* __restrict__ Bm, const float* __restrict__ dt,
    const float* __restrict__ Acum, bf16* __restrict__ xwt, bf16* __restrict__ bt){
  int pt = blockIdx.x, tt = blockIdx.y, b = blockIdx.z;
  int tid = threadIdx.x;
  __shared__ unsigned short tile[64][72];
  __shared__ float wf[64];
  int t0 = tt*64;
  if (pt < 32){
    int h = pt, c = t0 >> 8;
    if (tid < 64){
      const float* AcB = Acum + ((size_t)(b*NHEADS + h)*NCHUNK + c)*CHUNK;
      int t = t0 + tid;
      wf[tid] = dt[(size_t)(b*SEQ + t)*NHEADS + h] * expf(AcB[255] - AcB[t & 255]);
    }
    __syncthreads();
    const bf16* src = x + (size_t)(b*SEQ + t0)*INTER + pt*64;
    #pragma unroll
    for (int i = 0; i < 2; i++){
      int u = tid + i*256;
      int r = u >> 3, po = (u & 7)*8;
      bfx8 v = *(const bfx8*)(src + (size_t)r*INTER + po);
      float d = wf[r];
      #pragma unroll
      for (int j = 0; j < 8; j++)
        tile[r][po + j] = f2bits(bits2f((unsigned short)v[j]) * d);
    }
    __syncthreads();
    bf16* dst = xwt + ((size_t)(b*INTER) + pt*64)*SEQ + t0;
    #pragma unroll
    for (int i = 0; i < 2; i++){
      int u = tid + i*256;
      int p = u >> 3, tc = (u & 7)*8;
      bfx8 v;
      #pragma unroll
      for (int j = 0; j < 8; j++) v[j] = (short)tile[tc + j][p];
      *(bfx8*)(dst + (size_t)p*SEQ + tc) = v;
    }
  } else {
    int n0 = (pt - 32)*64;
    const bf16* src = Bm + (size_t)(b*SEQ + t0)*DSTATE + n0;
    #pragma unroll
    for (int i = 0; i < 2; i++){
      int u = tid + i*256;
      int r = u >> 3, po = (u & 7)*8;
      bfx8 v = *(const bfx8*)(src + (size_t)r*DSTATE + po);
      *(bfx8*)&tile[r][po] = v;
    }
    __syncthreads();
    bf16* dst = bt + ((size_t)(b*DSTATE) + n0)*SEQ + t0;
    #pragma unroll
    for (int i = 0; i < 2; i++){
      int u = tid + i*256;
      int p = u >> 3, tc = (u & 7)*8;
      bfx8 v;
      #pragma unroll
      for (int j = 0; j < 8; j++) v[j] = (short)tile[tc + j][p];
      *(bfx8*)(dst + (size_t)p*SEQ + tc) = v;
    }
  }
}

// ---------------- MFMA chunk-states ----------------
__global__ __launch_bounds__(256) void chunk_states_mfma(const bf16* __restrict__ xwt,
    const bf16* __restrict__ bt, float* __restrict__ states){
  int bi = blockIdx.x;            // (b*NCHUNK+c)*NHEADS + h
  int h = bi & 31; int c = (bi >> 5) & 15; int b = bi >> 9;
  int tid = threadIdx.x, lane = tid & 63, w = tid >> 6;
  int wm = w >> 1, wn = w & 1;
  const bf16* Arow = xwt + ((size_t)(b*INTER) + h*64)*SEQ + c*CHUNK;
  const bf16* Brow = bt + (size_t)(b*DSTATE)*SEQ + c*CHUNK;
  f32x4 acc[2][4] = {};
  #pragma unroll
  for (int kk = 0; kk < 8; kk++){
    bfx8 af[2], bfr[4];
    #pragma unroll
    for (int m = 0; m < 2; m++)
      af[m] = *(const bfx8*)(Arow + (size_t)(wm*32 + m*16 + (lane&15))*SEQ + kk*32 + (lane>>4)*8);
    #pragma unroll
    for (int n = 0; n < 4; n++)
      bfr[n] = *(const bfx8*)(Brow + (size_t)(wn*64 + n*16 + (lane&15))*SEQ + kk*32 + (lane>>4)*8);
    #pragma unroll
    for (int m = 0; m < 2; m++)
      #pragma unroll
      for (int n = 0; n < 4; n++)
        acc[m][n] = MFMA16(af[m], bfr[n], acc[m][n]);
  }
  float* dst = states + (size_t)bi*HDIM*DSTATE;
  #pragma unroll
  for (int m = 0; m < 2; m++)
    #pragma unroll
    for (int n = 0; n < 4; n++)
      #pragma unroll
      for (int r = 0; r < 4; r++){
        int p = wm*32 + m*16 + (lane>>4)*4 + r;
        int nn = wn*64 + n*16 + (lane&15);
        dst[(size_t)p*DSTATE + nn] = acc[m][n][r];
      }
}

// ---------------- inter-chunk scan ----------------
__global__ __launch_bounds__(256) void scan_kernel(float* __restrict__ states,
    const float* __restrict__ Acum){
  int idx = blockIdx.x*256 + threadIdx.x;
  int n = idx & 127; int p = (idx >> 7) & 63; int h = (idx >> 13) & 31; int b = idx >> 18;
  float R = 0.f;
  for (int c = 0; c < NCHUNK; c++){
    size_t o = (((size_t)((b*NCHUNK + c)*NHEADS + h))*HDIM + p)*DSTATE + n;
    float s = states[o];
    states[o] = R;
    float dA = expf(Acum[((size_t)(b*NHEADS + h)*NCHUNK + c)*CHUNK + CHUNK-1]);
    R = R*dA + s;
  }
}

// ================= fused MFMA Y kernel (S from global, in-register transform) =================
__global__ __launch_bounds__(256, 3) void ydiag_mfma(
    const bf16* x, const float* __restrict__ dt,
    const float* __restrict__ Acum, const bf16* __restrict__ Sg,
    const bf16* __restrict__ Cm, const float* __restrict__ states,
    const float* __restrict__ Dp, bf16* y){
  int bi = blockIdx.x;            // (b*NCHUNK+c)*NHEADS + h
  int h = bi & 31; int c = (bi >> 5) & 15; int b = bi >> 9;
  int bc = b*NCHUNK + c;
  int tid = threadIdx.x, lane = tid & 63, w = tid >> 6;

  __shared__ unsigned short XdtT[64*264];
  __shared__ unsigned short pool[128*72];
  __shared__ float Acs[CHUNK];
  __shared__ float dts[CHUNK];

  const float* AcBase = Acum + ((size_t)(b*NHEADS + h)*NCHUNK + c)*CHUNK;
  Acs[tid] = AcBase[tid];
  dts[tid] = dt[(size_t)(b*SEQ + c*CHUNK + tid)*NHEADS + h];
  {
    const float* src = states + (size_t)bi*HDIM*DSTATE;
    #pragma unroll
    for (int i = 0; i < 32; i++){
      int idx = tid + i*256;
      int p = idx >> 7, n = idx & 127;
      pool[p*136 + n] = f2bits(src[idx]);
    }
  }
  __syncthreads();

  const bf16* Crow = Cm + (size_t)(b*SEQ + c*CHUNK)*DSTATE;

  f32x4 accY[4][4] = {};
  #pragma unroll
  for (int kk = 0; kk < 4; kk++){
    bfx8 af[4], bfr[4];
    #pragma unroll
    for (int m = 0; m < 4; m++)
      af[m] = *(const bfx8*)(Crow + (size_t)(w*64 + m*16 + (lane&15))*DSTATE + kk*32 + (lane>>4)*8);
    #pragma unroll
    for (int n = 0; n < 4; n++)
      bfr[n] = *(const bfx8*)(pool + (n*16 + (lane&15))*136 + kk*32 + (lane>>4)*8);
    #pragma unroll
    for (int m = 0; m < 4; m++)
      #pragma unroll
      for (int n = 0; n < 4; n++)
        accY[m][n] = MFMA16(af[m], bfr[n], accY[m][n]);
  }
  {
    float eAl[4][4];
    #pragma unroll
    for (int m = 0; m < 4; m++)
      #pragma unroll
      for (int r = 0; r < 4; r++)
        eAl[m][r] = expf(Acs[w*64 + m*16 + (lane>>4)*4 + r]);
    #pragma unroll
    for (int m = 0; m < 4; m++)
      #pragma unroll
      for (int n = 0; n < 4; n++)
        #pragma unroll
        for (int r = 0; r < 4; r++)
          accY[m][n][r] *= eAl[m][r];
  }
  __syncthreads();

  #pragma unroll 1
  for (int q = 0; q < 2; q++){
    const bf16* xg = x + (size_t)(b*SEQ + c*CHUNK + q*128)*INTER + h*HDIM;
    #pragma unroll
    for (int i = 0; i < 4; i++){
      int u = tid + i*256;
      int s = u >> 3, p0 = (u & 7)*8;
      bfx8 v = *(const bfx8*)(xg + (size_t)s*INTER + p0);
      float d = dts[q*128 + s];
      bfx8 o;
      #pragma unroll
      for (int j = 0; j < 8; j++)
        o[j] = (short)f2bits(bits2f((unsigned short)v[j]) * d);
      *(bfx8*)(pool + s*72 + p0) = o;
    }
    __syncthreads();
    {
      int p = tid & 63, sb = tid >> 6;
      #pragma unroll
      for (int i = 0; i < 4; i++){
        int s0 = (sb + i*4)*8;
        bfx8 v;
        #pragma unroll
        for (int j = 0; j < 8; j++)
          v[j] = (short)pool[(s0 + j)*72 + p];
        *(bfx8*)(XdtT + p*264 + q*128 + s0) = v;
      }
    }
    __syncthreads();
  }

  const bf16* Srow = Sg + (size_t)bc*CHUNK*CHUNK + (size_t)(w*64)*CHUNK;
  float Dh = Dp[h];
  for (int j = 0; j <= w; j++){
    int s0 = j*64;
    bfx8 wfr[4][2];
    if (j < w){
      float m_ = Acs[s0 + 63];
      float rowf[4];
      #pragma unroll
      for (int m = 0; m < 4; m++)
        rowf[m] = expf(Acs[w*64 + m*16 + (lane&15)] - m_);
      #pragma unroll
      for (int kk = 0; kk < 2; kk++){
        float colf[8];
        #pragma unroll
        for (int t = 0; t < 8; t++)
          colf[t] = expf(m_ - Acs[s0 + kk*32 + (lane>>4)*8 + t]);
        #pragma unroll
        for (int m = 0; m < 4; m++){
          bfx8 raw = *(const bfx8*)(Srow + (size_t)(m*16 + (lane&15))*CHUNK + s0 + kk*32 + (lane>>4)*8);
          bfx8 o;
          #pragma unroll
          for (int t = 0; t < 8; t++)
            o[t] = (short)f2bits(bits2f((unsigned short)raw[t]) * rowf[m] * colf[t]);
          wfr[m][kk] = o;
        }
      }
    } else {
      #pragma unroll
      for (int kk = 0; kk < 2; kk++)
        #pragma unroll
        for (int m = 0; m < 4; m++){
          int lg = w*64 + m*16 + (lane&15);
          float Al = Acs[lg];
          bfx8 raw = *(const bfx8*)(Srow + (size_t)(m*16 + (lane&15))*CHUNK + s0 + kk*32 + (lane>>4)*8);
          bfx8 o;
          #pragma unroll
          for (int t = 0; t < 8; t++){
            int sg = s0 + kk*32 + (lane>>4)*8 + t;
            float v;
            if (sg > lg)       v = 0.f;
            else if (sg == lg) v = bits2f((unsigned short)raw[t]) + Dh/dts[lg];
            else               v = bits2f((unsigned short)raw[t]) * expf(Al - Acs[sg]);
            o[t] = (short)f2bits(v);
          }
          wfr[m][kk] = o;
        }
    }
    #pragma unroll
    for (int kk = 0; kk < 2; kk++){
      bfx8 bfr[4];
      #pragma unroll
      for (int n = 0; n < 4; n++)
        bfr[n] = *(const bfx8*)(XdtT + (n*16 + (lane&15))*264 + s0 + kk*32 + (lane>>4)*8);
      #pragma unroll
      for (int m = 0; m < 4; m++)
        #pragma unroll
        for (int n = 0; n < 4; n++)
          accY[m][n] = MFMA16(wfr[m][kk], bfr[n], accY[m][n]);
    }
  }
  bf16* yg = y + (size_t)(b*SEQ + c*CHUNK)*INTER + h*HDIM;
  #pragma unroll
  for (int m = 0; m < 4; m++)
    #pragma unroll
    for (int n = 0; n < 4; n++)
      #pragma unroll
      for (int r = 0; r < 4; r++)
        yg[(size_t)(w*64 + m*16 + (lane>>4)*4 + r)*INTER + n*16 + (lane&15)]
          = f2b(accY[m][n][r]);
}

// ---------------- gate + RMSNorm (vectorized bfx8 loads/stores) ----------------
__global__ __launch_bounds__(256) void gatenorm_kernel(bf16* __restrict__ y,
    const bf16* __restrict__ z, const float* __restrict__ nw){
  int row = blockIdx.x;
  const bf16* zr = z + (size_t)row*INTER;
  bf16* yr = y + (size_t)row*INTER;
  int tid = threadIdx.x;
  bfx8 zv = *(const bfx8*)(zr + tid*8);
  bfx8 yv = *(const bfx8*)(yr + tid*8);
  float g[8]; float ss = 0.f;
  #pragma unroll
  for (int j = 0; j < 8; j++){
    float zf = bits2f((unsigned short)zv[j]);
    float gv = bits2f((unsigned short)yv[j]) * zf * sigmoidf_(zf);
    g[j] = gv; ss += gv*gv;
  }
  #pragma unroll
  for (int off = 32; off > 0; off >>= 1) ss += __shfl_down(ss, off);
  __shared__ float red[4];
  __shared__ float stot;
  int lane = tid & 63, wid = tid >> 6;
  if (lane == 0) red[wid] = ss;
  __syncthreads();
  if (tid == 0) stot = rsqrtf((red[0]+red[1]+red[2]+red[3]) * (1.f/INTER) + 1e-5f);
  __syncthreads();
  float sc = stot;
  float4 nw0 = *(const float4*)(nw + tid*8);
  float4 nw1 = *(const float4*)(nw + tid*8 + 4);
  bfx8 o;
  o[0] = (short)f2bits(g[0]*sc*nw0.x);
  o[1] = (short)f2bits(g[1]*sc*nw0.y);
  o[2] = (short)f2bits(g[2]*sc*nw0.z);
  o[3] = (short)f2bits(g[3]*sc*nw0.w);
  o[4] = (short)f2bits(g[4]*sc*nw1.x);
  o[5] = (short)f2bits(g[5]*sc*nw1.y);
  o[6] = (short)f2bits(g[6]*sc*nw1.z);
  o[7] = (short)f2bits(g[7]*sc*nw1.w);
  *(bfx8*)(yr + tid*8) = o;
}

extern "C" void kernel_launch(void* const* d_in, const int* in_sizes, int n_in,
                              void* d_out, int out_size, void* d_ws, size_t ws_size,
                              hipStream_t stream){
  const float* u    = (const float*)d_in[0];
  const float* w_in = (const float*)d_in[1];
  const float* cw   = (const float*)d_in[2];
  const float* cb   = (const float*)d_in[3];
  const float* dtb  = (const float*)d_in[4];
  const float* Alog = (const float*)d_in[5];
  const float* Dp   = (const float*)d_in[6];
  const float* nw   = (const float*)d_in[7];
  const float* w_out= (const float*)d_in[8];
  float* out = (float*)d_out;
  char* ws = (char*)d_ws;

  // layout (bytes)
  const size_t OFF_Z     = 0;              // bf16 [8192][2048]
  const size_t OFF_XBC   = 33554432;       // bf16 [8192][2304]; states f32 aliases after conv
  const size_t OFF_DT    = 67108864;       // f32 [8192][32]  (xbc TAIL — write only after conv!)
  const size_t OFF_ACUM  = 68157440;       // f32 [2*32*16*256] (xbc TAIL — write only after conv!)
  const size_t OFF_X     = 71303168;       // bf16 [8192][2048]; y aliases
  const size_t OFF_UBF   = 104857600;      // bf16 u; XW_T aliases after inproj
  const size_t OFF_WINT  = 121634816;      // bf16 w_inT
  const size_t OFF_XWT   = 104857600;      // bf16 [2][2048][4096]
  const size_t OFF_BM    = 138412032;      // bf16 [8192][128]
  const size_t OFF_CM    = 140509184;      // bf16 [8192][128]
  const size_t OFF_BT    = 143654912;      // bf16 [2][128][4096]
  const size_t OFF_WOUTT = 145752064;      // bf16 [1024][2048]
  const size_t OFF_PART  = 149946368;      // f32 [8][8192][32]; S aliases after acum_fused
  const size_t NEED      = 158334976;

  if (ws_size < NEED){
    zero_out_kernel<<<(out_size + 255)/256, 256, 0, stream>>>(out, out_size);
    return;
  }

  bf16*  z      = (bf16*)(ws + OFF_Z);
  bf16*  xbc    = (bf16*)(ws + OFF_XBC);
  float* states = (float*)(ws + OFF_XBC);
  float* dt     = (float*)(ws + OFF_DT);
  float* Acum   = (float*)(ws + OFF_ACUM);
  bf16*  x      = (bf16*)(ws + OFF_X);
  bf16*  y      = (bf16*)(ws + OFF_X);
  bf16*  u_bf   = (bf16*)(ws + OFF_UBF);
  bf16*  w_inT  = (bf16*)(ws + OFF_WINT);
  bf16*  xwt    = (bf16*)(ws + OFF_XWT);
  bf16*  Bm     = (bf16*)(ws + OFF_BM);
  bf16*  Cm     = (bf16*)(ws + OFF_CM);
  bf16*  bt     = (bf16*)(ws + OFF_BT);
  bf16*  w_outT = (bf16*)(ws + OFF_WOUTT);
  float* part   = (float*)(ws + OFF_PART);
  bf16*  S      = (bf16*)(ws + OFF_PART);   // alias: part dead after acum_fused

  bool use8 = true;
  if (hipFuncSetAttribute((const void*)gemm8_inproj,
        hipFuncAttributeMaxDynamicSharedMemorySize, 131072) != hipSuccess) use8 = false;

  // 1) split-K dt partials + fused u->bf16 cast
  dt_partial<<<dim3(8, ROWS/64), 256, 0, stream>>>(u, w_in, part, (unsigned short*)u_bf);
  // 2) w_in transpose/cast
  transcast_kernel<<<dim3(NGEMM/64, DMODEL/64), 256, 0, stream>>>(w_in, w_inT, DMODEL, PROJDIM, 0);
  // 3) inproj GEMM: main (cols 0..4095, grid 512 = 2 clean rounds) + strip (cols 4096..4351)
  if (use8){
    gemm8_inproj<<<512, 512, 131072, stream>>>(u_bf, w_inT, z, xbc);
    gemm_mfma_strip<<<dim3(2, ROWS/128), 256, 0, stream>>>(u_bf, w_inT + (size_t)NMAIN*DMODEL, xbc);
  } else {
    gemm_mfma_inproj<<<dim3(NGEMM/128, ROWS/128), 256, 0, stream>>>(u_bf, w_inT, z, xbc);
  }
  // 4) conv + silu + split (MUST precede acum_fused: dt/Acum alias xbc tail)
  conv_kernel<<<dim3(9, SEQ/64, B_SZ), 256, 0, stream>>>(xbc, cw, cb, x, Bm, Cm);
  // 5) fused reduce+softplus -> dt, cumsum -> Acum (xbc now dead)
  acum_fused<<<B_SZ*NHEADS*NCHUNK, 256, 0, stream>>>(part, dtb, Alog, dt, Acum);
  // 6) head-shared scores (S overwrites part region)
  scores_mfma<<<dim3(B_SZ*NCHUNK, 3), 256, 0, stream>>>(Bm, Cm, S);
  // 7) weighted transpose XW_T + BT
  xwt_kernel<<<dim3(34, 64, 2), 256, 0, stream>>>(x, Bm, dt, Acum, xwt, bt);
  // 8) MFMA chunk-states
  chunk_states_mfma<<<B_SZ*NCHUNK*NHEADS, 256, 0, stream>>>(xwt, bt, states);
  // 9) inter-chunk scan
  scan_kernel<<<(B_SZ*NHEADS*HDIM*DSTATE)/256, 256, 0, stream>>>(states, Acum);
  // 10) fused MFMA Y (y aliases x; S from global)
  ydiag_mfma<<<B_SZ*NCHUNK*NHEADS, 256, 0, stream>>>(x, dt, Acum, S, Cm, states, Dp, y);
  // 11) prep out_proj weight
  transcast_kernel<<<dim3(DMODEL/64, INTER/64), 256, 0, stream>>>(w_out, w_outT, INTER, DMODEL, 0);
  // 12) gate + RMSNorm
  gatenorm_kernel<<<ROWS, 256, 0, stream>>>(y, z, nw);
  // 13) out_proj — m97 128^2 kernel (512 blocks, ~3/CU)
  gemm_mfma_outproj<<<dim3(DMODEL/128, ROWS/128), 256, 0, stream>>>(y, w_outT, out);
}